// Round 1
// 9505.011 us; speedup vs baseline: 1.2320x; 1.2320x over previous
//
#include <hip/hip_runtime.h>

typedef double rl;
#define NT 256
#define NSV 71
#define LDA 128
#define LDV 72
#define SML 25
#define VOCAB 128000
#define LP 27   // LDS leaf pitch
#define PB 129  // LDS pitch for bidiag working matrix (odd => minimal fp64 bank aliasing)

// fp32 LAPACK constants (reference is numpy sgesdd in float32)
#define EPS32 1.1920928955078125e-7
#define UNFL32 1.17549435e-38

// g_ws offsets (doubles)
#define O_CAR   0
#define O_COLS  4608
#define O_VEC   4800
#define O_MA    5120
#define O_MU    23552
#define O_MQ    32768
#define O_MVT   41984
#define O_SUB   47168
#define O_SVTB  52352
#define O_U2    57536
#define O_VT2   62720
#define O_QU    67904
#define O_QV    73088
#define O_TB    78272

__device__ double g_ws[84000];

// Per-wave leaf context: one D&C leaf (n<=25, np<=26) runs entirely inside a
// single wave; 4 leaves execute concurrently on the 4 SIMDs of the CU.
struct LeafCtx {
  rl LVT[26*LP], LU[26*LP];
  rl b1[26], b2[26], b3[26], b4[26];
  rl sc[6];
  int ia[26], ib[26], ic[26];
  int si[12];
};

struct Sh {
  rl d[72], e[72], tq[72], tp[72], rc[72], rs[72];
  rl dsig[72], zz[72], zh[72], sigm[72], vals[72];
  rl ta[72], tb[72];
  int srcU[72], srcVT[72], perm[72];
  int ia[72], ib[72], ic[72];
  int opk[12], opf[12], opa[12], opb[12], opq[12];
  rl sc[8];
  int si[16];
};

// Wave-local "barrier": a wave executes one instruction stream and its LDS ops
// complete in order, so ordering the compiler's memory ops + draining counters
// is sufficient for lane0 -> other-lane LDS communication.
__device__ __forceinline__ void wsync(){
  asm volatile("s_waitcnt vmcnt(0) lgkmcnt(0)" ::: "memory");
}

__device__ __forceinline__ rl d_sign(rl a, rl b){ return (b >= 0.0) ? fabs(a) : -fabs(a); }
__device__ __forceinline__ rl dlapy2(rl x, rl y){
  rl ax=fabs(x), ay=fabs(y);
  rl w = ax>ay?ax:ay, z = ax>ay?ay:ax;
  if(z==0.0) return w;
  rl t = z/w; return w*sqrt(1.0+t*t);
}
// LAPACK >= 3.10 dlartg convention (modern OpenBLAS)
__device__ void dlartg(rl f, rl g, rl* cs, rl* sn, rl* r){
  if(g==0.0){ *cs=1.0; *sn=0.0; *r=f; }
  else if(f==0.0){ *cs=0.0; *sn=d_sign(1.0,g); *r=fabs(g); }
  else{
    rl dd = sqrt(f*f+g*g);
    *cs = fabs(f)/dd;
    *r  = d_sign(dd, f);
    *sn = g/(*r);
  }
}

__device__ void dlas2(rl f, rl g, rl h, rl* ssmin, rl* ssmax){
  rl fa=fabs(f), ga=fabs(g), ha=fabs(h);
  rl fhmn=fmin(fa,ha), fhmx=fmax(fa,ha);
  if(fhmn==0.0){
    *ssmin=0.0;
    if(fhmx==0.0) *ssmax=ga;
    else { rl mx=fmax(fhmx,ga), mn=fmin(fhmx,ga); rl q=mn/mx; *ssmax=mx*sqrt(1.0+q*q); }
  } else {
    if(ga < fhmx){
      rl as=1.0+fhmn/fhmx, at=(fhmx-fhmn)/fhmx;
      rl au=(ga/fhmx); au=au*au;
      rl c=2.0/(sqrt(as*as+au)+sqrt(at*at+au));
      *ssmin=fhmn*c; *ssmax=fhmx/c;
    } else {
      rl au=fhmx/ga;
      if(au==0.0){ *ssmin=(fhmn*fhmx)/ga; *ssmax=ga; }
      else{
        rl as=1.0+fhmn/fhmx, at=(fhmx-fhmn)/fhmx;
        rl c=1.0/(sqrt(1.0+(as*au)*(as*au))+sqrt(1.0+(at*au)*(at*au)));
        *ssmin=(fhmn*c)*au; *ssmin=*ssmin+*ssmin;
        *ssmax=ga/(c+c);
      }
    }
  }
}

__device__ void dlasv2(rl f, rl g, rl h, rl* ssmin, rl* ssmax, rl* snr, rl* csr, rl* snl, rl* csl){
  rl ft=f, fa=fabs(f), ht=h, ha=fabs(h);
  int pmax=1;
  bool swp = (ha > fa);
  if(swp){ pmax=3; rl t=ft; ft=ht; ht=t; t=fa; fa=ha; ha=t; }
  rl gt=g, ga=fabs(g);
  rl clt=0, crt=0, slt=0, srt=0;
  if(ga==0.0){ *ssmin=ha; *ssmax=fa; clt=1.0; crt=1.0; slt=0.0; srt=0.0; }
  else{
    bool gasmal=true;
    if(ga > fa){
      pmax=2;
      if((fa/ga) < EPS32){
        gasmal=false;
        *ssmax=ga;
        if(ha>1.0) *ssmin=fa/(ga/ha); else *ssmin=(fa/ga)*ha;
        clt=1.0; slt=ht/gt; srt=1.0; crt=ft/gt;
      }
    }
    if(gasmal){
      rl dd=fa-ha;
      rl lv = (dd==fa) ? 1.0 : dd/fa;
      rl mq = gt/ft;
      rl tv = 2.0-lv;
      rl mm = mq*mq, tt = tv*tv;
      rl sv = sqrt(tt+mm);
      rl rv = (lv==0.0) ? fabs(mq) : sqrt(lv*lv+mm);
      rl a = 0.5*(sv+rv);
      *ssmin = ha/a; *ssmax = fa*a;
      rl t3;
      if(mm==0.0){
        if(lv==0.0) t3 = d_sign(2.0, ft)*d_sign(1.0, gt);
        else t3 = gt/d_sign(dd, ft) + mq/tv;
      } else {
        t3 = (mq/(sv+tv) + mq/(rv+lv))*(1.0+a);
      }
      rl l2 = sqrt(t3*t3+4.0);
      crt = 2.0/l2; srt = t3/l2;
      clt = (crt + srt*mq)/a;
      slt = (ht/ft)*srt/a;
    }
  }
  if(swp){ *csl=srt; *snl=crt; *csr=slt; *snr=clt; }
  else  { *csl=clt; *snl=slt; *csr=crt; *snr=srt; }
  rl tsign=1.0;
  if(pmax==1) tsign = d_sign(1.0,*csr)*d_sign(1.0,*csl)*d_sign(1.0,f);
  if(pmax==2) tsign = d_sign(1.0,*snr)*d_sign(1.0,*csl)*d_sign(1.0,g);
  if(pmax==3) tsign = d_sign(1.0,*snr)*d_sign(1.0,*snl)*d_sign(1.0,h);
  *ssmax = d_sign(*ssmax, tsign);
  *ssmin = d_sign(*ssmin, tsign*d_sign(1.0,f)*d_sign(1.0,h));
}

// Householder apply, order-preserving unroll-4 (grouped loads, sequential adds:
// bit-identical to the scalar loop).
__device__ __forceinline__ void app_left(rl* A, int ld, int r0, int m, int c0, int n, const rl* vbase, rl tau, int tid){
  const int len = m - r0 - 1;
  const rl* v = vbase + r0 + 1;
  for(int c=c0+tid; c<n; c+=NT){
    rl* col = A + (size_t)ld*c + r0;
    rl s = col[0];
    int i=0;
    for(; i+4<=len; i+=4){
      rl a0=col[1+i],a1=col[2+i],a2=col[3+i],a3=col[4+i];
      rl b0=v[i],b1=v[i+1],b2=v[i+2],b3=v[i+3];
      s+=a0*b0; s+=a1*b1; s+=a2*b2; s+=a3*b3;
    }
    for(; i<len; ++i) s += col[1+i]*v[i];
    rl w = s*tau;
    col[0] -= w;
    i=0;
    for(; i+4<=len; i+=4){
      rl b0=v[i],b1=v[i+1],b2=v[i+2],b3=v[i+3];
      col[1+i]-=w*b0; col[2+i]-=w*b1; col[3+i]-=w*b2; col[4+i]-=w*b3;
    }
    for(; i<len; ++i) col[1+i] -= w*v[i];
  }
}
__device__ __forceinline__ void app_right(rl* A, int ld, int r0, int m, int c0, int n, const rl* vbase, int vstride, rl tau, int tid){
  const int len = n - c0 - 1;
  const rl* v = vbase + (size_t)vstride*(c0+1);
  for(int r=r0+tid; r<m; r+=NT){
    rl* row = A + r + (size_t)ld*c0;
    rl s = row[0];
    int i=0;
    for(; i+4<=len; i+=4){
      rl a0=row[(size_t)ld*(1+i)], a1=row[(size_t)ld*(2+i)], a2=row[(size_t)ld*(3+i)], a3=row[(size_t)ld*(4+i)];
      rl b0=v[(size_t)vstride*i], b1=v[(size_t)vstride*(i+1)], b2=v[(size_t)vstride*(i+2)], b3=v[(size_t)vstride*(i+3)];
      s+=a0*b0; s+=a1*b1; s+=a2*b2; s+=a3*b3;
    }
    for(; i<len; ++i) s += row[(size_t)ld*(1+i)]*v[(size_t)vstride*i];
    rl w = s*tau;
    row[0] -= w;
    i=0;
    for(; i+4<=len; i+=4){
      rl b0=v[(size_t)vstride*i], b1=v[(size_t)vstride*(i+1)], b2=v[(size_t)vstride*(i+2)], b3=v[(size_t)vstride*(i+3)];
      row[(size_t)ld*(1+i)]-=w*b0; row[(size_t)ld*(2+i)]-=w*b1; row[(size_t)ld*(3+i)]-=w*b2; row[(size_t)ld*(4+i)]-=w*b3;
    }
    for(; i<len; ++i) row[(size_t)ld*(1+i)] -= w*v[(size_t)vstride*i];
  }
}

// ---- wave-scoped dbdsqr on a private LDS leaf block ----
// Identical arithmetic to the block version; tid->lane, __syncthreads->wsync.
__device__ void bdsqr_wave(int n, rl* d, rl* e, int ncvt, int nru, LeafCtx* lc, int lane){
  if(n>1){
    rl eps=EPS32, unfl=UNFL32;
    rl tolmul=fmax(10.0,fmin(100.0,pow(eps,-0.125)));
    rl tol=tolmul*eps;
    rl thresh=0.0;
    int mm=n-1, oldll=-2, oldm=-2, idir=0, iter=0, maxit=6*n*n;
    if(lane==0){
      rl sminoa=fabs(d[0]);
      if(sminoa!=0.0){
        rl mu=sminoa;
        for(int i=1;i<n;++i){ mu=fabs(d[i])*(mu/(mu+fabs(e[i-1]))); sminoa=fmin(sminoa,mu); if(sminoa==0.0)break; }
      }
      sminoa=sminoa/sqrt((rl)n);
      thresh=fmax(tol*sminoa,(rl)(6*n*n)*unfl);
    }
    while(true){
      if(lane==0){
        int act=0, p_lo=0, p_cnt=0, p_fwd=1, p_mm=0;
        while(mm>0){
          if(iter>maxit) break;
          rl smax=fabs(d[mm]), smin=smax;
          int ll=-1;
          for(int lll=mm-1;lll>=0;--lll){
            rl abss=fabs(d[lll]), abse=fabs(e[lll]);
            if(abse<=thresh){ ll=lll; break; }
            smin=fmin(smin,abss);
            smax=fmax(smax,fmax(abss,abse));
          }
          if(ll==mm-1){ e[ll]=0.0; mm=mm-1; continue; }
          if(ll>=0) e[ll]=0.0;
          int lo=ll+1;
          if(mm==lo+1){
            rl sigmn,sigmx,sinr,cosr,sinl,cosl;
            dlasv2(d[lo],e[lo],d[mm],&sigmn,&sigmx,&sinr,&cosr,&sinl,&cosl);
            d[lo]=sigmx; d[mm]=sigmn; e[lo]=0.0;
            lc->sc[0]=cosr; lc->sc[1]=sinr; lc->sc[2]=cosl; lc->sc[3]=sinl;
            act=2; p_lo=lo; p_mm=mm;
            mm-=2;
            break;
          }
          if(lo>oldm || mm<oldll) idir=(fabs(d[lo])>=fabs(d[mm]))?1:2;
          rl sminl=0.0; int conv=0;
          if(idir==1){
            if(fabs(e[mm-1])<=tol*fabs(d[mm])){ e[mm-1]=0.0; conv=1; }
            if(!conv){
              rl mu=fabs(d[lo]); sminl=mu;
              for(int lll=lo;lll<mm;++lll){
                if(fabs(e[lll])<=tol*mu){ e[lll]=0.0; conv=1; break; }
                mu=fabs(d[lll+1])*(mu/(mu+fabs(e[lll])));
                sminl=fmin(sminl,mu);
              }
            }
          } else {
            if(fabs(e[lo])<=tol*fabs(d[lo])){ e[lo]=0.0; conv=1; }
            if(!conv){
              rl mu=fabs(d[mm]); sminl=mu;
              for(int lll=mm-1;lll>=lo;--lll){
                if(fabs(e[lll])<=tol*mu){ e[lll]=0.0; conv=1; break; }
                mu=fabs(d[lll])*(mu/(mu+fabs(e[lll])));
                sminl=fmin(sminl,mu);
              }
            }
          }
          if(conv) continue;
          oldll=lo; oldm=mm;
          rl shift=0.0, rr_;
          if(!((rl)n*tol*(sminl/smax) <= fmax(eps, 0.01*tol))){
            rl sll;
            if(idir==1){ sll=fabs(d[lo]); dlas2(d[mm-1],e[mm-1],d[mm],&shift,&rr_); }
            else { sll=fabs(d[mm]); dlas2(d[lo],e[lo],d[lo+1],&shift,&rr_); }
            if(sll>0.0){ rl q=shift/sll; if(q*q<eps) shift=0.0; }
          }
          iter += mm-lo;
          int cnt=mm-lo;
          if(shift==0.0){
            if(idir==1){
              rl cs=1.0, oldcs=1.0, sn=0.0, oldsn=0.0, r;
              for(int i=lo;i<mm;++i){
                dlartg(d[i]*cs,e[i],&cs,&sn,&r);
                if(i>lo) e[i-1]=oldsn*r;
                dlartg(oldcs*r, d[i+1]*sn, &oldcs,&oldsn,&d[i]);
                lc->b1[i-lo]=cs; lc->b2[i-lo]=sn; lc->b3[i-lo]=oldcs; lc->b4[i-lo]=oldsn;
              }
              rl h=d[mm]*cs; d[mm]=h*oldcs; e[mm-1]=h*oldsn;
              p_fwd=1;
              if(fabs(e[mm-1])<=thresh) e[mm-1]=0.0;
            } else {
              rl cs=1.0, oldcs=1.0, sn=0.0, oldsn=0.0, r;
              for(int i=mm;i>lo;--i){
                dlartg(d[i]*cs,e[i-1],&cs,&sn,&r);
                if(i<mm) e[i]=oldsn*r;
                dlartg(oldcs*r,d[i-1]*sn,&oldcs,&oldsn,&d[i]);
                int j=i-lo-1;
                lc->b1[j]=oldcs; lc->b2[j]=-oldsn; lc->b3[j]=cs; lc->b4[j]=-sn;
              }
              rl h=d[lo]*cs; d[lo]=h*oldcs; e[lo]=h*oldsn;
              p_fwd=0;
              if(fabs(e[lo])<=thresh) e[lo]=0.0;
            }
          } else {
            if(idir==1){
              rl f2=(fabs(d[lo])-shift)*(d_sign(1.0,d[lo])+shift/d[lo]);
              rl g2=e[lo], r, cosr,sinr,cosl,sinl;
              for(int i=lo;i<mm;++i){
                dlartg(f2,g2,&cosr,&sinr,&r);
                if(i>lo) e[i-1]=r;
                f2=cosr*d[i]+sinr*e[i];
                e[i]=cosr*e[i]-sinr*d[i];
                g2=sinr*d[i+1];
                d[i+1]=cosr*d[i+1];
                dlartg(f2,g2,&cosl,&sinl,&r);
                d[i]=r;
                f2=cosl*e[i]+sinl*d[i+1];
                d[i+1]=cosl*d[i+1]-sinl*e[i];
                if(i<mm-1){ g2=sinl*e[i+1]; e[i+1]=cosl*e[i+1]; }
                lc->b1[i-lo]=cosr; lc->b2[i-lo]=sinr; lc->b3[i-lo]=cosl; lc->b4[i-lo]=sinl;
              }
              e[mm-1]=f2;
              p_fwd=1;
              if(fabs(e[mm-1])<=thresh) e[mm-1]=0.0;
            } else {
              rl f2=(fabs(d[mm])-shift)*(d_sign(1.0,d[mm])+shift/d[mm]);
              rl g2=e[mm-1], r, cosr,sinr,cosl,sinl;
              for(int i=mm;i>lo;--i){
                dlartg(f2,g2,&cosr,&sinr,&r);
                if(i<mm) e[i]=r;
                f2=cosr*d[i]+sinr*e[i-1];
                e[i-1]=cosr*e[i-1]-sinr*d[i];
                g2=sinr*d[i-1];
                d[i-1]=cosr*d[i-1];
                dlartg(f2,g2,&cosl,&sinl,&r);
                d[i]=r;
                f2=cosl*e[i-1]+sinl*d[i-1];
                d[i-1]=cosl*d[i-1]-sinl*e[i-1];
                if(i>lo+1){ g2=sinl*e[i-2]; e[i-2]=cosl*e[i-2]; }
                int j=i-lo-1;
                lc->b1[j]=cosl; lc->b2[j]=-sinl; lc->b3[j]=cosr; lc->b4[j]=-sinr;
              }
              e[lo]=f2;
              p_fwd=0;
              if(fabs(e[lo])<=thresh) e[lo]=0.0;
            }
          }
          act=1; p_lo=lo; p_cnt=cnt;
          break;
        }
        lc->si[7]=act; lc->si[8]=p_lo; lc->si[9]=p_cnt; lc->si[10]=p_fwd; lc->si[11]=p_mm;
      }
      wsync();
      int act=lc->si[7];
      if(act==0) break;
      if(act==1){
        int lo=lc->si[8], cnt=lc->si[9], fwd=lc->si[10];
        if(lane<ncvt){
          int k=lane;
          if(fwd){
            for(int j=0;j<cnt;++j){
              rl c=lc->b1[j], s=lc->b2[j];
              rl t=lc->LVT[(lo+j+1)*LP+k];
              lc->LVT[(lo+j+1)*LP+k]=c*t-s*lc->LVT[(lo+j)*LP+k];
              lc->LVT[(lo+j)*LP+k]=s*t+c*lc->LVT[(lo+j)*LP+k];
            }
          } else {
            for(int j=cnt-1;j>=0;--j){
              rl c=lc->b1[j], s=lc->b2[j];
              rl t=lc->LVT[(lo+j+1)*LP+k];
              lc->LVT[(lo+j+1)*LP+k]=c*t-s*lc->LVT[(lo+j)*LP+k];
              lc->LVT[(lo+j)*LP+k]=s*t+c*lc->LVT[(lo+j)*LP+k];
            }
          }
        } else if(lane<ncvt+nru){
          int r2=lane-ncvt;
          if(fwd){
            for(int j=0;j<cnt;++j){
              rl c=lc->b3[j], s=lc->b4[j];
              rl t=lc->LU[r2*LP+(lo+j+1)];
              lc->LU[r2*LP+(lo+j+1)]=c*t-s*lc->LU[r2*LP+(lo+j)];
              lc->LU[r2*LP+(lo+j)]=s*t+c*lc->LU[r2*LP+(lo+j)];
            }
          } else {
            for(int j=cnt-1;j>=0;--j){
              rl c=lc->b3[j], s=lc->b4[j];
              rl t=lc->LU[r2*LP+(lo+j+1)];
              lc->LU[r2*LP+(lo+j+1)]=c*t-s*lc->LU[r2*LP+(lo+j)];
              lc->LU[r2*LP+(lo+j)]=s*t+c*lc->LU[r2*LP+(lo+j)];
            }
          }
        }
      } else {
        int lo=lc->si[8], m2=lc->si[11];
        rl cosr=lc->sc[0], sinr=lc->sc[1], cosl=lc->sc[2], sinl=lc->sc[3];
        if(lane<ncvt){
          rl x=lc->LVT[lo*LP+lane], y=lc->LVT[m2*LP+lane];
          lc->LVT[lo*LP+lane]=cosr*x+sinr*y; lc->LVT[m2*LP+lane]=cosr*y-sinr*x;
        } else if(lane<ncvt+nru){
          int r2=lane-ncvt;
          rl x=lc->LU[r2*LP+lo], y=lc->LU[r2*LP+m2];
          lc->LU[r2*LP+lo]=cosl*x+sinl*y; lc->LU[r2*LP+m2]=cosl*y-sinl*x;
        }
      }
      wsync();
    }
  }
  if(lane==0){
    for(int i=0;i<n;++i){ lc->ic[i]=(d[i]<0.0)?1:0; if(d[i]<0.0) d[i]=-d[i]; }
    int nsw=0;
    for(int i=0;i<n-1;++i){
      int isub=0; rl smin=d[0];
      for(int j=1;j<n-i;++j){ if(d[j]<=smin){ isub=j; smin=d[j]; } }
      int tgt=n-1-i;
      if(isub!=tgt){
        d[isub]=d[tgt]; d[tgt]=smin;
        lc->ia[nsw]=isub; lc->ib[nsw]=tgt; ++nsw;
      }
    }
    lc->si[7]=nsw;
  }
  wsync();
  int nsw=lc->si[7];
  if(lane<ncvt){
    for(int i=0;i<n;++i) if(lc->ic[i]) lc->LVT[i*LP+lane]=-lc->LVT[i*LP+lane];
    for(int w2=0;w2<nsw;++w2){
      int a=lc->ia[w2], b=lc->ib[w2];
      rl t=lc->LVT[a*LP+lane]; lc->LVT[a*LP+lane]=lc->LVT[b*LP+lane]; lc->LVT[b*LP+lane]=t;
    }
  } else if(lane<ncvt+nru){
    int r2=lane-ncvt;
    for(int w2=0;w2<nsw;++w2){
      int a=lc->ia[w2], b=lc->ib[w2];
      rl t=lc->LU[r2*LP+a]; lc->LU[r2*LP+a]=lc->LU[r2*LP+b]; lc->LU[r2*LP+b]=t;
    }
  }
  wsync();
}

// ---- leaf: dlasdq, entirely within one wave (no block barriers inside) ----
__device__ void leaf_exec(int f, int n, int sqre, int wantU, LeafCtx* lc, Sh* sh, int lane){
  rl* SVTB = g_ws + O_SVTB; rl* SUB = g_ws + O_SUB;
  int np = n + sqre;
  for(int w=lane; w<np*np; w+=64){ int r2=w/np, c=w-r2*np; lc->LVT[r2*LP+c]=SVTB[(f+r2)+(size_t)LDV*(f+c)]; }
  if(wantU) for(int w=lane; w<n*n; w+=64){ int r2=w/n, c=w-r2*n; lc->LU[r2*LP+c]=SUB[(f+r2)+(size_t)LDV*(f+c)]; }
  wsync();
  if(sqre==1){
    if(lane==0){
      rl cs,snv,rv; rl* dd=sh->d+f; rl* ee=sh->e+f;
      for(int i=0;i<n;++i){
        dlartg(dd[i],ee[i],&cs,&snv,&rv);
        dd[i]=rv;
        if(i<n-1){ ee[i]=snv*dd[i+1]; dd[i+1]=cs*dd[i+1]; }
        else ee[i]=0.0;
        lc->b1[i]=cs; lc->b2[i]=snv;
      }
    }
    wsync();
    if(lane<np){
      for(int j=0;j<n;++j){
        rl cj=lc->b1[j], sj=lc->b2[j];
        rl t=lc->LVT[(j+1)*LP+lane];
        lc->LVT[(j+1)*LP+lane]=cj*t-sj*lc->LVT[j*LP+lane];
        lc->LVT[j*LP+lane]=sj*t+cj*lc->LVT[j*LP+lane];
      }
    }
    wsync();
    if(lane==0){
      rl cs,snv,rv; rl* dd=sh->d+f; rl* ee=sh->e+f;
      for(int i=0;i<n-1;++i){
        dlartg(dd[i],ee[i],&cs,&snv,&rv);
        dd[i]=rv; ee[i]=snv*dd[i+1]; dd[i+1]=cs*dd[i+1];
        lc->b1[i]=cs; lc->b2[i]=snv;
      }
    }
    wsync();
    if(wantU && lane<n){
      for(int j=0;j<n-1;++j){
        rl cj=lc->b1[j], sj=lc->b2[j];
        rl t=lc->LU[lane*LP+(j+1)];
        lc->LU[lane*LP+(j+1)]=cj*t-sj*lc->LU[lane*LP+j];
        lc->LU[lane*LP+j]=sj*t+cj*lc->LU[lane*LP+j];
      }
    }
    wsync();
  }
  bdsqr_wave(n, sh->d+f, sh->e+f, np, wantU? n:0, lc, lane);
  for(int w=lane; w<np*np; w+=64){ int r2=w/np, c=w-r2*np; SVTB[(f+r2)+(size_t)LDV*(f+c)]=lc->LVT[r2*LP+c]; }
  if(wantU) for(int w=lane; w<n*n; w+=64){ int r2=w/n, c=w-r2*n; SUB[(f+r2)+(size_t)LDV*(f+c)]=lc->LU[r2*LP+c]; }
}

// ---- D&C merge (dlasd1/2/3) ---- (block-wide, unchanged)
__device__ void lasd1_merge(int f, int nl, int nr, int sqre, int wantU, Sh* sh, int tid){
  rl* SUB = g_ws + O_SUB; rl* SVTB = g_ws + O_SVTB;
  rl* U2 = g_ws + O_U2; rl* VT2 = g_ws + O_VT2; rl* QU = g_ws + O_QU; rl* QV = g_ws + O_QV;
  int n = nl+nr+1, m = n+sqre;
  if(tid==0){
    rl alpha = sh->d[f+nl], beta = sh->e[f+nl];
    sh->vals[0]=0.0;
    sh->zz[0] = alpha*SVTB[(f+nl)+(size_t)LDV*(f+nl)];
    sh->srcU[0]=-1; sh->srcVT[0]=f+nl;
    for(int i=0;i<nl;++i){
      sh->vals[1+i]=sh->d[f+i];
      sh->zz[1+i]=alpha*SVTB[(f+i)+(size_t)LDV*(f+nl)];
      sh->srcU[1+i]=f+i; sh->srcVT[1+i]=f+i;
    }
    for(int j=0;j<nr;++j){
      sh->vals[1+nl+j]=sh->d[f+nl+1+j];
      sh->zz[1+nl+j]=beta*SVTB[(f+nl+1+j)+(size_t)LDV*(f+nl+1)];
      sh->srcU[1+nl+j]=f+nl+1+j; sh->srcVT[1+nl+j]=f+nl+1+j;
    }
    sh->sc[0]=alpha; sh->sc[1]=beta;
    if(sqre==1){
      rl zM = beta*SVTB[(f+n)+(size_t)LDV*(f+nl+1)];
      rl c,s,r2;
      dlartg(sh->zz[0], zM, &c, &s, &r2);
      sh->zz[0]=r2; sh->sc[2]=c; sh->sc[3]=s;
    }
  }
  __syncthreads();
  if(sqre==1){
    rl c=sh->sc[2], s=sh->sc[3];
    int ra=f+nl, rb=f+n;
    for(int k=tid;k<m;k+=NT){
      size_t ci=(size_t)LDV*(f+k);
      rl a=SVTB[ra+ci], b=SVTB[rb+ci];
      SVTB[ra+ci]=c*a+s*b; SVTB[rb+ci]=-s*a+c*b;
    }
  }
  __syncthreads();
  if(tid==0){
    rl maxd=0.0; for(int i=0;i<n;++i) maxd=fmax(maxd,fabs(sh->vals[i]));
    rl tol = 8.0*EPS32*fmax(maxd, fmax(fabs(sh->sc[0]), fabs(sh->sc[1])));
    int nds=0;
    sh->ic[nds++]=0;
    for(int i=1;i<n;++i) if(fabs(sh->zz[i]) > tol) sh->ic[nds++]=i;
    for(int a=1;a<nds;++a){
      int key=sh->ic[a]; rl kv=sh->vals[key]; int b=a-1;
      while(b>=1 && sh->vals[sh->ic[b]] > kv){ sh->ic[b+1]=sh->ic[b]; --b; }
      sh->ic[b+1]=key;
    }
    int K=nds, pos=nds;
    for(int i=1;i<n;++i) if(fabs(sh->zz[i]) <= tol) sh->ic[pos++]=i;
    for(int a=K+1;a<n;++a){
      int key=sh->ic[a]; rl kv=sh->vals[key]; int b=a-1;
      while(b>=K && sh->vals[sh->ic[b]] > kv){ sh->ic[b+1]=sh->ic[b]; --b; }
      sh->ic[b+1]=key;
    }
    for(int t=0;t<n;++t){ sh->ta[t]=sh->vals[t]; sh->tb[t]=sh->zz[t]; sh->ia[t]=sh->srcU[t]; sh->ib[t]=sh->srcVT[t]; }
    for(int t=0;t<n;++t){
      int p=sh->ic[t];
      sh->dsig[t]=sh->ta[p]; sh->zz[t]=sh->tb[p]; sh->srcU[t]=sh->ia[p]; sh->srcVT[t]=sh->ib[p];
    }
    rl rho=0.0; for(int t=0;t<K;++t){ rl zv=sh->zz[t]; rho += zv*zv; }
    sh->sc[4]=rho;
    sh->si[0]=K; sh->si[1]=n; sh->si[2]=m; sh->si[3]=f; sh->si[4]=nl;
  }
  __syncthreads();
  int K=sh->si[0], n_=sh->si[1], m_=sh->si[2], f_=sh->si[3], nl_=sh->si[4];
  if(wantU){
    for(int w=tid; w<n_*n_; w+=NT){
      int col=w/n_, row=w-col*n_;
      int su=sh->srcU[col];
      rl v;
      if(su<0) v = (row==nl_) ? 1.0 : 0.0;
      else v = SUB[(f_+row)+(size_t)LDV*su];
      U2[row+(size_t)LDV*col]=v;
    }
  }
  for(int w=tid; w<n_*m_; w+=NT){
    int row=w/m_, col=w-row*m_;
    VT2[row+(size_t)LDV*col] = SVTB[sh->srcVT[row]+(size_t)LDV*(f_+col)];
  }
  __syncthreads();
  rl rho=sh->sc[4];
  for(int j=tid;j<K;j+=NT){
    rl lo=sh->dsig[j];
    rl hi=(j<K-1)? sh->dsig[j+1] : sqrt(sh->dsig[K-1]*sh->dsig[K-1]+rho);
    for(int it=0; it<130; ++it){
      rl mid=0.5*(lo+hi);
      if(mid<=lo || mid>=hi) break;
      rl g=1.0;
      for(int i2=0;i2<K;++i2){
        rl zi=sh->zz[i2];
        g += zi*zi/((sh->dsig[i2]-mid)*(sh->dsig[i2]+mid));
      }
      if(g<0.0) lo=mid; else hi=mid;
    }
    sh->sigm[j]=0.5*(lo+hi);
  }
  __syncthreads();
  for(int i2=tid;i2<K;i2+=NT){
    rl di=sh->dsig[i2];
    rl p=(di - sh->sigm[K-1])*(di + sh->sigm[K-1]);
    for(int j=0;j<i2;++j)
      p *= (di - sh->sigm[j])*(di + sh->sigm[j])/((di - sh->dsig[j])*(di + sh->dsig[j]));
    for(int j=i2;j<K-1;++j)
      p *= (di - sh->sigm[j])*(di + sh->sigm[j])/((di - sh->dsig[j+1])*(di + sh->dsig[j+1]));
    sh->zh[i2] = d_sign(sqrt(fabs(p)), sh->zz[i2]);
  }
  __syncthreads();
  for(int j=tid;j<K;j+=NT){
    rl sj=sh->sigm[j];
    rl nu=0.0, nv=0.0;
    for(int i2=0;i2<K;++i2){
      rl di=sh->dsig[i2];
      rl vv=sh->zh[i2]/((di-sj)*(di+sj));
      QV[i2+(size_t)LDV*j]=vv; nv+=vv*vv;
      if(wantU){
        rl uu=(i2==0)? -1.0 : di*vv;
        QU[i2+(size_t)LDV*j]=uu; nu+=uu*uu;
      }
    }
    nv=1.0/sqrt(nv);
    for(int i2=0;i2<K;++i2) QV[i2+(size_t)LDV*j]*=nv;
    if(wantU){
      nu=1.0/sqrt(nu);
      for(int i2=0;i2<K;++i2) QU[i2+(size_t)LDV*j]*=nu;
    }
  }
  __syncthreads();
  if(tid==0){
    int nd2=n_-K;
    for(int t=0;t<nd2;++t) sh->ia[t]=K+t;
    int ps=K-1, pd=nd2-1;
    int t=0;
    while(t<n_){
      rl vs = (ps>=0)? sh->sigm[ps] : -1.0;
      rl vd = (pd>=0)? sh->dsig[sh->ia[pd]] : -1.0;
      if(vs >= vd){ sh->perm[t]=ps; sh->vals[t]=vs; --ps; }
      else { sh->perm[t]=1000+sh->ia[pd]; sh->vals[t]=vd; --pd; }
      ++t;
    }
    for(int q=0;q<n_;++q) sh->d[f_+q]=sh->vals[q];
  }
  __syncthreads();
  if(wantU){
    for(int w=tid; w<n_*n_; w+=NT){
      int t=w/n_, row=w-t*n_;
      int src=sh->perm[t];
      rl acc;
      if(src>=1000) acc = U2[row+(size_t)LDV*(src-1000)];
      else{
        const rl* urow = U2 + row;
        const rl* qcol = QU + (size_t)LDV*src;
        rl s=0.0; int i=0;
        for(; i+4<=K; i+=4){
          rl a0=urow[(size_t)LDV*i], a1=urow[(size_t)LDV*(i+1)], a2=urow[(size_t)LDV*(i+2)], a3=urow[(size_t)LDV*(i+3)];
          rl b0=qcol[i], b1=qcol[i+1], b2=qcol[i+2], b3=qcol[i+3];
          s+=a0*b0; s+=a1*b1; s+=a2*b2; s+=a3*b3;
        }
        for(; i<K; ++i) s += urow[(size_t)LDV*i]*qcol[i];
        acc=s;
      }
      SUB[(f_+row)+(size_t)LDV*(f_+t)] = acc;
    }
  }
  for(int w=tid; w<n_*m_; w+=NT){
    int t=w/m_, col=w-t*m_;
    int src=sh->perm[t];
    rl acc;
    if(src>=1000) acc = VT2[(src-1000)+(size_t)LDV*col];
    else{
      const rl* qcol = QV + (size_t)LDV*src;
      const rl* vcol = VT2 + (size_t)LDV*col;
      rl s=0.0; int i=0;
      for(; i+4<=K; i+=4){
        rl a0=qcol[i],a1=qcol[i+1],a2=qcol[i+2],a3=qcol[i+3];
        rl b0=vcol[i],b1=vcol[i+1],b2=vcol[i+2],b3=vcol[i+3];
        s+=a0*b0; s+=a1*b1; s+=a2*b2; s+=a3*b3;
      }
      for(; i<K; ++i) s += qcol[i]*vcol[i];
      acc=s;
    }
    SVTB[(f_+t)+(size_t)LDV*(f_+col)] = acc;
  }
  __syncthreads();
}

// ---- dlasd0: post-order over the D&C tree, leaves batched onto waves ----
__device__ void run_dc(int n, int wantU, LeafCtx* lct, Sh* sh, int tid){
  if(tid==0){
    int sf[12], sn2[12], sq[12], sv[12]; int sp=0, no=0;
    sf[0]=0; sn2[0]=n; sq[0]=0; sv[0]=0; sp=1;
    while(sp>0){
      --sp;
      int f=sf[sp], nn=sn2[sp], q=sq[sp], v=sv[sp];
      if(nn<=SML){ sh->opk[no]=0; sh->opf[no]=f; sh->opa[no]=nn; sh->opb[no]=0; sh->opq[no]=q; ++no; }
      else if(v==0){
        int nl=nn/2, nr=nn-nl-1;
        sf[sp]=f; sn2[sp]=nn; sq[sp]=q; sv[sp]=1; ++sp;
        sf[sp]=f+nl+1; sn2[sp]=nr; sq[sp]=q; sv[sp]=0; ++sp;
        sf[sp]=f; sn2[sp]=nl; sq[sp]=1; sv[sp]=0; ++sp;
      } else {
        int nl=nn/2, nr=nn-nl-1;
        sh->opk[no]=1; sh->opf[no]=f; sh->opa[no]=nl; sh->opb[no]=nr; sh->opq[no]=q; ++no;
      }
    }
    // Stable-partition: all leaves first, then merges. Safe because leaves are
    // mutually independent (disjoint d/e + SVTB/SUB ranges) and independent of
    // every non-ancestor merge; post-order already puts each leaf before its
    // ancestor merges, and we only move leaves EARLIER. Merge relative order
    // is preserved (respects tree dependencies).
    int tk[12], tf2[12], ta2[12], tb3[12], tq3[12]; int c=0;
    for(int i=0;i<no;++i) if(sh->opk[i]==0){ tk[c]=0; tf2[c]=sh->opf[i]; ta2[c]=sh->opa[i]; tb3[c]=sh->opb[i]; tq3[c]=sh->opq[i]; ++c; }
    for(int i=0;i<no;++i) if(sh->opk[i]==1){ tk[c]=1; tf2[c]=sh->opf[i]; ta2[c]=sh->opa[i]; tb3[c]=sh->opb[i]; tq3[c]=sh->opq[i]; ++c; }
    for(int i=0;i<no;++i){ sh->opk[i]=tk[i]; sh->opf[i]=tf2[i]; sh->opa[i]=ta2[i]; sh->opb[i]=tb3[i]; sh->opq[i]=tq3[i]; }
    sh->si[6]=no;
  }
  __syncthreads();
  int no=sh->si[6];
  int o=0;
  while(o<no){
    if(sh->opk[o]==0){
      int cnt=1;
      while(o+cnt<no && sh->opk[o+cnt]==0 && cnt<4) ++cnt;
      int wid = tid>>6;
      if(wid<cnt) leaf_exec(sh->opf[o+wid], sh->opa[o+wid], sh->opq[o+wid], wantU, &lct[wid], sh, tid&63);
      __syncthreads();
      o += cnt;
    } else {
      lasd1_merge(sh->opf[o], sh->opa[o], sh->opb[o], sh->opq[o], wantU, sh, tid);
      ++o;
    }
  }
}

__device__ void dbdsdc_U(int n, int wantU, LeafCtx* lct, Sh* sh, int tid){
  rl* SUB = g_ws + O_SUB; rl* SVTB = g_ws + O_SVTB;
  for(int w=tid; w<LDV*LDV; w+=NT){
    int c=w/LDV, r2=w-c*LDV; rl v=(r2==c)?1.0:0.0;
    SVTB[w]=v;
    if(wantU) SUB[w]=v;
  }
  __syncthreads();
  if(n <= SML){
    if((tid>>6)==0) leaf_exec(0, n, 0, wantU, &lct[0], sh, tid&63);
    __syncthreads();
  } else run_dc(n, wantU, lct, sh, tid);
}

__device__ void dbdsdc_L(int n, int wantU, LeafCtx* lct, Sh* sh, int tid){
  if(tid==0){
    for(int i=0;i<n-1;++i){
      rl cs,snv,rv;
      dlartg(sh->d[i], sh->e[i], &cs,&snv,&rv);
      sh->d[i]=rv; sh->e[i]=snv*sh->d[i+1]; sh->d[i+1]=cs*sh->d[i+1];
      sh->rc[i]=cs; sh->rs[i]=snv;
    }
  }
  __syncthreads();
  dbdsdc_U(n, wantU, lct, sh, tid);
  if(wantU){
    rl* SUB = g_ws + O_SUB;
    for(int c=tid;c<n;c+=NT){
      size_t ci=(size_t)LDV*c;
      for(int k=n-2;k>=0;--k){
        rl a=SUB[k+ci], b=SUB[k+1+ci];
        SUB[k+ci]  = sh->rc[k]*a - sh->rs[k]*b;
        SUB[k+1+ci]= sh->rs[k]*a + sh->rc[k]*b;
      }
    }
  }
  __syncthreads();
}

// ---- Householder helpers (wave-parallel norm) ----
__device__ __forceinline__ void gen_reflect_col(rl* A, int ld, int i, int r0, int m, rl* outBeta, rl* outTau, Sh* sh, int tid){
  if(tid<64){
    rl ps=0.0;
    for(int r=r0+1+tid;r<m;r+=64){ rl v=A[r+(size_t)ld*i]; ps+=v*v; }
    for(int off=32;off>0;off>>=1) ps += __shfl_down(ps,off,64);
    if(tid==0){
      rl alpha=A[r0+(size_t)ld*i];
      rl xn=sqrt(ps);
      rl beta, tau, scl; int doscale;
      if(xn==0.0){ tau=0.0; beta=alpha; scl=0.0; doscale=0; }
      else{ beta=-d_sign(dlapy2(alpha,xn),alpha); tau=(beta-alpha)/beta; scl=1.0/(alpha-beta); doscale=1; }
      sh->sc[5]=beta; sh->sc[6]=tau; sh->sc[7]=scl; sh->si[5]=doscale;
    }
  }
  __syncthreads();
  if(sh->si[5]) for(int r=r0+1+tid;r<m;r+=NT) A[r+(size_t)ld*i]*=sh->sc[7];
  __syncthreads();
  if(tid==0){ *outBeta=sh->sc[5]; *outTau=sh->sc[6]; }
}
__device__ __forceinline__ void gen_reflect_row(rl* A, int ld, int i, int c0, int n, rl* outBeta, rl* outTau, Sh* sh, int tid){
  if(tid<64){
    rl ps=0.0;
    for(int c=c0+1+tid;c<n;c+=64){ rl v=A[i+(size_t)ld*c]; ps+=v*v; }
    for(int off=32;off>0;off>>=1) ps += __shfl_down(ps,off,64);
    if(tid==0){
      rl alpha=A[i+(size_t)ld*c0];
      rl xn=sqrt(ps);
      rl beta, tau, scl; int doscale;
      if(xn==0.0){ tau=0.0; beta=alpha; scl=0.0; doscale=0; }
      else{ beta=-d_sign(dlapy2(alpha,xn),alpha); tau=(beta-alpha)/beta; scl=1.0/(alpha-beta); doscale=1; }
      sh->sc[5]=beta; sh->sc[6]=tau; sh->sc[7]=scl; sh->si[5]=doscale;
    }
  }
  __syncthreads();
  if(sh->si[5]) for(int c=c0+1+tid;c<n;c+=NT) A[i+(size_t)ld*c]*=sh->sc[7];
  __syncthreads();
  if(tid==0){ *outBeta=sh->sc[5]; *outTau=sh->sc[6]; }
}

__device__ __forceinline__ void gebd2_upper(rl* A, int ld, int m, int n, Sh* sh, int tid){
  for(int i=0;i<n;++i){
    gen_reflect_col(A, ld, i, i, m, &sh->d[i], &sh->tq[i], sh, tid);
    __syncthreads();
    if(sh->tq[i]!=0.0) app_left(A, ld, i, m, i+1, n, A+(size_t)ld*i, sh->tq[i], tid);
    __syncthreads();
    if(i<n-1){
      gen_reflect_row(A, ld, i, i+1, n, &sh->e[i], &sh->tp[i], sh, tid);
      __syncthreads();
      if(sh->tp[i]!=0.0) app_right(A, ld, i+1, m, i+1, n, A+i, ld, sh->tp[i], tid);
      __syncthreads();
    } else { if(tid==0) sh->tp[i]=0.0; __syncthreads(); }
  }
}
__device__ __forceinline__ void gebd2_lower(rl* A, int ld, int m, int n, Sh* sh, int tid){
  for(int i=0;i<m;++i){
    gen_reflect_row(A, ld, i, i, n, &sh->d[i], &sh->tp[i], sh, tid);
    __syncthreads();
    if(sh->tp[i]!=0.0) app_right(A, ld, i+1, m, i, n, A+i, ld, sh->tp[i], tid);
    __syncthreads();
    if(i<m-1){
      gen_reflect_col(A, ld, i, i+1, m, &sh->e[i], &sh->tq[i], sh, tid);
      __syncthreads();
      if(sh->tq[i]!=0.0) app_left(A, ld, i+1, m, i+1, n, A+(size_t)ld*i, sh->tq[i], tid);
      __syncthreads();
    }
  }
}
__device__ __forceinline__ void gelq2(rl* A, int ld, int m, int n, Sh* sh, int tid){
  for(int i=0;i<m;++i){
    rl beta, tau;
    gen_reflect_row(A, ld, i, i, n, &beta, &tau, sh, tid);
    if(tid==0){ sh->rs[i]=sh->sc[6]; A[i+(size_t)ld*i]=sh->sc[5]; }
    __syncthreads();
    if(i<m-1 && sh->rs[i]!=0.0) app_right(A, ld, i+1, m, i, n, A+i, ld, sh->rs[i], tid);
    __syncthreads();
  }
}

// ---- per-shape drivers (MBL = LDS working matrix, pitch PB) ----
__device__ void svd_tall(int wantU, int wantVT, rl* MBL, LeafCtx* lct, Sh* sh, int tid){ // 128 x 71
  rl* MA=g_ws+O_MA; rl* MU=g_ws+O_MU; rl* MVT=g_ws+O_MVT;
  rl* SUB=g_ws+O_SUB; rl* SVTB=g_ws+O_SVTB;
  for(int w=tid;w<128*NSV;w+=NT){ int c=w>>7, r2=w&127; MBL[r2+(size_t)PB*c]=MA[r2+(size_t)LDA*c]; }
  __syncthreads();
  gebd2_upper(MBL, PB, 128, NSV, sh, tid);
  dbdsdc_U(NSV, wantU, lct, sh, tid);
  if(wantU){
    for(int w=tid;w<128*NSV;w+=NT){ int c=w>>7, r2=w&127; MU[r2+(size_t)LDA*c]=(r2<NSV)? SUB[r2+(size_t)LDV*c]:0.0; }
    __syncthreads();
    for(int i=NSV-1;i>=0;--i){
      if(sh->tq[i]!=0.0) app_left(MU, LDA, i, 128, 0, NSV, MBL+(size_t)PB*i, sh->tq[i], tid);
      __syncthreads();
    }
  }
  if(wantVT){
    for(int w=tid;w<LDV*NSV;w+=NT) MVT[w]=SVTB[w];
    __syncthreads();
    for(int i=NSV-2;i>=0;--i){
      if(sh->tp[i]!=0.0) app_right(MVT, LDV, 0, NSV, i+1, NSV, MBL+i, PB, sh->tp[i], tid);
      __syncthreads();
    }
  }
}
__device__ void svd_mid(rl* MBL, LeafCtx* lct, Sh* sh, int tid){ // 64 x 71, wantU=0, wantVT=1
  rl* MA=g_ws+O_MA; rl* MVT=g_ws+O_MVT;
  rl* SVTB=g_ws+O_SVTB;
  for(int w=tid;w<64*NSV;w+=NT){ int c=w>>6, r2=w&63; MBL[r2+(size_t)PB*c]=MA[r2+(size_t)LDA*c]; }
  __syncthreads();
  gebd2_lower(MBL, PB, 64, NSV, sh, tid);
  dbdsdc_L(64, 0, lct, sh, tid);
  for(int w=tid;w<64*NSV;w+=NT){ int c=w>>6, r2=w&63; MVT[r2+(size_t)LDV*c]=(c<64)? SVTB[r2+(size_t)LDV*c]:0.0; }
  __syncthreads();
  for(int i=63;i>=0;--i){
    if(sh->tp[i]!=0.0) app_right(MVT, LDV, 0, 64, i, NSV, MBL+i, PB, sh->tp[i], tid);
    __syncthreads();
  }
}
__device__ void svd_wide(int m, rl* MBL, LeafCtx* lct, Sh* sh, int tid){ // m x 71, m in {2,4,8,16,32}; wantU=0, wantVT=1
  rl* MA=g_ws+O_MA; rl* MQ=g_ws+O_MQ; rl* MVT=g_ws+O_MVT;
  rl* SVTB=g_ws+O_SVTB; rl* TB=g_ws+O_TB; rl* VT2=g_ws+O_VT2;
  for(int w=tid;w<m*NSV;w+=NT){ int c=w/m, r2=w-c*m; MBL[r2+(size_t)PB*c]=MA[r2+(size_t)LDA*c]; }
  __syncthreads();
  gelq2(MBL, PB, m, NSV, sh, tid);
  for(int w=tid;w<m*NSV;w+=NT){ int c=w/m, r2=w-c*m; MQ[r2+(size_t)LDA*c]=(r2==c)?1.0:0.0; }
  __syncthreads();
  for(int j=m-1;j>=0;--j){
    if(sh->rs[j]!=0.0) app_right(MQ, LDA, 0, m, j, NSV, MBL+j, PB, sh->rs[j], tid);
    __syncthreads();
  }
  for(int w=tid;w<m*m;w+=NT){ int c=w/m, r2=w-c*m; TB[r2+(size_t)LDV*c]=(r2>=c)? MBL[r2+(size_t)PB*c]:0.0; }
  __syncthreads();
  gebd2_upper(TB, LDV, m, m, sh, tid);
  dbdsdc_U(m, 0, lct, sh, tid);
  for(int w=tid;w<m*m;w+=NT){ int c=w/m, r2=w-c*m; VT2[r2+(size_t)LDV*c]=SVTB[r2+(size_t)LDV*c]; }
  __syncthreads();
  for(int i=m-2;i>=0;--i){
    if(sh->tp[i]!=0.0) app_right(VT2, LDV, 0, m, i+1, m, TB+i, LDV, sh->tp[i], tid);
    __syncthreads();
  }
  for(int w=tid;w<m*NSV;w+=NT){
    int c=w/m, r2=w-c*m;
    const rl* vrow = VT2 + r2;
    const rl* qcol = MQ + (size_t)LDA*c;
    rl s=0.0; int t=0;
    for(; t+4<=m; t+=4){
      rl a0=vrow[(size_t)LDV*t], a1=vrow[(size_t)LDV*(t+1)], a2=vrow[(size_t)LDV*(t+2)], a3=vrow[(size_t)LDV*(t+3)];
      rl b0=qcol[t], b1=qcol[t+1], b2=qcol[t+2], b3=qcol[t+3];
      s+=a0*b0; s+=a1*b1; s+=a2*b2; s+=a3*b3;
    }
    for(; t<m; ++t) s += vrow[(size_t)LDV*t]*qcol[t];
    MVT[r2+(size_t)LDV*c]=s;
  }
  __syncthreads();
}

// ---- main kernel ----
__global__ __launch_bounds__(NT)
void mps_kernel(const float* __restrict__ ch, const float* __restrict__ ci,
                const float* __restrict__ ictx, const int* __restrict__ tok)
{
  __shared__ Sh sh;
  __shared__ LeafCtx lct[4];
  extern __shared__ rl MBL[];   // PB*NSV doubles (73272 B dynamic LDS)
  int tid = threadIdx.x;
  rl* MA = g_ws + O_MA; rl* MU = g_ws + O_MU; rl* MVT = g_ws + O_MVT;
  int kprev = 0;
  for(int s=0;s<9;++s){
    if(tid==0){
      rl W00=ch[s*4+0], W01=ch[s*4+1], W10=ch[s*4+2], W11=ch[s*4+3];
      rl P00=1,P01=0,P10=0,P11=1;
      for(int mexp=0;mexp<=70;++mexp){
        int j=70-mexp;
        rl v0,v1;
        if(j==0){ v0=ictx[s*2+0]; v1=ictx[s*2+1]; }
        else{
          int b=(tok[j-1]>>(15-s))&1;
          v0=ci[s*4+b]; v1=ci[s*4+2+b];
        }
        g_ws[O_COLS + 0 + 2*j] = P00*v0+P01*v1;
        g_ws[O_COLS + 1 + 2*j] = P10*v0+P11*v1;
        rl n00=W00*P00+W01*P10, n01=W00*P01+W01*P11;
        rl n10=W10*P00+W11*P10, n11=W10*P01+W11*P11;
        P00=n00;P01=n01;P10=n10;P11=n11;
      }
    }
    __syncthreads();
    int m = (s==0)?2:2*kprev;
    for(int w=tid; w<m*NSV; w+=NT){
      int j=w/m, r2=w-j*m;
      int l=r2>>1, dd2=r2&1;
      rl cv = g_ws[O_COLS + dd2 + 2*j];
      MA[r2+(size_t)LDA*j] = (s==0)? cv : g_ws[O_CAR + l + 64*j]*cv;
    }
    __syncthreads();
    int wantU = (s==8)?1:0;
    if(m==128) svd_tall(wantU, wantU?0:1, MBL, lct, &sh, tid);
    else if(m==64) svd_mid(MBL, lct, &sh, tid);
    else svd_wide(m, MBL, lct, &sh, tid);
    int k = min(64, min(m, NSV));
    __syncthreads();
    if(s<8){
      for(int w=tid; w<k*NSV; w+=NT){
        int j=w/k, l=w-j*k;
        g_ws[O_CAR + l + 64*j] = sh.d[l]*MVT[l+(size_t)LDV*j];
      }
    }
    __syncthreads();
    if(s==8){
      if(tid==0){
        rl W00=ch[8*4+0], W01=ch[8*4+1], W10=ch[8*4+2], W11=ch[8*4+3];
        rl P00=1,P01=0,P10=0,P11=1;
        for(int it=0;it<30;++it){
          rl n00=W00*P00+W01*P10, n01=W00*P01+W01*P11;
          rl n10=W10*P00+W11*P10, n11=W10*P01+W11*P11;
          P00=n00;P01=n01;P10=n10;P11=n11;
        }
        sh.sc[0]=P00+P10; sh.sc[1]=P01+P11;
      }
      __syncthreads();
      for(int r2=tid; r2<64; r2+=NT){
        rl acc=0.0;
        for(int l=0;l<64;++l)
          acc += sh.sc[0]*MU[(2*l)+(size_t)LDA*r2] + sh.sc[1]*MU[(2*l+1)+(size_t)LDA*r2];
        g_ws[O_VEC + r2] = acc/188.0;
      }
    }
    kprev = k;
    __syncthreads();
  }
}

__global__ __launch_bounds__(NT)
void head_kernel(const float* __restrict__ hw, const float* __restrict__ hb,
                 float* __restrict__ out)
{
  __shared__ float v[64];
  int tid=threadIdx.x;
  if(tid<64) v[tid]=(float)g_ws[O_VEC + tid];
  __syncthreads();
  int i = blockIdx.x*NT + tid;
  if(i<VOCAB){
    const float4* row = (const float4*)(hw + (size_t)i*64);
    float acc=0.f;
    #pragma unroll
    for(int c4=0;c4<16;++c4){
      float4 r4=row[c4];
      acc += r4.x*v[4*c4] + r4.y*v[4*c4+1] + r4.z*v[4*c4+2] + r4.w*v[4*c4+3];
    }
    out[i]=acc+hb[i];
  }
}

extern "C" void kernel_launch(void* const* d_in, const int* in_sizes, int n_in,
                              void* d_out, int out_size, void* d_ws, size_t ws_size,
                              hipStream_t stream)
{
  const float* ch  = (const float*)d_in[0];
  const float* ci  = (const float*)d_in[1];
  const float* hw  = (const float*)d_in[2];
  const float* hb  = (const float*)d_in[3];
  const float* ict = (const float*)d_in[4];
  const int*   tk  = (const int*)d_in[5];
  (void)d_ws; (void)ws_size; (void)in_sizes; (void)n_in; (void)out_size;

  size_t dynls = (size_t)PB*NSV*sizeof(double);   // 73272 B
  hipLaunchKernelGGL(mps_kernel, dim3(1), dim3(NT), dynls, stream, ch, ci, ict, tk);
  hipLaunchKernelGGL(head_kernel, dim3((VOCAB+NT-1)/NT), dim3(NT), 0, stream,
                     hw, hb, (float*)d_out);
}

// Round 2
// 9486.153 us; speedup vs baseline: 1.2344x; 1.0020x over previous
//
#include <hip/hip_runtime.h>

typedef double rl;
#define NT 256
#define NSV 71
#define LDA 128
#define LDV 72
#define SML 25
#define VOCAB 128000
#define LP 27   // LDS leaf pitch
#define PB 129  // LDS pitch for bidiag working matrix (odd => minimal fp64 bank aliasing)

// fp32 LAPACK constants (reference is numpy sgesdd in float32)
#define EPS32 1.1920928955078125e-7
#define UNFL32 1.17549435e-38

// g_ws offsets (doubles)
#define O_CAR   0
#define O_COLS  4608
#define O_VEC   4800
#define O_MA    5120
#define O_MU    23552
#define O_MQ    32768
#define O_MVT   41984
#define O_SUB   47168
#define O_SVTB  52352
#define O_U2    57536
#define O_VT2   62720
#define O_QU    67904
#define O_QV    73088
#define O_TB    78272

__device__ double g_ws[84000];

// Per-wave leaf context: one D&C leaf (n<=25, np<=26) runs entirely inside a
// single wave; 4 leaves execute concurrently on the 4 SIMDs of the CU.
struct LeafCtx {
  rl LVT[26*LP], LU[26*LP];
  rl b1[26], b2[26], b3[26], b4[26];
  rl sc[6];
  int ia[26], ib[26], ic[26];
  int si[12];
};

struct Sh {
  rl d[72], e[72], tq[72], tp[72], rc[72], rs[72];
  rl dsig[72], zz[72], zh[72], sigm[72], vals[72];
  rl ta[72], tb[72];
  int srcU[72], srcVT[72], perm[72];
  int ia[72], ib[72], ic[72];
  int opk[12], opf[12], opa[12], opb[12], opq[12];
  rl sc[8];
  int si[16];
};

// Wave-local "barrier": a wave executes one instruction stream and its LDS ops
// complete in order, so ordering the compiler's memory ops + draining counters
// is sufficient for lane0 -> other-lane LDS communication.
__device__ __forceinline__ void wsync(){
  asm volatile("s_waitcnt vmcnt(0) lgkmcnt(0)" ::: "memory");
}

__device__ __forceinline__ rl d_sign(rl a, rl b){ return (b >= 0.0) ? fabs(a) : -fabs(a); }
__device__ __forceinline__ rl dlapy2(rl x, rl y){
  rl ax=fabs(x), ay=fabs(y);
  rl w = ax>ay?ax:ay, z = ax>ay?ay:ax;
  if(z==0.0) return w;
  rl t = z/w; return w*sqrt(1.0+t*t);
}
// LAPACK >= 3.10 dlartg convention (modern OpenBLAS)
__device__ void dlartg(rl f, rl g, rl* cs, rl* sn, rl* r){
  if(g==0.0){ *cs=1.0; *sn=0.0; *r=f; }
  else if(f==0.0){ *cs=0.0; *sn=d_sign(1.0,g); *r=fabs(g); }
  else{
    rl dd = sqrt(f*f+g*g);
    *cs = fabs(f)/dd;
    *r  = d_sign(dd, f);
    *sn = g/(*r);
  }
}

__device__ void dlas2(rl f, rl g, rl h, rl* ssmin, rl* ssmax){
  rl fa=fabs(f), ga=fabs(g), ha=fabs(h);
  rl fhmn=fmin(fa,ha), fhmx=fmax(fa,ha);
  if(fhmn==0.0){
    *ssmin=0.0;
    if(fhmx==0.0) *ssmax=ga;
    else { rl mx=fmax(fhmx,ga), mn=fmin(fhmx,ga); rl q=mn/mx; *ssmax=mx*sqrt(1.0+q*q); }
  } else {
    if(ga < fhmx){
      rl as=1.0+fhmn/fhmx, at=(fhmx-fhmn)/fhmx;
      rl au=(ga/fhmx); au=au*au;
      rl c=2.0/(sqrt(as*as+au)+sqrt(at*at+au));
      *ssmin=fhmn*c; *ssmax=fhmx/c;
    } else {
      rl au=fhmx/ga;
      if(au==0.0){ *ssmin=(fhmn*fhmx)/ga; *ssmax=ga; }
      else{
        rl as=1.0+fhmn/fhmx, at=(fhmx-fhmn)/fhmx;
        rl c=1.0/(sqrt(1.0+(as*au)*(as*au))+sqrt(1.0+(at*au)*(at*au)));
        *ssmin=(fhmn*c)*au; *ssmin=*ssmin+*ssmin;
        *ssmax=ga/(c+c);
      }
    }
  }
}

__device__ void dlasv2(rl f, rl g, rl h, rl* ssmin, rl* ssmax, rl* snr, rl* csr, rl* snl, rl* csl){
  rl ft=f, fa=fabs(f), ht=h, ha=fabs(h);
  int pmax=1;
  bool swp = (ha > fa);
  if(swp){ pmax=3; rl t=ft; ft=ht; ht=t; t=fa; fa=ha; ha=t; }
  rl gt=g, ga=fabs(g);
  rl clt=0, crt=0, slt=0, srt=0;
  if(ga==0.0){ *ssmin=ha; *ssmax=fa; clt=1.0; crt=1.0; slt=0.0; srt=0.0; }
  else{
    bool gasmal=true;
    if(ga > fa){
      pmax=2;
      if((fa/ga) < EPS32){
        gasmal=false;
        *ssmax=ga;
        if(ha>1.0) *ssmin=fa/(ga/ha); else *ssmin=(fa/ga)*ha;
        clt=1.0; slt=ht/gt; srt=1.0; crt=ft/gt;
      }
    }
    if(gasmal){
      rl dd=fa-ha;
      rl lv = (dd==fa) ? 1.0 : dd/fa;
      rl mq = gt/ft;
      rl tv = 2.0-lv;
      rl mm = mq*mq, tt = tv*tv;
      rl sv = sqrt(tt+mm);
      rl rv = (lv==0.0) ? fabs(mq) : sqrt(lv*lv+mm);
      rl a = 0.5*(sv+rv);
      *ssmin = ha/a; *ssmax = fa*a;
      rl t3;
      if(mm==0.0){
        if(lv==0.0) t3 = d_sign(2.0, ft)*d_sign(1.0, gt);
        else t3 = gt/d_sign(dd, ft) + mq/tv;
      } else {
        t3 = (mq/(sv+tv) + mq/(rv+lv))*(1.0+a);
      }
      rl l2 = sqrt(t3*t3+4.0);
      crt = 2.0/l2; srt = t3/l2;
      clt = (crt + srt*mq)/a;
      slt = (ht/ft)*srt/a;
    }
  }
  if(swp){ *csl=srt; *snl=crt; *csr=slt; *snr=clt; }
  else  { *csl=clt; *snl=slt; *csr=crt; *snr=srt; }
  rl tsign=1.0;
  if(pmax==1) tsign = d_sign(1.0,*csr)*d_sign(1.0,*csl)*d_sign(1.0,f);
  if(pmax==2) tsign = d_sign(1.0,*snr)*d_sign(1.0,*csl)*d_sign(1.0,g);
  if(pmax==3) tsign = d_sign(1.0,*snr)*d_sign(1.0,*snl)*d_sign(1.0,h);
  *ssmax = d_sign(*ssmax, tsign);
  *ssmin = d_sign(*ssmin, tsign*d_sign(1.0,f)*d_sign(1.0,h));
}

// Householder apply, order-preserving unroll-4 (grouped loads, sequential adds:
// bit-identical to the scalar loop). Used by the back-transforms (v already scaled).
__device__ __forceinline__ void app_left(rl* A, int ld, int r0, int m, int c0, int n, const rl* vbase, rl tau, int tid){
  const int len = m - r0 - 1;
  const rl* v = vbase + r0 + 1;
  for(int c=c0+tid; c<n; c+=NT){
    rl* col = A + (size_t)ld*c + r0;
    rl s = col[0];
    int i=0;
    for(; i+4<=len; i+=4){
      rl a0=col[1+i],a1=col[2+i],a2=col[3+i],a3=col[4+i];
      rl b0=v[i],b1=v[i+1],b2=v[i+2],b3=v[i+3];
      s+=a0*b0; s+=a1*b1; s+=a2*b2; s+=a3*b3;
    }
    for(; i<len; ++i) s += col[1+i]*v[i];
    rl w = s*tau;
    col[0] -= w;
    i=0;
    for(; i+4<=len; i+=4){
      rl b0=v[i],b1=v[i+1],b2=v[i+2],b3=v[i+3];
      col[1+i]-=w*b0; col[2+i]-=w*b1; col[3+i]-=w*b2; col[4+i]-=w*b3;
    }
    for(; i<len; ++i) col[1+i] -= w*v[i];
  }
}
__device__ __forceinline__ void app_right(rl* A, int ld, int r0, int m, int c0, int n, const rl* vbase, int vstride, rl tau, int tid){
  const int len = n - c0 - 1;
  const rl* v = vbase + (size_t)vstride*(c0+1);
  for(int r=r0+tid; r<m; r+=NT){
    rl* row = A + r + (size_t)ld*c0;
    rl s = row[0];
    int i=0;
    for(; i+4<=len; i+=4){
      rl a0=row[(size_t)ld*(1+i)], a1=row[(size_t)ld*(2+i)], a2=row[(size_t)ld*(3+i)], a3=row[(size_t)ld*(4+i)];
      rl b0=v[(size_t)vstride*i], b1=v[(size_t)vstride*(i+1)], b2=v[(size_t)vstride*(i+2)], b3=v[(size_t)vstride*(i+3)];
      s+=a0*b0; s+=a1*b1; s+=a2*b2; s+=a3*b3;
    }
    for(; i<len; ++i) s += row[(size_t)ld*(1+i)]*v[(size_t)vstride*i];
    rl w = s*tau;
    row[0] -= w;
    i=0;
    for(; i+4<=len; i+=4){
      rl b0=v[(size_t)vstride*i], b1=v[(size_t)vstride*(i+1)], b2=v[(size_t)vstride*(i+2)], b3=v[(size_t)vstride*(i+3)];
      row[(size_t)ld*(1+i)]-=w*b0; row[(size_t)ld*(2+i)]-=w*b1; row[(size_t)ld*(3+i)]-=w*b2; row[(size_t)ld*(4+i)]-=w*b3;
    }
    for(; i<len; ++i) row[(size_t)ld*(1+i)] -= w*v[(size_t)vstride*i];
  }
}

// Apply-with-on-the-fly scale: v holds RAW (pre-scale) values; b = fl(raw*scl)
// is the exact same single rounding as the stored scaled value, so the result
// is bit-identical to scale-then-apply. ONE column/row per thread (counts < NT).
__device__ __forceinline__ void app_left_s(rl* A, int ld, int r0, int m, int c0, int n, const rl* vbase, rl scl, rl tau, int tid){
  const int len = m - r0 - 1;
  const rl* v = vbase + r0 + 1;
  int c = c0 + tid;
  if(c < n){
    rl* col = A + (size_t)ld*c + r0;
    rl s = col[0];
    int i=0;
    for(; i+4<=len; i+=4){
      rl a0=col[1+i],a1=col[2+i],a2=col[3+i],a3=col[4+i];
      rl b0=v[i]*scl,b1=v[i+1]*scl,b2=v[i+2]*scl,b3=v[i+3]*scl;
      s+=a0*b0; s+=a1*b1; s+=a2*b2; s+=a3*b3;
    }
    for(; i<len; ++i) s += col[1+i]*(v[i]*scl);
    rl w = s*tau;
    col[0] -= w;
    i=0;
    for(; i+4<=len; i+=4){
      rl b0=v[i]*scl,b1=v[i+1]*scl,b2=v[i+2]*scl,b3=v[i+3]*scl;
      col[1+i]-=w*b0; col[2+i]-=w*b1; col[3+i]-=w*b2; col[4+i]-=w*b3;
    }
    for(; i<len; ++i) col[1+i] -= w*(v[i]*scl);
  }
}
__device__ __forceinline__ void app_right_s(rl* A, int ld, int r0, int m, int c0, int n, const rl* vbase, int vstride, rl scl, rl tau, int tid){
  const int len = n - c0 - 1;
  const rl* v = vbase + (size_t)vstride*(c0+1);
  int r = r0 + tid;
  if(r < m){
    rl* row = A + r + (size_t)ld*c0;
    rl s = row[0];
    int i=0;
    for(; i+4<=len; i+=4){
      rl a0=row[(size_t)ld*(1+i)], a1=row[(size_t)ld*(2+i)], a2=row[(size_t)ld*(3+i)], a3=row[(size_t)ld*(4+i)];
      rl b0=v[(size_t)vstride*i]*scl, b1=v[(size_t)vstride*(i+1)]*scl, b2=v[(size_t)vstride*(i+2)]*scl, b3=v[(size_t)vstride*(i+3)]*scl;
      s+=a0*b0; s+=a1*b1; s+=a2*b2; s+=a3*b3;
    }
    for(; i<len; ++i) s += row[(size_t)ld*(1+i)]*(v[(size_t)vstride*i]*scl);
    rl w = s*tau;
    row[0] -= w;
    i=0;
    for(; i+4<=len; i+=4){
      rl b0=v[(size_t)vstride*i]*scl, b1=v[(size_t)vstride*(i+1)]*scl, b2=v[(size_t)vstride*(i+2)]*scl, b3=v[(size_t)vstride*(i+3)]*scl;
      row[(size_t)ld*(1+i)]-=w*b0; row[(size_t)ld*(2+i)]-=w*b1; row[(size_t)ld*(3+i)]-=w*b2; row[(size_t)ld*(4+i)]-=w*b3;
    }
    for(; i<len; ++i) row[(size_t)ld*(1+i)] -= w*(v[(size_t)vstride*i]*scl);
  }
}

// Redundant (all-wave) reflector head: every thread ends with the bit-identical
// norm^2 (lane pattern + reduction tree match the original lane-0 computation).
#define REFLECT_HEAD(PS_EXPR_LOOP)                                  \
  rl ps=0.0;                                                        \
  PS_EXPR_LOOP                                                      \
  for(int off=32;off>0;off>>=1) ps += __shfl_xor(ps,off,64);

// ---- wave-scoped dbdsqr on a private LDS leaf block ----
// Identical arithmetic to the block version; tid->lane, __syncthreads->wsync.
__device__ void bdsqr_wave(int n, rl* d, rl* e, int ncvt, int nru, LeafCtx* lc, int lane){
  if(n>1){
    rl eps=EPS32, unfl=UNFL32;
    rl tolmul=fmax(10.0,fmin(100.0,pow(eps,-0.125)));
    rl tol=tolmul*eps;
    rl thresh=0.0;
    int mm=n-1, oldll=-2, oldm=-2, idir=0, iter=0, maxit=6*n*n;
    if(lane==0){
      rl sminoa=fabs(d[0]);
      if(sminoa!=0.0){
        rl mu=sminoa;
        for(int i=1;i<n;++i){ mu=fabs(d[i])*(mu/(mu+fabs(e[i-1]))); sminoa=fmin(sminoa,mu); if(sminoa==0.0)break; }
      }
      sminoa=sminoa/sqrt((rl)n);
      thresh=fmax(tol*sminoa,(rl)(6*n*n)*unfl);
    }
    while(true){
      if(lane==0){
        int act=0, p_lo=0, p_cnt=0, p_fwd=1, p_mm=0;
        while(mm>0){
          if(iter>maxit) break;
          rl smax=fabs(d[mm]), smin=smax;
          int ll=-1;
          for(int lll=mm-1;lll>=0;--lll){
            rl abss=fabs(d[lll]), abse=fabs(e[lll]);
            if(abse<=thresh){ ll=lll; break; }
            smin=fmin(smin,abss);
            smax=fmax(smax,fmax(abss,abse));
          }
          if(ll==mm-1){ e[ll]=0.0; mm=mm-1; continue; }
          if(ll>=0) e[ll]=0.0;
          int lo=ll+1;
          if(mm==lo+1){
            rl sigmn,sigmx,sinr,cosr,sinl,cosl;
            dlasv2(d[lo],e[lo],d[mm],&sigmn,&sigmx,&sinr,&cosr,&sinl,&cosl);
            d[lo]=sigmx; d[mm]=sigmn; e[lo]=0.0;
            lc->sc[0]=cosr; lc->sc[1]=sinr; lc->sc[2]=cosl; lc->sc[3]=sinl;
            act=2; p_lo=lo; p_mm=mm;
            mm-=2;
            break;
          }
          if(lo>oldm || mm<oldll) idir=(fabs(d[lo])>=fabs(d[mm]))?1:2;
          rl sminl=0.0; int conv=0;
          if(idir==1){
            if(fabs(e[mm-1])<=tol*fabs(d[mm])){ e[mm-1]=0.0; conv=1; }
            if(!conv){
              rl mu=fabs(d[lo]); sminl=mu;
              for(int lll=lo;lll<mm;++lll){
                if(fabs(e[lll])<=tol*mu){ e[lll]=0.0; conv=1; break; }
                mu=fabs(d[lll+1])*(mu/(mu+fabs(e[lll])));
                sminl=fmin(sminl,mu);
              }
            }
          } else {
            if(fabs(e[lo])<=tol*fabs(d[lo])){ e[lo]=0.0; conv=1; }
            if(!conv){
              rl mu=fabs(d[mm]); sminl=mu;
              for(int lll=mm-1;lll>=lo;--lll){
                if(fabs(e[lll])<=tol*mu){ e[lll]=0.0; conv=1; break; }
                mu=fabs(d[lll])*(mu/(mu+fabs(e[lll])));
                sminl=fmin(sminl,mu);
              }
            }
          }
          if(conv) continue;
          oldll=lo; oldm=mm;
          rl shift=0.0, rr_;
          if(!((rl)n*tol*(sminl/smax) <= fmax(eps, 0.01*tol))){
            rl sll;
            if(idir==1){ sll=fabs(d[lo]); dlas2(d[mm-1],e[mm-1],d[mm],&shift,&rr_); }
            else { sll=fabs(d[mm]); dlas2(d[lo],e[lo],d[lo+1],&shift,&rr_); }
            if(sll>0.0){ rl q=shift/sll; if(q*q<eps) shift=0.0; }
          }
          iter += mm-lo;
          int cnt=mm-lo;
          if(shift==0.0){
            if(idir==1){
              rl cs=1.0, oldcs=1.0, sn=0.0, oldsn=0.0, r;
              for(int i=lo;i<mm;++i){
                dlartg(d[i]*cs,e[i],&cs,&sn,&r);
                if(i>lo) e[i-1]=oldsn*r;
                dlartg(oldcs*r, d[i+1]*sn, &oldcs,&oldsn,&d[i]);
                lc->b1[i-lo]=cs; lc->b2[i-lo]=sn; lc->b3[i-lo]=oldcs; lc->b4[i-lo]=oldsn;
              }
              rl h=d[mm]*cs; d[mm]=h*oldcs; e[mm-1]=h*oldsn;
              p_fwd=1;
              if(fabs(e[mm-1])<=thresh) e[mm-1]=0.0;
            } else {
              rl cs=1.0, oldcs=1.0, sn=0.0, oldsn=0.0, r;
              for(int i=mm;i>lo;--i){
                dlartg(d[i]*cs,e[i-1],&cs,&sn,&r);
                if(i<mm) e[i]=oldsn*r;
                dlartg(oldcs*r,d[i-1]*sn,&oldcs,&oldsn,&d[i]);
                int j=i-lo-1;
                lc->b1[j]=oldcs; lc->b2[j]=-oldsn; lc->b3[j]=cs; lc->b4[j]=-sn;
              }
              rl h=d[lo]*cs; d[lo]=h*oldcs; e[lo]=h*oldsn;
              p_fwd=0;
              if(fabs(e[lo])<=thresh) e[lo]=0.0;
            }
          } else {
            if(idir==1){
              rl f2=(fabs(d[lo])-shift)*(d_sign(1.0,d[lo])+shift/d[lo]);
              rl g2=e[lo], r, cosr,sinr,cosl,sinl;
              for(int i=lo;i<mm;++i){
                dlartg(f2,g2,&cosr,&sinr,&r);
                if(i>lo) e[i-1]=r;
                f2=cosr*d[i]+sinr*e[i];
                e[i]=cosr*e[i]-sinr*d[i];
                g2=sinr*d[i+1];
                d[i+1]=cosr*d[i+1];
                dlartg(f2,g2,&cosl,&sinl,&r);
                d[i]=r;
                f2=cosl*e[i]+sinl*d[i+1];
                d[i+1]=cosl*d[i+1]-sinl*e[i];
                if(i<mm-1){ g2=sinl*e[i+1]; e[i+1]=cosl*e[i+1]; }
                lc->b1[i-lo]=cosr; lc->b2[i-lo]=sinr; lc->b3[i-lo]=cosl; lc->b4[i-lo]=sinl;
              }
              e[mm-1]=f2;
              p_fwd=1;
              if(fabs(e[mm-1])<=thresh) e[mm-1]=0.0;
            } else {
              rl f2=(fabs(d[mm])-shift)*(d_sign(1.0,d[mm])+shift/d[mm]);
              rl g2=e[mm-1], r, cosr,sinr,cosl,sinl;
              for(int i=mm;i>lo;--i){
                dlartg(f2,g2,&cosr,&sinr,&r);
                if(i<mm) e[i]=r;
                f2=cosr*d[i]+sinr*e[i-1];
                e[i-1]=cosr*e[i-1]-sinr*d[i];
                g2=sinr*d[i-1];
                d[i-1]=cosr*d[i-1];
                dlartg(f2,g2,&cosl,&sinl,&r);
                d[i]=r;
                f2=cosl*e[i-1]+sinl*d[i-1];
                d[i-1]=cosl*d[i-1]-sinl*e[i-1];
                if(i>lo+1){ g2=sinl*e[i-2]; e[i-2]=cosl*e[i-2]; }
                int j=i-lo-1;
                lc->b1[j]=cosl; lc->b2[j]=-sinl; lc->b3[j]=cosr; lc->b4[j]=-sinr;
              }
              e[lo]=f2;
              p_fwd=0;
              if(fabs(e[lo])<=thresh) e[lo]=0.0;
            }
          }
          act=1; p_lo=lo; p_cnt=cnt;
          break;
        }
        lc->si[7]=act; lc->si[8]=p_lo; lc->si[9]=p_cnt; lc->si[10]=p_fwd; lc->si[11]=p_mm;
      }
      wsync();
      int act=lc->si[7];
      if(act==0) break;
      if(act==1){
        int lo=lc->si[8], cnt=lc->si[9], fwd=lc->si[10];
        if(lane<ncvt){
          int k=lane;
          if(fwd){
            for(int j=0;j<cnt;++j){
              rl c=lc->b1[j], s=lc->b2[j];
              rl t=lc->LVT[(lo+j+1)*LP+k];
              lc->LVT[(lo+j+1)*LP+k]=c*t-s*lc->LVT[(lo+j)*LP+k];
              lc->LVT[(lo+j)*LP+k]=s*t+c*lc->LVT[(lo+j)*LP+k];
            }
          } else {
            for(int j=cnt-1;j>=0;--j){
              rl c=lc->b1[j], s=lc->b2[j];
              rl t=lc->LVT[(lo+j+1)*LP+k];
              lc->LVT[(lo+j+1)*LP+k]=c*t-s*lc->LVT[(lo+j)*LP+k];
              lc->LVT[(lo+j)*LP+k]=s*t+c*lc->LVT[(lo+j)*LP+k];
            }
          }
        } else if(lane<ncvt+nru){
          int r2=lane-ncvt;
          if(fwd){
            for(int j=0;j<cnt;++j){
              rl c=lc->b3[j], s=lc->b4[j];
              rl t=lc->LU[r2*LP+(lo+j+1)];
              lc->LU[r2*LP+(lo+j+1)]=c*t-s*lc->LU[r2*LP+(lo+j)];
              lc->LU[r2*LP+(lo+j)]=s*t+c*lc->LU[r2*LP+(lo+j)];
            }
          } else {
            for(int j=cnt-1;j>=0;--j){
              rl c=lc->b3[j], s=lc->b4[j];
              rl t=lc->LU[r2*LP+(lo+j+1)];
              lc->LU[r2*LP+(lo+j+1)]=c*t-s*lc->LU[r2*LP+(lo+j)];
              lc->LU[r2*LP+(lo+j)]=s*t+c*lc->LU[r2*LP+(lo+j)];
            }
          }
        }
      } else {
        int lo=lc->si[8], m2=lc->si[11];
        rl cosr=lc->sc[0], sinr=lc->sc[1], cosl=lc->sc[2], sinl=lc->sc[3];
        if(lane<ncvt){
          rl x=lc->LVT[lo*LP+lane], y=lc->LVT[m2*LP+lane];
          lc->LVT[lo*LP+lane]=cosr*x+sinr*y; lc->LVT[m2*LP+lane]=cosr*y-sinr*x;
        } else if(lane<ncvt+nru){
          int r2=lane-ncvt;
          rl x=lc->LU[r2*LP+lo], y=lc->LU[r2*LP+m2];
          lc->LU[r2*LP+lo]=cosl*x+sinl*y; lc->LU[r2*LP+m2]=cosl*y-sinl*x;
        }
      }
      wsync();
    }
  }
  if(lane==0){
    for(int i=0;i<n;++i){ lc->ic[i]=(d[i]<0.0)?1:0; if(d[i]<0.0) d[i]=-d[i]; }
    int nsw=0;
    for(int i=0;i<n-1;++i){
      int isub=0; rl smin=d[0];
      for(int j=1;j<n-i;++j){ if(d[j]<=smin){ isub=j; smin=d[j]; } }
      int tgt=n-1-i;
      if(isub!=tgt){
        d[isub]=d[tgt]; d[tgt]=smin;
        lc->ia[nsw]=isub; lc->ib[nsw]=tgt; ++nsw;
      }
    }
    lc->si[7]=nsw;
  }
  wsync();
  int nsw=lc->si[7];
  if(lane<ncvt){
    for(int i=0;i<n;++i) if(lc->ic[i]) lc->LVT[i*LP+lane]=-lc->LVT[i*LP+lane];
    for(int w2=0;w2<nsw;++w2){
      int a=lc->ia[w2], b=lc->ib[w2];
      rl t=lc->LVT[a*LP+lane]; lc->LVT[a*LP+lane]=lc->LVT[b*LP+lane]; lc->LVT[b*LP+lane]=t;
    }
  } else if(lane<ncvt+nru){
    int r2=lane-ncvt;
    for(int w2=0;w2<nsw;++w2){
      int a=lc->ia[w2], b=lc->ib[w2];
      rl t=lc->LU[r2*LP+a]; lc->LU[r2*LP+a]=lc->LU[r2*LP+b]; lc->LU[r2*LP+b]=t;
    }
  }
  wsync();
}

// ---- leaf: dlasdq, entirely within one wave (no block barriers inside) ----
__device__ void leaf_exec(int f, int n, int sqre, int wantU, LeafCtx* lc, Sh* sh, int lane){
  rl* SVTB = g_ws + O_SVTB; rl* SUB = g_ws + O_SUB;
  int np = n + sqre;
  for(int w=lane; w<np*np; w+=64){ int r2=w/np, c=w-r2*np; lc->LVT[r2*LP+c]=SVTB[(f+r2)+(size_t)LDV*(f+c)]; }
  if(wantU) for(int w=lane; w<n*n; w+=64){ int r2=w/n, c=w-r2*n; lc->LU[r2*LP+c]=SUB[(f+r2)+(size_t)LDV*(f+c)]; }
  wsync();
  if(sqre==1){
    if(lane==0){
      rl cs,snv,rv; rl* dd=sh->d+f; rl* ee=sh->e+f;
      for(int i=0;i<n;++i){
        dlartg(dd[i],ee[i],&cs,&snv,&rv);
        dd[i]=rv;
        if(i<n-1){ ee[i]=snv*dd[i+1]; dd[i+1]=cs*dd[i+1]; }
        else ee[i]=0.0;
        lc->b1[i]=cs; lc->b2[i]=snv;
      }
    }
    wsync();
    if(lane<np){
      for(int j=0;j<n;++j){
        rl cj=lc->b1[j], sj=lc->b2[j];
        rl t=lc->LVT[(j+1)*LP+lane];
        lc->LVT[(j+1)*LP+lane]=cj*t-sj*lc->LVT[j*LP+lane];
        lc->LVT[j*LP+lane]=sj*t+cj*lc->LVT[j*LP+lane];
      }
    }
    wsync();
    if(lane==0){
      rl cs,snv,rv; rl* dd=sh->d+f; rl* ee=sh->e+f;
      for(int i=0;i<n-1;++i){
        dlartg(dd[i],ee[i],&cs,&snv,&rv);
        dd[i]=rv; ee[i]=snv*dd[i+1]; dd[i+1]=cs*dd[i+1];
        lc->b1[i]=cs; lc->b2[i]=snv;
      }
    }
    wsync();
    if(wantU && lane<n){
      for(int j=0;j<n-1;++j){
        rl cj=lc->b1[j], sj=lc->b2[j];
        rl t=lc->LU[lane*LP+(j+1)];
        lc->LU[lane*LP+(j+1)]=cj*t-sj*lc->LU[lane*LP+j];
        lc->LU[lane*LP+j]=sj*t+cj*lc->LU[lane*LP+j];
      }
    }
    wsync();
  }
  bdsqr_wave(n, sh->d+f, sh->e+f, np, wantU? n:0, lc, lane);
  for(int w=lane; w<np*np; w+=64){ int r2=w/np, c=w-r2*np; SVTB[(f+r2)+(size_t)LDV*(f+c)]=lc->LVT[r2*LP+c]; }
  if(wantU) for(int w=lane; w<n*n; w+=64){ int r2=w/n, c=w-r2*n; SUB[(f+r2)+(size_t)LDV*(f+c)]=lc->LU[r2*LP+c]; }
}

// ---- D&C merge (dlasd1/2/3) ---- (block-wide, unchanged)
__device__ void lasd1_merge(int f, int nl, int nr, int sqre, int wantU, Sh* sh, int tid){
  rl* SUB = g_ws + O_SUB; rl* SVTB = g_ws + O_SVTB;
  rl* U2 = g_ws + O_U2; rl* VT2 = g_ws + O_VT2; rl* QU = g_ws + O_QU; rl* QV = g_ws + O_QV;
  int n = nl+nr+1, m = n+sqre;
  if(tid==0){
    rl alpha = sh->d[f+nl], beta = sh->e[f+nl];
    sh->vals[0]=0.0;
    sh->zz[0] = alpha*SVTB[(f+nl)+(size_t)LDV*(f+nl)];
    sh->srcU[0]=-1; sh->srcVT[0]=f+nl;
    for(int i=0;i<nl;++i){
      sh->vals[1+i]=sh->d[f+i];
      sh->zz[1+i]=alpha*SVTB[(f+i)+(size_t)LDV*(f+nl)];
      sh->srcU[1+i]=f+i; sh->srcVT[1+i]=f+i;
    }
    for(int j=0;j<nr;++j){
      sh->vals[1+nl+j]=sh->d[f+nl+1+j];
      sh->zz[1+nl+j]=beta*SVTB[(f+nl+1+j)+(size_t)LDV*(f+nl+1)];
      sh->srcU[1+nl+j]=f+nl+1+j; sh->srcVT[1+nl+j]=f+nl+1+j;
    }
    sh->sc[0]=alpha; sh->sc[1]=beta;
    if(sqre==1){
      rl zM = beta*SVTB[(f+n)+(size_t)LDV*(f+nl+1)];
      rl c,s,r2;
      dlartg(sh->zz[0], zM, &c, &s, &r2);
      sh->zz[0]=r2; sh->sc[2]=c; sh->sc[3]=s;
    }
  }
  __syncthreads();
  if(sqre==1){
    rl c=sh->sc[2], s=sh->sc[3];
    int ra=f+nl, rb=f+n;
    for(int k=tid;k<m;k+=NT){
      size_t ci=(size_t)LDV*(f+k);
      rl a=SVTB[ra+ci], b=SVTB[rb+ci];
      SVTB[ra+ci]=c*a+s*b; SVTB[rb+ci]=-s*a+c*b;
    }
  }
  __syncthreads();
  if(tid==0){
    rl maxd=0.0; for(int i=0;i<n;++i) maxd=fmax(maxd,fabs(sh->vals[i]));
    rl tol = 8.0*EPS32*fmax(maxd, fmax(fabs(sh->sc[0]), fabs(sh->sc[1])));
    int nds=0;
    sh->ic[nds++]=0;
    for(int i=1;i<n;++i) if(fabs(sh->zz[i]) > tol) sh->ic[nds++]=i;
    for(int a=1;a<nds;++a){
      int key=sh->ic[a]; rl kv=sh->vals[key]; int b=a-1;
      while(b>=1 && sh->vals[sh->ic[b]] > kv){ sh->ic[b+1]=sh->ic[b]; --b; }
      sh->ic[b+1]=key;
    }
    int K=nds, pos=nds;
    for(int i=1;i<n;++i) if(fabs(sh->zz[i]) <= tol) sh->ic[pos++]=i;
    for(int a=K+1;a<n;++a){
      int key=sh->ic[a]; rl kv=sh->vals[key]; int b=a-1;
      while(b>=K && sh->vals[sh->ic[b]] > kv){ sh->ic[b+1]=sh->ic[b]; --b; }
      sh->ic[b+1]=key;
    }
    for(int t=0;t<n;++t){ sh->ta[t]=sh->vals[t]; sh->tb[t]=sh->zz[t]; sh->ia[t]=sh->srcU[t]; sh->ib[t]=sh->srcVT[t]; }
    for(int t=0;t<n;++t){
      int p=sh->ic[t];
      sh->dsig[t]=sh->ta[p]; sh->zz[t]=sh->tb[p]; sh->srcU[t]=sh->ia[p]; sh->srcVT[t]=sh->ib[p];
    }
    rl rho=0.0; for(int t=0;t<K;++t){ rl zv=sh->zz[t]; rho += zv*zv; }
    sh->sc[4]=rho;
    sh->si[0]=K; sh->si[1]=n; sh->si[2]=m; sh->si[3]=f; sh->si[4]=nl;
  }
  __syncthreads();
  int K=sh->si[0], n_=sh->si[1], m_=sh->si[2], f_=sh->si[3], nl_=sh->si[4];
  if(wantU){
    for(int w=tid; w<n_*n_; w+=NT){
      int col=w/n_, row=w-col*n_;
      int su=sh->srcU[col];
      rl v;
      if(su<0) v = (row==nl_) ? 1.0 : 0.0;
      else v = SUB[(f_+row)+(size_t)LDV*su];
      U2[row+(size_t)LDV*col]=v;
    }
  }
  for(int w=tid; w<n_*m_; w+=NT){
    int row=w/m_, col=w-row*m_;
    VT2[row+(size_t)LDV*col] = SVTB[sh->srcVT[row]+(size_t)LDV*(f_+col)];
  }
  __syncthreads();
  rl rho=sh->sc[4];
  for(int j=tid;j<K;j+=NT){
    rl lo=sh->dsig[j];
    rl hi=(j<K-1)? sh->dsig[j+1] : sqrt(sh->dsig[K-1]*sh->dsig[K-1]+rho);
    for(int it=0; it<130; ++it){
      rl mid=0.5*(lo+hi);
      if(mid<=lo || mid>=hi) break;
      rl g=1.0;
      for(int i2=0;i2<K;++i2){
        rl zi=sh->zz[i2];
        g += zi*zi/((sh->dsig[i2]-mid)*(sh->dsig[i2]+mid));
      }
      if(g<0.0) lo=mid; else hi=mid;
    }
    sh->sigm[j]=0.5*(lo+hi);
  }
  __syncthreads();
  for(int i2=tid;i2<K;i2+=NT){
    rl di=sh->dsig[i2];
    rl p=(di - sh->sigm[K-1])*(di + sh->sigm[K-1]);
    for(int j=0;j<i2;++j)
      p *= (di - sh->sigm[j])*(di + sh->sigm[j])/((di - sh->dsig[j])*(di + sh->dsig[j]));
    for(int j=i2;j<K-1;++j)
      p *= (di - sh->sigm[j])*(di + sh->sigm[j])/((di - sh->dsig[j+1])*(di + sh->dsig[j+1]));
    sh->zh[i2] = d_sign(sqrt(fabs(p)), sh->zz[i2]);
  }
  __syncthreads();
  for(int j=tid;j<K;j+=NT){
    rl sj=sh->sigm[j];
    rl nu=0.0, nv=0.0;
    for(int i2=0;i2<K;++i2){
      rl di=sh->dsig[i2];
      rl vv=sh->zh[i2]/((di-sj)*(di+sj));
      QV[i2+(size_t)LDV*j]=vv; nv+=vv*vv;
      if(wantU){
        rl uu=(i2==0)? -1.0 : di*vv;
        QU[i2+(size_t)LDV*j]=uu; nu+=uu*uu;
      }
    }
    nv=1.0/sqrt(nv);
    for(int i2=0;i2<K;++i2) QV[i2+(size_t)LDV*j]*=nv;
    if(wantU){
      nu=1.0/sqrt(nu);
      for(int i2=0;i2<K;++i2) QU[i2+(size_t)LDV*j]*=nu;
    }
  }
  __syncthreads();
  if(tid==0){
    int nd2=n_-K;
    for(int t=0;t<nd2;++t) sh->ia[t]=K+t;
    int ps=K-1, pd=nd2-1;
    int t=0;
    while(t<n_){
      rl vs = (ps>=0)? sh->sigm[ps] : -1.0;
      rl vd = (pd>=0)? sh->dsig[sh->ia[pd]] : -1.0;
      if(vs >= vd){ sh->perm[t]=ps; sh->vals[t]=vs; --ps; }
      else { sh->perm[t]=1000+sh->ia[pd]; sh->vals[t]=vd; --pd; }
      ++t;
    }
    for(int q=0;q<n_;++q) sh->d[f_+q]=sh->vals[q];
  }
  __syncthreads();
  if(wantU){
    for(int w=tid; w<n_*n_; w+=NT){
      int t=w/n_, row=w-t*n_;
      int src=sh->perm[t];
      rl acc;
      if(src>=1000) acc = U2[row+(size_t)LDV*(src-1000)];
      else{
        const rl* urow = U2 + row;
        const rl* qcol = QU + (size_t)LDV*src;
        rl s=0.0; int i=0;
        for(; i+4<=K; i+=4){
          rl a0=urow[(size_t)LDV*i], a1=urow[(size_t)LDV*(i+1)], a2=urow[(size_t)LDV*(i+2)], a3=urow[(size_t)LDV*(i+3)];
          rl b0=qcol[i], b1=qcol[i+1], b2=qcol[i+2], b3=qcol[i+3];
          s+=a0*b0; s+=a1*b1; s+=a2*b2; s+=a3*b3;
        }
        for(; i<K; ++i) s += urow[(size_t)LDV*i]*qcol[i];
        acc=s;
      }
      SUB[(f_+row)+(size_t)LDV*(f_+t)] = acc;
    }
  }
  for(int w=tid; w<n_*m_; w+=NT){
    int t=w/m_, col=w-t*m_;
    int src=sh->perm[t];
    rl acc;
    if(src>=1000) acc = VT2[(src-1000)+(size_t)LDV*col];
    else{
      const rl* qcol = QV + (size_t)LDV*src;
      const rl* vcol = VT2 + (size_t)LDV*col;
      rl s=0.0; int i=0;
      for(; i+4<=K; i+=4){
        rl a0=qcol[i],a1=qcol[i+1],a2=qcol[i+2],a3=qcol[i+3];
        rl b0=vcol[i],b1=vcol[i+1],b2=vcol[i+2],b3=vcol[i+3];
        s+=a0*b0; s+=a1*b1; s+=a2*b2; s+=a3*b3;
      }
      for(; i<K; ++i) s += qcol[i]*vcol[i];
      acc=s;
    }
    SVTB[(f_+t)+(size_t)LDV*(f_+col)] = acc;
  }
  __syncthreads();
}

// ---- dlasd0: post-order over the D&C tree, leaves batched onto waves ----
__device__ void run_dc(int n, int wantU, LeafCtx* lct, Sh* sh, int tid){
  if(tid==0){
    int sf[12], sn2[12], sq[12], sv[12]; int sp=0, no=0;
    sf[0]=0; sn2[0]=n; sq[0]=0; sv[0]=0; sp=1;
    while(sp>0){
      --sp;
      int f=sf[sp], nn=sn2[sp], q=sq[sp], v=sv[sp];
      if(nn<=SML){ sh->opk[no]=0; sh->opf[no]=f; sh->opa[no]=nn; sh->opb[no]=0; sh->opq[no]=q; ++no; }
      else if(v==0){
        int nl=nn/2, nr=nn-nl-1;
        sf[sp]=f; sn2[sp]=nn; sq[sp]=q; sv[sp]=1; ++sp;
        sf[sp]=f+nl+1; sn2[sp]=nr; sq[sp]=q; sv[sp]=0; ++sp;
        sf[sp]=f; sn2[sp]=nl; sq[sp]=1; sv[sp]=0; ++sp;
      } else {
        int nl=nn/2, nr=nn-nl-1;
        sh->opk[no]=1; sh->opf[no]=f; sh->opa[no]=nl; sh->opb[no]=nr; sh->opq[no]=q; ++no;
      }
    }
    // Stable-partition: all leaves first, then merges. Safe because leaves are
    // mutually independent (disjoint d/e + SVTB/SUB ranges) and independent of
    // every non-ancestor merge; post-order already puts each leaf before its
    // ancestor merges, and we only move leaves EARLIER. Merge relative order
    // is preserved (respects tree dependencies).
    int tk[12], tf2[12], ta2[12], tb3[12], tq3[12]; int c=0;
    for(int i=0;i<no;++i) if(sh->opk[i]==0){ tk[c]=0; tf2[c]=sh->opf[i]; ta2[c]=sh->opa[i]; tb3[c]=sh->opb[i]; tq3[c]=sh->opq[i]; ++c; }
    for(int i=0;i<no;++i) if(sh->opk[i]==1){ tk[c]=1; tf2[c]=sh->opf[i]; ta2[c]=sh->opa[i]; tb3[c]=sh->opb[i]; tq3[c]=sh->opq[i]; ++c; }
    for(int i=0;i<no;++i){ sh->opk[i]=tk[i]; sh->opf[i]=tf2[i]; sh->opa[i]=ta2[i]; sh->opb[i]=tb3[i]; sh->opq[i]=tq3[i]; }
    sh->si[6]=no;
  }
  __syncthreads();
  int no=sh->si[6];
  int o=0;
  while(o<no){
    if(sh->opk[o]==0){
      int cnt=1;
      while(o+cnt<no && sh->opk[o+cnt]==0 && cnt<4) ++cnt;
      int wid = tid>>6;
      if(wid<cnt) leaf_exec(sh->opf[o+wid], sh->opa[o+wid], sh->opq[o+wid], wantU, &lct[wid], sh, tid&63);
      __syncthreads();
      o += cnt;
    } else {
      lasd1_merge(sh->opf[o], sh->opa[o], sh->opb[o], sh->opq[o], wantU, sh, tid);
      ++o;
    }
  }
}

__device__ void dbdsdc_U(int n, int wantU, LeafCtx* lct, Sh* sh, int tid){
  rl* SUB = g_ws + O_SUB; rl* SVTB = g_ws + O_SVTB;
  for(int w=tid; w<LDV*LDV; w+=NT){
    int c=w/LDV, r2=w-c*LDV; rl v=(r2==c)?1.0:0.0;
    SVTB[w]=v;
    if(wantU) SUB[w]=v;
  }
  __syncthreads();
  if(n <= SML){
    if((tid>>6)==0) leaf_exec(0, n, 0, wantU, &lct[0], sh, tid&63);
    __syncthreads();
  } else run_dc(n, wantU, lct, sh, tid);
}

__device__ void dbdsdc_L(int n, int wantU, LeafCtx* lct, Sh* sh, int tid){
  if(tid==0){
    for(int i=0;i<n-1;++i){
      rl cs,snv,rv;
      dlartg(sh->d[i], sh->e[i], &cs,&snv,&rv);
      sh->d[i]=rv; sh->e[i]=snv*sh->d[i+1]; sh->d[i+1]=cs*sh->d[i+1];
      sh->rc[i]=cs; sh->rs[i]=snv;
    }
  }
  __syncthreads();
  dbdsdc_U(n, wantU, lct, sh, tid);
  if(wantU){
    rl* SUB = g_ws + O_SUB;
    for(int c=tid;c<n;c+=NT){
      size_t ci=(size_t)LDV*c;
      for(int k=n-2;k>=0;--k){
        rl a=SUB[k+ci], b=SUB[k+1+ci];
        SUB[k+ci]  = sh->rc[k]*a - sh->rs[k]*b;
        SUB[k+1+ci]= sh->rs[k]*a + sh->rc[k]*b;
      }
    }
  }
  __syncthreads();
}

// ======================================================================
// Bidiagonalization, 2 barriers / iteration:
//  - redundant all-wave norm reduction (bit-identical across waves/lanes)
//  - beta/tau/scl computed redundantly in registers (no LDS broadcast)
//  - apply reads raw v and multiplies by scl on the fly (same rounding as
//    scale-then-apply)
//  - the actual scale-WRITE of the v vector is deferred and piggybacked into
//    the next phase on threads tid>=128 (read/write sets disjoint by phase)
// ======================================================================

__device__ __forceinline__ void gebd2_upper(rl* A, int ld, int m, int n, Sh* sh, int tid){
  const int lane = tid & 63;
  rl pend_scl = 0.0; int pend_ds = 0;   // pending row-(i-1) v-scale
  for(int i=0;i<n;++i){
    // ---- PHASE 1: column reflector i (+ app_left) + piggyback row-(i-1) scale ----
    rl ps=0.0;
    for(int r=i+1+lane;r<m;r+=64){ rl vv=A[r+(size_t)ld*i]; ps+=vv*vv; }
    for(int off=32;off>0;off>>=1) ps += __shfl_xor(ps,off,64);
    rl alpha=A[i+(size_t)ld*i];
    rl xn=sqrt(ps);
    rl beta,tau,scl; int ds;
    if(xn==0.0){ tau=0.0; beta=alpha; scl=0.0; ds=0; }
    else{ beta=-d_sign(dlapy2(alpha,xn),alpha); tau=(beta-alpha)/beta; scl=1.0/(alpha-beta); ds=1; }
    if(tid==0){ sh->d[i]=beta; sh->tq[i]=tau; }
    if(tau!=0.0)
      app_left_s(A, ld, i, m, i+1, n, A+(size_t)ld*i, scl, tau, tid);   // active tids < n-i-1 <= 70
    if(pend_ds && tid>=128){
      int c = i+1 + (tid-128);                                          // row i-1, cols i+1..n-1
      if(c < n) A[(i-1)+(size_t)ld*c] *= pend_scl;
    }
    __syncthreads();
    if(i<n-1){
      // ---- PHASE 2: row reflector i (+ app_right) + piggyback col-i scale ----
      rl ps2=0.0;
      for(int c=i+2+lane;c<n;c+=64){ rl vv=A[i+(size_t)ld*c]; ps2+=vv*vv; }
      for(int off=32;off>0;off>>=1) ps2 += __shfl_xor(ps2,off,64);
      rl alpha2=A[i+(size_t)ld*(i+1)];
      rl xn2=sqrt(ps2);
      rl beta2,tau2,scl2; int ds2;
      if(xn2==0.0){ tau2=0.0; beta2=alpha2; scl2=0.0; ds2=0; }
      else{ beta2=-d_sign(dlapy2(alpha2,xn2),alpha2); tau2=(beta2-alpha2)/beta2; scl2=1.0/(alpha2-beta2); ds2=1; }
      if(tid==0){ sh->e[i]=beta2; sh->tp[i]=tau2; }
      if(tau2!=0.0)
        app_right_s(A, ld, i+1, m, i+1, n, A+i, ld, scl2, tau2, tid);   // active tids < m-i-1 <= 127
      if(ds && tid>=128){
        int r = i+1 + (tid-128);                                        // col i, rows i+1..m-1
        if(r < m) A[r+(size_t)ld*i] *= scl;
      }
      pend_ds = ds2; pend_scl = scl2;
      __syncthreads();
    } else {
      if(tid==0) sh->tp[i]=0.0;
      __syncthreads();
      // epilogue: deferred scale of column n-1
      if(ds) for(int r=i+1+tid; r<m; r+=NT) A[r+(size_t)ld*(n-1)] *= scl;
      __syncthreads();
    }
  }
}

__device__ __forceinline__ void gebd2_lower(rl* A, int ld, int m, int n, Sh* sh, int tid){
  const int lane = tid & 63;
  rl pend_scl = 0.0; int pend_ds = 0;   // pending col-(i-1) v-scale
  int last_ds = 0; rl last_scl = 0.0;
  for(int i=0;i<m;++i){
    // ---- PHASE 1: row reflector i (+ app_right) + piggyback col-(i-1) scale ----
    rl ps=0.0;
    for(int c=i+1+lane;c<n;c+=64){ rl vv=A[i+(size_t)ld*c]; ps+=vv*vv; }
    for(int off=32;off>0;off>>=1) ps += __shfl_xor(ps,off,64);
    rl alpha=A[i+(size_t)ld*i];
    rl xn=sqrt(ps);
    rl beta,tau,scl; int ds;
    if(xn==0.0){ tau=0.0; beta=alpha; scl=0.0; ds=0; }
    else{ beta=-d_sign(dlapy2(alpha,xn),alpha); tau=(beta-alpha)/beta; scl=1.0/(alpha-beta); ds=1; }
    if(tid==0){ sh->d[i]=beta; sh->tp[i]=tau; }
    if(tau!=0.0)
      app_right_s(A, ld, i+1, m, i, n, A+i, ld, scl, tau, tid);         // active tids < m-i-1 <= 63
    if(pend_ds && tid>=128){
      int r = i+1 + (tid-128);                                          // col i-1, rows i+1..m-1
      if(r < m) A[r+(size_t)ld*(i-1)] *= pend_scl;
    }
    __syncthreads();
    if(i<m-1){
      // ---- PHASE 2: col reflector i (+ app_left) + piggyback row-i scale ----
      rl ps2=0.0;
      for(int r=i+2+lane;r<m;r+=64){ rl vv=A[r+(size_t)ld*i]; ps2+=vv*vv; }
      for(int off=32;off>0;off>>=1) ps2 += __shfl_xor(ps2,off,64);
      rl alpha2=A[(i+1)+(size_t)ld*i];
      rl xn2=sqrt(ps2);
      rl beta2,tau2,scl2; int ds2;
      if(xn2==0.0){ tau2=0.0; beta2=alpha2; scl2=0.0; ds2=0; }
      else{ beta2=-d_sign(dlapy2(alpha2,xn2),alpha2); tau2=(beta2-alpha2)/beta2; scl2=1.0/(alpha2-beta2); ds2=1; }
      if(tid==0){ sh->e[i]=beta2; sh->tq[i]=tau2; }
      if(tau2!=0.0)
        app_left_s(A, ld, i+1, m, i+1, n, A+(size_t)ld*i, scl2, tau2, tid); // active tids < n-i-1 <= 70
      if(ds && tid>=128){
        int c = i+1 + (tid-128);                                        // row i, cols i+1..n-1
        if(c < n) A[i+(size_t)ld*c] *= scl;
      }
      pend_ds = ds2; pend_scl = scl2;
      __syncthreads();
    } else {
      last_ds = ds; last_scl = scl;
      __syncthreads();
      // epilogue: deferred scale of row m-1
      if(last_ds) for(int c=i+1+tid; c<n; c+=NT) A[(m-1)+(size_t)ld*c] *= last_scl;
      __syncthreads();
    }
  }
}

__device__ __forceinline__ void gelq2(rl* A, int ld, int m, int n, Sh* sh, int tid){
  const int lane = tid & 63;
  rl pend_scl=0.0, pend_beta=0.0; int pend_ds=0;
  for(int i=0;i<m;++i){
    rl ps=0.0;
    for(int c=i+1+lane;c<n;c+=64){ rl vv=A[i+(size_t)ld*c]; ps+=vv*vv; }
    for(int off=32;off>0;off>>=1) ps += __shfl_xor(ps,off,64);
    rl alpha=A[i+(size_t)ld*i];
    rl xn=sqrt(ps);
    rl beta,tau,scl; int ds;
    if(xn==0.0){ tau=0.0; beta=alpha; scl=0.0; ds=0; }
    else{ beta=-d_sign(dlapy2(alpha,xn),alpha); tau=(beta-alpha)/beta; scl=1.0/(alpha-beta); ds=1; }
    if(tid==0) sh->rs[i]=tau;
    if(i<m-1 && tau!=0.0)
      app_right_s(A, ld, i+1, m, i, n, A+i, ld, scl, tau, tid);         // active tids < m-i-1 <= 31
    if(i>0 && tid>=128){                                                // piggyback row i-1 finalize
      if(pend_ds){ int c = i + (tid-128); if(c<n) A[(i-1)+(size_t)ld*c] *= pend_scl; }
      if(tid==128) A[(i-1)+(size_t)ld*(i-1)] = pend_beta;
    }
    pend_ds=ds; pend_scl=scl; pend_beta=beta;
    __syncthreads();
  }
  // epilogue: finalize row m-1
  if(tid>=128){
    if(pend_ds){ int c = m + (tid-128); if(c<n) A[(m-1)+(size_t)ld*c] *= pend_scl; }
    if(tid==128) A[(m-1)+(size_t)ld*(m-1)] = pend_beta;
  }
  __syncthreads();
}

// ---- per-shape drivers (MBL = LDS working matrix, pitch PB) ----
__device__ void svd_tall(int wantU, int wantVT, rl* MBL, LeafCtx* lct, Sh* sh, int tid){ // 128 x 71
  rl* MA=g_ws+O_MA; rl* MU=g_ws+O_MU; rl* MVT=g_ws+O_MVT;
  rl* SUB=g_ws+O_SUB; rl* SVTB=g_ws+O_SVTB;
  for(int w=tid;w<128*NSV;w+=NT){ int c=w>>7, r2=w&127; MBL[r2+(size_t)PB*c]=MA[r2+(size_t)LDA*c]; }
  __syncthreads();
  gebd2_upper(MBL, PB, 128, NSV, sh, tid);
  dbdsdc_U(NSV, wantU, lct, sh, tid);
  if(wantU){
    for(int w=tid;w<128*NSV;w+=NT){ int c=w>>7, r2=w&127; MU[r2+(size_t)LDA*c]=(r2<NSV)? SUB[r2+(size_t)LDV*c]:0.0; }
    __syncthreads();
    for(int i=NSV-1;i>=0;--i){
      if(sh->tq[i]!=0.0) app_left(MU, LDA, i, 128, 0, NSV, MBL+(size_t)PB*i, sh->tq[i], tid);
      __syncthreads();
    }
  }
  if(wantVT){
    for(int w=tid;w<LDV*NSV;w+=NT) MVT[w]=SVTB[w];
    __syncthreads();
    for(int i=NSV-2;i>=0;--i){
      if(sh->tp[i]!=0.0) app_right(MVT, LDV, 0, NSV, i+1, NSV, MBL+i, PB, sh->tp[i], tid);
      __syncthreads();
    }
  }
}
__device__ void svd_mid(rl* MBL, LeafCtx* lct, Sh* sh, int tid){ // 64 x 71, wantU=0, wantVT=1
  rl* MA=g_ws+O_MA; rl* MVT=g_ws+O_MVT;
  rl* SVTB=g_ws+O_SVTB;
  for(int w=tid;w<64*NSV;w+=NT){ int c=w>>6, r2=w&63; MBL[r2+(size_t)PB*c]=MA[r2+(size_t)LDA*c]; }
  __syncthreads();
  gebd2_lower(MBL, PB, 64, NSV, sh, tid);
  dbdsdc_L(64, 0, lct, sh, tid);
  for(int w=tid;w<64*NSV;w+=NT){ int c=w>>6, r2=w&63; MVT[r2+(size_t)LDV*c]=(c<64)? SVTB[r2+(size_t)LDV*c]:0.0; }
  __syncthreads();
  for(int i=63;i>=0;--i){
    if(sh->tp[i]!=0.0) app_right(MVT, LDV, 0, 64, i, NSV, MBL+i, PB, sh->tp[i], tid);
    __syncthreads();
  }
}
__device__ void svd_wide(int m, rl* MBL, LeafCtx* lct, Sh* sh, int tid){ // m x 71, m in {2,4,8,16,32}; wantU=0, wantVT=1
  rl* MA=g_ws+O_MA; rl* MQ=g_ws+O_MQ; rl* MVT=g_ws+O_MVT;
  rl* SVTB=g_ws+O_SVTB; rl* TB=g_ws+O_TB; rl* VT2=g_ws+O_VT2;
  for(int w=tid;w<m*NSV;w+=NT){ int c=w/m, r2=w-c*m; MBL[r2+(size_t)PB*c]=MA[r2+(size_t)LDA*c]; }
  __syncthreads();
  gelq2(MBL, PB, m, NSV, sh, tid);
  for(int w=tid;w<m*NSV;w+=NT){ int c=w/m, r2=w-c*m; MQ[r2+(size_t)LDA*c]=(r2==c)?1.0:0.0; }
  __syncthreads();
  for(int j=m-1;j>=0;--j){
    if(sh->rs[j]!=0.0) app_right(MQ, LDA, 0, m, j, NSV, MBL+j, PB, sh->rs[j], tid);
    __syncthreads();
  }
  for(int w=tid;w<m*m;w+=NT){ int c=w/m, r2=w-c*m; TB[r2+(size_t)LDV*c]=(r2>=c)? MBL[r2+(size_t)PB*c]:0.0; }
  __syncthreads();
  gebd2_upper(TB, LDV, m, m, sh, tid);
  dbdsdc_U(m, 0, lct, sh, tid);
  for(int w=tid;w<m*m;w+=NT){ int c=w/m, r2=w-c*m; VT2[r2+(size_t)LDV*c]=SVTB[r2+(size_t)LDV*c]; }
  __syncthreads();
  for(int i=m-2;i>=0;--i){
    if(sh->tp[i]!=0.0) app_right(VT2, LDV, 0, m, i+1, m, TB+i, LDV, sh->tp[i], tid);
    __syncthreads();
  }
  for(int w=tid;w<m*NSV;w+=NT){
    int c=w/m, r2=w-c*m;
    const rl* vrow = VT2 + r2;
    const rl* qcol = MQ + (size_t)LDA*c;
    rl s=0.0; int t=0;
    for(; t+4<=m; t+=4){
      rl a0=vrow[(size_t)LDV*t], a1=vrow[(size_t)LDV*(t+1)], a2=vrow[(size_t)LDV*(t+2)], a3=vrow[(size_t)LDV*(t+3)];
      rl b0=qcol[t], b1=qcol[t+1], b2=qcol[t+2], b3=qcol[t+3];
      s+=a0*b0; s+=a1*b1; s+=a2*b2; s+=a3*b3;
    }
    for(; t<m; ++t) s += vrow[(size_t)LDV*t]*qcol[t];
    MVT[r2+(size_t)LDV*c]=s;
  }
  __syncthreads();
}

// ---- main kernel ----
__global__ __launch_bounds__(NT)
void mps_kernel(const float* __restrict__ ch, const float* __restrict__ ci,
                const float* __restrict__ ictx, const int* __restrict__ tok)
{
  __shared__ Sh sh;
  __shared__ LeafCtx lct[4];
  extern __shared__ rl MBL[];   // PB*NSV doubles (73272 B dynamic LDS)
  int tid = threadIdx.x;
  rl* MA = g_ws + O_MA; rl* MU = g_ws + O_MU; rl* MVT = g_ws + O_MVT;
  int kprev = 0;
  for(int s=0;s<9;++s){
    if(tid==0){
      rl W00=ch[s*4+0], W01=ch[s*4+1], W10=ch[s*4+2], W11=ch[s*4+3];
      rl P00=1,P01=0,P10=0,P11=1;
      for(int mexp=0;mexp<=70;++mexp){
        int j=70-mexp;
        rl v0,v1;
        if(j==0){ v0=ictx[s*2+0]; v1=ictx[s*2+1]; }
        else{
          int b=(tok[j-1]>>(15-s))&1;
          v0=ci[s*4+b]; v1=ci[s*4+2+b];
        }
        g_ws[O_COLS + 0 + 2*j] = P00*v0+P01*v1;
        g_ws[O_COLS + 1 + 2*j] = P10*v0+P11*v1;
        rl n00=W00*P00+W01*P10, n01=W00*P01+W01*P11;
        rl n10=W10*P00+W11*P10, n11=W10*P01+W11*P11;
        P00=n00;P01=n01;P10=n10;P11=n11;
      }
    }
    __syncthreads();
    int m = (s==0)?2:2*kprev;
    for(int w=tid; w<m*NSV; w+=NT){
      int j=w/m, r2=w-j*m;
      int l=r2>>1, dd2=r2&1;
      rl cv = g_ws[O_COLS + dd2 + 2*j];
      MA[r2+(size_t)LDA*j] = (s==0)? cv : g_ws[O_CAR + l + 64*j]*cv;
    }
    __syncthreads();
    int wantU = (s==8)?1:0;
    if(m==128) svd_tall(wantU, wantU?0:1, MBL, lct, &sh, tid);
    else if(m==64) svd_mid(MBL, lct, &sh, tid);
    else svd_wide(m, MBL, lct, &sh, tid);
    int k = min(64, min(m, NSV));
    __syncthreads();
    if(s<8){
      for(int w=tid; w<k*NSV; w+=NT){
        int j=w/k, l=w-j*k;
        g_ws[O_CAR + l + 64*j] = sh.d[l]*MVT[l+(size_t)LDV*j];
      }
    }
    __syncthreads();
    if(s==8){
      if(tid==0){
        rl W00=ch[8*4+0], W01=ch[8*4+1], W10=ch[8*4+2], W11=ch[8*4+3];
        rl P00=1,P01=0,P10=0,P11=1;
        for(int it=0;it<30;++it){
          rl n00=W00*P00+W01*P10, n01=W00*P01+W01*P11;
          rl n10=W10*P00+W11*P10, n11=W10*P01+W11*P11;
          P00=n00;P01=n01;P10=n10;P11=n11;
        }
        sh.sc[0]=P00+P10; sh.sc[1]=P01+P11;
      }
      __syncthreads();
      for(int r2=tid; r2<64; r2+=NT){
        rl acc=0.0;
        for(int l=0;l<64;++l)
          acc += sh.sc[0]*MU[(2*l)+(size_t)LDA*r2] + sh.sc[1]*MU[(2*l+1)+(size_t)LDA*r2];
        g_ws[O_VEC + r2] = acc/188.0;
      }
    }
    kprev = k;
    __syncthreads();
  }
}

__global__ __launch_bounds__(NT)
void head_kernel(const float* __restrict__ hw, const float* __restrict__ hb,
                 float* __restrict__ out)
{
  __shared__ float v[64];
  int tid=threadIdx.x;
  if(tid<64) v[tid]=(float)g_ws[O_VEC + tid];
  __syncthreads();
  int i = blockIdx.x*NT + tid;
  if(i<VOCAB){
    const float4* row = (const float4*)(hw + (size_t)i*64);
    float acc=0.f;
    #pragma unroll
    for(int c4=0;c4<16;++c4){
      float4 r4=row[c4];
      acc += r4.x*v[4*c4] + r4.y*v[4*c4+1] + r4.z*v[4*c4+2] + r4.w*v[4*c4+3];
    }
    out[i]=acc+hb[i];
  }
}

extern "C" void kernel_launch(void* const* d_in, const int* in_sizes, int n_in,
                              void* d_out, int out_size, void* d_ws, size_t ws_size,
                              hipStream_t stream)
{
  const float* ch  = (const float*)d_in[0];
  const float* ci  = (const float*)d_in[1];
  const float* hw  = (const float*)d_in[2];
  const float* hb  = (const float*)d_in[3];
  const float* ict = (const float*)d_in[4];
  const int*   tk  = (const int*)d_in[5];
  (void)d_ws; (void)ws_size; (void)in_sizes; (void)n_in; (void)out_size;

  size_t dynls = (size_t)PB*NSV*sizeof(double);   // 73272 B
  hipLaunchKernelGGL(mps_kernel, dim3(1), dim3(NT), dynls, stream, ch, ci, ict, tk);
  hipLaunchKernelGGL(head_kernel, dim3((VOCAB+NT-1)/NT), dim3(NT), 0, stream,
                     hw, hb, (float*)d_out);
}

// Round 3
// 9243.597 us; speedup vs baseline: 1.2668x; 1.0262x over previous
//
#include <hip/hip_runtime.h>

typedef double rl;
#define NT 256
#define NSV 71
#define LDA 128
#define LDV 72
#define SML 25
#define VOCAB 128000
#define LP 27   // LDS leaf pitch
#define PB 129  // LDS pitch for bidiag working matrix (odd => minimal fp64 bank aliasing)

// fp32 LAPACK constants (reference is numpy sgesdd in float32)
#define EPS32 1.1920928955078125e-7
#define UNFL32 1.17549435e-38

// g_ws offsets (doubles)
#define O_CAR   0
#define O_COLS  4608
#define O_VEC   4800
#define O_MA    5120
#define O_MU    23552
#define O_MQ    32768
#define O_MVT   41984
#define O_SUB   47168
#define O_SVTB  52352
#define O_U2    57536
#define O_VT2   62720
#define O_QU    67904
#define O_QV    73088
#define O_TB    78272

__device__ double g_ws[84000];

// Per-wave leaf context: one D&C leaf (n<=25, np<=26) runs entirely inside a
// single wave; 4 leaves execute concurrently on the 4 SIMDs of the CU.
struct LeafCtx {
  rl LVT[26*LP], LU[26*LP];
  rl b1[26], b2[26], b3[26], b4[26];
  rl sc[6];
  int ia[26], ib[26], ic[26];
  int si[12];
};

struct Sh {
  rl d[72], e[72], tq[72], tp[72], rc[72], rs[72];
  rl dsig[72], zz[72], zh[72], sigm[72], vals[72];
  rl ta[72], tb[72];
  int srcU[72], srcVT[72], perm[72];
  int ia[72], ib[72], ic[72];
  int opk[12], opf[12], opa[12], opb[12], opq[12];
  rl sc[8];
  int si[16];
};

// Wave-local "barrier": a wave executes one instruction stream and its LDS ops
// complete in order, so ordering the compiler's memory ops + draining counters
// is sufficient for lane0 -> other-lane LDS communication.
__device__ __forceinline__ void wsync(){
  asm volatile("s_waitcnt vmcnt(0) lgkmcnt(0)" ::: "memory");
}

__device__ __forceinline__ rl d_sign(rl a, rl b){ return (b >= 0.0) ? fabs(a) : -fabs(a); }
__device__ __forceinline__ rl dlapy2(rl x, rl y){
  rl ax=fabs(x), ay=fabs(y);
  rl w = ax>ay?ax:ay, z = ax>ay?ay:ax;
  if(z==0.0) return w;
  rl t = z/w; return w*sqrt(1.0+t*t);
}
// LAPACK >= 3.10 dlartg convention (modern OpenBLAS)
__device__ void dlartg(rl f, rl g, rl* cs, rl* sn, rl* r){
  if(g==0.0){ *cs=1.0; *sn=0.0; *r=f; }
  else if(f==0.0){ *cs=0.0; *sn=d_sign(1.0,g); *r=fabs(g); }
  else{
    rl dd = sqrt(f*f+g*g);
    *cs = fabs(f)/dd;
    *r  = d_sign(dd, f);
    *sn = g/(*r);
  }
}

__device__ void dlas2(rl f, rl g, rl h, rl* ssmin, rl* ssmax){
  rl fa=fabs(f), ga=fabs(g), ha=fabs(h);
  rl fhmn=fmin(fa,ha), fhmx=fmax(fa,ha);
  if(fhmn==0.0){
    *ssmin=0.0;
    if(fhmx==0.0) *ssmax=ga;
    else { rl mx=fmax(fhmx,ga), mn=fmin(fhmx,ga); rl q=mn/mx; *ssmax=mx*sqrt(1.0+q*q); }
  } else {
    if(ga < fhmx){
      rl as=1.0+fhmn/fhmx, at=(fhmx-fhmn)/fhmx;
      rl au=(ga/fhmx); au=au*au;
      rl c=2.0/(sqrt(as*as+au)+sqrt(at*at+au));
      *ssmin=fhmn*c; *ssmax=fhmx/c;
    } else {
      rl au=fhmx/ga;
      if(au==0.0){ *ssmin=(fhmn*fhmx)/ga; *ssmax=ga; }
      else{
        rl as=1.0+fhmn/fhmx, at=(fhmx-fhmn)/fhmx;
        rl c=1.0/(sqrt(1.0+(as*au)*(as*au))+sqrt(1.0+(at*au)*(at*au)));
        *ssmin=(fhmn*c)*au; *ssmin=*ssmin+*ssmin;
        *ssmax=ga/(c+c);
      }
    }
  }
}

__device__ void dlasv2(rl f, rl g, rl h, rl* ssmin, rl* ssmax, rl* snr, rl* csr, rl* snl, rl* csl){
  rl ft=f, fa=fabs(f), ht=h, ha=fabs(h);
  int pmax=1;
  bool swp = (ha > fa);
  if(swp){ pmax=3; rl t=ft; ft=ht; ht=t; t=fa; fa=ha; ha=t; }
  rl gt=g, ga=fabs(g);
  rl clt=0, crt=0, slt=0, srt=0;
  if(ga==0.0){ *ssmin=ha; *ssmax=fa; clt=1.0; crt=1.0; slt=0.0; srt=0.0; }
  else{
    bool gasmal=true;
    if(ga > fa){
      pmax=2;
      if((fa/ga) < EPS32){
        gasmal=false;
        *ssmax=ga;
        if(ha>1.0) *ssmin=fa/(ga/ha); else *ssmin=(fa/ga)*ha;
        clt=1.0; slt=ht/gt; srt=1.0; crt=ft/gt;
      }
    }
    if(gasmal){
      rl dd=fa-ha;
      rl lv = (dd==fa) ? 1.0 : dd/fa;
      rl mq = gt/ft;
      rl tv = 2.0-lv;
      rl mm = mq*mq, tt = tv*tv;
      rl sv = sqrt(tt+mm);
      rl rv = (lv==0.0) ? fabs(mq) : sqrt(lv*lv+mm);
      rl a = 0.5*(sv+rv);
      *ssmin = ha/a; *ssmax = fa*a;
      rl t3;
      if(mm==0.0){
        if(lv==0.0) t3 = d_sign(2.0, ft)*d_sign(1.0, gt);
        else t3 = gt/d_sign(dd, ft) + mq/tv;
      } else {
        t3 = (mq/(sv+tv) + mq/(rv+lv))*(1.0+a);
      }
      rl l2 = sqrt(t3*t3+4.0);
      crt = 2.0/l2; srt = t3/l2;
      clt = (crt + srt*mq)/a;
      slt = (ht/ft)*srt/a;
    }
  }
  if(swp){ *csl=srt; *snl=crt; *csr=slt; *snr=clt; }
  else  { *csl=clt; *snl=slt; *csr=crt; *snr=srt; }
  rl tsign=1.0;
  if(pmax==1) tsign = d_sign(1.0,*csr)*d_sign(1.0,*csl)*d_sign(1.0,f);
  if(pmax==2) tsign = d_sign(1.0,*snr)*d_sign(1.0,*csl)*d_sign(1.0,g);
  if(pmax==3) tsign = d_sign(1.0,*snr)*d_sign(1.0,*snl)*d_sign(1.0,h);
  *ssmax = d_sign(*ssmax, tsign);
  *ssmin = d_sign(*ssmin, tsign*d_sign(1.0,f)*d_sign(1.0,h));
}

// Thread-local Householder apply to ONE row/column (elements at stride ld after
// the pivot; reflector v at stride vs). Grouped 16-wide loads + strictly
// sequential adds: bit-identical to the original scalar loop (load grouping
// does not change the addition order or any rounding).
__device__ __forceinline__ void row_apply(rl* row, size_t ld, const rl* v, size_t vs, int len, rl tau){
  rl s = row[0];
  int i=0;
  for(; i+16<=len; i+=16){
    rl a[16], b[16];
    #pragma unroll
    for(int u=0;u<16;++u){ a[u]=row[ld*(size_t)(1+i+u)]; b[u]=v[vs*(size_t)(i+u)]; }
    #pragma unroll
    for(int u=0;u<16;++u) s += a[u]*b[u];
  }
  for(; i<len; ++i) s += row[ld*(size_t)(1+i)]*v[vs*(size_t)i];
  rl w = s*tau;
  row[0] -= w;
  i=0;
  for(; i+16<=len; i+=16){
    rl b[16];
    #pragma unroll
    for(int u=0;u<16;++u) b[u]=v[vs*(size_t)(i+u)];
    #pragma unroll
    for(int u=0;u<16;++u) row[ld*(size_t)(1+i+u)] -= w*b[u];
  }
  for(; i<len; ++i) row[ld*(size_t)(1+i)] -= w*v[vs*(size_t)i];
}

// Apply-with-on-the-fly scale: v holds RAW (pre-scale) values; b = fl(raw*scl)
// is the exact same single rounding as the stored scaled value, so the result
// is bit-identical to scale-then-apply. ONE column/row per thread (counts < NT).
__device__ __forceinline__ void app_left_s(rl* A, int ld, int r0, int m, int c0, int n, const rl* vbase, rl scl, rl tau, int tid){
  const int len = m - r0 - 1;
  const rl* v = vbase + r0 + 1;
  int c = c0 + tid;
  if(c < n){
    rl* col = A + (size_t)ld*c + r0;
    rl s = col[0];
    int i=0;
    for(; i+4<=len; i+=4){
      rl a0=col[1+i],a1=col[2+i],a2=col[3+i],a3=col[4+i];
      rl b0=v[i]*scl,b1=v[i+1]*scl,b2=v[i+2]*scl,b3=v[i+3]*scl;
      s+=a0*b0; s+=a1*b1; s+=a2*b2; s+=a3*b3;
    }
    for(; i<len; ++i) s += col[1+i]*(v[i]*scl);
    rl w = s*tau;
    col[0] -= w;
    i=0;
    for(; i+4<=len; i+=4){
      rl b0=v[i]*scl,b1=v[i+1]*scl,b2=v[i+2]*scl,b3=v[i+3]*scl;
      col[1+i]-=w*b0; col[2+i]-=w*b1; col[3+i]-=w*b2; col[4+i]-=w*b3;
    }
    for(; i<len; ++i) col[1+i] -= w*(v[i]*scl);
  }
}
__device__ __forceinline__ void app_right_s(rl* A, int ld, int r0, int m, int c0, int n, const rl* vbase, int vstride, rl scl, rl tau, int tid){
  const int len = n - c0 - 1;
  const rl* v = vbase + (size_t)vstride*(c0+1);
  int r = r0 + tid;
  if(r < m){
    rl* row = A + r + (size_t)ld*c0;
    rl s = row[0];
    int i=0;
    for(; i+4<=len; i+=4){
      rl a0=row[(size_t)ld*(1+i)], a1=row[(size_t)ld*(2+i)], a2=row[(size_t)ld*(3+i)], a3=row[(size_t)ld*(4+i)];
      rl b0=v[(size_t)vstride*i]*scl, b1=v[(size_t)vstride*(i+1)]*scl, b2=v[(size_t)vstride*(i+2)]*scl, b3=v[(size_t)vstride*(i+3)]*scl;
      s+=a0*b0; s+=a1*b1; s+=a2*b2; s+=a3*b3;
    }
    for(; i<len; ++i) s += row[(size_t)ld*(1+i)]*(v[(size_t)vstride*i]*scl);
    rl w = s*tau;
    row[0] -= w;
    i=0;
    for(; i+4<=len; i+=4){
      rl b0=v[(size_t)vstride*i]*scl, b1=v[(size_t)vstride*(i+1)]*scl, b2=v[(size_t)vstride*(i+2)]*scl, b3=v[(size_t)vstride*(i+3)]*scl;
      row[(size_t)ld*(1+i)]-=w*b0; row[(size_t)ld*(2+i)]-=w*b1; row[(size_t)ld*(3+i)]-=w*b2; row[(size_t)ld*(4+i)]-=w*b3;
    }
    for(; i<len; ++i) row[(size_t)ld*(1+i)] -= w*(v[(size_t)vstride*i]*scl);
  }
}

// ---- wave-scoped dbdsqr on a private LDS leaf block ----
// Identical arithmetic to the block version; tid->lane, __syncthreads->wsync.
// Rotation applies use a register carry: the loop-carried element equals the
// value written in the previous step, so it is kept in a register instead of
// round-tripping through LDS (same mul/add expressions on the same values).
__device__ void bdsqr_wave(int n, rl* d, rl* e, int ncvt, int nru, LeafCtx* lc, int lane){
  if(n>1){
    rl eps=EPS32, unfl=UNFL32;
    rl tolmul=fmax(10.0,fmin(100.0,pow(eps,-0.125)));
    rl tol=tolmul*eps;
    rl thresh=0.0;
    int mm=n-1, oldll=-2, oldm=-2, idir=0, iter=0, maxit=6*n*n;
    if(lane==0){
      rl sminoa=fabs(d[0]);
      if(sminoa!=0.0){
        rl mu=sminoa;
        for(int i=1;i<n;++i){ mu=fabs(d[i])*(mu/(mu+fabs(e[i-1]))); sminoa=fmin(sminoa,mu); if(sminoa==0.0)break; }
      }
      sminoa=sminoa/sqrt((rl)n);
      thresh=fmax(tol*sminoa,(rl)(6*n*n)*unfl);
    }
    while(true){
      if(lane==0){
        int act=0, p_lo=0, p_cnt=0, p_fwd=1, p_mm=0;
        while(mm>0){
          if(iter>maxit) break;
          rl smax=fabs(d[mm]), smin=smax;
          int ll=-1;
          for(int lll=mm-1;lll>=0;--lll){
            rl abss=fabs(d[lll]), abse=fabs(e[lll]);
            if(abse<=thresh){ ll=lll; break; }
            smin=fmin(smin,abss);
            smax=fmax(smax,fmax(abss,abse));
          }
          if(ll==mm-1){ e[ll]=0.0; mm=mm-1; continue; }
          if(ll>=0) e[ll]=0.0;
          int lo=ll+1;
          if(mm==lo+1){
            rl sigmn,sigmx,sinr,cosr,sinl,cosl;
            dlasv2(d[lo],e[lo],d[mm],&sigmn,&sigmx,&sinr,&cosr,&sinl,&cosl);
            d[lo]=sigmx; d[mm]=sigmn; e[lo]=0.0;
            lc->sc[0]=cosr; lc->sc[1]=sinr; lc->sc[2]=cosl; lc->sc[3]=sinl;
            act=2; p_lo=lo; p_mm=mm;
            mm-=2;
            break;
          }
          if(lo>oldm || mm<oldll) idir=(fabs(d[lo])>=fabs(d[mm]))?1:2;
          rl sminl=0.0; int conv=0;
          if(idir==1){
            if(fabs(e[mm-1])<=tol*fabs(d[mm])){ e[mm-1]=0.0; conv=1; }
            if(!conv){
              rl mu=fabs(d[lo]); sminl=mu;
              for(int lll=lo;lll<mm;++lll){
                if(fabs(e[lll])<=tol*mu){ e[lll]=0.0; conv=1; break; }
                mu=fabs(d[lll+1])*(mu/(mu+fabs(e[lll])));
                sminl=fmin(sminl,mu);
              }
            }
          } else {
            if(fabs(e[lo])<=tol*fabs(d[lo])){ e[lo]=0.0; conv=1; }
            if(!conv){
              rl mu=fabs(d[mm]); sminl=mu;
              for(int lll=mm-1;lll>=lo;--lll){
                if(fabs(e[lll])<=tol*mu){ e[lll]=0.0; conv=1; break; }
                mu=fabs(d[lll])*(mu/(mu+fabs(e[lll])));
                sminl=fmin(sminl,mu);
              }
            }
          }
          if(conv) continue;
          oldll=lo; oldm=mm;
          rl shift=0.0, rr_;
          if(!((rl)n*tol*(sminl/smax) <= fmax(eps, 0.01*tol))){
            rl sll;
            if(idir==1){ sll=fabs(d[lo]); dlas2(d[mm-1],e[mm-1],d[mm],&shift,&rr_); }
            else { sll=fabs(d[mm]); dlas2(d[lo],e[lo],d[lo+1],&shift,&rr_); }
            if(sll>0.0){ rl q=shift/sll; if(q*q<eps) shift=0.0; }
          }
          iter += mm-lo;
          int cnt=mm-lo;
          if(shift==0.0){
            if(idir==1){
              rl cs=1.0, oldcs=1.0, sn=0.0, oldsn=0.0, r;
              for(int i=lo;i<mm;++i){
                dlartg(d[i]*cs,e[i],&cs,&sn,&r);
                if(i>lo) e[i-1]=oldsn*r;
                dlartg(oldcs*r, d[i+1]*sn, &oldcs,&oldsn,&d[i]);
                lc->b1[i-lo]=cs; lc->b2[i-lo]=sn; lc->b3[i-lo]=oldcs; lc->b4[i-lo]=oldsn;
              }
              rl h=d[mm]*cs; d[mm]=h*oldcs; e[mm-1]=h*oldsn;
              p_fwd=1;
              if(fabs(e[mm-1])<=thresh) e[mm-1]=0.0;
            } else {
              rl cs=1.0, oldcs=1.0, sn=0.0, oldsn=0.0, r;
              for(int i=mm;i>lo;--i){
                dlartg(d[i]*cs,e[i-1],&cs,&sn,&r);
                if(i<mm) e[i]=oldsn*r;
                dlartg(oldcs*r,d[i-1]*sn,&oldcs,&oldsn,&d[i]);
                int j=i-lo-1;
                lc->b1[j]=oldcs; lc->b2[j]=-oldsn; lc->b3[j]=cs; lc->b4[j]=-sn;
              }
              rl h=d[lo]*cs; d[lo]=h*oldcs; e[lo]=h*oldsn;
              p_fwd=0;
              if(fabs(e[lo])<=thresh) e[lo]=0.0;
            }
          } else {
            if(idir==1){
              rl f2=(fabs(d[lo])-shift)*(d_sign(1.0,d[lo])+shift/d[lo]);
              rl g2=e[lo], r, cosr,sinr,cosl,sinl;
              for(int i=lo;i<mm;++i){
                dlartg(f2,g2,&cosr,&sinr,&r);
                if(i>lo) e[i-1]=r;
                f2=cosr*d[i]+sinr*e[i];
                e[i]=cosr*e[i]-sinr*d[i];
                g2=sinr*d[i+1];
                d[i+1]=cosr*d[i+1];
                dlartg(f2,g2,&cosl,&sinl,&r);
                d[i]=r;
                f2=cosl*e[i]+sinl*d[i+1];
                d[i+1]=cosl*d[i+1]-sinl*e[i];
                if(i<mm-1){ g2=sinl*e[i+1]; e[i+1]=cosl*e[i+1]; }
                lc->b1[i-lo]=cosr; lc->b2[i-lo]=sinr; lc->b3[i-lo]=cosl; lc->b4[i-lo]=sinl;
              }
              e[mm-1]=f2;
              p_fwd=1;
              if(fabs(e[mm-1])<=thresh) e[mm-1]=0.0;
            } else {
              rl f2=(fabs(d[mm])-shift)*(d_sign(1.0,d[mm])+shift/d[mm]);
              rl g2=e[mm-1], r, cosr,sinr,cosl,sinl;
              for(int i=mm;i>lo;--i){
                dlartg(f2,g2,&cosr,&sinr,&r);
                if(i<mm) e[i]=r;
                f2=cosr*d[i]+sinr*e[i-1];
                e[i-1]=cosr*e[i-1]-sinr*d[i];
                g2=sinr*d[i-1];
                d[i-1]=cosr*d[i-1];
                dlartg(f2,g2,&cosl,&sinl,&r);
                d[i]=r;
                f2=cosl*e[i-1]+sinl*d[i-1];
                d[i-1]=cosl*d[i-1]-sinl*e[i-1];
                if(i>lo+1){ g2=sinl*e[i-2]; e[i-2]=cosl*e[i-2]; }
                int j=i-lo-1;
                lc->b1[j]=cosl; lc->b2[j]=-sinl; lc->b3[j]=cosr; lc->b4[j]=-sinr;
              }
              e[lo]=f2;
              p_fwd=0;
              if(fabs(e[lo])<=thresh) e[lo]=0.0;
            }
          }
          act=1; p_lo=lo; p_cnt=cnt;
          break;
        }
        lc->si[7]=act; lc->si[8]=p_lo; lc->si[9]=p_cnt; lc->si[10]=p_fwd; lc->si[11]=p_mm;
      }
      wsync();
      int act=lc->si[7];
      if(act==0) break;
      if(act==1){
        int lo=lc->si[8], cnt=lc->si[9], fwd=lc->si[10];
        if(lane<ncvt){
          int k=lane;
          if(fwd){
            // carry: row lo+j's entry value came from previous step's hi-write
            rl cur = lc->LVT[lo*LP+k];
            for(int j=0;j<cnt;++j){
              rl c=lc->b1[j], s=lc->b2[j];
              rl t = lc->LVT[(lo+j+1)*LP+k];          // untouched row: independent load
              lc->LVT[(lo+j)*LP+k] = s*t + c*cur;     // final value for row lo+j
              cur = c*t - s*cur;                       // value of row lo+j+1 (next carry)
            }
            lc->LVT[(lo+cnt)*LP+k] = cur;
          } else {
            rl tcar = lc->LVT[(lo+cnt)*LP+k];
            for(int j=cnt-1;j>=0;--j){
              rl c=lc->b1[j], s=lc->b2[j];
              rl low = lc->LVT[(lo+j)*LP+k];          // untouched row: independent load
              lc->LVT[(lo+j+1)*LP+k] = c*tcar - s*low; // final value for row lo+j+1
              tcar = s*tcar + c*low;                   // value of row lo+j (next carry)
            }
            lc->LVT[lo*LP+k] = tcar;
          }
        } else if(lane<ncvt+nru){
          int r2=lane-ncvt;
          if(fwd){
            rl cur = lc->LU[r2*LP+lo];
            for(int j=0;j<cnt;++j){
              rl c=lc->b3[j], s=lc->b4[j];
              rl t = lc->LU[r2*LP+(lo+j+1)];
              lc->LU[r2*LP+(lo+j)] = s*t + c*cur;
              cur = c*t - s*cur;
            }
            lc->LU[r2*LP+(lo+cnt)] = cur;
          } else {
            rl tcar = lc->LU[r2*LP+(lo+cnt)];
            for(int j=cnt-1;j>=0;--j){
              rl c=lc->b3[j], s=lc->b4[j];
              rl low = lc->LU[r2*LP+(lo+j)];
              lc->LU[r2*LP+(lo+j+1)] = c*tcar - s*low;
              tcar = s*tcar + c*low;
            }
            lc->LU[r2*LP+lo] = tcar;
          }
        }
      } else {
        int lo=lc->si[8], m2=lc->si[11];
        rl cosr=lc->sc[0], sinr=lc->sc[1], cosl=lc->sc[2], sinl=lc->sc[3];
        if(lane<ncvt){
          rl x=lc->LVT[lo*LP+lane], y=lc->LVT[m2*LP+lane];
          lc->LVT[lo*LP+lane]=cosr*x+sinr*y; lc->LVT[m2*LP+lane]=cosr*y-sinr*x;
        } else if(lane<ncvt+nru){
          int r2=lane-ncvt;
          rl x=lc->LU[r2*LP+lo], y=lc->LU[r2*LP+m2];
          lc->LU[r2*LP+lo]=cosl*x+sinl*y; lc->LU[r2*LP+m2]=cosl*y-sinl*x;
        }
      }
      wsync();
    }
  }
  if(lane==0){
    for(int i=0;i<n;++i){ lc->ic[i]=(d[i]<0.0)?1:0; if(d[i]<0.0) d[i]=-d[i]; }
    int nsw=0;
    for(int i=0;i<n-1;++i){
      int isub=0; rl smin=d[0];
      for(int j=1;j<n-i;++j){ if(d[j]<=smin){ isub=j; smin=d[j]; } }
      int tgt=n-1-i;
      if(isub!=tgt){
        d[isub]=d[tgt]; d[tgt]=smin;
        lc->ia[nsw]=isub; lc->ib[nsw]=tgt; ++nsw;
      }
    }
    lc->si[7]=nsw;
  }
  wsync();
  int nsw=lc->si[7];
  if(lane<ncvt){
    for(int i=0;i<n;++i) if(lc->ic[i]) lc->LVT[i*LP+lane]=-lc->LVT[i*LP+lane];
    for(int w2=0;w2<nsw;++w2){
      int a=lc->ia[w2], b=lc->ib[w2];
      rl t=lc->LVT[a*LP+lane]; lc->LVT[a*LP+lane]=lc->LVT[b*LP+lane]; lc->LVT[b*LP+lane]=t;
    }
  } else if(lane<ncvt+nru){
    int r2=lane-ncvt;
    for(int w2=0;w2<nsw;++w2){
      int a=lc->ia[w2], b=lc->ib[w2];
      rl t=lc->LU[r2*LP+a]; lc->LU[r2*LP+a]=lc->LU[r2*LP+b]; lc->LU[r2*LP+b]=t;
    }
  }
  wsync();
}

// ---- leaf: dlasdq, entirely within one wave (no block barriers inside) ----
__device__ void leaf_exec(int f, int n, int sqre, int wantU, LeafCtx* lc, Sh* sh, int lane){
  rl* SVTB = g_ws + O_SVTB; rl* SUB = g_ws + O_SUB;
  int np = n + sqre;
  for(int w=lane; w<np*np; w+=64){ int r2=w/np, c=w-r2*np; lc->LVT[r2*LP+c]=SVTB[(f+r2)+(size_t)LDV*(f+c)]; }
  if(wantU) for(int w=lane; w<n*n; w+=64){ int r2=w/n, c=w-r2*n; lc->LU[r2*LP+c]=SUB[(f+r2)+(size_t)LDV*(f+c)]; }
  wsync();
  if(sqre==1){
    if(lane==0){
      rl cs,snv,rv; rl* dd=sh->d+f; rl* ee=sh->e+f;
      for(int i=0;i<n;++i){
        dlartg(dd[i],ee[i],&cs,&snv,&rv);
        dd[i]=rv;
        if(i<n-1){ ee[i]=snv*dd[i+1]; dd[i+1]=cs*dd[i+1]; }
        else ee[i]=0.0;
        lc->b1[i]=cs; lc->b2[i]=snv;
      }
    }
    wsync();
    if(lane<np){
      rl cur = lc->LVT[0*LP+lane];
      for(int j=0;j<n;++j){
        rl cj=lc->b1[j], sj=lc->b2[j];
        rl t=lc->LVT[(j+1)*LP+lane];
        lc->LVT[j*LP+lane] = sj*t + cj*cur;
        cur = cj*t - sj*cur;
      }
      lc->LVT[n*LP+lane] = cur;
    }
    wsync();
    if(lane==0){
      rl cs,snv,rv; rl* dd=sh->d+f; rl* ee=sh->e+f;
      for(int i=0;i<n-1;++i){
        dlartg(dd[i],ee[i],&cs,&snv,&rv);
        dd[i]=rv; ee[i]=snv*dd[i+1]; dd[i+1]=cs*dd[i+1];
        lc->b1[i]=cs; lc->b2[i]=snv;
      }
    }
    wsync();
    if(wantU && lane<n){
      rl cur = lc->LU[lane*LP+0];
      for(int j=0;j<n-1;++j){
        rl cj=lc->b1[j], sj=lc->b2[j];
        rl t=lc->LU[lane*LP+(j+1)];
        lc->LU[lane*LP+j] = sj*t + cj*cur;
        cur = cj*t - sj*cur;
      }
      lc->LU[lane*LP+(n-1)] = cur;
    }
    wsync();
  }
  bdsqr_wave(n, sh->d+f, sh->e+f, np, wantU? n:0, lc, lane);
  for(int w=lane; w<np*np; w+=64){ int r2=w/np, c=w-r2*np; SVTB[(f+r2)+(size_t)LDV*(f+c)]=lc->LVT[r2*LP+c]; }
  if(wantU) for(int w=lane; w<n*n; w+=64){ int r2=w/n, c=w-r2*n; SUB[(f+r2)+(size_t)LDV*(f+c)]=lc->LU[r2*LP+c]; }
}

// ---- D&C merge (dlasd1/2/3) ---- (block-wide, unchanged)
__device__ void lasd1_merge(int f, int nl, int nr, int sqre, int wantU, Sh* sh, int tid){
  rl* SUB = g_ws + O_SUB; rl* SVTB = g_ws + O_SVTB;
  rl* U2 = g_ws + O_U2; rl* VT2 = g_ws + O_VT2; rl* QU = g_ws + O_QU; rl* QV = g_ws + O_QV;
  int n = nl+nr+1, m = n+sqre;
  if(tid==0){
    rl alpha = sh->d[f+nl], beta = sh->e[f+nl];
    sh->vals[0]=0.0;
    sh->zz[0] = alpha*SVTB[(f+nl)+(size_t)LDV*(f+nl)];
    sh->srcU[0]=-1; sh->srcVT[0]=f+nl;
    for(int i=0;i<nl;++i){
      sh->vals[1+i]=sh->d[f+i];
      sh->zz[1+i]=alpha*SVTB[(f+i)+(size_t)LDV*(f+nl)];
      sh->srcU[1+i]=f+i; sh->srcVT[1+i]=f+i;
    }
    for(int j=0;j<nr;++j){
      sh->vals[1+nl+j]=sh->d[f+nl+1+j];
      sh->zz[1+nl+j]=beta*SVTB[(f+nl+1+j)+(size_t)LDV*(f+nl+1)];
      sh->srcU[1+nl+j]=f+nl+1+j; sh->srcVT[1+nl+j]=f+nl+1+j;
    }
    sh->sc[0]=alpha; sh->sc[1]=beta;
    if(sqre==1){
      rl zM = beta*SVTB[(f+n)+(size_t)LDV*(f+nl+1)];
      rl c,s,r2;
      dlartg(sh->zz[0], zM, &c, &s, &r2);
      sh->zz[0]=r2; sh->sc[2]=c; sh->sc[3]=s;
    }
  }
  __syncthreads();
  if(sqre==1){
    rl c=sh->sc[2], s=sh->sc[3];
    int ra=f+nl, rb=f+n;
    for(int k=tid;k<m;k+=NT){
      size_t ci=(size_t)LDV*(f+k);
      rl a=SVTB[ra+ci], b=SVTB[rb+ci];
      SVTB[ra+ci]=c*a+s*b; SVTB[rb+ci]=-s*a+c*b;
    }
  }
  __syncthreads();
  if(tid==0){
    rl maxd=0.0; for(int i=0;i<n;++i) maxd=fmax(maxd,fabs(sh->vals[i]));
    rl tol = 8.0*EPS32*fmax(maxd, fmax(fabs(sh->sc[0]), fabs(sh->sc[1])));
    int nds=0;
    sh->ic[nds++]=0;
    for(int i=1;i<n;++i) if(fabs(sh->zz[i]) > tol) sh->ic[nds++]=i;
    for(int a=1;a<nds;++a){
      int key=sh->ic[a]; rl kv=sh->vals[key]; int b=a-1;
      while(b>=1 && sh->vals[sh->ic[b]] > kv){ sh->ic[b+1]=sh->ic[b]; --b; }
      sh->ic[b+1]=key;
    }
    int K=nds, pos=nds;
    for(int i=1;i<n;++i) if(fabs(sh->zz[i]) <= tol) sh->ic[pos++]=i;
    for(int a=K+1;a<n;++a){
      int key=sh->ic[a]; rl kv=sh->vals[key]; int b=a-1;
      while(b>=K && sh->vals[sh->ic[b]] > kv){ sh->ic[b+1]=sh->ic[b]; --b; }
      sh->ic[b+1]=key;
    }
    for(int t=0;t<n;++t){ sh->ta[t]=sh->vals[t]; sh->tb[t]=sh->zz[t]; sh->ia[t]=sh->srcU[t]; sh->ib[t]=sh->srcVT[t]; }
    for(int t=0;t<n;++t){
      int p=sh->ic[t];
      sh->dsig[t]=sh->ta[p]; sh->zz[t]=sh->tb[p]; sh->srcU[t]=sh->ia[p]; sh->srcVT[t]=sh->ib[p];
    }
    rl rho=0.0; for(int t=0;t<K;++t){ rl zv=sh->zz[t]; rho += zv*zv; }
    sh->sc[4]=rho;
    sh->si[0]=K; sh->si[1]=n; sh->si[2]=m; sh->si[3]=f; sh->si[4]=nl;
  }
  __syncthreads();
  int K=sh->si[0], n_=sh->si[1], m_=sh->si[2], f_=sh->si[3], nl_=sh->si[4];
  if(wantU){
    for(int w=tid; w<n_*n_; w+=NT){
      int col=w/n_, row=w-col*n_;
      int su=sh->srcU[col];
      rl v;
      if(su<0) v = (row==nl_) ? 1.0 : 0.0;
      else v = SUB[(f_+row)+(size_t)LDV*su];
      U2[row+(size_t)LDV*col]=v;
    }
  }
  for(int w=tid; w<n_*m_; w+=NT){
    int row=w/m_, col=w-row*m_;
    VT2[row+(size_t)LDV*col] = SVTB[sh->srcVT[row]+(size_t)LDV*(f_+col)];
  }
  __syncthreads();
  rl rho=sh->sc[4];
  for(int j=tid;j<K;j+=NT){
    rl lo=sh->dsig[j];
    rl hi=(j<K-1)? sh->dsig[j+1] : sqrt(sh->dsig[K-1]*sh->dsig[K-1]+rho);
    for(int it=0; it<130; ++it){
      rl mid=0.5*(lo+hi);
      if(mid<=lo || mid>=hi) break;
      rl g=1.0;
      for(int i2=0;i2<K;++i2){
        rl zi=sh->zz[i2];
        g += zi*zi/((sh->dsig[i2]-mid)*(sh->dsig[i2]+mid));
      }
      if(g<0.0) lo=mid; else hi=mid;
    }
    sh->sigm[j]=0.5*(lo+hi);
  }
  __syncthreads();
  for(int i2=tid;i2<K;i2+=NT){
    rl di=sh->dsig[i2];
    rl p=(di - sh->sigm[K-1])*(di + sh->sigm[K-1]);
    for(int j=0;j<i2;++j)
      p *= (di - sh->sigm[j])*(di + sh->sigm[j])/((di - sh->dsig[j])*(di + sh->dsig[j]));
    for(int j=i2;j<K-1;++j)
      p *= (di - sh->sigm[j])*(di + sh->sigm[j])/((di - sh->dsig[j+1])*(di + sh->dsig[j+1]));
    sh->zh[i2] = d_sign(sqrt(fabs(p)), sh->zz[i2]);
  }
  __syncthreads();
  for(int j=tid;j<K;j+=NT){
    rl sj=sh->sigm[j];
    rl nu=0.0, nv=0.0;
    for(int i2=0;i2<K;++i2){
      rl di=sh->dsig[i2];
      rl vv=sh->zh[i2]/((di-sj)*(di+sj));
      QV[i2+(size_t)LDV*j]=vv; nv+=vv*vv;
      if(wantU){
        rl uu=(i2==0)? -1.0 : di*vv;
        QU[i2+(size_t)LDV*j]=uu; nu+=uu*uu;
      }
    }
    nv=1.0/sqrt(nv);
    for(int i2=0;i2<K;++i2) QV[i2+(size_t)LDV*j]*=nv;
    if(wantU){
      nu=1.0/sqrt(nu);
      for(int i2=0;i2<K;++i2) QU[i2+(size_t)LDV*j]*=nu;
    }
  }
  __syncthreads();
  if(tid==0){
    int nd2=n_-K;
    for(int t=0;t<nd2;++t) sh->ia[t]=K+t;
    int ps=K-1, pd=nd2-1;
    int t=0;
    while(t<n_){
      rl vs = (ps>=0)? sh->sigm[ps] : -1.0;
      rl vd = (pd>=0)? sh->dsig[sh->ia[pd]] : -1.0;
      if(vs >= vd){ sh->perm[t]=ps; sh->vals[t]=vs; --ps; }
      else { sh->perm[t]=1000+sh->ia[pd]; sh->vals[t]=vd; --pd; }
      ++t;
    }
    for(int q=0;q<n_;++q) sh->d[f_+q]=sh->vals[q];
  }
  __syncthreads();
  if(wantU){
    for(int w=tid; w<n_*n_; w+=NT){
      int t=w/n_, row=w-t*n_;
      int src=sh->perm[t];
      rl acc;
      if(src>=1000) acc = U2[row+(size_t)LDV*(src-1000)];
      else{
        const rl* urow = U2 + row;
        const rl* qcol = QU + (size_t)LDV*src;
        rl s=0.0; int i=0;
        for(; i+4<=K; i+=4){
          rl a0=urow[(size_t)LDV*i], a1=urow[(size_t)LDV*(i+1)], a2=urow[(size_t)LDV*(i+2)], a3=urow[(size_t)LDV*(i+3)];
          rl b0=qcol[i], b1=qcol[i+1], b2=qcol[i+2], b3=qcol[i+3];
          s+=a0*b0; s+=a1*b1; s+=a2*b2; s+=a3*b3;
        }
        for(; i<K; ++i) s += urow[(size_t)LDV*i]*qcol[i];
        acc=s;
      }
      SUB[(f_+row)+(size_t)LDV*(f_+t)] = acc;
    }
  }
  for(int w=tid; w<n_*m_; w+=NT){
    int t=w/m_, col=w-t*m_;
    int src=sh->perm[t];
    rl acc;
    if(src>=1000) acc = VT2[(src-1000)+(size_t)LDV*col];
    else{
      const rl* qcol = QV + (size_t)LDV*src;
      const rl* vcol = VT2 + (size_t)LDV*col;
      rl s=0.0; int i=0;
      for(; i+4<=K; i+=4){
        rl a0=qcol[i],a1=qcol[i+1],a2=qcol[i+2],a3=qcol[i+3];
        rl b0=vcol[i],b1=vcol[i+1],b2=vcol[i+2],b3=vcol[i+3];
        s+=a0*b0; s+=a1*b1; s+=a2*b2; s+=a3*b3;
      }
      for(; i<K; ++i) s += qcol[i]*vcol[i];
      acc=s;
    }
    SVTB[(f_+t)+(size_t)LDV*(f_+col)] = acc;
  }
  __syncthreads();
}

// ---- dlasd0: post-order over the D&C tree, leaves batched onto waves ----
__device__ void run_dc(int n, int wantU, LeafCtx* lct, Sh* sh, int tid){
  if(tid==0){
    int sf[12], sn2[12], sq[12], sv[12]; int sp=0, no=0;
    sf[0]=0; sn2[0]=n; sq[0]=0; sv[0]=0; sp=1;
    while(sp>0){
      --sp;
      int f=sf[sp], nn=sn2[sp], q=sq[sp], v=sv[sp];
      if(nn<=SML){ sh->opk[no]=0; sh->opf[no]=f; sh->opa[no]=nn; sh->opb[no]=0; sh->opq[no]=q; ++no; }
      else if(v==0){
        int nl=nn/2, nr=nn-nl-1;
        sf[sp]=f; sn2[sp]=nn; sq[sp]=q; sv[sp]=1; ++sp;
        sf[sp]=f+nl+1; sn2[sp]=nr; sq[sp]=q; sv[sp]=0; ++sp;
        sf[sp]=f; sn2[sp]=nl; sq[sp]=1; sv[sp]=0; ++sp;
      } else {
        int nl=nn/2, nr=nn-nl-1;
        sh->opk[no]=1; sh->opf[no]=f; sh->opa[no]=nl; sh->opb[no]=nr; sh->opq[no]=q; ++no;
      }
    }
    // Stable-partition: all leaves first, then merges (leaves are mutually
    // independent and independent of non-ancestor merges; merge order kept).
    int tk[12], tf2[12], ta2[12], tb3[12], tq3[12]; int c=0;
    for(int i=0;i<no;++i) if(sh->opk[i]==0){ tk[c]=0; tf2[c]=sh->opf[i]; ta2[c]=sh->opa[i]; tb3[c]=sh->opb[i]; tq3[c]=sh->opq[i]; ++c; }
    for(int i=0;i<no;++i) if(sh->opk[i]==1){ tk[c]=1; tf2[c]=sh->opf[i]; ta2[c]=sh->opa[i]; tb3[c]=sh->opb[i]; tq3[c]=sh->opq[i]; ++c; }
    for(int i=0;i<no;++i){ sh->opk[i]=tk[i]; sh->opf[i]=tf2[i]; sh->opa[i]=ta2[i]; sh->opb[i]=tb3[i]; sh->opq[i]=tq3[i]; }
    sh->si[6]=no;
  }
  __syncthreads();
  int no=sh->si[6];
  int o=0;
  while(o<no){
    if(sh->opk[o]==0){
      int cnt=1;
      while(o+cnt<no && sh->opk[o+cnt]==0 && cnt<4) ++cnt;
      int wid = tid>>6;
      if(wid<cnt) leaf_exec(sh->opf[o+wid], sh->opa[o+wid], sh->opq[o+wid], wantU, &lct[wid], sh, tid&63);
      __syncthreads();
      o += cnt;
    } else {
      lasd1_merge(sh->opf[o], sh->opa[o], sh->opb[o], sh->opq[o], wantU, sh, tid);
      ++o;
    }
  }
}

__device__ void dbdsdc_U(int n, int wantU, LeafCtx* lct, Sh* sh, int tid){
  rl* SUB = g_ws + O_SUB; rl* SVTB = g_ws + O_SVTB;
  for(int w=tid; w<LDV*LDV; w+=NT){
    int c=w/LDV, r2=w-c*LDV; rl v=(r2==c)?1.0:0.0;
    SVTB[w]=v;
    if(wantU) SUB[w]=v;
  }
  __syncthreads();
  if(n <= SML){
    if((tid>>6)==0) leaf_exec(0, n, 0, wantU, &lct[0], sh, tid&63);
    __syncthreads();
  } else run_dc(n, wantU, lct, sh, tid);
}

__device__ void dbdsdc_L(int n, int wantU, LeafCtx* lct, Sh* sh, int tid){
  if(tid==0){
    for(int i=0;i<n-1;++i){
      rl cs,snv,rv;
      dlartg(sh->d[i], sh->e[i], &cs,&snv,&rv);
      sh->d[i]=rv; sh->e[i]=snv*sh->d[i+1]; sh->d[i+1]=cs*sh->d[i+1];
      sh->rc[i]=cs; sh->rs[i]=snv;
    }
  }
  __syncthreads();
  dbdsdc_U(n, wantU, lct, sh, tid);
  if(wantU){
    rl* SUB = g_ws + O_SUB;
    for(int c=tid;c<n;c+=NT){
      size_t ci=(size_t)LDV*c;
      // register-carry: step k reads SUB[k+1] == previous step's first-stmt value
      rl carry = SUB[(n-1)+ci];
      for(int k=n-2;k>=0;--k){
        rl a = SUB[k+ci];                               // untouched: independent load
        SUB[k+1+ci] = sh->rs[k]*a + sh->rc[k]*carry;    // final value for row k+1
        carry = sh->rc[k]*a - sh->rs[k]*carry;          // value of row k (next carry)
      }
      SUB[0+ci] = carry;
    }
  }
  __syncthreads();
}

// ======================================================================
// Bidiagonalization, 2 barriers / iteration (R2 structure, unchanged)
// ======================================================================

__device__ __forceinline__ void gebd2_upper(rl* A, int ld, int m, int n, Sh* sh, int tid){
  const int lane = tid & 63;
  rl pend_scl = 0.0; int pend_ds = 0;   // pending row-(i-1) v-scale
  for(int i=0;i<n;++i){
    rl ps=0.0;
    for(int r=i+1+lane;r<m;r+=64){ rl vv=A[r+(size_t)ld*i]; ps+=vv*vv; }
    for(int off=32;off>0;off>>=1) ps += __shfl_xor(ps,off,64);
    rl alpha=A[i+(size_t)ld*i];
    rl xn=sqrt(ps);
    rl beta,tau,scl; int ds;
    if(xn==0.0){ tau=0.0; beta=alpha; scl=0.0; ds=0; }
    else{ beta=-d_sign(dlapy2(alpha,xn),alpha); tau=(beta-alpha)/beta; scl=1.0/(alpha-beta); ds=1; }
    if(tid==0){ sh->d[i]=beta; sh->tq[i]=tau; }
    if(tau!=0.0)
      app_left_s(A, ld, i, m, i+1, n, A+(size_t)ld*i, scl, tau, tid);
    if(pend_ds && tid>=128){
      int c = i+1 + (tid-128);
      if(c < n) A[(i-1)+(size_t)ld*c] *= pend_scl;
    }
    __syncthreads();
    if(i<n-1){
      rl ps2=0.0;
      for(int c=i+2+lane;c<n;c+=64){ rl vv=A[i+(size_t)ld*c]; ps2+=vv*vv; }
      for(int off=32;off>0;off>>=1) ps2 += __shfl_xor(ps2,off,64);
      rl alpha2=A[i+(size_t)ld*(i+1)];
      rl xn2=sqrt(ps2);
      rl beta2,tau2,scl2; int ds2;
      if(xn2==0.0){ tau2=0.0; beta2=alpha2; scl2=0.0; ds2=0; }
      else{ beta2=-d_sign(dlapy2(alpha2,xn2),alpha2); tau2=(beta2-alpha2)/beta2; scl2=1.0/(alpha2-beta2); ds2=1; }
      if(tid==0){ sh->e[i]=beta2; sh->tp[i]=tau2; }
      if(tau2!=0.0)
        app_right_s(A, ld, i+1, m, i+1, n, A+i, ld, scl2, tau2, tid);
      if(ds && tid>=128){
        int r = i+1 + (tid-128);
        if(r < m) A[r+(size_t)ld*i] *= scl;
      }
      pend_ds = ds2; pend_scl = scl2;
      __syncthreads();
    } else {
      if(tid==0) sh->tp[i]=0.0;
      __syncthreads();
      if(ds) for(int r=i+1+tid; r<m; r+=NT) A[r+(size_t)ld*(n-1)] *= scl;
      __syncthreads();
    }
  }
}

__device__ __forceinline__ void gebd2_lower(rl* A, int ld, int m, int n, Sh* sh, int tid){
  const int lane = tid & 63;
  rl pend_scl = 0.0; int pend_ds = 0;
  int last_ds = 0; rl last_scl = 0.0;
  for(int i=0;i<m;++i){
    rl ps=0.0;
    for(int c=i+1+lane;c<n;c+=64){ rl vv=A[i+(size_t)ld*c]; ps+=vv*vv; }
    for(int off=32;off>0;off>>=1) ps += __shfl_xor(ps,off,64);
    rl alpha=A[i+(size_t)ld*i];
    rl xn=sqrt(ps);
    rl beta,tau,scl; int ds;
    if(xn==0.0){ tau=0.0; beta=alpha; scl=0.0; ds=0; }
    else{ beta=-d_sign(dlapy2(alpha,xn),alpha); tau=(beta-alpha)/beta; scl=1.0/(alpha-beta); ds=1; }
    if(tid==0){ sh->d[i]=beta; sh->tp[i]=tau; }
    if(tau!=0.0)
      app_right_s(A, ld, i+1, m, i, n, A+i, ld, scl, tau, tid);
    if(pend_ds && tid>=128){
      int r = i+1 + (tid-128);
      if(r < m) A[r+(size_t)ld*(i-1)] *= pend_scl;
    }
    __syncthreads();
    if(i<m-1){
      rl ps2=0.0;
      for(int r=i+2+lane;r<m;r+=64){ rl vv=A[r+(size_t)ld*i]; ps2+=vv*vv; }
      for(int off=32;off>0;off>>=1) ps2 += __shfl_xor(ps2,off,64);
      rl alpha2=A[(i+1)+(size_t)ld*i];
      rl xn2=sqrt(ps2);
      rl beta2,tau2,scl2; int ds2;
      if(xn2==0.0){ tau2=0.0; beta2=alpha2; scl2=0.0; ds2=0; }
      else{ beta2=-d_sign(dlapy2(alpha2,xn2),alpha2); tau2=(beta2-alpha2)/beta2; scl2=1.0/(alpha2-beta2); ds2=1; }
      if(tid==0){ sh->e[i]=beta2; sh->tq[i]=tau2; }
      if(tau2!=0.0)
        app_left_s(A, ld, i+1, m, i+1, n, A+(size_t)ld*i, scl2, tau2, tid);
      if(ds && tid>=128){
        int c = i+1 + (tid-128);
        if(c < n) A[i+(size_t)ld*c] *= scl;
      }
      pend_ds = ds2; pend_scl = scl2;
      __syncthreads();
    } else {
      last_ds = ds; last_scl = scl;
      __syncthreads();
      if(last_ds) for(int c=i+1+tid; c<n; c+=NT) A[(m-1)+(size_t)ld*c] *= last_scl;
      __syncthreads();
    }
  }
}

__device__ __forceinline__ void gelq2(rl* A, int ld, int m, int n, Sh* sh, int tid){
  const int lane = tid & 63;
  rl pend_scl=0.0, pend_beta=0.0; int pend_ds=0;
  for(int i=0;i<m;++i){
    rl ps=0.0;
    for(int c=i+1+lane;c<n;c+=64){ rl vv=A[i+(size_t)ld*c]; ps+=vv*vv; }
    for(int off=32;off>0;off>>=1) ps += __shfl_xor(ps,off,64);
    rl alpha=A[i+(size_t)ld*i];
    rl xn=sqrt(ps);
    rl beta,tau,scl; int ds;
    if(xn==0.0){ tau=0.0; beta=alpha; scl=0.0; ds=0; }
    else{ beta=-d_sign(dlapy2(alpha,xn),alpha); tau=(beta-alpha)/beta; scl=1.0/(alpha-beta); ds=1; }
    if(tid==0) sh->rs[i]=tau;
    if(i<m-1 && tau!=0.0)
      app_right_s(A, ld, i+1, m, i, n, A+i, ld, scl, tau, tid);
    if(i>0 && tid>=128){
      if(pend_ds){ int c = i + (tid-128); if(c<n) A[(i-1)+(size_t)ld*c] *= pend_scl; }
      if(tid==128) A[(i-1)+(size_t)ld*(i-1)] = pend_beta;
    }
    pend_ds=ds; pend_scl=scl; pend_beta=beta;
    __syncthreads();
  }
  if(tid>=128){
    if(pend_ds){ int c = m + (tid-128); if(c<n) A[(m-1)+(size_t)ld*c] *= pend_scl; }
    if(tid==128) A[(m-1)+(size_t)ld*(m-1)] = pend_beta;
  }
  __syncthreads();
}

// ---- per-shape drivers (MBL = LDS working matrix, pitch PB) ----
// Back-transforms are THREAD-LOCAL: each thread owns one row/column and applies
// the full reflector sequence with zero barriers (v/tau read-only; rows/cols
// independent). Same per-row arithmetic order as the barriered loop.
__device__ void svd_tall(int wantU, int wantVT, rl* MBL, LeafCtx* lct, Sh* sh, int tid){ // 128 x 71
  rl* MA=g_ws+O_MA; rl* MU=g_ws+O_MU; rl* MVT=g_ws+O_MVT;
  rl* SUB=g_ws+O_SUB; rl* SVTB=g_ws+O_SVTB;
  for(int w=tid;w<128*NSV;w+=NT){ int c=w>>7, r2=w&127; MBL[r2+(size_t)PB*c]=MA[r2+(size_t)LDA*c]; }
  __syncthreads();
  gebd2_upper(MBL, PB, 128, NSV, sh, tid);
  dbdsdc_U(NSV, wantU, lct, sh, tid);
  if(wantU){
    for(int w=tid;w<128*NSV;w+=NT){ int c=w>>7, r2=w&127; MU[r2+(size_t)LDA*c]=(r2<NSV)? SUB[r2+(size_t)LDV*c]:0.0; }
    __syncthreads();
    if(tid<NSV){
      int c=tid;
      rl* colb = MU + (size_t)LDA*c;
      for(int i=NSV-1;i>=0;--i){
        rl tau=sh->tq[i];
        if(tau!=0.0) row_apply(colb+i, 1, MBL + (size_t)PB*i + i + 1, 1, 128-i-1, tau);
      }
    }
    __syncthreads();
  }
  if(wantVT){
    for(int w=tid;w<LDV*NSV;w+=NT) MVT[w]=SVTB[w];
    __syncthreads();
    if(tid<NSV){
      int r=tid;
      for(int i=NSV-2;i>=0;--i){
        rl tau=sh->tp[i];
        if(tau!=0.0) row_apply(MVT + r + (size_t)LDV*(i+1), LDV, MBL + i + (size_t)PB*(i+2), PB, NSV-i-2, tau);
      }
    }
    __syncthreads();
  }
}
__device__ void svd_mid(rl* MBL, LeafCtx* lct, Sh* sh, int tid){ // 64 x 71, wantU=0, wantVT=1
  rl* MA=g_ws+O_MA; rl* MVT=g_ws+O_MVT;
  rl* SVTB=g_ws+O_SVTB;
  for(int w=tid;w<64*NSV;w+=NT){ int c=w>>6, r2=w&63; MBL[r2+(size_t)PB*c]=MA[r2+(size_t)LDA*c]; }
  __syncthreads();
  gebd2_lower(MBL, PB, 64, NSV, sh, tid);
  dbdsdc_L(64, 0, lct, sh, tid);
  for(int w=tid;w<64*NSV;w+=NT){ int c=w>>6, r2=w&63; MVT[r2+(size_t)LDV*c]=(c<64)? SVTB[r2+(size_t)LDV*c]:0.0; }
  __syncthreads();
  if(tid<64){
    int r=tid;
    for(int i=63;i>=0;--i){
      rl tau=sh->tp[i];
      if(tau!=0.0) row_apply(MVT + r + (size_t)LDV*i, LDV, MBL + i + (size_t)PB*(i+1), PB, NSV-i-1, tau);
    }
  }
  __syncthreads();
}
__device__ void svd_wide(int m, rl* MBL, LeafCtx* lct, Sh* sh, int tid){ // m x 71, m in {2,4,8,16,32}; wantU=0, wantVT=1
  rl* MA=g_ws+O_MA; rl* MQ=g_ws+O_MQ; rl* MVT=g_ws+O_MVT;
  rl* SVTB=g_ws+O_SVTB; rl* TB=g_ws+O_TB; rl* VT2=g_ws+O_VT2;
  for(int w=tid;w<m*NSV;w+=NT){ int c=w/m, r2=w-c*m; MBL[r2+(size_t)PB*c]=MA[r2+(size_t)LDA*c]; }
  __syncthreads();
  gelq2(MBL, PB, m, NSV, sh, tid);
  for(int w=tid;w<m*NSV;w+=NT){ int c=w/m, r2=w-c*m; MQ[r2+(size_t)LDA*c]=(r2==c)?1.0:0.0; }
  __syncthreads();
  if(tid<m){
    int r=tid;
    for(int j=m-1;j>=0;--j){
      rl tau=sh->rs[j];
      if(tau!=0.0) row_apply(MQ + r + (size_t)LDA*j, LDA, MBL + j + (size_t)PB*(j+1), PB, NSV-j-1, tau);
    }
  }
  __syncthreads();
  for(int w=tid;w<m*m;w+=NT){ int c=w/m, r2=w-c*m; TB[r2+(size_t)LDV*c]=(r2>=c)? MBL[r2+(size_t)PB*c]:0.0; }
  __syncthreads();
  gebd2_upper(TB, LDV, m, m, sh, tid);
  dbdsdc_U(m, 0, lct, sh, tid);
  for(int w=tid;w<m*m;w+=NT){ int c=w/m, r2=w-c*m; VT2[r2+(size_t)LDV*c]=SVTB[r2+(size_t)LDV*c]; }
  __syncthreads();
  if(tid<m){
    int r=tid;
    for(int i=m-2;i>=0;--i){
      rl tau=sh->tp[i];
      if(tau!=0.0) row_apply(VT2 + r + (size_t)LDV*(i+1), LDV, TB + i + (size_t)LDV*(i+2), LDV, m-i-2, tau);
    }
  }
  __syncthreads();
  for(int w=tid;w<m*NSV;w+=NT){
    int c=w/m, r2=w-c*m;
    const rl* vrow = VT2 + r2;
    const rl* qcol = MQ + (size_t)LDA*c;
    rl s=0.0; int t=0;
    for(; t+4<=m; t+=4){
      rl a0=vrow[(size_t)LDV*t], a1=vrow[(size_t)LDV*(t+1)], a2=vrow[(size_t)LDV*(t+2)], a3=vrow[(size_t)LDV*(t+3)];
      rl b0=qcol[t], b1=qcol[t+1], b2=qcol[t+2], b3=qcol[t+3];
      s+=a0*b0; s+=a1*b1; s+=a2*b2; s+=a3*b3;
    }
    for(; t<m; ++t) s += vrow[(size_t)LDV*t]*qcol[t];
    MVT[r2+(size_t)LDV*c]=s;
  }
  __syncthreads();
}

// ---- main kernel ----
__global__ __launch_bounds__(NT)
void mps_kernel(const float* __restrict__ ch, const float* __restrict__ ci,
                const float* __restrict__ ictx, const int* __restrict__ tok)
{
  __shared__ Sh sh;
  __shared__ LeafCtx lct[4];
  extern __shared__ rl MBL[];   // PB*NSV doubles (73272 B dynamic LDS)
  int tid = threadIdx.x;
  rl* MA = g_ws + O_MA; rl* MU = g_ws + O_MU; rl* MVT = g_ws + O_MVT;
  int kprev = 0;
  for(int s=0;s<9;++s){
    if(tid==0){
      rl W00=ch[s*4+0], W01=ch[s*4+1], W10=ch[s*4+2], W11=ch[s*4+3];
      rl P00=1,P01=0,P10=0,P11=1;
      for(int mexp=0;mexp<=70;++mexp){
        int j=70-mexp;
        rl v0,v1;
        if(j==0){ v0=ictx[s*2+0]; v1=ictx[s*2+1]; }
        else{
          int b=(tok[j-1]>>(15-s))&1;
          v0=ci[s*4+b]; v1=ci[s*4+2+b];
        }
        g_ws[O_COLS + 0 + 2*j] = P00*v0+P01*v1;
        g_ws[O_COLS + 1 + 2*j] = P10*v0+P11*v1;
        rl n00=W00*P00+W01*P10, n01=W00*P01+W01*P11;
        rl n10=W10*P00+W11*P10, n11=W10*P01+W11*P11;
        P00=n00;P01=n01;P10=n10;P11=n11;
      }
    }
    __syncthreads();
    int m = (s==0)?2:2*kprev;
    for(int w=tid; w<m*NSV; w+=NT){
      int j=w/m, r2=w-j*m;
      int l=r2>>1, dd2=r2&1;
      rl cv = g_ws[O_COLS + dd2 + 2*j];
      MA[r2+(size_t)LDA*j] = (s==0)? cv : g_ws[O_CAR + l + 64*j]*cv;
    }
    __syncthreads();
    int wantU = (s==8)?1:0;
    if(m==128) svd_tall(wantU, wantU?0:1, MBL, lct, &sh, tid);
    else if(m==64) svd_mid(MBL, lct, &sh, tid);
    else svd_wide(m, MBL, lct, &sh, tid);
    int k = min(64, min(m, NSV));
    __syncthreads();
    if(s<8){
      for(int w=tid; w<k*NSV; w+=NT){
        int j=w/k, l=w-j*k;
        g_ws[O_CAR + l + 64*j] = sh.d[l]*MVT[l+(size_t)LDV*j];
      }
    }
    __syncthreads();
    if(s==8){
      if(tid==0){
        rl W00=ch[8*4+0], W01=ch[8*4+1], W10=ch[8*4+2], W11=ch[8*4+3];
        rl P00=1,P01=0,P10=0,P11=1;
        for(int it=0;it<30;++it){
          rl n00=W00*P00+W01*P10, n01=W00*P01+W01*P11;
          rl n10=W10*P00+W11*P10, n11=W10*P01+W11*P11;
          P00=n00;P01=n01;P10=n10;P11=n11;
        }
        sh.sc[0]=P00+P10; sh.sc[1]=P01+P11;
      }
      __syncthreads();
      for(int r2=tid; r2<64; r2+=NT){
        rl acc=0.0;
        for(int l=0;l<64;++l)
          acc += sh.sc[0]*MU[(2*l)+(size_t)LDA*r2] + sh.sc[1]*MU[(2*l+1)+(size_t)LDA*r2];
        g_ws[O_VEC + r2] = acc/188.0;
      }
    }
    kprev = k;
    __syncthreads();
  }
}

__global__ __launch_bounds__(NT)
void head_kernel(const float* __restrict__ hw, const float* __restrict__ hb,
                 float* __restrict__ out)
{
  __shared__ float v[64];
  int tid=threadIdx.x;
  if(tid<64) v[tid]=(float)g_ws[O_VEC + tid];
  __syncthreads();
  int i = blockIdx.x*NT + tid;
  if(i<VOCAB){
    const float4* row = (const float4*)(hw + (size_t)i*64);
    float acc=0.f;
    #pragma unroll
    for(int c4=0;c4<16;++c4){
      float4 r4=row[c4];
      acc += r4.x*v[4*c4] + r4.y*v[4*c4+1] + r4.z*v[4*c4+2] + r4.w*v[4*c4+3];
    }
    out[i]=acc+hb[i];
  }
}

extern "C" void kernel_launch(void* const* d_in, const int* in_sizes, int n_in,
                              void* d_out, int out_size, void* d_ws, size_t ws_size,
                              hipStream_t stream)
{
  const float* ch  = (const float*)d_in[0];
  const float* ci  = (const float*)d_in[1];
  const float* hw  = (const float*)d_in[2];
  const float* hb  = (const float*)d_in[3];
  const float* ict = (const float*)d_in[4];
  const int*   tk  = (const int*)d_in[5];
  (void)d_ws; (void)ws_size; (void)in_sizes; (void)n_in; (void)out_size;

  size_t dynls = (size_t)PB*NSV*sizeof(double);   // 73272 B
  hipLaunchKernelGGL(mps_kernel, dim3(1), dim3(NT), dynls, stream, ch, ci, ict, tk);
  hipLaunchKernelGGL(head_kernel, dim3((VOCAB+NT-1)/NT), dim3(NT), 0, stream,
                     hw, hb, (float*)d_out);
}

// Round 4
// 9010.188 us; speedup vs baseline: 1.2996x; 1.0259x over previous
//
#include <hip/hip_runtime.h>

typedef double rl;
#define NT 256
#define NSV 71
#define LDA 128
#define LDV 72
#define SML 25
#define VOCAB 128000
#define LP 27   // LDS leaf pitch
#define PB 129  // LDS pitch for bidiag working matrix (odd => minimal fp64 bank aliasing)

// fp32 LAPACK constants (reference is numpy sgesdd in float32)
#define EPS32 1.1920928955078125e-7
#define UNFL32 1.17549435e-38

// g_ws offsets (doubles)
#define O_CAR   0
#define O_COLS  4608
#define O_VEC   4800
#define O_MA    5120
#define O_MU    23552
#define O_MQ    32768
#define O_MVT   41984
#define O_SUB   47168
#define O_SVTB  52352
#define O_U2    57536
#define O_VT2   62720
#define O_QU    67904
#define O_QV    73088
#define O_TB    78272

__device__ double g_ws[84000];

// Per-wave leaf context: one D&C leaf (n<=25, np<=26) runs entirely inside a
// single wave; 4 leaves execute concurrently on the 4 SIMDs of the CU.
// NOTE: during merges (which strictly follow all leaves), this 50KB LDS region
// is dead and is overlaid with the QV matrix (<=72*71 doubles = 41KB).
struct LeafCtx {
  rl LVT[26*LP], LU[26*LP];
  rl b1[26], b2[26], b3[26], b4[26];
  rl sc[6];
  int ia[26], ib[26], ic[26];
  int si[12];
};

struct Sh {
  rl d[72], e[72], tq[72], tp[72], rc[72], rs[72];
  rl dsig[72], zz[72], zh[72], sigm[72], vals[72];
  rl ta[72], tb[72];
  int srcU[72], srcVT[72], perm[72];
  int ia[72], ib[72], ic[72];
  int opk[12], opf[12], opa[12], opb[12], opq[12];
  rl sc[8];
  int si[16];
};

// Wave-local "barrier": a wave executes one instruction stream and its LDS ops
// complete in order, so ordering the compiler's memory ops + draining counters
// is sufficient for lane0 -> other-lane LDS communication.
__device__ __forceinline__ void wsync(){
  asm volatile("s_waitcnt vmcnt(0) lgkmcnt(0)" ::: "memory");
}

__device__ __forceinline__ rl d_sign(rl a, rl b){ return (b >= 0.0) ? fabs(a) : -fabs(a); }
__device__ __forceinline__ rl dlapy2(rl x, rl y){
  rl ax=fabs(x), ay=fabs(y);
  rl w = ax>ay?ax:ay, z = ax>ay?ay:ax;
  if(z==0.0) return w;
  rl t = z/w; return w*sqrt(1.0+t*t);
}
// LAPACK >= 3.10 dlartg convention (modern OpenBLAS)
__device__ void dlartg(rl f, rl g, rl* cs, rl* sn, rl* r){
  if(g==0.0){ *cs=1.0; *sn=0.0; *r=f; }
  else if(f==0.0){ *cs=0.0; *sn=d_sign(1.0,g); *r=fabs(g); }
  else{
    rl dd = sqrt(f*f+g*g);
    *cs = fabs(f)/dd;
    *r  = d_sign(dd, f);
    *sn = g/(*r);
  }
}

__device__ void dlas2(rl f, rl g, rl h, rl* ssmin, rl* ssmax){
  rl fa=fabs(f), ga=fabs(g), ha=fabs(h);
  rl fhmn=fmin(fa,ha), fhmx=fmax(fa,ha);
  if(fhmn==0.0){
    *ssmin=0.0;
    if(fhmx==0.0) *ssmax=ga;
    else { rl mx=fmax(fhmx,ga), mn=fmin(fhmx,ga); rl q=mn/mx; *ssmax=mx*sqrt(1.0+q*q); }
  } else {
    if(ga < fhmx){
      rl as=1.0+fhmn/fhmx, at=(fhmx-fhmn)/fhmx;
      rl au=(ga/fhmx); au=au*au;
      rl c=2.0/(sqrt(as*as+au)+sqrt(at*at+au));
      *ssmin=fhmn*c; *ssmax=fhmx/c;
    } else {
      rl au=fhmx/ga;
      if(au==0.0){ *ssmin=(fhmn*fhmx)/ga; *ssmax=ga; }
      else{
        rl as=1.0+fhmn/fhmx, at=(fhmx-fhmn)/fhmx;
        rl c=1.0/(sqrt(1.0+(as*au)*(as*au))+sqrt(1.0+(at*au)*(at*au)));
        *ssmin=(fhmn*c)*au; *ssmin=*ssmin+*ssmin;
        *ssmax=ga/(c+c);
      }
    }
  }
}

__device__ void dlasv2(rl f, rl g, rl h, rl* ssmin, rl* ssmax, rl* snr, rl* csr, rl* snl, rl* csl){
  rl ft=f, fa=fabs(f), ht=h, ha=fabs(h);
  int pmax=1;
  bool swp = (ha > fa);
  if(swp){ pmax=3; rl t=ft; ft=ht; ht=t; t=fa; fa=ha; ha=t; }
  rl gt=g, ga=fabs(g);
  rl clt=0, crt=0, slt=0, srt=0;
  if(ga==0.0){ *ssmin=ha; *ssmax=fa; clt=1.0; crt=1.0; slt=0.0; srt=0.0; }
  else{
    bool gasmal=true;
    if(ga > fa){
      pmax=2;
      if((fa/ga) < EPS32){
        gasmal=false;
        *ssmax=ga;
        if(ha>1.0) *ssmin=fa/(ga/ha); else *ssmin=(fa/ga)*ha;
        clt=1.0; slt=ht/gt; srt=1.0; crt=ft/gt;
      }
    }
    if(gasmal){
      rl dd=fa-ha;
      rl lv = (dd==fa) ? 1.0 : dd/fa;
      rl mq = gt/ft;
      rl tv = 2.0-lv;
      rl mm = mq*mq, tt = tv*tv;
      rl sv = sqrt(tt+mm);
      rl rv = (lv==0.0) ? fabs(mq) : sqrt(lv*lv+mm);
      rl a = 0.5*(sv+rv);
      *ssmin = ha/a; *ssmax = fa*a;
      rl t3;
      if(mm==0.0){
        if(lv==0.0) t3 = d_sign(2.0, ft)*d_sign(1.0, gt);
        else t3 = gt/d_sign(dd, ft) + mq/tv;
      } else {
        t3 = (mq/(sv+tv) + mq/(rv+lv))*(1.0+a);
      }
      rl l2 = sqrt(t3*t3+4.0);
      crt = 2.0/l2; srt = t3/l2;
      clt = (crt + srt*mq)/a;
      slt = (ht/ft)*srt/a;
    }
  }
  if(swp){ *csl=srt; *snl=crt; *csr=slt; *snr=clt; }
  else  { *csl=clt; *snl=slt; *csr=crt; *snr=srt; }
  rl tsign=1.0;
  if(pmax==1) tsign = d_sign(1.0,*csr)*d_sign(1.0,*csl)*d_sign(1.0,f);
  if(pmax==2) tsign = d_sign(1.0,*snr)*d_sign(1.0,*csl)*d_sign(1.0,g);
  if(pmax==3) tsign = d_sign(1.0,*snr)*d_sign(1.0,*snl)*d_sign(1.0,h);
  *ssmax = d_sign(*ssmax, tsign);
  *ssmin = d_sign(*ssmin, tsign*d_sign(1.0,f)*d_sign(1.0,h));
}

// Thread-local Householder apply to ONE row/column (elements at stride ld after
// the pivot; reflector v at stride vs). Grouped 16-wide loads + strictly
// sequential adds: bit-identical to the original scalar loop.
__device__ __forceinline__ void row_apply(rl* row, size_t ld, const rl* v, size_t vs, int len, rl tau){
  rl s = row[0];
  int i=0;
  for(; i+16<=len; i+=16){
    rl a[16], b[16];
    #pragma unroll
    for(int u=0;u<16;++u){ a[u]=row[ld*(size_t)(1+i+u)]; b[u]=v[vs*(size_t)(i+u)]; }
    #pragma unroll
    for(int u=0;u<16;++u) s += a[u]*b[u];
  }
  for(; i<len; ++i) s += row[ld*(size_t)(1+i)]*v[vs*(size_t)i];
  rl w = s*tau;
  row[0] -= w;
  i=0;
  for(; i+16<=len; i+=16){
    rl b[16];
    #pragma unroll
    for(int u=0;u<16;++u) b[u]=v[vs*(size_t)(i+u)];
    #pragma unroll
    for(int u=0;u<16;++u) row[ld*(size_t)(1+i+u)] -= w*b[u];
  }
  for(; i<len; ++i) row[ld*(size_t)(1+i)] -= w*v[vs*(size_t)i];
}

// Apply-with-on-the-fly scale: v holds RAW (pre-scale) values; b = fl(raw*scl)
// is the exact same single rounding as the stored scaled value. 16-wide grouped
// loads, sequential adds: bit-identical. ONE column/row per thread.
__device__ __forceinline__ void app_left_s(rl* A, int ld, int r0, int m, int c0, int n, const rl* vbase, rl scl, rl tau, int tid){
  const int len = m - r0 - 1;
  const rl* v = vbase + r0 + 1;
  int c = c0 + tid;
  if(c < n){
    rl* col = A + (size_t)ld*c + r0;
    rl s = col[0];
    int i=0;
    for(; i+16<=len; i+=16){
      rl a[16], b[16];
      #pragma unroll
      for(int u=0;u<16;++u){ a[u]=col[1+i+u]; b[u]=v[i+u]*scl; }
      #pragma unroll
      for(int u=0;u<16;++u) s += a[u]*b[u];
    }
    for(; i<len; ++i) s += col[1+i]*(v[i]*scl);
    rl w = s*tau;
    col[0] -= w;
    i=0;
    for(; i+16<=len; i+=16){
      rl b[16];
      #pragma unroll
      for(int u=0;u<16;++u) b[u]=v[i+u]*scl;
      #pragma unroll
      for(int u=0;u<16;++u) col[1+i+u] -= w*b[u];
    }
    for(; i<len; ++i) col[1+i] -= w*(v[i]*scl);
  }
}
__device__ __forceinline__ void app_right_s(rl* A, int ld, int r0, int m, int c0, int n, const rl* vbase, int vstride, rl scl, rl tau, int tid){
  const int len = n - c0 - 1;
  const rl* v = vbase + (size_t)vstride*(c0+1);
  int r = r0 + tid;
  if(r < m){
    rl* row = A + r + (size_t)ld*c0;
    rl s = row[0];
    int i=0;
    for(; i+16<=len; i+=16){
      rl a[16], b[16];
      #pragma unroll
      for(int u=0;u<16;++u){ a[u]=row[(size_t)ld*(size_t)(1+i+u)]; b[u]=v[(size_t)vstride*(size_t)(i+u)]*scl; }
      #pragma unroll
      for(int u=0;u<16;++u) s += a[u]*b[u];
    }
    for(; i<len; ++i) s += row[(size_t)ld*(1+i)]*(v[(size_t)vstride*i]*scl);
    rl w = s*tau;
    row[0] -= w;
    i=0;
    for(; i+16<=len; i+=16){
      rl b[16];
      #pragma unroll
      for(int u=0;u<16;++u) b[u]=v[(size_t)vstride*(size_t)(i+u)]*scl;
      #pragma unroll
      for(int u=0;u<16;++u) row[(size_t)ld*(size_t)(1+i+u)] -= w*b[u];
    }
    for(; i<len; ++i) row[(size_t)ld*(1+i)] -= w*(v[(size_t)vstride*i]*scl);
  }
}

// ---- wave-scoped dbdsqr on a private LDS leaf block ----
__device__ void bdsqr_wave(int n, rl* d, rl* e, int ncvt, int nru, LeafCtx* lc, int lane){
  if(n>1){
    rl eps=EPS32, unfl=UNFL32;
    rl tolmul=fmax(10.0,fmin(100.0,pow(eps,-0.125)));
    rl tol=tolmul*eps;
    rl thresh=0.0;
    int mm=n-1, oldll=-2, oldm=-2, idir=0, iter=0, maxit=6*n*n;
    if(lane==0){
      rl sminoa=fabs(d[0]);
      if(sminoa!=0.0){
        rl mu=sminoa;
        for(int i=1;i<n;++i){ mu=fabs(d[i])*(mu/(mu+fabs(e[i-1]))); sminoa=fmin(sminoa,mu); if(sminoa==0.0)break; }
      }
      sminoa=sminoa/sqrt((rl)n);
      thresh=fmax(tol*sminoa,(rl)(6*n*n)*unfl);
    }
    while(true){
      if(lane==0){
        int act=0, p_lo=0, p_cnt=0, p_fwd=1, p_mm=0;
        while(mm>0){
          if(iter>maxit) break;
          rl smax=fabs(d[mm]), smin=smax;
          int ll=-1;
          for(int lll=mm-1;lll>=0;--lll){
            rl abss=fabs(d[lll]), abse=fabs(e[lll]);
            if(abse<=thresh){ ll=lll; break; }
            smin=fmin(smin,abss);
            smax=fmax(smax,fmax(abss,abse));
          }
          if(ll==mm-1){ e[ll]=0.0; mm=mm-1; continue; }
          if(ll>=0) e[ll]=0.0;
          int lo=ll+1;
          if(mm==lo+1){
            rl sigmn,sigmx,sinr,cosr,sinl,cosl;
            dlasv2(d[lo],e[lo],d[mm],&sigmn,&sigmx,&sinr,&cosr,&sinl,&cosl);
            d[lo]=sigmx; d[mm]=sigmn; e[lo]=0.0;
            lc->sc[0]=cosr; lc->sc[1]=sinr; lc->sc[2]=cosl; lc->sc[3]=sinl;
            act=2; p_lo=lo; p_mm=mm;
            mm-=2;
            break;
          }
          if(lo>oldm || mm<oldll) idir=(fabs(d[lo])>=fabs(d[mm]))?1:2;
          rl sminl=0.0; int conv=0;
          if(idir==1){
            if(fabs(e[mm-1])<=tol*fabs(d[mm])){ e[mm-1]=0.0; conv=1; }
            if(!conv){
              rl mu=fabs(d[lo]); sminl=mu;
              for(int lll=lo;lll<mm;++lll){
                if(fabs(e[lll])<=tol*mu){ e[lll]=0.0; conv=1; break; }
                mu=fabs(d[lll+1])*(mu/(mu+fabs(e[lll])));
                sminl=fmin(sminl,mu);
              }
            }
          } else {
            if(fabs(e[lo])<=tol*fabs(d[lo])){ e[lo]=0.0; conv=1; }
            if(!conv){
              rl mu=fabs(d[mm]); sminl=mu;
              for(int lll=mm-1;lll>=lo;--lll){
                if(fabs(e[lll])<=tol*mu){ e[lll]=0.0; conv=1; break; }
                mu=fabs(d[lll])*(mu/(mu+fabs(e[lll])));
                sminl=fmin(sminl,mu);
              }
            }
          }
          if(conv) continue;
          oldll=lo; oldm=mm;
          rl shift=0.0, rr_;
          if(!((rl)n*tol*(sminl/smax) <= fmax(eps, 0.01*tol))){
            rl sll;
            if(idir==1){ sll=fabs(d[lo]); dlas2(d[mm-1],e[mm-1],d[mm],&shift,&rr_); }
            else { sll=fabs(d[mm]); dlas2(d[lo],e[lo],d[lo+1],&shift,&rr_); }
            if(sll>0.0){ rl q=shift/sll; if(q*q<eps) shift=0.0; }
          }
          iter += mm-lo;
          int cnt=mm-lo;
          if(shift==0.0){
            if(idir==1){
              rl cs=1.0, oldcs=1.0, sn=0.0, oldsn=0.0, r;
              for(int i=lo;i<mm;++i){
                dlartg(d[i]*cs,e[i],&cs,&sn,&r);
                if(i>lo) e[i-1]=oldsn*r;
                dlartg(oldcs*r, d[i+1]*sn, &oldcs,&oldsn,&d[i]);
                lc->b1[i-lo]=cs; lc->b2[i-lo]=sn; lc->b3[i-lo]=oldcs; lc->b4[i-lo]=oldsn;
              }
              rl h=d[mm]*cs; d[mm]=h*oldcs; e[mm-1]=h*oldsn;
              p_fwd=1;
              if(fabs(e[mm-1])<=thresh) e[mm-1]=0.0;
            } else {
              rl cs=1.0, oldcs=1.0, sn=0.0, oldsn=0.0, r;
              for(int i=mm;i>lo;--i){
                dlartg(d[i]*cs,e[i-1],&cs,&sn,&r);
                if(i<mm) e[i]=oldsn*r;
                dlartg(oldcs*r,d[i-1]*sn,&oldcs,&oldsn,&d[i]);
                int j=i-lo-1;
                lc->b1[j]=oldcs; lc->b2[j]=-oldsn; lc->b3[j]=cs; lc->b4[j]=-sn;
              }
              rl h=d[lo]*cs; d[lo]=h*oldcs; e[lo]=h*oldsn;
              p_fwd=0;
              if(fabs(e[lo])<=thresh) e[lo]=0.0;
            }
          } else {
            if(idir==1){
              rl f2=(fabs(d[lo])-shift)*(d_sign(1.0,d[lo])+shift/d[lo]);
              rl g2=e[lo], r, cosr,sinr,cosl,sinl;
              for(int i=lo;i<mm;++i){
                dlartg(f2,g2,&cosr,&sinr,&r);
                if(i>lo) e[i-1]=r;
                f2=cosr*d[i]+sinr*e[i];
                e[i]=cosr*e[i]-sinr*d[i];
                g2=sinr*d[i+1];
                d[i+1]=cosr*d[i+1];
                dlartg(f2,g2,&cosl,&sinl,&r);
                d[i]=r;
                f2=cosl*e[i]+sinl*d[i+1];
                d[i+1]=cosl*d[i+1]-sinl*e[i];
                if(i<mm-1){ g2=sinl*e[i+1]; e[i+1]=cosl*e[i+1]; }
                lc->b1[i-lo]=cosr; lc->b2[i-lo]=sinr; lc->b3[i-lo]=cosl; lc->b4[i-lo]=sinl;
              }
              e[mm-1]=f2;
              p_fwd=1;
              if(fabs(e[mm-1])<=thresh) e[mm-1]=0.0;
            } else {
              rl f2=(fabs(d[mm])-shift)*(d_sign(1.0,d[mm])+shift/d[mm]);
              rl g2=e[mm-1], r, cosr,sinr,cosl,sinl;
              for(int i=mm;i>lo;--i){
                dlartg(f2,g2,&cosr,&sinr,&r);
                if(i<mm) e[i]=r;
                f2=cosr*d[i]+sinr*e[i-1];
                e[i-1]=cosr*e[i-1]-sinr*d[i];
                g2=sinr*d[i-1];
                d[i-1]=cosr*d[i-1];
                dlartg(f2,g2,&cosl,&sinl,&r);
                d[i]=r;
                f2=cosl*e[i-1]+sinl*d[i-1];
                d[i-1]=cosl*d[i-1]-sinl*e[i-1];
                if(i>lo+1){ g2=sinl*e[i-2]; e[i-2]=cosl*e[i-2]; }
                int j=i-lo-1;
                lc->b1[j]=cosl; lc->b2[j]=-sinl; lc->b3[j]=cosr; lc->b4[j]=-sinr;
              }
              e[lo]=f2;
              p_fwd=0;
              if(fabs(e[lo])<=thresh) e[lo]=0.0;
            }
          }
          act=1; p_lo=lo; p_cnt=cnt;
          break;
        }
        lc->si[7]=act; lc->si[8]=p_lo; lc->si[9]=p_cnt; lc->si[10]=p_fwd; lc->si[11]=p_mm;
      }
      wsync();
      int act=lc->si[7];
      if(act==0) break;
      if(act==1){
        int lo=lc->si[8], cnt=lc->si[9], fwd=lc->si[10];
        if(lane<ncvt){
          int k=lane;
          if(fwd){
            rl cur = lc->LVT[lo*LP+k];
            for(int j=0;j<cnt;++j){
              rl c=lc->b1[j], s=lc->b2[j];
              rl t = lc->LVT[(lo+j+1)*LP+k];
              lc->LVT[(lo+j)*LP+k] = s*t + c*cur;
              cur = c*t - s*cur;
            }
            lc->LVT[(lo+cnt)*LP+k] = cur;
          } else {
            rl tcar = lc->LVT[(lo+cnt)*LP+k];
            for(int j=cnt-1;j>=0;--j){
              rl c=lc->b1[j], s=lc->b2[j];
              rl low = lc->LVT[(lo+j)*LP+k];
              lc->LVT[(lo+j+1)*LP+k] = c*tcar - s*low;
              tcar = s*tcar + c*low;
            }
            lc->LVT[lo*LP+k] = tcar;
          }
        } else if(lane<ncvt+nru){
          int r2=lane-ncvt;
          if(fwd){
            rl cur = lc->LU[r2*LP+lo];
            for(int j=0;j<cnt;++j){
              rl c=lc->b3[j], s=lc->b4[j];
              rl t = lc->LU[r2*LP+(lo+j+1)];
              lc->LU[r2*LP+(lo+j)] = s*t + c*cur;
              cur = c*t - s*cur;
            }
            lc->LU[r2*LP+(lo+cnt)] = cur;
          } else {
            rl tcar = lc->LU[r2*LP+(lo+cnt)];
            for(int j=cnt-1;j>=0;--j){
              rl c=lc->b3[j], s=lc->b4[j];
              rl low = lc->LU[r2*LP+(lo+j)];
              lc->LU[r2*LP+(lo+j+1)] = c*tcar - s*low;
              tcar = s*tcar + c*low;
            }
            lc->LU[r2*LP+lo] = tcar;
          }
        }
      } else {
        int lo=lc->si[8], m2=lc->si[11];
        rl cosr=lc->sc[0], sinr=lc->sc[1], cosl=lc->sc[2], sinl=lc->sc[3];
        if(lane<ncvt){
          rl x=lc->LVT[lo*LP+lane], y=lc->LVT[m2*LP+lane];
          lc->LVT[lo*LP+lane]=cosr*x+sinr*y; lc->LVT[m2*LP+lane]=cosr*y-sinr*x;
        } else if(lane<ncvt+nru){
          int r2=lane-ncvt;
          rl x=lc->LU[r2*LP+lo], y=lc->LU[r2*LP+m2];
          lc->LU[r2*LP+lo]=cosl*x+sinl*y; lc->LU[r2*LP+m2]=cosl*y-sinl*x;
        }
      }
      wsync();
    }
  }
  if(lane==0){
    for(int i=0;i<n;++i){ lc->ic[i]=(d[i]<0.0)?1:0; if(d[i]<0.0) d[i]=-d[i]; }
    int nsw=0;
    for(int i=0;i<n-1;++i){
      int isub=0; rl smin=d[0];
      for(int j=1;j<n-i;++j){ if(d[j]<=smin){ isub=j; smin=d[j]; } }
      int tgt=n-1-i;
      if(isub!=tgt){
        d[isub]=d[tgt]; d[tgt]=smin;
        lc->ia[nsw]=isub; lc->ib[nsw]=tgt; ++nsw;
      }
    }
    lc->si[7]=nsw;
  }
  wsync();
  int nsw=lc->si[7];
  if(lane<ncvt){
    for(int i=0;i<n;++i) if(lc->ic[i]) lc->LVT[i*LP+lane]=-lc->LVT[i*LP+lane];
    for(int w2=0;w2<nsw;++w2){
      int a=lc->ia[w2], b=lc->ib[w2];
      rl t=lc->LVT[a*LP+lane]; lc->LVT[a*LP+lane]=lc->LVT[b*LP+lane]; lc->LVT[b*LP+lane]=t;
    }
  } else if(lane<ncvt+nru){
    int r2=lane-ncvt;
    for(int w2=0;w2<nsw;++w2){
      int a=lc->ia[w2], b=lc->ib[w2];
      rl t=lc->LU[r2*LP+a]; lc->LU[r2*LP+a]=lc->LU[r2*LP+b]; lc->LU[r2*LP+b]=t;
    }
  }
  wsync();
}

// ---- leaf: dlasdq, entirely within one wave (no block barriers inside) ----
__device__ void leaf_exec(int f, int n, int sqre, int wantU, LeafCtx* lc, Sh* sh, int lane){
  rl* SVTB = g_ws + O_SVTB; rl* SUB = g_ws + O_SUB;
  int np = n + sqre;
  for(int w=lane; w<np*np; w+=64){ int r2=w/np, c=w-r2*np; lc->LVT[r2*LP+c]=SVTB[(f+r2)+(size_t)LDV*(f+c)]; }
  if(wantU) for(int w=lane; w<n*n; w+=64){ int r2=w/n, c=w-r2*n; lc->LU[r2*LP+c]=SUB[(f+r2)+(size_t)LDV*(f+c)]; }
  wsync();
  if(sqre==1){
    if(lane==0){
      rl cs,snv,rv; rl* dd=sh->d+f; rl* ee=sh->e+f;
      for(int i=0;i<n;++i){
        dlartg(dd[i],ee[i],&cs,&snv,&rv);
        dd[i]=rv;
        if(i<n-1){ ee[i]=snv*dd[i+1]; dd[i+1]=cs*dd[i+1]; }
        else ee[i]=0.0;
        lc->b1[i]=cs; lc->b2[i]=snv;
      }
    }
    wsync();
    if(lane<np){
      rl cur = lc->LVT[0*LP+lane];
      for(int j=0;j<n;++j){
        rl cj=lc->b1[j], sj=lc->b2[j];
        rl t=lc->LVT[(j+1)*LP+lane];
        lc->LVT[j*LP+lane] = sj*t + cj*cur;
        cur = cj*t - sj*cur;
      }
      lc->LVT[n*LP+lane] = cur;
    }
    wsync();
    if(lane==0){
      rl cs,snv,rv; rl* dd=sh->d+f; rl* ee=sh->e+f;
      for(int i=0;i<n-1;++i){
        dlartg(dd[i],ee[i],&cs,&snv,&rv);
        dd[i]=rv; ee[i]=snv*dd[i+1]; dd[i+1]=cs*dd[i+1];
        lc->b1[i]=cs; lc->b2[i]=snv;
      }
    }
    wsync();
    if(wantU && lane<n){
      rl cur = lc->LU[lane*LP+0];
      for(int j=0;j<n-1;++j){
        rl cj=lc->b1[j], sj=lc->b2[j];
        rl t=lc->LU[lane*LP+(j+1)];
        lc->LU[lane*LP+j] = sj*t + cj*cur;
        cur = cj*t - sj*cur;
      }
      lc->LU[lane*LP+(n-1)] = cur;
    }
    wsync();
  }
  bdsqr_wave(n, sh->d+f, sh->e+f, np, wantU? n:0, lc, lane);
  for(int w=lane; w<np*np; w+=64){ int r2=w/np, c=w-r2*np; SVTB[(f+r2)+(size_t)LDV*(f+c)]=lc->LVT[r2*LP+c]; }
  if(wantU) for(int w=lane; w<n*n; w+=64){ int r2=w/n, c=w-r2*n; SUB[(f+r2)+(size_t)LDV*(f+c)]=lc->LU[r2*LP+c]; }
}

// ---- D&C merge (dlasd1/2/3) ----
// QV lives in LDS (overlay of the dead LeafCtx region); QU stays in g_ws.
// Matmul dots are 16-wide grouped (sequential adds -> bit-identical).
__device__ void lasd1_merge(int f, int nl, int nr, int sqre, int wantU, rl* QV, Sh* sh, int tid){
  rl* SUB = g_ws + O_SUB; rl* SVTB = g_ws + O_SVTB;
  rl* U2 = g_ws + O_U2; rl* VT2 = g_ws + O_VT2; rl* QU = g_ws + O_QU;
  int n = nl+nr+1, m = n+sqre;
  if(tid==0){
    rl alpha = sh->d[f+nl], beta = sh->e[f+nl];
    sh->vals[0]=0.0;
    sh->zz[0] = alpha*SVTB[(f+nl)+(size_t)LDV*(f+nl)];
    sh->srcU[0]=-1; sh->srcVT[0]=f+nl;
    for(int i=0;i<nl;++i){
      sh->vals[1+i]=sh->d[f+i];
      sh->zz[1+i]=alpha*SVTB[(f+i)+(size_t)LDV*(f+nl)];
      sh->srcU[1+i]=f+i; sh->srcVT[1+i]=f+i;
    }
    for(int j=0;j<nr;++j){
      sh->vals[1+nl+j]=sh->d[f+nl+1+j];
      sh->zz[1+nl+j]=beta*SVTB[(f+nl+1+j)+(size_t)LDV*(f+nl+1)];
      sh->srcU[1+nl+j]=f+nl+1+j; sh->srcVT[1+nl+j]=f+nl+1+j;
    }
    sh->sc[0]=alpha; sh->sc[1]=beta;
    if(sqre==1){
      rl zM = beta*SVTB[(f+n)+(size_t)LDV*(f+nl+1)];
      rl c,s,r2;
      dlartg(sh->zz[0], zM, &c, &s, &r2);
      sh->zz[0]=r2; sh->sc[2]=c; sh->sc[3]=s;
    }
  }
  __syncthreads();
  if(sqre==1){
    rl c=sh->sc[2], s=sh->sc[3];
    int ra=f+nl, rb=f+n;
    for(int k=tid;k<m;k+=NT){
      size_t ci=(size_t)LDV*(f+k);
      rl a=SVTB[ra+ci], b=SVTB[rb+ci];
      SVTB[ra+ci]=c*a+s*b; SVTB[rb+ci]=-s*a+c*b;
    }
  }
  __syncthreads();
  if(tid==0){
    rl maxd=0.0; for(int i=0;i<n;++i) maxd=fmax(maxd,fabs(sh->vals[i]));
    rl tol = 8.0*EPS32*fmax(maxd, fmax(fabs(sh->sc[0]), fabs(sh->sc[1])));
    int nds=0;
    sh->ic[nds++]=0;
    for(int i=1;i<n;++i) if(fabs(sh->zz[i]) > tol) sh->ic[nds++]=i;
    for(int a=1;a<nds;++a){
      int key=sh->ic[a]; rl kv=sh->vals[key]; int b=a-1;
      while(b>=1 && sh->vals[sh->ic[b]] > kv){ sh->ic[b+1]=sh->ic[b]; --b; }
      sh->ic[b+1]=key;
    }
    int K=nds, pos=nds;
    for(int i=1;i<n;++i) if(fabs(sh->zz[i]) <= tol) sh->ic[pos++]=i;
    for(int a=K+1;a<n;++a){
      int key=sh->ic[a]; rl kv=sh->vals[key]; int b=a-1;
      while(b>=K && sh->vals[sh->ic[b]] > kv){ sh->ic[b+1]=sh->ic[b]; --b; }
      sh->ic[b+1]=key;
    }
    for(int t=0;t<n;++t){ sh->ta[t]=sh->vals[t]; sh->tb[t]=sh->zz[t]; sh->ia[t]=sh->srcU[t]; sh->ib[t]=sh->srcVT[t]; }
    for(int t=0;t<n;++t){
      int p=sh->ic[t];
      sh->dsig[t]=sh->ta[p]; sh->zz[t]=sh->tb[p]; sh->srcU[t]=sh->ia[p]; sh->srcVT[t]=sh->ib[p];
    }
    rl rho=0.0; for(int t=0;t<K;++t){ rl zv=sh->zz[t]; rho += zv*zv; }
    sh->sc[4]=rho;
    sh->si[0]=K; sh->si[1]=n; sh->si[2]=m; sh->si[3]=f; sh->si[4]=nl;
  }
  __syncthreads();
  int K=sh->si[0], n_=sh->si[1], m_=sh->si[2], f_=sh->si[3], nl_=sh->si[4];
  if(wantU){
    for(int w=tid; w<n_*n_; w+=NT){
      int col=w/n_, row=w-col*n_;
      int su=sh->srcU[col];
      rl v;
      if(su<0) v = (row==nl_) ? 1.0 : 0.0;
      else v = SUB[(f_+row)+(size_t)LDV*su];
      U2[row+(size_t)LDV*col]=v;
    }
  }
  for(int w=tid; w<n_*m_; w+=NT){
    int row=w/m_, col=w-row*m_;
    VT2[row+(size_t)LDV*col] = SVTB[sh->srcVT[row]+(size_t)LDV*(f_+col)];
  }
  __syncthreads();
  rl rho=sh->sc[4];
  for(int j=tid;j<K;j+=NT){
    rl lo=sh->dsig[j];
    rl hi=(j<K-1)? sh->dsig[j+1] : sqrt(sh->dsig[K-1]*sh->dsig[K-1]+rho);
    for(int it=0; it<130; ++it){
      rl mid=0.5*(lo+hi);
      if(mid<=lo || mid>=hi) break;
      rl g=1.0;
      for(int i2=0;i2<K;++i2){
        rl zi=sh->zz[i2];
        g += zi*zi/((sh->dsig[i2]-mid)*(sh->dsig[i2]+mid));
      }
      if(g<0.0) lo=mid; else hi=mid;
    }
    sh->sigm[j]=0.5*(lo+hi);
  }
  __syncthreads();
  for(int i2=tid;i2<K;i2+=NT){
    rl di=sh->dsig[i2];
    rl p=(di - sh->sigm[K-1])*(di + sh->sigm[K-1]);
    for(int j=0;j<i2;++j)
      p *= (di - sh->sigm[j])*(di + sh->sigm[j])/((di - sh->dsig[j])*(di + sh->dsig[j]));
    for(int j=i2;j<K-1;++j)
      p *= (di - sh->sigm[j])*(di + sh->sigm[j])/((di - sh->dsig[j+1])*(di + sh->dsig[j+1]));
    sh->zh[i2] = d_sign(sqrt(fabs(p)), sh->zz[i2]);
  }
  __syncthreads();
  for(int j=tid;j<K;j+=NT){
    rl sj=sh->sigm[j];
    rl nu=0.0, nv=0.0;
    for(int i2=0;i2<K;++i2){
      rl di=sh->dsig[i2];
      rl vv=sh->zh[i2]/((di-sj)*(di+sj));
      QV[i2+(size_t)LDV*j]=vv; nv+=vv*vv;
      if(wantU){
        rl uu=(i2==0)? -1.0 : di*vv;
        QU[i2+(size_t)LDV*j]=uu; nu+=uu*uu;
      }
    }
    nv=1.0/sqrt(nv);
    for(int i2=0;i2<K;++i2) QV[i2+(size_t)LDV*j]*=nv;
    if(wantU){
      nu=1.0/sqrt(nu);
      for(int i2=0;i2<K;++i2) QU[i2+(size_t)LDV*j]*=nu;
    }
  }
  __syncthreads();
  if(tid==0){
    int nd2=n_-K;
    for(int t=0;t<nd2;++t) sh->ia[t]=K+t;
    int ps=K-1, pd=nd2-1;
    int t=0;
    while(t<n_){
      rl vs = (ps>=0)? sh->sigm[ps] : -1.0;
      rl vd = (pd>=0)? sh->dsig[sh->ia[pd]] : -1.0;
      if(vs >= vd){ sh->perm[t]=ps; sh->vals[t]=vs; --ps; }
      else { sh->perm[t]=1000+sh->ia[pd]; sh->vals[t]=vd; --pd; }
      ++t;
    }
    for(int q=0;q<n_;++q) sh->d[f_+q]=sh->vals[q];
  }
  __syncthreads();
  if(wantU){
    for(int w=tid; w<n_*n_; w+=NT){
      int t=w/n_, row=w-t*n_;
      int src=sh->perm[t];
      rl acc;
      if(src>=1000) acc = U2[row+(size_t)LDV*(src-1000)];
      else{
        const rl* urow = U2 + row;
        const rl* qcol = QU + (size_t)LDV*src;
        rl s=0.0; int i=0;
        for(; i+16<=K; i+=16){
          rl a[16], b[16];
          #pragma unroll
          for(int u=0;u<16;++u){ a[u]=urow[(size_t)LDV*(size_t)(i+u)]; b[u]=qcol[i+u]; }
          #pragma unroll
          for(int u=0;u<16;++u) s += a[u]*b[u];
        }
        for(; i<K; ++i) s += urow[(size_t)LDV*i]*qcol[i];
        acc=s;
      }
      SUB[(f_+row)+(size_t)LDV*(f_+t)] = acc;
    }
  }
  for(int w=tid; w<n_*m_; w+=NT){
    int t=w/m_, col=w-t*m_;
    int src=sh->perm[t];
    rl acc;
    if(src>=1000) acc = VT2[(src-1000)+(size_t)LDV*col];
    else{
      const rl* qcol = QV + (size_t)LDV*src;
      const rl* vcol = VT2 + (size_t)LDV*col;
      rl s=0.0; int i=0;
      for(; i+16<=K; i+=16){
        rl a[16], b[16];
        #pragma unroll
        for(int u=0;u<16;++u){ a[u]=qcol[i+u]; b[u]=vcol[i+u]; }
        #pragma unroll
        for(int u=0;u<16;++u) s += a[u]*b[u];
      }
      for(; i<K; ++i) s += qcol[i]*vcol[i];
      acc=s;
    }
    SVTB[(f_+t)+(size_t)LDV*(f_+col)] = acc;
  }
  __syncthreads();
}

// ---- dlasd0: post-order over the D&C tree, leaves batched onto waves ----
__device__ void run_dc(int n, int wantU, LeafCtx* lct, Sh* sh, int tid){
  if(tid==0){
    int sf[12], sn2[12], sq[12], sv[12]; int sp=0, no=0;
    sf[0]=0; sn2[0]=n; sq[0]=0; sv[0]=0; sp=1;
    while(sp>0){
      --sp;
      int f=sf[sp], nn=sn2[sp], q=sq[sp], v=sv[sp];
      if(nn<=SML){ sh->opk[no]=0; sh->opf[no]=f; sh->opa[no]=nn; sh->opb[no]=0; sh->opq[no]=q; ++no; }
      else if(v==0){
        int nl=nn/2, nr=nn-nl-1;
        sf[sp]=f; sn2[sp]=nn; sq[sp]=q; sv[sp]=1; ++sp;
        sf[sp]=f+nl+1; sn2[sp]=nr; sq[sp]=q; sv[sp]=0; ++sp;
        sf[sp]=f; sn2[sp]=nl; sq[sp]=1; sv[sp]=0; ++sp;
      } else {
        int nl=nn/2, nr=nn-nl-1;
        sh->opk[no]=1; sh->opf[no]=f; sh->opa[no]=nl; sh->opb[no]=nr; sh->opq[no]=q; ++no;
      }
    }
    // Stable-partition: all leaves first, then merges (leaves are mutually
    // independent and independent of non-ancestor merges; merge order kept).
    // This also guarantees the LeafCtx LDS region is dead during ALL merges,
    // enabling the QV overlay.
    int tk[12], tf2[12], ta2[12], tb3[12], tq3[12]; int c=0;
    for(int i=0;i<no;++i) if(sh->opk[i]==0){ tk[c]=0; tf2[c]=sh->opf[i]; ta2[c]=sh->opa[i]; tb3[c]=sh->opb[i]; tq3[c]=sh->opq[i]; ++c; }
    for(int i=0;i<no;++i) if(sh->opk[i]==1){ tk[c]=1; tf2[c]=sh->opf[i]; ta2[c]=sh->opa[i]; tb3[c]=sh->opb[i]; tq3[c]=sh->opq[i]; ++c; }
    for(int i=0;i<no;++i){ sh->opk[i]=tk[i]; sh->opf[i]=tf2[i]; sh->opa[i]=ta2[i]; sh->opb[i]=tb3[i]; sh->opq[i]=tq3[i]; }
    sh->si[6]=no;
  }
  __syncthreads();
  int no=sh->si[6];
  int o=0;
  while(o<no){
    if(sh->opk[o]==0){
      int cnt=1;
      while(o+cnt<no && sh->opk[o+cnt]==0 && cnt<4) ++cnt;
      int wid = tid>>6;
      if(wid<cnt) leaf_exec(sh->opf[o+wid], sh->opa[o+wid], sh->opq[o+wid], wantU, &lct[wid], sh, tid&63);
      __syncthreads();
      o += cnt;
    } else {
      lasd1_merge(sh->opf[o], sh->opa[o], sh->opb[o], sh->opq[o], wantU, (rl*)lct, sh, tid);
      ++o;
    }
  }
}

__device__ void dbdsdc_U(int n, int wantU, LeafCtx* lct, Sh* sh, int tid){
  rl* SUB = g_ws + O_SUB; rl* SVTB = g_ws + O_SVTB;
  for(int w=tid; w<LDV*LDV; w+=NT){
    int c=w/LDV, r2=w-c*LDV; rl v=(r2==c)?1.0:0.0;
    SVTB[w]=v;
    if(wantU) SUB[w]=v;
  }
  __syncthreads();
  if(n <= SML){
    if((tid>>6)==0) leaf_exec(0, n, 0, wantU, &lct[0], sh, tid&63);
    __syncthreads();
  } else run_dc(n, wantU, lct, sh, tid);
}

__device__ void dbdsdc_L(int n, int wantU, LeafCtx* lct, Sh* sh, int tid){
  if(tid==0){
    for(int i=0;i<n-1;++i){
      rl cs,snv,rv;
      dlartg(sh->d[i], sh->e[i], &cs,&snv,&rv);
      sh->d[i]=rv; sh->e[i]=snv*sh->d[i+1]; sh->d[i+1]=cs*sh->d[i+1];
      sh->rc[i]=cs; sh->rs[i]=snv;
    }
  }
  __syncthreads();
  dbdsdc_U(n, wantU, lct, sh, tid);
  if(wantU){
    rl* SUB = g_ws + O_SUB;
    for(int c=tid;c<n;c+=NT){
      size_t ci=(size_t)LDV*c;
      rl carry = SUB[(n-1)+ci];
      for(int k=n-2;k>=0;--k){
        rl a = SUB[k+ci];
        SUB[k+1+ci] = sh->rs[k]*a + sh->rc[k]*carry;
        carry = sh->rc[k]*a - sh->rs[k]*carry;
      }
      SUB[0+ci] = carry;
    }
  }
  __syncthreads();
}

// ======================================================================
// Bidiagonalization, 2 barriers / iteration (R2 structure)
// ======================================================================

__device__ __forceinline__ void gebd2_upper(rl* A, int ld, int m, int n, Sh* sh, int tid){
  const int lane = tid & 63;
  rl pend_scl = 0.0; int pend_ds = 0;   // pending row-(i-1) v-scale
  for(int i=0;i<n;++i){
    rl ps=0.0;
    for(int r=i+1+lane;r<m;r+=64){ rl vv=A[r+(size_t)ld*i]; ps+=vv*vv; }
    for(int off=32;off>0;off>>=1) ps += __shfl_xor(ps,off,64);
    rl alpha=A[i+(size_t)ld*i];
    rl xn=sqrt(ps);
    rl beta,tau,scl; int ds;
    if(xn==0.0){ tau=0.0; beta=alpha; scl=0.0; ds=0; }
    else{ beta=-d_sign(dlapy2(alpha,xn),alpha); tau=(beta-alpha)/beta; scl=1.0/(alpha-beta); ds=1; }
    if(tid==0){ sh->d[i]=beta; sh->tq[i]=tau; }
    if(tau!=0.0)
      app_left_s(A, ld, i, m, i+1, n, A+(size_t)ld*i, scl, tau, tid);
    if(pend_ds && tid>=128){
      int c = i+1 + (tid-128);
      if(c < n) A[(i-1)+(size_t)ld*c] *= pend_scl;
    }
    __syncthreads();
    if(i<n-1){
      rl ps2=0.0;
      for(int c=i+2+lane;c<n;c+=64){ rl vv=A[i+(size_t)ld*c]; ps2+=vv*vv; }
      for(int off=32;off>0;off>>=1) ps2 += __shfl_xor(ps2,off,64);
      rl alpha2=A[i+(size_t)ld*(i+1)];
      rl xn2=sqrt(ps2);
      rl beta2,tau2,scl2; int ds2;
      if(xn2==0.0){ tau2=0.0; beta2=alpha2; scl2=0.0; ds2=0; }
      else{ beta2=-d_sign(dlapy2(alpha2,xn2),alpha2); tau2=(beta2-alpha2)/beta2; scl2=1.0/(alpha2-beta2); ds2=1; }
      if(tid==0){ sh->e[i]=beta2; sh->tp[i]=tau2; }
      if(tau2!=0.0)
        app_right_s(A, ld, i+1, m, i+1, n, A+i, ld, scl2, tau2, tid);
      if(ds && tid>=128){
        int r = i+1 + (tid-128);
        if(r < m) A[r+(size_t)ld*i] *= scl;
      }
      pend_ds = ds2; pend_scl = scl2;
      __syncthreads();
    } else {
      if(tid==0) sh->tp[i]=0.0;
      __syncthreads();
      if(ds) for(int r=i+1+tid; r<m; r+=NT) A[r+(size_t)ld*(n-1)] *= scl;
      __syncthreads();
    }
  }
}

__device__ __forceinline__ void gebd2_lower(rl* A, int ld, int m, int n, Sh* sh, int tid){
  const int lane = tid & 63;
  rl pend_scl = 0.0; int pend_ds = 0;
  int last_ds = 0; rl last_scl = 0.0;
  for(int i=0;i<m;++i){
    rl ps=0.0;
    for(int c=i+1+lane;c<n;c+=64){ rl vv=A[i+(size_t)ld*c]; ps+=vv*vv; }
    for(int off=32;off>0;off>>=1) ps += __shfl_xor(ps,off,64);
    rl alpha=A[i+(size_t)ld*i];
    rl xn=sqrt(ps);
    rl beta,tau,scl; int ds;
    if(xn==0.0){ tau=0.0; beta=alpha; scl=0.0; ds=0; }
    else{ beta=-d_sign(dlapy2(alpha,xn),alpha); tau=(beta-alpha)/beta; scl=1.0/(alpha-beta); ds=1; }
    if(tid==0){ sh->d[i]=beta; sh->tp[i]=tau; }
    if(tau!=0.0)
      app_right_s(A, ld, i+1, m, i, n, A+i, ld, scl, tau, tid);
    if(pend_ds && tid>=128){
      int r = i+1 + (tid-128);
      if(r < m) A[r+(size_t)ld*(i-1)] *= pend_scl;
    }
    __syncthreads();
    if(i<m-1){
      rl ps2=0.0;
      for(int r=i+2+lane;r<m;r+=64){ rl vv=A[r+(size_t)ld*i]; ps2+=vv*vv; }
      for(int off=32;off>0;off>>=1) ps2 += __shfl_xor(ps2,off,64);
      rl alpha2=A[(i+1)+(size_t)ld*i];
      rl xn2=sqrt(ps2);
      rl beta2,tau2,scl2; int ds2;
      if(xn2==0.0){ tau2=0.0; beta2=alpha2; scl2=0.0; ds2=0; }
      else{ beta2=-d_sign(dlapy2(alpha2,xn2),alpha2); tau2=(beta2-alpha2)/beta2; scl2=1.0/(alpha2-beta2); ds2=1; }
      if(tid==0){ sh->e[i]=beta2; sh->tq[i]=tau2; }
      if(tau2!=0.0)
        app_left_s(A, ld, i+1, m, i+1, n, A+(size_t)ld*i, scl2, tau2, tid);
      if(ds && tid>=128){
        int c = i+1 + (tid-128);
        if(c < n) A[i+(size_t)ld*c] *= scl;
      }
      pend_ds = ds2; pend_scl = scl2;
      __syncthreads();
    } else {
      last_ds = ds; last_scl = scl;
      __syncthreads();
      if(last_ds) for(int c=i+1+tid; c<n; c+=NT) A[(m-1)+(size_t)ld*c] *= last_scl;
      __syncthreads();
    }
  }
}

__device__ __forceinline__ void gelq2(rl* A, int ld, int m, int n, Sh* sh, int tid){
  const int lane = tid & 63;
  rl pend_scl=0.0, pend_beta=0.0; int pend_ds=0;
  for(int i=0;i<m;++i){
    rl ps=0.0;
    for(int c=i+1+lane;c<n;c+=64){ rl vv=A[i+(size_t)ld*c]; ps+=vv*vv; }
    for(int off=32;off>0;off>>=1) ps += __shfl_xor(ps,off,64);
    rl alpha=A[i+(size_t)ld*i];
    rl xn=sqrt(ps);
    rl beta,tau,scl; int ds;
    if(xn==0.0){ tau=0.0; beta=alpha; scl=0.0; ds=0; }
    else{ beta=-d_sign(dlapy2(alpha,xn),alpha); tau=(beta-alpha)/beta; scl=1.0/(alpha-beta); ds=1; }
    if(tid==0) sh->rs[i]=tau;
    if(i<m-1 && tau!=0.0)
      app_right_s(A, ld, i+1, m, i, n, A+i, ld, scl, tau, tid);
    if(i>0 && tid>=128){
      if(pend_ds){ int c = i + (tid-128); if(c<n) A[(i-1)+(size_t)ld*c] *= pend_scl; }
      if(tid==128) A[(i-1)+(size_t)ld*(i-1)] = pend_beta;
    }
    pend_ds=ds; pend_scl=scl; pend_beta=beta;
    __syncthreads();
  }
  if(tid>=128){
    if(pend_ds){ int c = m + (tid-128); if(c<n) A[(m-1)+(size_t)ld*c] *= pend_scl; }
    if(tid==128) A[(m-1)+(size_t)ld*(m-1)] = pend_beta;
  }
  __syncthreads();
}

// ---- per-shape drivers (MBL = LDS working matrix, pitch PB) ----
__device__ void svd_tall(int wantU, int wantVT, rl* MBL, LeafCtx* lct, Sh* sh, int tid){ // 128 x 71
  rl* MA=g_ws+O_MA; rl* MU=g_ws+O_MU; rl* MVT=g_ws+O_MVT;
  rl* SUB=g_ws+O_SUB; rl* SVTB=g_ws+O_SVTB;
  for(int w=tid;w<128*NSV;w+=NT){ int c=w>>7, r2=w&127; MBL[r2+(size_t)PB*c]=MA[r2+(size_t)LDA*c]; }
  __syncthreads();
  gebd2_upper(MBL, PB, 128, NSV, sh, tid);
  dbdsdc_U(NSV, wantU, lct, sh, tid);
  if(wantU){
    for(int w=tid;w<128*NSV;w+=NT){ int c=w>>7, r2=w&127; MU[r2+(size_t)LDA*c]=(r2<NSV)? SUB[r2+(size_t)LDV*c]:0.0; }
    __syncthreads();
    if(tid<NSV){
      int c=tid;
      rl* colb = MU + (size_t)LDA*c;
      for(int i=NSV-1;i>=0;--i){
        rl tau=sh->tq[i];
        if(tau!=0.0) row_apply(colb+i, 1, MBL + (size_t)PB*i + i + 1, 1, 128-i-1, tau);
      }
    }
    __syncthreads();
  }
  if(wantVT){
    for(int w=tid;w<LDV*NSV;w+=NT) MVT[w]=SVTB[w];
    __syncthreads();
    if(tid<NSV){
      int r=tid;
      for(int i=NSV-2;i>=0;--i){
        rl tau=sh->tp[i];
        if(tau!=0.0) row_apply(MVT + r + (size_t)LDV*(i+1), LDV, MBL + i + (size_t)PB*(i+2), PB, NSV-i-2, tau);
      }
    }
    __syncthreads();
  }
}
__device__ void svd_mid(rl* MBL, LeafCtx* lct, Sh* sh, int tid){ // 64 x 71, wantU=0, wantVT=1
  rl* MA=g_ws+O_MA; rl* MVT=g_ws+O_MVT;
  rl* SVTB=g_ws+O_SVTB;
  for(int w=tid;w<64*NSV;w+=NT){ int c=w>>6, r2=w&63; MBL[r2+(size_t)PB*c]=MA[r2+(size_t)LDA*c]; }
  __syncthreads();
  gebd2_lower(MBL, PB, 64, NSV, sh, tid);
  dbdsdc_L(64, 0, lct, sh, tid);
  for(int w=tid;w<64*NSV;w+=NT){ int c=w>>6, r2=w&63; MVT[r2+(size_t)LDV*c]=(c<64)? SVTB[r2+(size_t)LDV*c]:0.0; }
  __syncthreads();
  if(tid<64){
    int r=tid;
    for(int i=63;i>=0;--i){
      rl tau=sh->tp[i];
      if(tau!=0.0) row_apply(MVT + r + (size_t)LDV*i, LDV, MBL + i + (size_t)PB*(i+1), PB, NSV-i-1, tau);
    }
  }
  __syncthreads();
}
__device__ void svd_wide(int m, rl* MBL, LeafCtx* lct, Sh* sh, int tid){ // m x 71, m in {2,4,8,16,32}; wantU=0, wantVT=1
  rl* MA=g_ws+O_MA; rl* MQ=g_ws+O_MQ; rl* MVT=g_ws+O_MVT;
  rl* SVTB=g_ws+O_SVTB; rl* TB=g_ws+O_TB; rl* VT2=g_ws+O_VT2;
  for(int w=tid;w<m*NSV;w+=NT){ int c=w/m, r2=w-c*m; MBL[r2+(size_t)PB*c]=MA[r2+(size_t)LDA*c]; }
  __syncthreads();
  gelq2(MBL, PB, m, NSV, sh, tid);
  for(int w=tid;w<m*NSV;w+=NT){ int c=w/m, r2=w-c*m; MQ[r2+(size_t)LDA*c]=(r2==c)?1.0:0.0; }
  __syncthreads();
  if(tid<m){
    int r=tid;
    for(int j=m-1;j>=0;--j){
      rl tau=sh->rs[j];
      if(tau!=0.0) row_apply(MQ + r + (size_t)LDA*j, LDA, MBL + j + (size_t)PB*(j+1), PB, NSV-j-1, tau);
    }
  }
  __syncthreads();
  for(int w=tid;w<m*m;w+=NT){ int c=w/m, r2=w-c*m; TB[r2+(size_t)LDV*c]=(r2>=c)? MBL[r2+(size_t)PB*c]:0.0; }
  __syncthreads();
  gebd2_upper(TB, LDV, m, m, sh, tid);
  dbdsdc_U(m, 0, lct, sh, tid);
  for(int w=tid;w<m*m;w+=NT){ int c=w/m, r2=w-c*m; VT2[r2+(size_t)LDV*c]=SVTB[r2+(size_t)LDV*c]; }
  __syncthreads();
  if(tid<m){
    int r=tid;
    for(int i=m-2;i>=0;--i){
      rl tau=sh->tp[i];
      if(tau!=0.0) row_apply(VT2 + r + (size_t)LDV*(i+1), LDV, TB + i + (size_t)LDV*(i+2), LDV, m-i-2, tau);
    }
  }
  __syncthreads();
  for(int w=tid;w<m*NSV;w+=NT){
    int c=w/m, r2=w-c*m;
    const rl* vrow = VT2 + r2;
    const rl* qcol = MQ + (size_t)LDA*c;
    rl s=0.0; int t=0;
    for(; t+16<=m; t+=16){
      rl a[16], b[16];
      #pragma unroll
      for(int u=0;u<16;++u){ a[u]=vrow[(size_t)LDV*(size_t)(t+u)]; b[u]=qcol[t+u]; }
      #pragma unroll
      for(int u=0;u<16;++u) s += a[u]*b[u];
    }
    for(; t+4<=m; t+=4){
      rl a0=vrow[(size_t)LDV*t], a1=vrow[(size_t)LDV*(t+1)], a2=vrow[(size_t)LDV*(t+2)], a3=vrow[(size_t)LDV*(t+3)];
      rl b0=qcol[t], b1=qcol[t+1], b2=qcol[t+2], b3=qcol[t+3];
      s+=a0*b0; s+=a1*b1; s+=a2*b2; s+=a3*b3;
    }
    for(; t<m; ++t) s += vrow[(size_t)LDV*t]*qcol[t];
    MVT[r2+(size_t)LDV*c]=s;
  }
  __syncthreads();
}

// ---- main kernel ----
__global__ __launch_bounds__(NT)
void mps_kernel(const float* __restrict__ ch, const float* __restrict__ ci,
                const float* __restrict__ ictx, const int* __restrict__ tok)
{
  __shared__ Sh sh;
  __shared__ LeafCtx lct[4];
  extern __shared__ rl MBL[];   // PB*NSV doubles (73272 B dynamic LDS)
  int tid = threadIdx.x;
  rl* MA = g_ws + O_MA; rl* MU = g_ws + O_MU; rl* MVT = g_ws + O_MVT;
  int kprev = 0;
  for(int s=0;s<9;++s){
    if(tid==0){
      rl W00=ch[s*4+0], W01=ch[s*4+1], W10=ch[s*4+2], W11=ch[s*4+3];
      rl P00=1,P01=0,P10=0,P11=1;
      for(int mexp=0;mexp<=70;++mexp){
        int j=70-mexp;
        rl v0,v1;
        if(j==0){ v0=ictx[s*2+0]; v1=ictx[s*2+1]; }
        else{
          int b=(tok[j-1]>>(15-s))&1;
          v0=ci[s*4+b]; v1=ci[s*4+2+b];
        }
        g_ws[O_COLS + 0 + 2*j] = P00*v0+P01*v1;
        g_ws[O_COLS + 1 + 2*j] = P10*v0+P11*v1;
        rl n00=W00*P00+W01*P10, n01=W00*P01+W01*P11;
        rl n10=W10*P00+W11*P10, n11=W10*P01+W11*P11;
        P00=n00;P01=n01;P10=n10;P11=n11;
      }
    }
    __syncthreads();
    int m = (s==0)?2:2*kprev;
    for(int w=tid; w<m*NSV; w+=NT){
      int j=w/m, r2=w-j*m;
      int l=r2>>1, dd2=r2&1;
      rl cv = g_ws[O_COLS + dd2 + 2*j];
      MA[r2+(size_t)LDA*j] = (s==0)? cv : g_ws[O_CAR + l + 64*j]*cv;
    }
    __syncthreads();
    int wantU = (s==8)?1:0;
    if(m==128) svd_tall(wantU, wantU?0:1, MBL, lct, &sh, tid);
    else if(m==64) svd_mid(MBL, lct, &sh, tid);
    else svd_wide(m, MBL, lct, &sh, tid);
    int k = min(64, min(m, NSV));
    __syncthreads();
    if(s<8){
      for(int w=tid; w<k*NSV; w+=NT){
        int j=w/k, l=w-j*k;
        g_ws[O_CAR + l + 64*j] = sh.d[l]*MVT[l+(size_t)LDV*j];
      }
    }
    __syncthreads();
    if(s==8){
      if(tid==0){
        rl W00=ch[8*4+0], W01=ch[8*4+1], W10=ch[8*4+2], W11=ch[8*4+3];
        rl P00=1,P01=0,P10=0,P11=1;
        for(int it=0;it<30;++it){
          rl n00=W00*P00+W01*P10, n01=W00*P01+W01*P11;
          rl n10=W10*P00+W11*P10, n11=W10*P01+W11*P11;
          P00=n00;P01=n01;P10=n10;P11=n11;
        }
        sh.sc[0]=P00+P10; sh.sc[1]=P01+P11;
      }
      __syncthreads();
      for(int r2=tid; r2<64; r2+=NT){
        rl acc=0.0;
        for(int l=0;l<64;++l)
          acc += sh.sc[0]*MU[(2*l)+(size_t)LDA*r2] + sh.sc[1]*MU[(2*l+1)+(size_t)LDA*r2];
        g_ws[O_VEC + r2] = acc/188.0;
      }
    }
    kprev = k;
    __syncthreads();
  }
}

__global__ __launch_bounds__(NT)
void head_kernel(const float* __restrict__ hw, const float* __restrict__ hb,
                 float* __restrict__ out)
{
  __shared__ float v[64];
  int tid=threadIdx.x;
  if(tid<64) v[tid]=(float)g_ws[O_VEC + tid];
  __syncthreads();
  int i = blockIdx.x*NT + tid;
  if(i<VOCAB){
    const float4* row = (const float4*)(hw + (size_t)i*64);
    float acc=0.f;
    #pragma unroll
    for(int c4=0;c4<16;++c4){
      float4 r4=row[c4];
      acc += r4.x*v[4*c4] + r4.y*v[4*c4+1] + r4.z*v[4*c4+2] + r4.w*v[4*c4+3];
    }
    out[i]=acc+hb[i];
  }
}

extern "C" void kernel_launch(void* const* d_in, const int* in_sizes, int n_in,
                              void* d_out, int out_size, void* d_ws, size_t ws_size,
                              hipStream_t stream)
{
  const float* ch  = (const float*)d_in[0];
  const float* ci  = (const float*)d_in[1];
  const float* hw  = (const float*)d_in[2];
  const float* hb  = (const float*)d_in[3];
  const float* ict = (const float*)d_in[4];
  const int*   tk  = (const int*)d_in[5];
  (void)d_ws; (void)ws_size; (void)in_sizes; (void)n_in; (void)out_size;

  size_t dynls = (size_t)PB*NSV*sizeof(double);   // 73272 B
  hipLaunchKernelGGL(mps_kernel, dim3(1), dim3(NT), dynls, stream, ch, ci, ict, tk);
  hipLaunchKernelGGL(head_kernel, dim3((VOCAB+NT-1)/NT), dim3(NT), 0, stream,
                     hw, hb, (float*)d_out);
}

// Round 5
// 8969.373 us; speedup vs baseline: 1.3055x; 1.0046x over previous
//
#include <hip/hip_runtime.h>

typedef double rl;
#define NT 256
#define NSV 71
#define LDA 128
#define LDV 72
#define SML 25
#define VOCAB 128000
#define LP 27   // LDS leaf pitch
#define PB 129  // LDS pitch for bidiag working matrix

// fp32 LAPACK constants (reference is numpy sgesdd in float32)
#define EPS32 1.1920928955078125e-7
#define UNFL32 1.17549435e-38

// g_ws offsets (doubles)
#define O_CAR   0
#define O_COLS  4608
#define O_VEC   4800
#define O_MA    5120
#define O_MBLG  14208   // MBL dump: PB*NSV=9159 doubles (gap before O_MU)
#define O_MU    23552
#define O_MQ    32768
#define O_MVT   41984
#define O_SUB   47168
#define O_SVTB  52352
#define O_U2    57536
#define O_VT2   62720
#define O_QU    67904
#define O_QV    73088
#define O_TB    78272
#define O_D     83456   // cross-kernel scalars (72 each)
#define O_E     83528
#define O_TQ    83600
#define O_TP    83672

__device__ double g_ws[84000];

struct LeafCtx {
  rl LVT[26*LP], LU[26*LP];
  rl b1[26], b2[26], b3[26], b4[26];
  rl sc[6];
  int ia[26], ib[26], ic[26];
  int si[12];
};

struct Sh {
  rl d[72], e[72], tq[72], tp[72], rc[72], rs[72];
  rl dsig[72], zz[72], zh[72], sigm[72], vals[72];
  rl ta[72], tb[72];
  int srcU[72], srcVT[72], perm[72];
  int ia[72], ib[72], ic[72];
  int opk[12], opf[12], opa[12], opb[12], opq[12];
  rl sc[8];
  int si[16];
};

__device__ __forceinline__ void wsync(){
  asm volatile("s_waitcnt vmcnt(0) lgkmcnt(0)" ::: "memory");
}

__device__ __forceinline__ rl d_sign(rl a, rl b){ return (b >= 0.0) ? fabs(a) : -fabs(a); }
__device__ __forceinline__ rl dlapy2(rl x, rl y){
  rl ax=fabs(x), ay=fabs(y);
  rl w = ax>ay?ax:ay, z = ax>ay?ay:ax;
  if(z==0.0) return w;
  rl t = z/w; return w*sqrt(1.0+t*t);
}
__device__ void dlartg(rl f, rl g, rl* cs, rl* sn, rl* r){
  if(g==0.0){ *cs=1.0; *sn=0.0; *r=f; }
  else if(f==0.0){ *cs=0.0; *sn=d_sign(1.0,g); *r=fabs(g); }
  else{
    rl dd = sqrt(f*f+g*g);
    *cs = fabs(f)/dd;
    *r  = d_sign(dd, f);
    *sn = g/(*r);
  }
}

__device__ void dlas2(rl f, rl g, rl h, rl* ssmin, rl* ssmax){
  rl fa=fabs(f), ga=fabs(g), ha=fabs(h);
  rl fhmn=fmin(fa,ha), fhmx=fmax(fa,ha);
  if(fhmn==0.0){
    *ssmin=0.0;
    if(fhmx==0.0) *ssmax=ga;
    else { rl mx=fmax(fhmx,ga), mn=fmin(fhmx,ga); rl q=mn/mx; *ssmax=mx*sqrt(1.0+q*q); }
  } else {
    if(ga < fhmx){
      rl as=1.0+fhmn/fhmx, at=(fhmx-fhmn)/fhmx;
      rl au=(ga/fhmx); au=au*au;
      rl c=2.0/(sqrt(as*as+au)+sqrt(at*at+au));
      *ssmin=fhmn*c; *ssmax=fhmx/c;
    } else {
      rl au=fhmx/ga;
      if(au==0.0){ *ssmin=(fhmn*fhmx)/ga; *ssmax=ga; }
      else{
        rl as=1.0+fhmn/fhmx, at=(fhmx-fhmn)/fhmx;
        rl c=1.0/(sqrt(1.0+(as*au)*(as*au))+sqrt(1.0+(at*au)*(at*au)));
        *ssmin=(fhmn*c)*au; *ssmin=*ssmin+*ssmin;
        *ssmax=ga/(c+c);
      }
    }
  }
}

__device__ void dlasv2(rl f, rl g, rl h, rl* ssmin, rl* ssmax, rl* snr, rl* csr, rl* snl, rl* csl){
  rl ft=f, fa=fabs(f), ht=h, ha=fabs(h);
  int pmax=1;
  bool swp = (ha > fa);
  if(swp){ pmax=3; rl t=ft; ft=ht; ht=t; t=fa; fa=ha; ha=t; }
  rl gt=g, ga=fabs(g);
  rl clt=0, crt=0, slt=0, srt=0;
  if(ga==0.0){ *ssmin=ha; *ssmax=fa; clt=1.0; crt=1.0; slt=0.0; srt=0.0; }
  else{
    bool gasmal=true;
    if(ga > fa){
      pmax=2;
      if((fa/ga) < EPS32){
        gasmal=false;
        *ssmax=ga;
        if(ha>1.0) *ssmin=fa/(ga/ha); else *ssmin=(fa/ga)*ha;
        clt=1.0; slt=ht/gt; srt=1.0; crt=ft/gt;
      }
    }
    if(gasmal){
      rl dd=fa-ha;
      rl lv = (dd==fa) ? 1.0 : dd/fa;
      rl mq = gt/ft;
      rl tv = 2.0-lv;
      rl mm = mq*mq, tt = tv*tv;
      rl sv = sqrt(tt+mm);
      rl rv = (lv==0.0) ? fabs(mq) : sqrt(lv*lv+mm);
      rl a = 0.5*(sv+rv);
      *ssmin = ha/a; *ssmax = fa*a;
      rl t3;
      if(mm==0.0){
        if(lv==0.0) t3 = d_sign(2.0, ft)*d_sign(1.0, gt);
        else t3 = gt/d_sign(dd, ft) + mq/tv;
      } else {
        t3 = (mq/(sv+tv) + mq/(rv+lv))*(1.0+a);
      }
      rl l2 = sqrt(t3*t3+4.0);
      crt = 2.0/l2; srt = t3/l2;
      clt = (crt + srt*mq)/a;
      slt = (ht/ft)*srt/a;
    }
  }
  if(swp){ *csl=srt; *snl=crt; *csr=slt; *snr=clt; }
  else  { *csl=clt; *snl=slt; *csr=crt; *snr=srt; }
  rl tsign=1.0;
  if(pmax==1) tsign = d_sign(1.0,*csr)*d_sign(1.0,*csl)*d_sign(1.0,f);
  if(pmax==2) tsign = d_sign(1.0,*snr)*d_sign(1.0,*csl)*d_sign(1.0,g);
  if(pmax==3) tsign = d_sign(1.0,*snr)*d_sign(1.0,*snl)*d_sign(1.0,h);
  *ssmax = d_sign(*ssmax, tsign);
  *ssmin = d_sign(*ssmin, tsign*d_sign(1.0,f)*d_sign(1.0,h));
}

// Thread-local Householder apply (16-wide grouped loads, sequential adds).
__device__ __forceinline__ void row_apply(rl* row, size_t ld, const rl* v, size_t vs, int len, rl tau){
  rl s = row[0];
  int i=0;
  for(; i+16<=len; i+=16){
    rl a[16], b[16];
    #pragma unroll
    for(int u=0;u<16;++u){ a[u]=row[ld*(size_t)(1+i+u)]; b[u]=v[vs*(size_t)(i+u)]; }
    #pragma unroll
    for(int u=0;u<16;++u) s += a[u]*b[u];
  }
  for(; i<len; ++i) s += row[ld*(size_t)(1+i)]*v[vs*(size_t)i];
  rl w = s*tau;
  row[0] -= w;
  i=0;
  for(; i+16<=len; i+=16){
    rl b[16];
    #pragma unroll
    for(int u=0;u<16;++u) b[u]=v[vs*(size_t)(i+u)];
    #pragma unroll
    for(int u=0;u<16;++u) row[ld*(size_t)(1+i+u)] -= w*b[u];
  }
  for(; i<len; ++i) row[ld*(size_t)(1+i)] -= w*v[vs*(size_t)i];
}

__device__ __forceinline__ void app_left_s(rl* A, int ld, int r0, int m, int c0, int n, const rl* vbase, rl scl, rl tau, int tid){
  const int len = m - r0 - 1;
  const rl* v = vbase + r0 + 1;
  int c = c0 + tid;
  if(c < n){
    rl* col = A + (size_t)ld*c + r0;
    rl s = col[0];
    int i=0;
    for(; i+16<=len; i+=16){
      rl a[16], b[16];
      #pragma unroll
      for(int u=0;u<16;++u){ a[u]=col[1+i+u]; b[u]=v[i+u]*scl; }
      #pragma unroll
      for(int u=0;u<16;++u) s += a[u]*b[u];
    }
    for(; i<len; ++i) s += col[1+i]*(v[i]*scl);
    rl w = s*tau;
    col[0] -= w;
    i=0;
    for(; i+16<=len; i+=16){
      rl b[16];
      #pragma unroll
      for(int u=0;u<16;++u) b[u]=v[i+u]*scl;
      #pragma unroll
      for(int u=0;u<16;++u) col[1+i+u] -= w*b[u];
    }
    for(; i<len; ++i) col[1+i] -= w*(v[i]*scl);
  }
}
__device__ __forceinline__ void app_right_s(rl* A, int ld, int r0, int m, int c0, int n, const rl* vbase, int vstride, rl scl, rl tau, int tid){
  const int len = n - c0 - 1;
  const rl* v = vbase + (size_t)vstride*(c0+1);
  int r = r0 + tid;
  if(r < m){
    rl* row = A + r + (size_t)ld*c0;
    rl s = row[0];
    int i=0;
    for(; i+16<=len; i+=16){
      rl a[16], b[16];
      #pragma unroll
      for(int u=0;u<16;++u){ a[u]=row[(size_t)ld*(size_t)(1+i+u)]; b[u]=v[(size_t)vstride*(size_t)(i+u)]*scl; }
      #pragma unroll
      for(int u=0;u<16;++u) s += a[u]*b[u];
    }
    for(; i<len; ++i) s += row[(size_t)ld*(1+i)]*(v[(size_t)vstride*i]*scl);
    rl w = s*tau;
    row[0] -= w;
    i=0;
    for(; i+16<=len; i+=16){
      rl b[16];
      #pragma unroll
      for(int u=0;u<16;++u) b[u]=v[(size_t)vstride*(size_t)(i+u)]*scl;
      #pragma unroll
      for(int u=0;u<16;++u) row[(size_t)ld*(size_t)(1+i+u)] -= w*b[u];
    }
    for(; i<len; ++i) row[(size_t)ld*(1+i)] -= w*(v[(size_t)vstride*i]*scl);
  }
}

// ---- wave-scoped dbdsqr on a private LDS leaf block ----
__device__ void bdsqr_wave(int n, rl* d, rl* e, int ncvt, int nru, LeafCtx* lc, int lane){
  if(n>1){
    rl eps=EPS32, unfl=UNFL32;
    rl tolmul=fmax(10.0,fmin(100.0,pow(eps,-0.125)));
    rl tol=tolmul*eps;
    rl thresh=0.0;
    int mm=n-1, oldll=-2, oldm=-2, idir=0, iter=0, maxit=6*n*n;
    if(lane==0){
      rl sminoa=fabs(d[0]);
      if(sminoa!=0.0){
        rl mu=sminoa;
        for(int i=1;i<n;++i){ mu=fabs(d[i])*(mu/(mu+fabs(e[i-1]))); sminoa=fmin(sminoa,mu); if(sminoa==0.0)break; }
      }
      sminoa=sminoa/sqrt((rl)n);
      thresh=fmax(tol*sminoa,(rl)(6*n*n)*unfl);
    }
    while(true){
      if(lane==0){
        int act=0, p_lo=0, p_cnt=0, p_fwd=1, p_mm=0;
        while(mm>0){
          if(iter>maxit) break;
          rl smax=fabs(d[mm]), smin=smax;
          int ll=-1;
          for(int lll=mm-1;lll>=0;--lll){
            rl abss=fabs(d[lll]), abse=fabs(e[lll]);
            if(abse<=thresh){ ll=lll; break; }
            smin=fmin(smin,abss);
            smax=fmax(smax,fmax(abss,abse));
          }
          if(ll==mm-1){ e[ll]=0.0; mm=mm-1; continue; }
          if(ll>=0) e[ll]=0.0;
          int lo=ll+1;
          if(mm==lo+1){
            rl sigmn,sigmx,sinr,cosr,sinl,cosl;
            dlasv2(d[lo],e[lo],d[mm],&sigmn,&sigmx,&sinr,&cosr,&sinl,&cosl);
            d[lo]=sigmx; d[mm]=sigmn; e[lo]=0.0;
            lc->sc[0]=cosr; lc->sc[1]=sinr; lc->sc[2]=cosl; lc->sc[3]=sinl;
            act=2; p_lo=lo; p_mm=mm;
            mm-=2;
            break;
          }
          if(lo>oldm || mm<oldll) idir=(fabs(d[lo])>=fabs(d[mm]))?1:2;
          rl sminl=0.0; int conv=0;
          if(idir==1){
            if(fabs(e[mm-1])<=tol*fabs(d[mm])){ e[mm-1]=0.0; conv=1; }
            if(!conv){
              rl mu=fabs(d[lo]); sminl=mu;
              for(int lll=lo;lll<mm;++lll){
                if(fabs(e[lll])<=tol*mu){ e[lll]=0.0; conv=1; break; }
                mu=fabs(d[lll+1])*(mu/(mu+fabs(e[lll])));
                sminl=fmin(sminl,mu);
              }
            }
          } else {
            if(fabs(e[lo])<=tol*fabs(d[lo])){ e[lo]=0.0; conv=1; }
            if(!conv){
              rl mu=fabs(d[mm]); sminl=mu;
              for(int lll=mm-1;lll>=lo;--lll){
                if(fabs(e[lll])<=tol*mu){ e[lll]=0.0; conv=1; break; }
                mu=fabs(d[lll])*(mu/(mu+fabs(e[lll])));
                sminl=fmin(sminl,mu);
              }
            }
          }
          if(conv) continue;
          oldll=lo; oldm=mm;
          rl shift=0.0, rr_;
          if(!((rl)n*tol*(sminl/smax) <= fmax(eps, 0.01*tol))){
            rl sll;
            if(idir==1){ sll=fabs(d[lo]); dlas2(d[mm-1],e[mm-1],d[mm],&shift,&rr_); }
            else { sll=fabs(d[mm]); dlas2(d[lo],e[lo],d[lo+1],&shift,&rr_); }
            if(sll>0.0){ rl q=shift/sll; if(q*q<eps) shift=0.0; }
          }
          iter += mm-lo;
          int cnt=mm-lo;
          if(shift==0.0){
            if(idir==1){
              rl cs=1.0, oldcs=1.0, sn=0.0, oldsn=0.0, r;
              for(int i=lo;i<mm;++i){
                dlartg(d[i]*cs,e[i],&cs,&sn,&r);
                if(i>lo) e[i-1]=oldsn*r;
                dlartg(oldcs*r, d[i+1]*sn, &oldcs,&oldsn,&d[i]);
                lc->b1[i-lo]=cs; lc->b2[i-lo]=sn; lc->b3[i-lo]=oldcs; lc->b4[i-lo]=oldsn;
              }
              rl h=d[mm]*cs; d[mm]=h*oldcs; e[mm-1]=h*oldsn;
              p_fwd=1;
              if(fabs(e[mm-1])<=thresh) e[mm-1]=0.0;
            } else {
              rl cs=1.0, oldcs=1.0, sn=0.0, oldsn=0.0, r;
              for(int i=mm;i>lo;--i){
                dlartg(d[i]*cs,e[i-1],&cs,&sn,&r);
                if(i<mm) e[i]=oldsn*r;
                dlartg(oldcs*r,d[i-1]*sn,&oldcs,&oldsn,&d[i]);
                int j=i-lo-1;
                lc->b1[j]=oldcs; lc->b2[j]=-oldsn; lc->b3[j]=cs; lc->b4[j]=-sn;
              }
              rl h=d[lo]*cs; d[lo]=h*oldcs; e[lo]=h*oldsn;
              p_fwd=0;
              if(fabs(e[lo])<=thresh) e[lo]=0.0;
            }
          } else {
            if(idir==1){
              rl f2=(fabs(d[lo])-shift)*(d_sign(1.0,d[lo])+shift/d[lo]);
              rl g2=e[lo], r, cosr,sinr,cosl,sinl;
              for(int i=lo;i<mm;++i){
                dlartg(f2,g2,&cosr,&sinr,&r);
                if(i>lo) e[i-1]=r;
                f2=cosr*d[i]+sinr*e[i];
                e[i]=cosr*e[i]-sinr*d[i];
                g2=sinr*d[i+1];
                d[i+1]=cosr*d[i+1];
                dlartg(f2,g2,&cosl,&sinl,&r);
                d[i]=r;
                f2=cosl*e[i]+sinl*d[i+1];
                d[i+1]=cosl*d[i+1]-sinl*e[i];
                if(i<mm-1){ g2=sinl*e[i+1]; e[i+1]=cosl*e[i+1]; }
                lc->b1[i-lo]=cosr; lc->b2[i-lo]=sinr; lc->b3[i-lo]=cosl; lc->b4[i-lo]=sinl;
              }
              e[mm-1]=f2;
              p_fwd=1;
              if(fabs(e[mm-1])<=thresh) e[mm-1]=0.0;
            } else {
              rl f2=(fabs(d[mm])-shift)*(d_sign(1.0,d[mm])+shift/d[mm]);
              rl g2=e[mm-1], r, cosr,sinr,cosl,sinl;
              for(int i=mm;i>lo;--i){
                dlartg(f2,g2,&cosr,&sinr,&r);
                if(i<mm) e[i]=r;
                f2=cosr*d[i]+sinr*e[i-1];
                e[i-1]=cosr*e[i-1]-sinr*d[i];
                g2=sinr*d[i-1];
                d[i-1]=cosr*d[i-1];
                dlartg(f2,g2,&cosl,&sinl,&r);
                d[i]=r;
                f2=cosl*e[i-1]+sinl*d[i-1];
                d[i-1]=cosl*d[i-1]-sinl*e[i-1];
                if(i>lo+1){ g2=sinl*e[i-2]; e[i-2]=cosl*e[i-2]; }
                int j=i-lo-1;
                lc->b1[j]=cosl; lc->b2[j]=-sinl; lc->b3[j]=cosr; lc->b4[j]=-sinr;
              }
              e[lo]=f2;
              p_fwd=0;
              if(fabs(e[lo])<=thresh) e[lo]=0.0;
            }
          }
          act=1; p_lo=lo; p_cnt=cnt;
          break;
        }
        lc->si[7]=act; lc->si[8]=p_lo; lc->si[9]=p_cnt; lc->si[10]=p_fwd; lc->si[11]=p_mm;
      }
      wsync();
      int act=lc->si[7];
      if(act==0) break;
      if(act==1){
        int lo=lc->si[8], cnt=lc->si[9], fwd=lc->si[10];
        if(lane<ncvt){
          int k=lane;
          if(fwd){
            rl cur = lc->LVT[lo*LP+k];
            for(int j=0;j<cnt;++j){
              rl c=lc->b1[j], s=lc->b2[j];
              rl t = lc->LVT[(lo+j+1)*LP+k];
              lc->LVT[(lo+j)*LP+k] = s*t + c*cur;
              cur = c*t - s*cur;
            }
            lc->LVT[(lo+cnt)*LP+k] = cur;
          } else {
            rl tcar = lc->LVT[(lo+cnt)*LP+k];
            for(int j=cnt-1;j>=0;--j){
              rl c=lc->b1[j], s=lc->b2[j];
              rl low = lc->LVT[(lo+j)*LP+k];
              lc->LVT[(lo+j+1)*LP+k] = c*tcar - s*low;
              tcar = s*tcar + c*low;
            }
            lc->LVT[lo*LP+k] = tcar;
          }
        } else if(lane<ncvt+nru){
          int r2=lane-ncvt;
          if(fwd){
            rl cur = lc->LU[r2*LP+lo];
            for(int j=0;j<cnt;++j){
              rl c=lc->b3[j], s=lc->b4[j];
              rl t = lc->LU[r2*LP+(lo+j+1)];
              lc->LU[r2*LP+(lo+j)] = s*t + c*cur;
              cur = c*t - s*cur;
            }
            lc->LU[r2*LP+(lo+cnt)] = cur;
          } else {
            rl tcar = lc->LU[r2*LP+(lo+cnt)];
            for(int j=cnt-1;j>=0;--j){
              rl c=lc->b3[j], s=lc->b4[j];
              rl low = lc->LU[r2*LP+(lo+j)];
              lc->LU[r2*LP+(lo+j+1)] = c*tcar - s*low;
              tcar = s*tcar + c*low;
            }
            lc->LU[r2*LP+lo] = tcar;
          }
        }
      } else {
        int lo=lc->si[8], m2=lc->si[11];
        rl cosr=lc->sc[0], sinr=lc->sc[1], cosl=lc->sc[2], sinl=lc->sc[3];
        if(lane<ncvt){
          rl x=lc->LVT[lo*LP+lane], y=lc->LVT[m2*LP+lane];
          lc->LVT[lo*LP+lane]=cosr*x+sinr*y; lc->LVT[m2*LP+lane]=cosr*y-sinr*x;
        } else if(lane<ncvt+nru){
          int r2=lane-ncvt;
          rl x=lc->LU[r2*LP+lo], y=lc->LU[r2*LP+m2];
          lc->LU[r2*LP+lo]=cosl*x+sinl*y; lc->LU[r2*LP+m2]=cosl*y-sinl*x;
        }
      }
      wsync();
    }
  }
  if(lane==0){
    for(int i=0;i<n;++i){ lc->ic[i]=(d[i]<0.0)?1:0; if(d[i]<0.0) d[i]=-d[i]; }
    int nsw=0;
    for(int i=0;i<n-1;++i){
      int isub=0; rl smin=d[0];
      for(int j=1;j<n-i;++j){ if(d[j]<=smin){ isub=j; smin=d[j]; } }
      int tgt=n-1-i;
      if(isub!=tgt){
        d[isub]=d[tgt]; d[tgt]=smin;
        lc->ia[nsw]=isub; lc->ib[nsw]=tgt; ++nsw;
      }
    }
    lc->si[7]=nsw;
  }
  wsync();
  int nsw=lc->si[7];
  if(lane<ncvt){
    for(int i=0;i<n;++i) if(lc->ic[i]) lc->LVT[i*LP+lane]=-lc->LVT[i*LP+lane];
    for(int w2=0;w2<nsw;++w2){
      int a=lc->ia[w2], b=lc->ib[w2];
      rl t=lc->LVT[a*LP+lane]; lc->LVT[a*LP+lane]=lc->LVT[b*LP+lane]; lc->LVT[b*LP+lane]=t;
    }
  } else if(lane<ncvt+nru){
    int r2=lane-ncvt;
    for(int w2=0;w2<nsw;++w2){
      int a=lc->ia[w2], b=lc->ib[w2];
      rl t=lc->LU[r2*LP+a]; lc->LU[r2*LP+a]=lc->LU[r2*LP+b]; lc->LU[r2*LP+b]=t;
    }
  }
  wsync();
}

// ---- leaf: dlasdq, entirely within one wave ----
__device__ void leaf_exec(int f, int n, int sqre, int wantU, LeafCtx* lc, Sh* sh, int lane){
  rl* SVTB = g_ws + O_SVTB; rl* SUB = g_ws + O_SUB;
  int np = n + sqre;
  for(int w=lane; w<np*np; w+=64){ int r2=w/np, c=w-r2*np; lc->LVT[r2*LP+c]=SVTB[(f+r2)+(size_t)LDV*(f+c)]; }
  if(wantU) for(int w=lane; w<n*n; w+=64){ int r2=w/n, c=w-r2*n; lc->LU[r2*LP+c]=SUB[(f+r2)+(size_t)LDV*(f+c)]; }
  wsync();
  if(sqre==1){
    if(lane==0){
      rl cs,snv,rv; rl* dd=sh->d+f; rl* ee=sh->e+f;
      for(int i=0;i<n;++i){
        dlartg(dd[i],ee[i],&cs,&snv,&rv);
        dd[i]=rv;
        if(i<n-1){ ee[i]=snv*dd[i+1]; dd[i+1]=cs*dd[i+1]; }
        else ee[i]=0.0;
        lc->b1[i]=cs; lc->b2[i]=snv;
      }
    }
    wsync();
    if(lane<np){
      rl cur = lc->LVT[0*LP+lane];
      for(int j=0;j<n;++j){
        rl cj=lc->b1[j], sj=lc->b2[j];
        rl t=lc->LVT[(j+1)*LP+lane];
        lc->LVT[j*LP+lane] = sj*t + cj*cur;
        cur = cj*t - sj*cur;
      }
      lc->LVT[n*LP+lane] = cur;
    }
    wsync();
    if(lane==0){
      rl cs,snv,rv; rl* dd=sh->d+f; rl* ee=sh->e+f;
      for(int i=0;i<n-1;++i){
        dlartg(dd[i],ee[i],&cs,&snv,&rv);
        dd[i]=rv; ee[i]=snv*dd[i+1]; dd[i+1]=cs*dd[i+1];
        lc->b1[i]=cs; lc->b2[i]=snv;
      }
    }
    wsync();
    if(wantU && lane<n){
      rl cur = lc->LU[lane*LP+0];
      for(int j=0;j<n-1;++j){
        rl cj=lc->b1[j], sj=lc->b2[j];
        rl t=lc->LU[lane*LP+(j+1)];
        lc->LU[lane*LP+j] = sj*t + cj*cur;
        cur = cj*t - sj*cur;
      }
      lc->LU[lane*LP+(n-1)] = cur;
    }
    wsync();
  }
  bdsqr_wave(n, sh->d+f, sh->e+f, np, wantU? n:0, lc, lane);
  for(int w=lane; w<np*np; w+=64){ int r2=w/np, c=w-r2*np; SVTB[(f+r2)+(size_t)LDV*(f+c)]=lc->LVT[r2*LP+c]; }
  if(wantU) for(int w=lane; w<n*n; w+=64){ int r2=w/n, c=w-r2*n; SUB[(f+r2)+(size_t)LDV*(f+c)]=lc->LU[r2*LP+c]; }
}

// ---- D&C merge (dlasd1/2/3); QV in LDS overlay ----
__device__ void lasd1_merge(int f, int nl, int nr, int sqre, int wantU, rl* QV, Sh* sh, int tid){
  rl* SUB = g_ws + O_SUB; rl* SVTB = g_ws + O_SVTB;
  rl* U2 = g_ws + O_U2; rl* VT2 = g_ws + O_VT2; rl* QU = g_ws + O_QU;
  int n = nl+nr+1, m = n+sqre;
  if(tid==0){
    rl alpha = sh->d[f+nl], beta = sh->e[f+nl];
    sh->vals[0]=0.0;
    sh->zz[0] = alpha*SVTB[(f+nl)+(size_t)LDV*(f+nl)];
    sh->srcU[0]=-1; sh->srcVT[0]=f+nl;
    for(int i=0;i<nl;++i){
      sh->vals[1+i]=sh->d[f+i];
      sh->zz[1+i]=alpha*SVTB[(f+i)+(size_t)LDV*(f+nl)];
      sh->srcU[1+i]=f+i; sh->srcVT[1+i]=f+i;
    }
    for(int j=0;j<nr;++j){
      sh->vals[1+nl+j]=sh->d[f+nl+1+j];
      sh->zz[1+nl+j]=beta*SVTB[(f+nl+1+j)+(size_t)LDV*(f+nl+1)];
      sh->srcU[1+nl+j]=f+nl+1+j; sh->srcVT[1+nl+j]=f+nl+1+j;
    }
    sh->sc[0]=alpha; sh->sc[1]=beta;
    if(sqre==1){
      rl zM = beta*SVTB[(f+n)+(size_t)LDV*(f+nl+1)];
      rl c,s,r2;
      dlartg(sh->zz[0], zM, &c, &s, &r2);
      sh->zz[0]=r2; sh->sc[2]=c; sh->sc[3]=s;
    }
  }
  __syncthreads();
  if(sqre==1){
    rl c=sh->sc[2], s=sh->sc[3];
    int ra=f+nl, rb=f+n;
    for(int k=tid;k<m;k+=NT){
      size_t ci=(size_t)LDV*(f+k);
      rl a=SVTB[ra+ci], b=SVTB[rb+ci];
      SVTB[ra+ci]=c*a+s*b; SVTB[rb+ci]=-s*a+c*b;
    }
  }
  __syncthreads();
  if(tid==0){
    rl maxd=0.0; for(int i=0;i<n;++i) maxd=fmax(maxd,fabs(sh->vals[i]));
    rl tol = 8.0*EPS32*fmax(maxd, fmax(fabs(sh->sc[0]), fabs(sh->sc[1])));
    int nds=0;
    sh->ic[nds++]=0;
    for(int i=1;i<n;++i) if(fabs(sh->zz[i]) > tol) sh->ic[nds++]=i;
    for(int a=1;a<nds;++a){
      int key=sh->ic[a]; rl kv=sh->vals[key]; int b=a-1;
      while(b>=1 && sh->vals[sh->ic[b]] > kv){ sh->ic[b+1]=sh->ic[b]; --b; }
      sh->ic[b+1]=key;
    }
    int K=nds, pos=nds;
    for(int i=1;i<n;++i) if(fabs(sh->zz[i]) <= tol) sh->ic[pos++]=i;
    for(int a=K+1;a<n;++a){
      int key=sh->ic[a]; rl kv=sh->vals[key]; int b=a-1;
      while(b>=K && sh->vals[sh->ic[b]] > kv){ sh->ic[b+1]=sh->ic[b]; --b; }
      sh->ic[b+1]=key;
    }
    for(int t=0;t<n;++t){ sh->ta[t]=sh->vals[t]; sh->tb[t]=sh->zz[t]; sh->ia[t]=sh->srcU[t]; sh->ib[t]=sh->srcVT[t]; }
    for(int t=0;t<n;++t){
      int p=sh->ic[t];
      sh->dsig[t]=sh->ta[p]; sh->zz[t]=sh->tb[p]; sh->srcU[t]=sh->ia[p]; sh->srcVT[t]=sh->ib[p];
    }
    rl rho=0.0; for(int t=0;t<K;++t){ rl zv=sh->zz[t]; rho += zv*zv; }
    sh->sc[4]=rho;
    sh->si[0]=K; sh->si[1]=n; sh->si[2]=m; sh->si[3]=f; sh->si[4]=nl;
  }
  __syncthreads();
  int K=sh->si[0], n_=sh->si[1], m_=sh->si[2], f_=sh->si[3], nl_=sh->si[4];
  if(wantU){
    for(int w=tid; w<n_*n_; w+=NT){
      int col=w/n_, row=w-col*n_;
      int su=sh->srcU[col];
      rl v;
      if(su<0) v = (row==nl_) ? 1.0 : 0.0;
      else v = SUB[(f_+row)+(size_t)LDV*su];
      U2[row+(size_t)LDV*col]=v;
    }
  }
  for(int w=tid; w<n_*m_; w+=NT){
    int row=w/m_, col=w-row*m_;
    VT2[row+(size_t)LDV*col] = SVTB[sh->srcVT[row]+(size_t)LDV*(f_+col)];
  }
  __syncthreads();
  rl rho=sh->sc[4];
  for(int j=tid;j<K;j+=NT){
    rl lo=sh->dsig[j];
    rl hi=(j<K-1)? sh->dsig[j+1] : sqrt(sh->dsig[K-1]*sh->dsig[K-1]+rho);
    for(int it=0; it<130; ++it){
      rl mid=0.5*(lo+hi);
      if(mid<=lo || mid>=hi) break;
      rl g=1.0;
      for(int i2=0;i2<K;++i2){
        rl zi=sh->zz[i2];
        g += zi*zi/((sh->dsig[i2]-mid)*(sh->dsig[i2]+mid));
      }
      if(g<0.0) lo=mid; else hi=mid;
    }
    sh->sigm[j]=0.5*(lo+hi);
  }
  __syncthreads();
  for(int i2=tid;i2<K;i2+=NT){
    rl di=sh->dsig[i2];
    rl p=(di - sh->sigm[K-1])*(di + sh->sigm[K-1]);
    for(int j=0;j<i2;++j)
      p *= (di - sh->sigm[j])*(di + sh->sigm[j])/((di - sh->dsig[j])*(di + sh->dsig[j]));
    for(int j=i2;j<K-1;++j)
      p *= (di - sh->sigm[j])*(di + sh->sigm[j])/((di - sh->dsig[j+1])*(di + sh->dsig[j+1]));
    sh->zh[i2] = d_sign(sqrt(fabs(p)), sh->zz[i2]);
  }
  __syncthreads();
  for(int j=tid;j<K;j+=NT){
    rl sj=sh->sigm[j];
    rl nu=0.0, nv=0.0;
    for(int i2=0;i2<K;++i2){
      rl di=sh->dsig[i2];
      rl vv=sh->zh[i2]/((di-sj)*(di+sj));
      QV[i2+(size_t)LDV*j]=vv; nv+=vv*vv;
      if(wantU){
        rl uu=(i2==0)? -1.0 : di*vv;
        QU[i2+(size_t)LDV*j]=uu; nu+=uu*uu;
      }
    }
    nv=1.0/sqrt(nv);
    for(int i2=0;i2<K;++i2) QV[i2+(size_t)LDV*j]*=nv;
    if(wantU){
      nu=1.0/sqrt(nu);
      for(int i2=0;i2<K;++i2) QU[i2+(size_t)LDV*j]*=nu;
    }
  }
  __syncthreads();
  if(tid==0){
    int nd2=n_-K;
    for(int t=0;t<nd2;++t) sh->ia[t]=K+t;
    int ps=K-1, pd=nd2-1;
    int t=0;
    while(t<n_){
      rl vs = (ps>=0)? sh->sigm[ps] : -1.0;
      rl vd = (pd>=0)? sh->dsig[sh->ia[pd]] : -1.0;
      if(vs >= vd){ sh->perm[t]=ps; sh->vals[t]=vs; --ps; }
      else { sh->perm[t]=1000+sh->ia[pd]; sh->vals[t]=vd; --pd; }
      ++t;
    }
    for(int q=0;q<n_;++q) sh->d[f_+q]=sh->vals[q];
  }
  __syncthreads();
  if(wantU){
    for(int w=tid; w<n_*n_; w+=NT){
      int t=w/n_, row=w-t*n_;
      int src=sh->perm[t];
      rl acc;
      if(src>=1000) acc = U2[row+(size_t)LDV*(src-1000)];
      else{
        const rl* urow = U2 + row;
        const rl* qcol = QU + (size_t)LDV*src;
        rl s=0.0; int i=0;
        for(; i+16<=K; i+=16){
          rl a[16], b[16];
          #pragma unroll
          for(int u=0;u<16;++u){ a[u]=urow[(size_t)LDV*(size_t)(i+u)]; b[u]=qcol[i+u]; }
          #pragma unroll
          for(int u=0;u<16;++u) s += a[u]*b[u];
        }
        for(; i<K; ++i) s += urow[(size_t)LDV*i]*qcol[i];
        acc=s;
      }
      SUB[(f_+row)+(size_t)LDV*(f_+t)] = acc;
    }
  }
  for(int w=tid; w<n_*m_; w+=NT){
    int t=w/m_, col=w-t*m_;
    int src=sh->perm[t];
    rl acc;
    if(src>=1000) acc = VT2[(src-1000)+(size_t)LDV*col];
    else{
      const rl* qcol = QV + (size_t)LDV*src;
      const rl* vcol = VT2 + (size_t)LDV*col;
      rl s=0.0; int i=0;
      for(; i+16<=K; i+=16){
        rl a[16], b[16];
        #pragma unroll
        for(int u=0;u<16;++u){ a[u]=qcol[i+u]; b[u]=vcol[i+u]; }
        #pragma unroll
        for(int u=0;u<16;++u) s += a[u]*b[u];
      }
      for(; i<K; ++i) s += qcol[i]*vcol[i];
      acc=s;
    }
    SVTB[(f_+t)+(size_t)LDV*(f_+col)] = acc;
  }
  __syncthreads();
}

// ---- dlasd0 ----
__device__ void run_dc(int n, int wantU, LeafCtx* lct, Sh* sh, int tid){
  if(tid==0){
    int sf[12], sn2[12], sq[12], sv[12]; int sp=0, no=0;
    sf[0]=0; sn2[0]=n; sq[0]=0; sv[0]=0; sp=1;
    while(sp>0){
      --sp;
      int f=sf[sp], nn=sn2[sp], q=sq[sp], v=sv[sp];
      if(nn<=SML){ sh->opk[no]=0; sh->opf[no]=f; sh->opa[no]=nn; sh->opb[no]=0; sh->opq[no]=q; ++no; }
      else if(v==0){
        int nl=nn/2, nr=nn-nl-1;
        sf[sp]=f; sn2[sp]=nn; sq[sp]=q; sv[sp]=1; ++sp;
        sf[sp]=f+nl+1; sn2[sp]=nr; sq[sp]=q; sv[sp]=0; ++sp;
        sf[sp]=f; sn2[sp]=nl; sq[sp]=1; sv[sp]=0; ++sp;
      } else {
        int nl=nn/2, nr=nn-nl-1;
        sh->opk[no]=1; sh->opf[no]=f; sh->opa[no]=nl; sh->opb[no]=nr; sh->opq[no]=q; ++no;
      }
    }
    int tk[12], tf2[12], ta2[12], tb3[12], tq3[12]; int c=0;
    for(int i=0;i<no;++i) if(sh->opk[i]==0){ tk[c]=0; tf2[c]=sh->opf[i]; ta2[c]=sh->opa[i]; tb3[c]=sh->opb[i]; tq3[c]=sh->opq[i]; ++c; }
    for(int i=0;i<no;++i) if(sh->opk[i]==1){ tk[c]=1; tf2[c]=sh->opf[i]; ta2[c]=sh->opa[i]; tb3[c]=sh->opb[i]; tq3[c]=sh->opq[i]; ++c; }
    for(int i=0;i<no;++i){ sh->opk[i]=tk[i]; sh->opf[i]=tf2[i]; sh->opa[i]=ta2[i]; sh->opb[i]=tb3[i]; sh->opq[i]=tq3[i]; }
    sh->si[6]=no;
  }
  __syncthreads();
  int no=sh->si[6];
  int o=0;
  while(o<no){
    if(sh->opk[o]==0){
      int cnt=1;
      while(o+cnt<no && sh->opk[o+cnt]==0 && cnt<4) ++cnt;
      int wid = tid>>6;
      if(wid<cnt) leaf_exec(sh->opf[o+wid], sh->opa[o+wid], sh->opq[o+wid], wantU, &lct[wid], sh, tid&63);
      __syncthreads();
      o += cnt;
    } else {
      lasd1_merge(sh->opf[o], sh->opa[o], sh->opb[o], sh->opq[o], wantU, (rl*)lct, sh, tid);
      ++o;
    }
  }
}

__device__ void dbdsdc_U(int n, int wantU, LeafCtx* lct, Sh* sh, int tid){
  rl* SUB = g_ws + O_SUB; rl* SVTB = g_ws + O_SVTB;
  for(int w=tid; w<LDV*LDV; w+=NT){
    int c=w/LDV, r2=w-c*LDV; rl v=(r2==c)?1.0:0.0;
    SVTB[w]=v;
    if(wantU) SUB[w]=v;
  }
  __syncthreads();
  if(n <= SML){
    if((tid>>6)==0) leaf_exec(0, n, 0, wantU, &lct[0], sh, tid&63);
    __syncthreads();
  } else run_dc(n, wantU, lct, sh, tid);
}

__device__ void dbdsdc_L(int n, int wantU, LeafCtx* lct, Sh* sh, int tid){
  if(tid==0){
    for(int i=0;i<n-1;++i){
      rl cs,snv,rv;
      dlartg(sh->d[i], sh->e[i], &cs,&snv,&rv);
      sh->d[i]=rv; sh->e[i]=snv*sh->d[i+1]; sh->d[i+1]=cs*sh->d[i+1];
      sh->rc[i]=cs; sh->rs[i]=snv;
    }
  }
  __syncthreads();
  dbdsdc_U(n, wantU, lct, sh, tid);
  if(wantU){
    rl* SUB = g_ws + O_SUB;
    for(int c=tid;c<n;c+=NT){
      size_t ci=(size_t)LDV*c;
      rl carry = SUB[(n-1)+ci];
      for(int k=n-2;k>=0;--k){
        rl a = SUB[k+ci];
        SUB[k+1+ci] = sh->rs[k]*a + sh->rc[k]*carry;
        carry = sh->rc[k]*a - sh->rs[k]*carry;
      }
      SUB[0+ci] = carry;
    }
  }
  __syncthreads();
}

// ---- bidiagonalization (R2 structure) ----
__device__ __forceinline__ void gebd2_upper(rl* A, int ld, int m, int n, Sh* sh, int tid){
  const int lane = tid & 63;
  rl pend_scl = 0.0; int pend_ds = 0;
  for(int i=0;i<n;++i){
    rl ps=0.0;
    for(int r=i+1+lane;r<m;r+=64){ rl vv=A[r+(size_t)ld*i]; ps+=vv*vv; }
    for(int off=32;off>0;off>>=1) ps += __shfl_xor(ps,off,64);
    rl alpha=A[i+(size_t)ld*i];
    rl xn=sqrt(ps);
    rl beta,tau,scl; int ds;
    if(xn==0.0){ tau=0.0; beta=alpha; scl=0.0; ds=0; }
    else{ beta=-d_sign(dlapy2(alpha,xn),alpha); tau=(beta-alpha)/beta; scl=1.0/(alpha-beta); ds=1; }
    if(tid==0){ sh->d[i]=beta; sh->tq[i]=tau; }
    if(tau!=0.0)
      app_left_s(A, ld, i, m, i+1, n, A+(size_t)ld*i, scl, tau, tid);
    if(pend_ds && tid>=128){
      int c = i+1 + (tid-128);
      if(c < n) A[(i-1)+(size_t)ld*c] *= pend_scl;
    }
    __syncthreads();
    if(i<n-1){
      rl ps2=0.0;
      for(int c=i+2+lane;c<n;c+=64){ rl vv=A[i+(size_t)ld*c]; ps2+=vv*vv; }
      for(int off=32;off>0;off>>=1) ps2 += __shfl_xor(ps2,off,64);
      rl alpha2=A[i+(size_t)ld*(i+1)];
      rl xn2=sqrt(ps2);
      rl beta2,tau2,scl2; int ds2;
      if(xn2==0.0){ tau2=0.0; beta2=alpha2; scl2=0.0; ds2=0; }
      else{ beta2=-d_sign(dlapy2(alpha2,xn2),alpha2); tau2=(beta2-alpha2)/beta2; scl2=1.0/(alpha2-beta2); ds2=1; }
      if(tid==0){ sh->e[i]=beta2; sh->tp[i]=tau2; }
      if(tau2!=0.0)
        app_right_s(A, ld, i+1, m, i+1, n, A+i, ld, scl2, tau2, tid);
      if(ds && tid>=128){
        int r = i+1 + (tid-128);
        if(r < m) A[r+(size_t)ld*i] *= scl;
      }
      pend_ds = ds2; pend_scl = scl2;
      __syncthreads();
    } else {
      if(tid==0) sh->tp[i]=0.0;
      __syncthreads();
      if(ds) for(int r=i+1+tid; r<m; r+=NT) A[r+(size_t)ld*(n-1)] *= scl;
      __syncthreads();
    }
  }
}

__device__ __forceinline__ void gebd2_lower(rl* A, int ld, int m, int n, Sh* sh, int tid){
  const int lane = tid & 63;
  rl pend_scl = 0.0; int pend_ds = 0;
  int last_ds = 0; rl last_scl = 0.0;
  for(int i=0;i<m;++i){
    rl ps=0.0;
    for(int c=i+1+lane;c<n;c+=64){ rl vv=A[i+(size_t)ld*c]; ps+=vv*vv; }
    for(int off=32;off>0;off>>=1) ps += __shfl_xor(ps,off,64);
    rl alpha=A[i+(size_t)ld*i];
    rl xn=sqrt(ps);
    rl beta,tau,scl; int ds;
    if(xn==0.0){ tau=0.0; beta=alpha; scl=0.0; ds=0; }
    else{ beta=-d_sign(dlapy2(alpha,xn),alpha); tau=(beta-alpha)/beta; scl=1.0/(alpha-beta); ds=1; }
    if(tid==0){ sh->d[i]=beta; sh->tp[i]=tau; }
    if(tau!=0.0)
      app_right_s(A, ld, i+1, m, i, n, A+i, ld, scl, tau, tid);
    if(pend_ds && tid>=128){
      int r = i+1 + (tid-128);
      if(r < m) A[r+(size_t)ld*(i-1)] *= pend_scl;
    }
    __syncthreads();
    if(i<m-1){
      rl ps2=0.0;
      for(int r=i+2+lane;r<m;r+=64){ rl vv=A[r+(size_t)ld*i]; ps2+=vv*vv; }
      for(int off=32;off>0;off>>=1) ps2 += __shfl_xor(ps2,off,64);
      rl alpha2=A[(i+1)+(size_t)ld*i];
      rl xn2=sqrt(ps2);
      rl beta2,tau2,scl2; int ds2;
      if(xn2==0.0){ tau2=0.0; beta2=alpha2; scl2=0.0; ds2=0; }
      else{ beta2=-d_sign(dlapy2(alpha2,xn2),alpha2); tau2=(beta2-alpha2)/beta2; scl2=1.0/(alpha2-beta2); ds2=1; }
      if(tid==0){ sh->e[i]=beta2; sh->tq[i]=tau2; }
      if(tau2!=0.0)
        app_left_s(A, ld, i+1, m, i+1, n, A+(size_t)ld*i, scl2, tau2, tid);
      if(ds && tid>=128){
        int c = i+1 + (tid-128);
        if(c < n) A[i+(size_t)ld*c] *= scl;
      }
      pend_ds = ds2; pend_scl = scl2;
      __syncthreads();
    } else {
      last_ds = ds; last_scl = scl;
      __syncthreads();
      if(last_ds) for(int c=i+1+tid; c<n; c+=NT) A[(m-1)+(size_t)ld*c] *= last_scl;
      __syncthreads();
    }
  }
}

__device__ __forceinline__ void gelq2(rl* A, int ld, int m, int n, Sh* sh, int tid){
  const int lane = tid & 63;
  rl pend_scl=0.0, pend_beta=0.0; int pend_ds=0;
  for(int i=0;i<m;++i){
    rl ps=0.0;
    for(int c=i+1+lane;c<n;c+=64){ rl vv=A[i+(size_t)ld*c]; ps+=vv*vv; }
    for(int off=32;off>0;off>>=1) ps += __shfl_xor(ps,off,64);
    rl alpha=A[i+(size_t)ld*i];
    rl xn=sqrt(ps);
    rl beta,tau,scl; int ds;
    if(xn==0.0){ tau=0.0; beta=alpha; scl=0.0; ds=0; }
    else{ beta=-d_sign(dlapy2(alpha,xn),alpha); tau=(beta-alpha)/beta; scl=1.0/(alpha-beta); ds=1; }
    if(tid==0) sh->rs[i]=tau;
    if(i<m-1 && tau!=0.0)
      app_right_s(A, ld, i+1, m, i, n, A+i, ld, scl, tau, tid);
    if(i>0 && tid>=128){
      if(pend_ds){ int c = i + (tid-128); if(c<n) A[(i-1)+(size_t)ld*c] *= pend_scl; }
      if(tid==128) A[(i-1)+(size_t)ld*(i-1)] = pend_beta;
    }
    pend_ds=ds; pend_scl=scl; pend_beta=beta;
    __syncthreads();
  }
  if(tid>=128){
    if(pend_ds){ int c = m + (tid-128); if(c<n) A[(m-1)+(size_t)ld*c] *= pend_scl; }
    if(tid==128) A[(m-1)+(size_t)ld*(m-1)] = pend_beta;
  }
  __syncthreads();
}

// ======================================================================
// PHASE KERNELS (instrumentation split — per-phase rocprof attribution)
// ======================================================================

// K1: build A + bidiagonalization (dump MBL + d/e/tq/tp to g_ws)
__global__ __launch_bounds__(NT)
void k_bidiag(const float* __restrict__ ch, const float* __restrict__ ci,
              const float* __restrict__ ictx, const int* __restrict__ tok,
              int s, int m)
{
  __shared__ Sh sh;
  extern __shared__ rl MBL[];
  int tid = threadIdx.x;
  rl* MA = g_ws + O_MA; rl* MQ = g_ws + O_MQ; rl* TB = g_ws + O_TB;
  if(tid==0){
    rl W00=ch[s*4+0], W01=ch[s*4+1], W10=ch[s*4+2], W11=ch[s*4+3];
    rl P00=1,P01=0,P10=0,P11=1;
    for(int mexp=0;mexp<=70;++mexp){
      int j=70-mexp;
      rl v0,v1;
      if(j==0){ v0=ictx[s*2+0]; v1=ictx[s*2+1]; }
      else{
        int b=(tok[j-1]>>(15-s))&1;
        v0=ci[s*4+b]; v1=ci[s*4+2+b];
      }
      g_ws[O_COLS + 0 + 2*j] = P00*v0+P01*v1;
      g_ws[O_COLS + 1 + 2*j] = P10*v0+P11*v1;
      rl n00=W00*P00+W01*P10, n01=W00*P01+W01*P11;
      rl n10=W10*P00+W11*P10, n11=W10*P01+W11*P11;
      P00=n00;P01=n01;P10=n10;P11=n11;
    }
  }
  __syncthreads();
  for(int w=tid; w<m*NSV; w+=NT){
    int j=w/m, r2=w-j*m;
    int l=r2>>1, dd2=r2&1;
    rl cv = g_ws[O_COLS + dd2 + 2*j];
    MA[r2+(size_t)LDA*j] = (s==0)? cv : g_ws[O_CAR + l + 64*j]*cv;
  }
  __syncthreads();
  if(m==128){
    for(int w=tid;w<128*NSV;w+=NT){ int c=w>>7, r2=w&127; MBL[r2+(size_t)PB*c]=MA[r2+(size_t)LDA*c]; }
    __syncthreads();
    gebd2_upper(MBL, PB, 128, NSV, &sh, tid);
    for(int w=tid;w<PB*NSV;w+=NT) g_ws[O_MBLG+w]=MBL[w];
  } else if(m==64){
    for(int w=tid;w<64*NSV;w+=NT){ int c=w>>6, r2=w&63; MBL[r2+(size_t)PB*c]=MA[r2+(size_t)LDA*c]; }
    __syncthreads();
    gebd2_lower(MBL, PB, 64, NSV, &sh, tid);
    for(int w=tid;w<PB*NSV;w+=NT) g_ws[O_MBLG+w]=MBL[w];
  } else {
    for(int w=tid;w<m*NSV;w+=NT){ int c=w/m, r2=w-c*m; MBL[r2+(size_t)PB*c]=MA[r2+(size_t)LDA*c]; }
    __syncthreads();
    gelq2(MBL, PB, m, NSV, &sh, tid);
    for(int w=tid;w<m*NSV;w+=NT){ int c=w/m, r2=w-c*m; MQ[r2+(size_t)LDA*c]=(r2==c)?1.0:0.0; }
    __syncthreads();
    if(tid<m){
      int r=tid;
      for(int j=m-1;j>=0;--j){
        rl tau=sh.rs[j];
        if(tau!=0.0) row_apply(MQ + r + (size_t)LDA*j, LDA, MBL + j + (size_t)PB*(j+1), PB, NSV-j-1, tau);
      }
    }
    __syncthreads();
    for(int w=tid;w<m*m;w+=NT){ int c=w/m, r2=w-c*m; TB[r2+(size_t)LDV*c]=(r2>=c)? MBL[r2+(size_t)PB*c]:0.0; }
    __syncthreads();
    gebd2_upper(TB, LDV, m, m, &sh, tid);
  }
  // gebd2_* end with __syncthreads; dump cross-kernel scalars
  if(tid<72){
    g_ws[O_D+tid]=sh.d[tid]; g_ws[O_E+tid]=sh.e[tid];
    g_ws[O_TQ+tid]=sh.tq[tid]; g_ws[O_TP+tid]=sh.tp[tid];
  }
}

// K2: divide & conquer (leaves + merges)
__global__ __launch_bounds__(NT)
void k_dc(int s, int m)
{
  __shared__ Sh sh;
  __shared__ LeafCtx lct[4];
  int tid = threadIdx.x;
  if(tid<72){ sh.d[tid]=g_ws[O_D+tid]; sh.e[tid]=g_ws[O_E+tid]; }
  __syncthreads();
  int wantU = (s==8)?1:0;
  if(m==128) dbdsdc_U(NSV, wantU, lct, &sh, tid);
  else if(m==64) dbdsdc_L(64, 0, lct, &sh, tid);
  else dbdsdc_U(m, 0, lct, &sh, tid);
  __syncthreads();
  if(tid<72) g_ws[O_D+tid]=sh.d[tid];
}

// K3: back-transforms + carry / final vec
__global__ __launch_bounds__(NT)
void k_post(const float* __restrict__ ch, int s, int m)
{
  __shared__ Sh sh;
  extern __shared__ rl MBL[];
  int tid = threadIdx.x;
  rl* MU=g_ws+O_MU; rl* MVT=g_ws+O_MVT; rl* MQ=g_ws+O_MQ;
  rl* SUB=g_ws+O_SUB; rl* SVTB=g_ws+O_SVTB; rl* TB=g_ws+O_TB; rl* VT2=g_ws+O_VT2;
  if(tid<72){
    sh.d[tid]=g_ws[O_D+tid];
    sh.tq[tid]=g_ws[O_TQ+tid];
    sh.tp[tid]=g_ws[O_TP+tid];
  }
  __syncthreads();
  int k = (m<64)? m : 64;
  if(m==128){
    if(s==8){
      for(int w=tid;w<128*NSV;w+=NT){ int c=w>>7, r2=w&127; MU[r2+(size_t)LDA*c]=(r2<NSV)? SUB[r2+(size_t)LDV*c]:0.0; }
      for(int w=tid;w<PB*NSV;w+=NT) MBL[w]=g_ws[O_MBLG+w];
      __syncthreads();
      if(tid<NSV){
        int c=tid;
        rl* colb = MU + (size_t)LDA*c;
        for(int i=NSV-1;i>=0;--i){
          rl tau=sh.tq[i];
          if(tau!=0.0) row_apply(colb+i, 1, MBL + (size_t)PB*i + i + 1, 1, 128-i-1, tau);
        }
      }
      __syncthreads();
      if(tid==0){
        rl W00=ch[8*4+0], W01=ch[8*4+1], W10=ch[8*4+2], W11=ch[8*4+3];
        rl P00=1,P01=0,P10=0,P11=1;
        for(int it=0;it<30;++it){
          rl n00=W00*P00+W01*P10, n01=W00*P01+W01*P11;
          rl n10=W10*P00+W11*P10, n11=W10*P01+W11*P11;
          P00=n00;P01=n01;P10=n10;P11=n11;
        }
        sh.sc[0]=P00+P10; sh.sc[1]=P01+P11;
      }
      __syncthreads();
      for(int r2=tid; r2<64; r2+=NT){
        rl acc=0.0;
        for(int l=0;l<64;++l)
          acc += sh.sc[0]*MU[(2*l)+(size_t)LDA*r2] + sh.sc[1]*MU[(2*l+1)+(size_t)LDA*r2];
        g_ws[O_VEC + r2] = acc/188.0;
      }
    } else {
      for(int w=tid;w<LDV*NSV;w+=NT) MVT[w]=SVTB[w];
      for(int w=tid;w<PB*NSV;w+=NT) MBL[w]=g_ws[O_MBLG+w];
      __syncthreads();
      if(tid<NSV){
        int r=tid;
        for(int i=NSV-2;i>=0;--i){
          rl tau=sh.tp[i];
          if(tau!=0.0) row_apply(MVT + r + (size_t)LDV*(i+1), LDV, MBL + i + (size_t)PB*(i+2), PB, NSV-i-2, tau);
        }
      }
      __syncthreads();
      for(int w=tid; w<k*NSV; w+=NT){
        int j=w/k, l=w-j*k;
        g_ws[O_CAR + l + 64*j] = sh.d[l]*MVT[l+(size_t)LDV*j];
      }
    }
  } else if(m==64){
    for(int w=tid;w<64*NSV;w+=NT){ int c=w>>6, r2=w&63; MVT[r2+(size_t)LDV*c]=(c<64)? SVTB[r2+(size_t)LDV*c]:0.0; }
    for(int w=tid;w<PB*NSV;w+=NT) MBL[w]=g_ws[O_MBLG+w];
    __syncthreads();
    if(tid<64){
      int r=tid;
      for(int i=63;i>=0;--i){
        rl tau=sh.tp[i];
        if(tau!=0.0) row_apply(MVT + r + (size_t)LDV*i, LDV, MBL + i + (size_t)PB*(i+1), PB, NSV-i-1, tau);
      }
    }
    __syncthreads();
    for(int w=tid; w<k*NSV; w+=NT){
      int j=w/k, l=w-j*k;
      g_ws[O_CAR + l + 64*j] = sh.d[l]*MVT[l+(size_t)LDV*j];
    }
  } else {
    for(int w=tid;w<m*m;w+=NT){ int c=w/m, r2=w-c*m; VT2[r2+(size_t)LDV*c]=SVTB[r2+(size_t)LDV*c]; }
    __syncthreads();
    if(tid<m){
      int r=tid;
      for(int i=m-2;i>=0;--i){
        rl tau=sh.tp[i];
        if(tau!=0.0) row_apply(VT2 + r + (size_t)LDV*(i+1), LDV, TB + i + (size_t)LDV*(i+2), LDV, m-i-2, tau);
      }
    }
    __syncthreads();
    for(int w=tid;w<m*NSV;w+=NT){
      int c=w/m, r2=w-c*m;
      const rl* vrow = VT2 + r2;
      const rl* qcol = MQ + (size_t)LDA*c;
      rl s2=0.0; int t=0;
      for(; t+16<=m; t+=16){
        rl a[16], b[16];
        #pragma unroll
        for(int u=0;u<16;++u){ a[u]=vrow[(size_t)LDV*(size_t)(t+u)]; b[u]=qcol[t+u]; }
        #pragma unroll
        for(int u=0;u<16;++u) s2 += a[u]*b[u];
      }
      for(; t+4<=m; t+=4){
        rl a0=vrow[(size_t)LDV*t], a1=vrow[(size_t)LDV*(t+1)], a2=vrow[(size_t)LDV*(t+2)], a3=vrow[(size_t)LDV*(t+3)];
        rl b0=qcol[t], b1=qcol[t+1], b2=qcol[t+2], b3=qcol[t+3];
        s2+=a0*b0; s2+=a1*b1; s2+=a2*b2; s2+=a3*b3;
      }
      for(; t<m; ++t) s2 += vrow[(size_t)LDV*t]*qcol[t];
      MVT[r2+(size_t)LDV*c]=s2;
    }
    __syncthreads();
    for(int w=tid; w<k*NSV; w+=NT){
      int j=w/k, l=w-j*k;
      g_ws[O_CAR + l + 64*j] = sh.d[l]*MVT[l+(size_t)LDV*j];
    }
  }
}

__global__ __launch_bounds__(NT)
void head_kernel(const float* __restrict__ hw, const float* __restrict__ hb,
                 float* __restrict__ out)
{
  __shared__ float v[64];
  int tid=threadIdx.x;
  if(tid<64) v[tid]=(float)g_ws[O_VEC + tid];
  __syncthreads();
  int i = blockIdx.x*NT + tid;
  if(i<VOCAB){
    const float4* row = (const float4*)(hw + (size_t)i*64);
    float acc=0.f;
    #pragma unroll
    for(int c4=0;c4<16;++c4){
      float4 r4=row[c4];
      acc += r4.x*v[4*c4] + r4.y*v[4*c4+1] + r4.z*v[4*c4+2] + r4.w*v[4*c4+3];
    }
    out[i]=acc+hb[i];
  }
}

extern "C" void kernel_launch(void* const* d_in, const int* in_sizes, int n_in,
                              void* d_out, int out_size, void* d_ws, size_t ws_size,
                              hipStream_t stream)
{
  const float* ch  = (const float*)d_in[0];
  const float* ci  = (const float*)d_in[1];
  const float* hw  = (const float*)d_in[2];
  const float* hb  = (const float*)d_in[3];
  const float* ict = (const float*)d_in[4];
  const int*   tk  = (const int*)d_in[5];
  (void)d_ws; (void)ws_size; (void)in_sizes; (void)n_in; (void)out_size;

  static const int ms[9] = {2,4,8,16,32,64,128,128,128};
  size_t dynls = (size_t)PB*NSV*sizeof(double);   // 73272 B
  for(int s=0;s<9;++s){
    hipLaunchKernelGGL(k_bidiag, dim3(1), dim3(NT), dynls, stream, ch, ci, ict, tk, s, ms[s]);
    hipLaunchKernelGGL(k_dc,     dim3(1), dim3(NT), 0,     stream, s, ms[s]);
    hipLaunchKernelGGL(k_post,   dim3(1), dim3(NT), dynls, stream, ch, s, ms[s]);
  }
  hipLaunchKernelGGL(head_kernel, dim3((VOCAB+NT-1)/NT), dim3(NT), 0, stream,
                     hw, hb, (float*)d_out);
}

// Round 6
// 8123.468 us; speedup vs baseline: 1.4415x; 1.1041x over previous
//
#include <hip/hip_runtime.h>

typedef double rl;
#define NT 256
#define NSV 71
#define LDA 128
#define LDV 72
#define SML 25
#define VOCAB 128000
#define LP 27   // LDS leaf pitch
#define PB 129  // LDS pitch for bidiag working matrix

// fp32 LAPACK constants (reference is numpy sgesdd in float32)
#define EPS32 1.1920928955078125e-7
#define UNFL32 1.17549435e-38

// g_ws offsets (doubles)
#define O_CAR   0
#define O_COLS  4608
#define O_VEC   4800
#define O_MA    5120
#define O_MBLG  14208   // MBL dump: PB*NSV=9159 doubles
#define O_MU    23552
#define O_MQ    32768
#define O_MVT   41984
#define O_SUB   47168
#define O_SVTB  52352
#define O_U2    57536
#define O_VT2   62720
#define O_QU    67904
#define O_QV    73088
#define O_TB    78272
#define O_D     83456   // cross-kernel scalars (72 each)
#define O_E     83528
#define O_TQ    83600
#define O_TP    83672

__device__ double g_ws[84000];

struct LeafCtx {
  rl LVT[26*LP], LU[26*LP];
  rl b1[26], b2[26], b3[26], b4[26];
  rl sc[6];
  int ia[26], ib[26], ic[26];
  int si[12];
};

struct Sh {
  rl d[72], e[72], tq[72], tp[72], rc[72], rs[72];
  rl dsig[72], zz[72], zh[72], sigm[72], vals[72];
  rl ta[72], tb[72];
  int srcU[72], srcVT[72], perm[72];
  int ia[72], ib[72], ic[72];
  int opk[12], opf[12], opa[12], opb[12], opq[12];
  rl sc[8];
  int si[16];
};

__device__ __forceinline__ void wsync(){
  asm volatile("s_waitcnt vmcnt(0) lgkmcnt(0)" ::: "memory");
}

__device__ __forceinline__ rl d_sign(rl a, rl b){ return (b >= 0.0) ? fabs(a) : -fabs(a); }
__device__ __forceinline__ rl dlapy2(rl x, rl y){
  rl ax=fabs(x), ay=fabs(y);
  rl w = ax>ay?ax:ay, z = ax>ay?ay:ax;
  if(z==0.0) return w;
  rl t = z/w; return w*sqrt(1.0+t*t);
}
__device__ void dlartg(rl f, rl g, rl* cs, rl* sn, rl* r){
  if(g==0.0){ *cs=1.0; *sn=0.0; *r=f; }
  else if(f==0.0){ *cs=0.0; *sn=d_sign(1.0,g); *r=fabs(g); }
  else{
    rl dd = sqrt(f*f+g*g);
    *cs = fabs(f)/dd;
    *r  = d_sign(dd, f);
    *sn = g/(*r);
  }
}

__device__ void dlas2(rl f, rl g, rl h, rl* ssmin, rl* ssmax){
  rl fa=fabs(f), ga=fabs(g), ha=fabs(h);
  rl fhmn=fmin(fa,ha), fhmx=fmax(fa,ha);
  if(fhmn==0.0){
    *ssmin=0.0;
    if(fhmx==0.0) *ssmax=ga;
    else { rl mx=fmax(fhmx,ga), mn=fmin(fhmx,ga); rl q=mn/mx; *ssmax=mx*sqrt(1.0+q*q); }
  } else {
    if(ga < fhmx){
      rl as=1.0+fhmn/fhmx, at=(fhmx-fhmn)/fhmx;
      rl au=(ga/fhmx); au=au*au;
      rl c=2.0/(sqrt(as*as+au)+sqrt(at*at+au));
      *ssmin=fhmn*c; *ssmax=fhmx/c;
    } else {
      rl au=fhmx/ga;
      if(au==0.0){ *ssmin=(fhmn*fhmx)/ga; *ssmax=ga; }
      else{
        rl as=1.0+fhmn/fhmx, at=(fhmx-fhmn)/fhmx;
        rl c=1.0/(sqrt(1.0+(as*au)*(as*au))+sqrt(1.0+(at*au)*(at*au)));
        *ssmin=(fhmn*c)*au; *ssmin=*ssmin+*ssmin;
        *ssmax=ga/(c+c);
      }
    }
  }
}

__device__ void dlasv2(rl f, rl g, rl h, rl* ssmin, rl* ssmax, rl* snr, rl* csr, rl* snl, rl* csl){
  rl ft=f, fa=fabs(f), ht=h, ha=fabs(h);
  int pmax=1;
  bool swp = (ha > fa);
  if(swp){ pmax=3; rl t=ft; ft=ht; ht=t; t=fa; fa=ha; ha=t; }
  rl gt=g, ga=fabs(g);
  rl clt=0, crt=0, slt=0, srt=0;
  if(ga==0.0){ *ssmin=ha; *ssmax=fa; clt=1.0; crt=1.0; slt=0.0; srt=0.0; }
  else{
    bool gasmal=true;
    if(ga > fa){
      pmax=2;
      if((fa/ga) < EPS32){
        gasmal=false;
        *ssmax=ga;
        if(ha>1.0) *ssmin=fa/(ga/ha); else *ssmin=(fa/ga)*ha;
        clt=1.0; slt=ht/gt; srt=1.0; crt=ft/gt;
      }
    }
    if(gasmal){
      rl dd=fa-ha;
      rl lv = (dd==fa) ? 1.0 : dd/fa;
      rl mq = gt/ft;
      rl tv = 2.0-lv;
      rl mm = mq*mq, tt = tv*tv;
      rl sv = sqrt(tt+mm);
      rl rv = (lv==0.0) ? fabs(mq) : sqrt(lv*lv+mm);
      rl a = 0.5*(sv+rv);
      *ssmin = ha/a; *ssmax = fa*a;
      rl t3;
      if(mm==0.0){
        if(lv==0.0) t3 = d_sign(2.0, ft)*d_sign(1.0, gt);
        else t3 = gt/d_sign(dd, ft) + mq/tv;
      } else {
        t3 = (mq/(sv+tv) + mq/(rv+lv))*(1.0+a);
      }
      rl l2 = sqrt(t3*t3+4.0);
      crt = 2.0/l2; srt = t3/l2;
      clt = (crt + srt*mq)/a;
      slt = (ht/ft)*srt/a;
    }
  }
  if(swp){ *csl=srt; *snl=crt; *csr=slt; *snr=clt; }
  else  { *csl=clt; *snl=slt; *csr=crt; *snr=srt; }
  rl tsign=1.0;
  if(pmax==1) tsign = d_sign(1.0,*csr)*d_sign(1.0,*csl)*d_sign(1.0,f);
  if(pmax==2) tsign = d_sign(1.0,*snr)*d_sign(1.0,*csl)*d_sign(1.0,g);
  if(pmax==3) tsign = d_sign(1.0,*snr)*d_sign(1.0,*snl)*d_sign(1.0,h);
  *ssmax = d_sign(*ssmax, tsign);
  *ssmin = d_sign(*ssmin, tsign*d_sign(1.0,f)*d_sign(1.0,h));
}

// Thread-local Householder apply (16-wide grouped loads, sequential adds).
__device__ __forceinline__ void row_apply(rl* row, size_t ld, const rl* v, size_t vs, int len, rl tau){
  rl s = row[0];
  int i=0;
  for(; i+16<=len; i+=16){
    rl a[16], b[16];
    #pragma unroll
    for(int u=0;u<16;++u){ a[u]=row[ld*(size_t)(1+i+u)]; b[u]=v[vs*(size_t)(i+u)]; }
    #pragma unroll
    for(int u=0;u<16;++u) s += a[u]*b[u];
  }
  for(; i<len; ++i) s += row[ld*(size_t)(1+i)]*v[vs*(size_t)i];
  rl w = s*tau;
  row[0] -= w;
  i=0;
  for(; i+16<=len; i+=16){
    rl b[16];
    #pragma unroll
    for(int u=0;u<16;++u) b[u]=v[vs*(size_t)(i+u)];
    #pragma unroll
    for(int u=0;u<16;++u) row[ld*(size_t)(1+i+u)] -= w*b[u];
  }
  for(; i<len; ++i) row[ld*(size_t)(1+i)] -= w*v[vs*(size_t)i];
}

__device__ __forceinline__ void app_left_s(rl* A, int ld, int r0, int m, int c0, int n, const rl* vbase, rl scl, rl tau, int tid){
  const int len = m - r0 - 1;
  const rl* v = vbase + r0 + 1;
  int c = c0 + tid;
  if(c < n){
    rl* col = A + (size_t)ld*c + r0;
    rl s = col[0];
    int i=0;
    for(; i+16<=len; i+=16){
      rl a[16], b[16];
      #pragma unroll
      for(int u=0;u<16;++u){ a[u]=col[1+i+u]; b[u]=v[i+u]*scl; }
      #pragma unroll
      for(int u=0;u<16;++u) s += a[u]*b[u];
    }
    for(; i<len; ++i) s += col[1+i]*(v[i]*scl);
    rl w = s*tau;
    col[0] -= w;
    i=0;
    for(; i+16<=len; i+=16){
      rl b[16];
      #pragma unroll
      for(int u=0;u<16;++u) b[u]=v[i+u]*scl;
      #pragma unroll
      for(int u=0;u<16;++u) col[1+i+u] -= w*b[u];
    }
    for(; i<len; ++i) col[1+i] -= w*(v[i]*scl);
  }
}
__device__ __forceinline__ void app_right_s(rl* A, int ld, int r0, int m, int c0, int n, const rl* vbase, int vstride, rl scl, rl tau, int tid){
  const int len = n - c0 - 1;
  const rl* v = vbase + (size_t)vstride*(c0+1);
  int r = r0 + tid;
  if(r < m){
    rl* row = A + r + (size_t)ld*c0;
    rl s = row[0];
    int i=0;
    for(; i+16<=len; i+=16){
      rl a[16], b[16];
      #pragma unroll
      for(int u=0;u<16;++u){ a[u]=row[(size_t)ld*(size_t)(1+i+u)]; b[u]=v[(size_t)vstride*(size_t)(i+u)]*scl; }
      #pragma unroll
      for(int u=0;u<16;++u) s += a[u]*b[u];
    }
    for(; i<len; ++i) s += row[(size_t)ld*(1+i)]*(v[(size_t)vstride*i]*scl);
    rl w = s*tau;
    row[0] -= w;
    i=0;
    for(; i+16<=len; i+=16){
      rl b[16];
      #pragma unroll
      for(int u=0;u<16;++u) b[u]=v[(size_t)vstride*(size_t)(i+u)]*scl;
      #pragma unroll
      for(int u=0;u<16;++u) row[(size_t)ld*(size_t)(1+i+u)] -= w*b[u];
    }
    for(; i<len; ++i) row[(size_t)ld*(1+i)] -= w*(v[(size_t)vstride*i]*scl);
  }
}

// ---- wave-scoped dbdsqr on a private LDS leaf block ----
__device__ void bdsqr_wave(int n, rl* d, rl* e, int ncvt, int nru, LeafCtx* lc, int lane){
  if(n>1){
    rl eps=EPS32, unfl=UNFL32;
    rl tolmul=fmax(10.0,fmin(100.0,pow(eps,-0.125)));
    rl tol=tolmul*eps;
    rl thresh=0.0;
    int mm=n-1, oldll=-2, oldm=-2, idir=0, iter=0, maxit=6*n*n;
    if(lane==0){
      rl sminoa=fabs(d[0]);
      if(sminoa!=0.0){
        rl mu=sminoa;
        for(int i=1;i<n;++i){ mu=fabs(d[i])*(mu/(mu+fabs(e[i-1]))); sminoa=fmin(sminoa,mu); if(sminoa==0.0)break; }
      }
      sminoa=sminoa/sqrt((rl)n);
      thresh=fmax(tol*sminoa,(rl)(6*n*n)*unfl);
    }
    while(true){
      if(lane==0){
        int act=0, p_lo=0, p_cnt=0, p_fwd=1, p_mm=0;
        while(mm>0){
          if(iter>maxit) break;
          rl smax=fabs(d[mm]), smin=smax;
          int ll=-1;
          for(int lll=mm-1;lll>=0;--lll){
            rl abss=fabs(d[lll]), abse=fabs(e[lll]);
            if(abse<=thresh){ ll=lll; break; }
            smin=fmin(smin,abss);
            smax=fmax(smax,fmax(abss,abse));
          }
          if(ll==mm-1){ e[ll]=0.0; mm=mm-1; continue; }
          if(ll>=0) e[ll]=0.0;
          int lo=ll+1;
          if(mm==lo+1){
            rl sigmn,sigmx,sinr,cosr,sinl,cosl;
            dlasv2(d[lo],e[lo],d[mm],&sigmn,&sigmx,&sinr,&cosr,&sinl,&cosl);
            d[lo]=sigmx; d[mm]=sigmn; e[lo]=0.0;
            lc->sc[0]=cosr; lc->sc[1]=sinr; lc->sc[2]=cosl; lc->sc[3]=sinl;
            act=2; p_lo=lo; p_mm=mm;
            mm-=2;
            break;
          }
          if(lo>oldm || mm<oldll) idir=(fabs(d[lo])>=fabs(d[mm]))?1:2;
          rl sminl=0.0; int conv=0;
          if(idir==1){
            if(fabs(e[mm-1])<=tol*fabs(d[mm])){ e[mm-1]=0.0; conv=1; }
            if(!conv){
              rl mu=fabs(d[lo]); sminl=mu;
              for(int lll=lo;lll<mm;++lll){
                if(fabs(e[lll])<=tol*mu){ e[lll]=0.0; conv=1; break; }
                mu=fabs(d[lll+1])*(mu/(mu+fabs(e[lll])));
                sminl=fmin(sminl,mu);
              }
            }
          } else {
            if(fabs(e[lo])<=tol*fabs(d[lo])){ e[lo]=0.0; conv=1; }
            if(!conv){
              rl mu=fabs(d[mm]); sminl=mu;
              for(int lll=mm-1;lll>=lo;--lll){
                if(fabs(e[lll])<=tol*mu){ e[lll]=0.0; conv=1; break; }
                mu=fabs(d[lll])*(mu/(mu+fabs(e[lll])));
                sminl=fmin(sminl,mu);
              }
            }
          }
          if(conv) continue;
          oldll=lo; oldm=mm;
          rl shift=0.0, rr_;
          if(!((rl)n*tol*(sminl/smax) <= fmax(eps, 0.01*tol))){
            rl sll;
            if(idir==1){ sll=fabs(d[lo]); dlas2(d[mm-1],e[mm-1],d[mm],&shift,&rr_); }
            else { sll=fabs(d[mm]); dlas2(d[lo],e[lo],d[lo+1],&shift,&rr_); }
            if(sll>0.0){ rl q=shift/sll; if(q*q<eps) shift=0.0; }
          }
          iter += mm-lo;
          int cnt=mm-lo;
          if(shift==0.0){
            if(idir==1){
              rl cs=1.0, oldcs=1.0, sn=0.0, oldsn=0.0, r;
              for(int i=lo;i<mm;++i){
                dlartg(d[i]*cs,e[i],&cs,&sn,&r);
                if(i>lo) e[i-1]=oldsn*r;
                dlartg(oldcs*r, d[i+1]*sn, &oldcs,&oldsn,&d[i]);
                lc->b1[i-lo]=cs; lc->b2[i-lo]=sn; lc->b3[i-lo]=oldcs; lc->b4[i-lo]=oldsn;
              }
              rl h=d[mm]*cs; d[mm]=h*oldcs; e[mm-1]=h*oldsn;
              p_fwd=1;
              if(fabs(e[mm-1])<=thresh) e[mm-1]=0.0;
            } else {
              rl cs=1.0, oldcs=1.0, sn=0.0, oldsn=0.0, r;
              for(int i=mm;i>lo;--i){
                dlartg(d[i]*cs,e[i-1],&cs,&sn,&r);
                if(i<mm) e[i]=oldsn*r;
                dlartg(oldcs*r,d[i-1]*sn,&oldcs,&oldsn,&d[i]);
                int j=i-lo-1;
                lc->b1[j]=oldcs; lc->b2[j]=-oldsn; lc->b3[j]=cs; lc->b4[j]=-sn;
              }
              rl h=d[lo]*cs; d[lo]=h*oldcs; e[lo]=h*oldsn;
              p_fwd=0;
              if(fabs(e[lo])<=thresh) e[lo]=0.0;
            }
          } else {
            if(idir==1){
              rl f2=(fabs(d[lo])-shift)*(d_sign(1.0,d[lo])+shift/d[lo]);
              rl g2=e[lo], r, cosr,sinr,cosl,sinl;
              for(int i=lo;i<mm;++i){
                dlartg(f2,g2,&cosr,&sinr,&r);
                if(i>lo) e[i-1]=r;
                f2=cosr*d[i]+sinr*e[i];
                e[i]=cosr*e[i]-sinr*d[i];
                g2=sinr*d[i+1];
                d[i+1]=cosr*d[i+1];
                dlartg(f2,g2,&cosl,&sinl,&r);
                d[i]=r;
                f2=cosl*e[i]+sinl*d[i+1];
                d[i+1]=cosl*d[i+1]-sinl*e[i];
                if(i<mm-1){ g2=sinl*e[i+1]; e[i+1]=cosl*e[i+1]; }
                lc->b1[i-lo]=cosr; lc->b2[i-lo]=sinr; lc->b3[i-lo]=cosl; lc->b4[i-lo]=sinl;
              }
              e[mm-1]=f2;
              p_fwd=1;
              if(fabs(e[mm-1])<=thresh) e[mm-1]=0.0;
            } else {
              rl f2=(fabs(d[mm])-shift)*(d_sign(1.0,d[mm])+shift/d[mm]);
              rl g2=e[mm-1], r, cosr,sinr,cosl,sinl;
              for(int i=mm;i>lo;--i){
                dlartg(f2,g2,&cosr,&sinr,&r);
                if(i<mm) e[i]=r;
                f2=cosr*d[i]+sinr*e[i-1];
                e[i-1]=cosr*e[i-1]-sinr*d[i];
                g2=sinr*d[i-1];
                d[i-1]=cosr*d[i-1];
                dlartg(f2,g2,&cosl,&sinl,&r);
                d[i]=r;
                f2=cosl*e[i-1]+sinl*d[i-1];
                d[i-1]=cosl*d[i-1]-sinl*e[i-1];
                if(i>lo+1){ g2=sinl*e[i-2]; e[i-2]=cosl*e[i-2]; }
                int j=i-lo-1;
                lc->b1[j]=cosl; lc->b2[j]=-sinl; lc->b3[j]=cosr; lc->b4[j]=-sinr;
              }
              e[lo]=f2;
              p_fwd=0;
              if(fabs(e[lo])<=thresh) e[lo]=0.0;
            }
          }
          act=1; p_lo=lo; p_cnt=cnt;
          break;
        }
        lc->si[7]=act; lc->si[8]=p_lo; lc->si[9]=p_cnt; lc->si[10]=p_fwd; lc->si[11]=p_mm;
      }
      wsync();
      int act=lc->si[7];
      if(act==0) break;
      if(act==1){
        int lo=lc->si[8], cnt=lc->si[9], fwd=lc->si[10];
        if(lane<ncvt){
          int k=lane;
          if(fwd){
            rl cur = lc->LVT[lo*LP+k];
            for(int j=0;j<cnt;++j){
              rl c=lc->b1[j], s=lc->b2[j];
              rl t = lc->LVT[(lo+j+1)*LP+k];
              lc->LVT[(lo+j)*LP+k] = s*t + c*cur;
              cur = c*t - s*cur;
            }
            lc->LVT[(lo+cnt)*LP+k] = cur;
          } else {
            rl tcar = lc->LVT[(lo+cnt)*LP+k];
            for(int j=cnt-1;j>=0;--j){
              rl c=lc->b1[j], s=lc->b2[j];
              rl low = lc->LVT[(lo+j)*LP+k];
              lc->LVT[(lo+j+1)*LP+k] = c*tcar - s*low;
              tcar = s*tcar + c*low;
            }
            lc->LVT[lo*LP+k] = tcar;
          }
        } else if(lane<ncvt+nru){
          int r2=lane-ncvt;
          if(fwd){
            rl cur = lc->LU[r2*LP+lo];
            for(int j=0;j<cnt;++j){
              rl c=lc->b3[j], s=lc->b4[j];
              rl t = lc->LU[r2*LP+(lo+j+1)];
              lc->LU[r2*LP+(lo+j)] = s*t + c*cur;
              cur = c*t - s*cur;
            }
            lc->LU[r2*LP+(lo+cnt)] = cur;
          } else {
            rl tcar = lc->LU[r2*LP+(lo+cnt)];
            for(int j=cnt-1;j>=0;--j){
              rl c=lc->b3[j], s=lc->b4[j];
              rl low = lc->LU[r2*LP+(lo+j)];
              lc->LU[r2*LP+(lo+j+1)] = c*tcar - s*low;
              tcar = s*tcar + c*low;
            }
            lc->LU[r2*LP+lo] = tcar;
          }
        }
      } else {
        int lo=lc->si[8], m2=lc->si[11];
        rl cosr=lc->sc[0], sinr=lc->sc[1], cosl=lc->sc[2], sinl=lc->sc[3];
        if(lane<ncvt){
          rl x=lc->LVT[lo*LP+lane], y=lc->LVT[m2*LP+lane];
          lc->LVT[lo*LP+lane]=cosr*x+sinr*y; lc->LVT[m2*LP+lane]=cosr*y-sinr*x;
        } else if(lane<ncvt+nru){
          int r2=lane-ncvt;
          rl x=lc->LU[r2*LP+lo], y=lc->LU[r2*LP+m2];
          lc->LU[r2*LP+lo]=cosl*x+sinl*y; lc->LU[r2*LP+m2]=cosl*y-sinl*x;
        }
      }
      wsync();
    }
  }
  if(lane==0){
    for(int i=0;i<n;++i){ lc->ic[i]=(d[i]<0.0)?1:0; if(d[i]<0.0) d[i]=-d[i]; }
    int nsw=0;
    for(int i=0;i<n-1;++i){
      int isub=0; rl smin=d[0];
      for(int j=1;j<n-i;++j){ if(d[j]<=smin){ isub=j; smin=d[j]; } }
      int tgt=n-1-i;
      if(isub!=tgt){
        d[isub]=d[tgt]; d[tgt]=smin;
        lc->ia[nsw]=isub; lc->ib[nsw]=tgt; ++nsw;
      }
    }
    lc->si[7]=nsw;
  }
  wsync();
  int nsw=lc->si[7];
  if(lane<ncvt){
    for(int i=0;i<n;++i) if(lc->ic[i]) lc->LVT[i*LP+lane]=-lc->LVT[i*LP+lane];
    for(int w2=0;w2<nsw;++w2){
      int a=lc->ia[w2], b=lc->ib[w2];
      rl t=lc->LVT[a*LP+lane]; lc->LVT[a*LP+lane]=lc->LVT[b*LP+lane]; lc->LVT[b*LP+lane]=t;
    }
  } else if(lane<ncvt+nru){
    int r2=lane-ncvt;
    for(int w2=0;w2<nsw;++w2){
      int a=lc->ia[w2], b=lc->ib[w2];
      rl t=lc->LU[r2*LP+a]; lc->LU[r2*LP+a]=lc->LU[r2*LP+b]; lc->LU[r2*LP+b]=t;
    }
  }
  wsync();
}

// ---- leaf: dlasdq, entirely within one wave ----
__device__ void leaf_exec(int f, int n, int sqre, int wantU, LeafCtx* lc, Sh* sh, int lane){
  rl* SVTB = g_ws + O_SVTB; rl* SUB = g_ws + O_SUB;
  int np = n + sqre;
  for(int w=lane; w<np*np; w+=64){ int r2=w/np, c=w-r2*np; lc->LVT[r2*LP+c]=SVTB[(f+r2)+(size_t)LDV*(f+c)]; }
  if(wantU) for(int w=lane; w<n*n; w+=64){ int r2=w/n, c=w-r2*n; lc->LU[r2*LP+c]=SUB[(f+r2)+(size_t)LDV*(f+c)]; }
  wsync();
  if(sqre==1){
    if(lane==0){
      rl cs,snv,rv; rl* dd=sh->d+f; rl* ee=sh->e+f;
      for(int i=0;i<n;++i){
        dlartg(dd[i],ee[i],&cs,&snv,&rv);
        dd[i]=rv;
        if(i<n-1){ ee[i]=snv*dd[i+1]; dd[i+1]=cs*dd[i+1]; }
        else ee[i]=0.0;
        lc->b1[i]=cs; lc->b2[i]=snv;
      }
    }
    wsync();
    if(lane<np){
      rl cur = lc->LVT[0*LP+lane];
      for(int j=0;j<n;++j){
        rl cj=lc->b1[j], sj=lc->b2[j];
        rl t=lc->LVT[(j+1)*LP+lane];
        lc->LVT[j*LP+lane] = sj*t + cj*cur;
        cur = cj*t - sj*cur;
      }
      lc->LVT[n*LP+lane] = cur;
    }
    wsync();
    if(lane==0){
      rl cs,snv,rv; rl* dd=sh->d+f; rl* ee=sh->e+f;
      for(int i=0;i<n-1;++i){
        dlartg(dd[i],ee[i],&cs,&snv,&rv);
        dd[i]=rv; ee[i]=snv*dd[i+1]; dd[i+1]=cs*dd[i+1];
        lc->b1[i]=cs; lc->b2[i]=snv;
      }
    }
    wsync();
    if(wantU && lane<n){
      rl cur = lc->LU[lane*LP+0];
      for(int j=0;j<n-1;++j){
        rl cj=lc->b1[j], sj=lc->b2[j];
        rl t=lc->LU[lane*LP+(j+1)];
        lc->LU[lane*LP+j] = sj*t + cj*cur;
        cur = cj*t - sj*cur;
      }
      lc->LU[lane*LP+(n-1)] = cur;
    }
    wsync();
  }
  bdsqr_wave(n, sh->d+f, sh->e+f, np, wantU? n:0, lc, lane);
  for(int w=lane; w<np*np; w+=64){ int r2=w/np, c=w-r2*np; SVTB[(f+r2)+(size_t)LDV*(f+c)]=lc->LVT[r2*LP+c]; }
  if(wantU) for(int w=lane; w<n*n; w+=64){ int r2=w/n, c=w-r2*n; SUB[(f+r2)+(size_t)LDV*(f+c)]=lc->LU[r2*LP+c]; }
}

// ---- op-list builder (post-order, leaves stable-partitioned first) ----
__device__ void build_ops(int n, Sh* sh, int tid){
  if(tid==0){
    int sf[12], sn2[12], sq[12], sv[12]; int sp=0, no=0;
    sf[0]=0; sn2[0]=n; sq[0]=0; sv[0]=0; sp=1;
    while(sp>0){
      --sp;
      int f=sf[sp], nn=sn2[sp], q=sq[sp], v=sv[sp];
      if(nn<=SML){ sh->opk[no]=0; sh->opf[no]=f; sh->opa[no]=nn; sh->opb[no]=0; sh->opq[no]=q; ++no; }
      else if(v==0){
        int nl=nn/2, nr=nn-nl-1;
        sf[sp]=f; sn2[sp]=nn; sq[sp]=q; sv[sp]=1; ++sp;
        sf[sp]=f+nl+1; sn2[sp]=nr; sq[sp]=q; sv[sp]=0; ++sp;
        sf[sp]=f; sn2[sp]=nl; sq[sp]=1; sv[sp]=0; ++sp;
      } else {
        int nl=nn/2, nr=nn-nl-1;
        sh->opk[no]=1; sh->opf[no]=f; sh->opa[no]=nl; sh->opb[no]=nr; sh->opq[no]=q; ++no;
      }
    }
    int tk[12], tf2[12], ta2[12], tb3[12], tq3[12]; int c=0;
    for(int i=0;i<no;++i) if(sh->opk[i]==0){ tk[c]=0; tf2[c]=sh->opf[i]; ta2[c]=sh->opa[i]; tb3[c]=sh->opb[i]; tq3[c]=sh->opq[i]; ++c; }
    for(int i=0;i<no;++i) if(sh->opk[i]==1){ tk[c]=1; tf2[c]=sh->opf[i]; ta2[c]=sh->opa[i]; tb3[c]=sh->opb[i]; tq3[c]=sh->opq[i]; ++c; }
    for(int i=0;i<no;++i){ sh->opk[i]=tk[i]; sh->opf[i]=tf2[i]; sh->opa[i]=ta2[i]; sh->opb[i]=tb3[i]; sh->opq[i]=tq3[i]; }
    sh->si[6]=no;
  }
  __syncthreads();
}

// ---- D&C merge (dlasd1/2/3) — setup parallelized bit-exactly ----
__device__ void lasd1_merge(int f, int nl, int nr, int sqre, int wantU, rl* QV, Sh* sh, int tid){
  rl* SUB = g_ws + O_SUB; rl* SVTB = g_ws + O_SVTB;
  rl* U2 = g_ws + O_U2; rl* VT2 = g_ws + O_VT2; rl* QU = g_ws + O_QU;
  int n = nl+nr+1, m = n+sqre;
  // A: parallel construction (independent pure expressions -> bit-identical)
  {
    rl alpha = sh->d[f+nl], beta = sh->e[f+nl];
    if(tid==0){
      sh->sc[0]=alpha; sh->sc[1]=beta;
      sh->vals[0]=0.0;
      sh->zz[0] = alpha*SVTB[(f+nl)+(size_t)LDV*(f+nl)];
      sh->srcU[0]=-1; sh->srcVT[0]=f+nl;
    } else if(tid<n){
      int i=tid;
      if(i<=nl){
        sh->vals[i]=sh->d[f+i-1];
        sh->zz[i]=alpha*SVTB[(f+i-1)+(size_t)LDV*(f+nl)];
        sh->srcU[i]=f+i-1; sh->srcVT[i]=f+i-1;
      } else {
        int j=i-1-nl;
        sh->vals[i]=sh->d[f+nl+1+j];
        sh->zz[i]=beta*SVTB[(f+nl+1+j)+(size_t)LDV*(f+nl+1)];
        sh->srcU[i]=f+nl+1+j; sh->srcVT[i]=f+nl+1+j;
      }
    }
  }
  __syncthreads();
  if(sqre==1){
    if(tid==0){
      rl zM = sh->sc[1]*SVTB[(f+n)+(size_t)LDV*(f+nl+1)];
      rl c,s2,r2;
      dlartg(sh->zz[0], zM, &c, &s2, &r2);
      sh->zz[0]=r2; sh->sc[2]=c; sh->sc[3]=s2;
    }
    __syncthreads();
    rl c=sh->sc[2], s=sh->sc[3];
    int ra=f+nl, rb=f+n;
    for(int k=tid;k<m;k+=NT){
      size_t ci=(size_t)LDV*(f+k);
      rl a=SVTB[ra+ci], b=SVTB[rb+ci];
      SVTB[ra+ci]=c*a+s*b; SVTB[rb+ci]=-s*a+c*b;
    }
  }
  __syncthreads();
  // B: parallel max reduce (fmax assoc+comm on non-NaN -> identical result)
  {
    rl lm = (tid<n)? fabs(sh->vals[tid]) : 0.0;
    for(int off=32;off>0;off>>=1) lm = fmax(lm, __shfl_xor(lm,off,64));
    if((tid&63)==0) sh->ta[tid>>6]=lm;
  }
  __syncthreads();
  {
    rl maxd = fmax(fmax(sh->ta[0],sh->ta[1]), fmax(sh->ta[2],sh->ta[3]));
    rl tol = 8.0*EPS32*fmax(maxd, fmax(fabs(sh->sc[0]), fabs(sh->sc[1])));
    // C: parallel stable rank-sort == exact insertion-sort permutation
    if(tid>=1 && tid<n){
      bool ndt = fabs(sh->zz[tid])>tol;
      rl vt = sh->vals[tid];
      int rank=0, Kc=0;
      for(int j=1;j<n;++j){
        bool ndj = fabs(sh->zz[j])>tol;
        if(ndj) ++Kc;
        if(ndj==ndt){
          rl vj=sh->vals[j];
          if(vj<vt || (vj==vt && j<tid)) ++rank;
        }
      }
      int pos = ndt ? (1+rank) : (1+Kc+rank);
      sh->ic[pos]=tid;
    }
    if(tid==0){
      int Kc=0;
      for(int j=1;j<n;++j) if(fabs(sh->zz[j])>tol) ++Kc;
      sh->ic[0]=0;
      sh->si[0]=1+Kc; sh->si[1]=n; sh->si[2]=m; sh->si[3]=f; sh->si[4]=nl;
    }
  }
  __syncthreads();
  int K=sh->si[0], n_=sh->si[1], m_=sh->si[2], f_=sh->si[3], nl_=sh->si[4];
  if(tid<n_){ sh->ta[tid]=sh->vals[tid]; sh->tb[tid]=sh->zz[tid]; sh->ia[tid]=sh->srcU[tid]; sh->ib[tid]=sh->srcVT[tid]; }
  __syncthreads();
  if(tid<n_){
    int p=sh->ic[tid];
    sh->dsig[tid]=sh->ta[p]; sh->zz[tid]=sh->tb[p]; sh->srcU[tid]=sh->ia[p]; sh->srcVT[tid]=sh->ib[p];
  }
  __syncthreads();
  // rho serial (order-sensitive sum) + parallel U2/VT2 gather
  if(tid==0){
    rl rho=0.0; for(int t=0;t<K;++t){ rl zv=sh->zz[t]; rho += zv*zv; }
    sh->sc[4]=rho;
  }
  if(wantU){
    for(int w=tid; w<n_*n_; w+=NT){
      int col=w/n_, row=w-col*n_;
      int su=sh->srcU[col];
      rl v;
      if(su<0) v = (row==nl_) ? 1.0 : 0.0;
      else v = SUB[(f_+row)+(size_t)LDV*su];
      U2[row+(size_t)LDV*col]=v;
    }
  }
  for(int w=tid; w<n_*m_; w+=NT){
    int row=w/m_, col=w-row*m_;
    VT2[row+(size_t)LDV*col] = SVTB[sh->srcVT[row]+(size_t)LDV*(f_+col)];
  }
  __syncthreads();
  rl rho=sh->sc[4];
  for(int j=tid;j<K;j+=NT){
    rl lo=sh->dsig[j];
    rl hi=(j<K-1)? sh->dsig[j+1] : sqrt(sh->dsig[K-1]*sh->dsig[K-1]+rho);
    for(int it=0; it<130; ++it){
      rl mid=0.5*(lo+hi);
      if(mid<=lo || mid>=hi) break;
      rl g=1.0;
      for(int i2=0;i2<K;++i2){
        rl zi=sh->zz[i2];
        g += zi*zi/((sh->dsig[i2]-mid)*(sh->dsig[i2]+mid));
      }
      if(g<0.0) lo=mid; else hi=mid;
    }
    sh->sigm[j]=0.5*(lo+hi);
  }
  __syncthreads();
  for(int i2=tid;i2<K;i2+=NT){
    rl di=sh->dsig[i2];
    rl p=(di - sh->sigm[K-1])*(di + sh->sigm[K-1]);
    for(int j=0;j<i2;++j)
      p *= (di - sh->sigm[j])*(di + sh->sigm[j])/((di - sh->dsig[j])*(di + sh->dsig[j]));
    for(int j=i2;j<K-1;++j)
      p *= (di - sh->sigm[j])*(di + sh->sigm[j])/((di - sh->dsig[j+1])*(di + sh->dsig[j+1]));
    sh->zh[i2] = d_sign(sqrt(fabs(p)), sh->zz[i2]);
  }
  __syncthreads();
  for(int j=tid;j<K;j+=NT){
    rl sj=sh->sigm[j];
    rl nu=0.0, nv=0.0;
    for(int i2=0;i2<K;++i2){
      rl di=sh->dsig[i2];
      rl vv=sh->zh[i2]/((di-sj)*(di+sj));
      QV[i2+(size_t)LDV*j]=vv; nv+=vv*vv;
      if(wantU){
        rl uu=(i2==0)? -1.0 : di*vv;
        QU[i2+(size_t)LDV*j]=uu; nu+=uu*uu;
      }
    }
    nv=1.0/sqrt(nv);
    for(int i2=0;i2<K;++i2) QV[i2+(size_t)LDV*j]*=nv;
    if(wantU){
      nu=1.0/sqrt(nu);
      for(int i2=0;i2<K;++i2) QU[i2+(size_t)LDV*j]*=nu;
    }
  }
  __syncthreads();
  if(tid==0){
    int nd2=n_-K;
    for(int t=0;t<nd2;++t) sh->ia[t]=K+t;
    int ps=K-1, pd=nd2-1;
    int t=0;
    while(t<n_){
      rl vs = (ps>=0)? sh->sigm[ps] : -1.0;
      rl vd = (pd>=0)? sh->dsig[sh->ia[pd]] : -1.0;
      if(vs >= vd){ sh->perm[t]=ps; sh->vals[t]=vs; --ps; }
      else { sh->perm[t]=1000+sh->ia[pd]; sh->vals[t]=vd; --pd; }
      ++t;
    }
  }
  __syncthreads();
  if(tid<n_) sh->d[f_+tid]=sh->vals[tid];
  if(wantU){
    for(int w=tid; w<n_*n_; w+=NT){
      int t=w/n_, row=w-t*n_;
      int src=sh->perm[t];
      rl acc;
      if(src>=1000) acc = U2[row+(size_t)LDV*(src-1000)];
      else{
        const rl* urow = U2 + row;
        const rl* qcol = QU + (size_t)LDV*src;
        rl s=0.0; int i=0;
        for(; i+16<=K; i+=16){
          rl a[16], b[16];
          #pragma unroll
          for(int u=0;u<16;++u){ a[u]=urow[(size_t)LDV*(size_t)(i+u)]; b[u]=qcol[i+u]; }
          #pragma unroll
          for(int u=0;u<16;++u) s += a[u]*b[u];
        }
        for(; i<K; ++i) s += urow[(size_t)LDV*i]*qcol[i];
        acc=s;
      }
      SUB[(f_+row)+(size_t)LDV*(f_+t)] = acc;
    }
  }
  for(int w=tid; w<n_*m_; w+=NT){
    int t=w/m_, col=w-t*m_;
    int src=sh->perm[t];
    rl acc;
    if(src>=1000) acc = VT2[(src-1000)+(size_t)LDV*col];
    else{
      const rl* qcol = QV + (size_t)LDV*src;
      const rl* vcol = VT2 + (size_t)LDV*col;
      rl s=0.0; int i=0;
      for(; i+16<=K; i+=16){
        rl a[16], b[16];
        #pragma unroll
        for(int u=0;u<16;++u){ a[u]=qcol[i+u]; b[u]=vcol[i+u]; }
        #pragma unroll
        for(int u=0;u<16;++u) s += a[u]*b[u];
      }
      for(; i<K; ++i) s += qcol[i]*vcol[i];
      acc=s;
    }
    SVTB[(f_+t)+(size_t)LDV*(f_+col)] = acc;
  }
  __syncthreads();
}

// ---- bidiagonalization (R2 structure) ----
__device__ __forceinline__ void gebd2_upper(rl* A, int ld, int m, int n, Sh* sh, int tid){
  const int lane = tid & 63;
  rl pend_scl = 0.0; int pend_ds = 0;
  for(int i=0;i<n;++i){
    rl ps=0.0;
    for(int r=i+1+lane;r<m;r+=64){ rl vv=A[r+(size_t)ld*i]; ps+=vv*vv; }
    for(int off=32;off>0;off>>=1) ps += __shfl_xor(ps,off,64);
    rl alpha=A[i+(size_t)ld*i];
    rl xn=sqrt(ps);
    rl beta,tau,scl; int ds;
    if(xn==0.0){ tau=0.0; beta=alpha; scl=0.0; ds=0; }
    else{ beta=-d_sign(dlapy2(alpha,xn),alpha); tau=(beta-alpha)/beta; scl=1.0/(alpha-beta); ds=1; }
    if(tid==0){ sh->d[i]=beta; sh->tq[i]=tau; }
    if(tau!=0.0)
      app_left_s(A, ld, i, m, i+1, n, A+(size_t)ld*i, scl, tau, tid);
    if(pend_ds && tid>=128){
      int c = i+1 + (tid-128);
      if(c < n) A[(i-1)+(size_t)ld*c] *= pend_scl;
    }
    __syncthreads();
    if(i<n-1){
      rl ps2=0.0;
      for(int c=i+2+lane;c<n;c+=64){ rl vv=A[i+(size_t)ld*c]; ps2+=vv*vv; }
      for(int off=32;off>0;off>>=1) ps2 += __shfl_xor(ps2,off,64);
      rl alpha2=A[i+(size_t)ld*(i+1)];
      rl xn2=sqrt(ps2);
      rl beta2,tau2,scl2; int ds2;
      if(xn2==0.0){ tau2=0.0; beta2=alpha2; scl2=0.0; ds2=0; }
      else{ beta2=-d_sign(dlapy2(alpha2,xn2),alpha2); tau2=(beta2-alpha2)/beta2; scl2=1.0/(alpha2-beta2); ds2=1; }
      if(tid==0){ sh->e[i]=beta2; sh->tp[i]=tau2; }
      if(tau2!=0.0)
        app_right_s(A, ld, i+1, m, i+1, n, A+i, ld, scl2, tau2, tid);
      if(ds && tid>=128){
        int r = i+1 + (tid-128);
        if(r < m) A[r+(size_t)ld*i] *= scl;
      }
      pend_ds = ds2; pend_scl = scl2;
      __syncthreads();
    } else {
      if(tid==0) sh->tp[i]=0.0;
      __syncthreads();
      if(ds) for(int r=i+1+tid; r<m; r+=NT) A[r+(size_t)ld*(n-1)] *= scl;
      __syncthreads();
    }
  }
}

__device__ __forceinline__ void gebd2_lower(rl* A, int ld, int m, int n, Sh* sh, int tid){
  const int lane = tid & 63;
  rl pend_scl = 0.0; int pend_ds = 0;
  int last_ds = 0; rl last_scl = 0.0;
  for(int i=0;i<m;++i){
    rl ps=0.0;
    for(int c=i+1+lane;c<n;c+=64){ rl vv=A[i+(size_t)ld*c]; ps+=vv*vv; }
    for(int off=32;off>0;off>>=1) ps += __shfl_xor(ps,off,64);
    rl alpha=A[i+(size_t)ld*i];
    rl xn=sqrt(ps);
    rl beta,tau,scl; int ds;
    if(xn==0.0){ tau=0.0; beta=alpha; scl=0.0; ds=0; }
    else{ beta=-d_sign(dlapy2(alpha,xn),alpha); tau=(beta-alpha)/beta; scl=1.0/(alpha-beta); ds=1; }
    if(tid==0){ sh->d[i]=beta; sh->tp[i]=tau; }
    if(tau!=0.0)
      app_right_s(A, ld, i+1, m, i, n, A+i, ld, scl, tau, tid);
    if(pend_ds && tid>=128){
      int r = i+1 + (tid-128);
      if(r < m) A[r+(size_t)ld*(i-1)] *= pend_scl;
    }
    __syncthreads();
    if(i<m-1){
      rl ps2=0.0;
      for(int r=i+2+lane;r<m;r+=64){ rl vv=A[r+(size_t)ld*i]; ps2+=vv*vv; }
      for(int off=32;off>0;off>>=1) ps2 += __shfl_xor(ps2,off,64);
      rl alpha2=A[(i+1)+(size_t)ld*i];
      rl xn2=sqrt(ps2);
      rl beta2,tau2,scl2; int ds2;
      if(xn2==0.0){ tau2=0.0; beta2=alpha2; scl2=0.0; ds2=0; }
      else{ beta2=-d_sign(dlapy2(alpha2,xn2),alpha2); tau2=(beta2-alpha2)/beta2; scl2=1.0/(alpha2-beta2); ds2=1; }
      if(tid==0){ sh->e[i]=beta2; sh->tq[i]=tau2; }
      if(tau2!=0.0)
        app_left_s(A, ld, i+1, m, i+1, n, A+(size_t)ld*i, scl2, tau2, tid);
      if(ds && tid>=128){
        int c = i+1 + (tid-128);
        if(c < n) A[i+(size_t)ld*c] *= scl;
      }
      pend_ds = ds2; pend_scl = scl2;
      __syncthreads();
    } else {
      last_ds = ds; last_scl = scl;
      __syncthreads();
      if(last_ds) for(int c=i+1+tid; c<n; c+=NT) A[(m-1)+(size_t)ld*c] *= last_scl;
      __syncthreads();
    }
  }
}

__device__ __forceinline__ void gelq2(rl* A, int ld, int m, int n, Sh* sh, int tid){
  const int lane = tid & 63;
  rl pend_scl=0.0, pend_beta=0.0; int pend_ds=0;
  for(int i=0;i<m;++i){
    rl ps=0.0;
    for(int c=i+1+lane;c<n;c+=64){ rl vv=A[i+(size_t)ld*c]; ps+=vv*vv; }
    for(int off=32;off>0;off>>=1) ps += __shfl_xor(ps,off,64);
    rl alpha=A[i+(size_t)ld*i];
    rl xn=sqrt(ps);
    rl beta,tau,scl; int ds;
    if(xn==0.0){ tau=0.0; beta=alpha; scl=0.0; ds=0; }
    else{ beta=-d_sign(dlapy2(alpha,xn),alpha); tau=(beta-alpha)/beta; scl=1.0/(alpha-beta); ds=1; }
    if(tid==0) sh->rs[i]=tau;
    if(i<m-1 && tau!=0.0)
      app_right_s(A, ld, i+1, m, i, n, A+i, ld, scl, tau, tid);
    if(i>0 && tid>=128){
      if(pend_ds){ int c = i + (tid-128); if(c<n) A[(i-1)+(size_t)ld*c] *= pend_scl; }
      if(tid==128) A[(i-1)+(size_t)ld*(i-1)] = pend_beta;
    }
    pend_ds=ds; pend_scl=scl; pend_beta=beta;
    __syncthreads();
  }
  if(tid>=128){
    if(pend_ds){ int c = m + (tid-128); if(c<n) A[(m-1)+(size_t)ld*c] *= pend_scl; }
    if(tid==128) A[(m-1)+(size_t)ld*(m-1)] = pend_beta;
  }
  __syncthreads();
}

// ======================================================================
// PHASE KERNELS
// ======================================================================

// K1: build A + bidiagonalization (dump MBL + d/e/tq/tp to g_ws)
__global__ __launch_bounds__(NT)
void k_bidiag(const float* __restrict__ ch, const float* __restrict__ ci,
              const float* __restrict__ ictx, const int* __restrict__ tok,
              int s, int m)
{
  __shared__ Sh sh;
  extern __shared__ rl MBL[];
  int tid = threadIdx.x;
  rl* MA = g_ws + O_MA; rl* MQ = g_ws + O_MQ; rl* TB = g_ws + O_TB;
  if(tid==0){
    rl W00=ch[s*4+0], W01=ch[s*4+1], W10=ch[s*4+2], W11=ch[s*4+3];
    rl P00=1,P01=0,P10=0,P11=1;
    for(int mexp=0;mexp<=70;++mexp){
      int j=70-mexp;
      rl v0,v1;
      if(j==0){ v0=ictx[s*2+0]; v1=ictx[s*2+1]; }
      else{
        int b=(tok[j-1]>>(15-s))&1;
        v0=ci[s*4+b]; v1=ci[s*4+2+b];
      }
      g_ws[O_COLS + 0 + 2*j] = P00*v0+P01*v1;
      g_ws[O_COLS + 1 + 2*j] = P10*v0+P11*v1;
      rl n00=W00*P00+W01*P10, n01=W00*P01+W01*P11;
      rl n10=W10*P00+W11*P10, n11=W10*P01+W11*P11;
      P00=n00;P01=n01;P10=n10;P11=n11;
    }
  }
  __syncthreads();
  for(int w=tid; w<m*NSV; w+=NT){
    int j=w/m, r2=w-j*m;
    int l=r2>>1, dd2=r2&1;
    rl cv = g_ws[O_COLS + dd2 + 2*j];
    MA[r2+(size_t)LDA*j] = (s==0)? cv : g_ws[O_CAR + l + 64*j]*cv;
  }
  __syncthreads();
  if(m==128){
    for(int w=tid;w<128*NSV;w+=NT){ int c=w>>7, r2=w&127; MBL[r2+(size_t)PB*c]=MA[r2+(size_t)LDA*c]; }
    __syncthreads();
    gebd2_upper(MBL, PB, 128, NSV, &sh, tid);
    for(int w=tid;w<PB*NSV;w+=NT) g_ws[O_MBLG+w]=MBL[w];
  } else if(m==64){
    for(int w=tid;w<64*NSV;w+=NT){ int c=w>>6, r2=w&63; MBL[r2+(size_t)PB*c]=MA[r2+(size_t)LDA*c]; }
    __syncthreads();
    gebd2_lower(MBL, PB, 64, NSV, &sh, tid);
    for(int w=tid;w<PB*NSV;w+=NT) g_ws[O_MBLG+w]=MBL[w];
  } else {
    for(int w=tid;w<m*NSV;w+=NT){ int c=w/m, r2=w-c*m; MBL[r2+(size_t)PB*c]=MA[r2+(size_t)LDA*c]; }
    __syncthreads();
    gelq2(MBL, PB, m, NSV, &sh, tid);
    for(int w=tid;w<m*NSV;w+=NT){ int c=w/m, r2=w-c*m; MQ[r2+(size_t)LDA*c]=(r2==c)?1.0:0.0; }
    __syncthreads();
    if(tid<m){
      int r=tid;
      for(int j=m-1;j>=0;--j){
        rl tau=sh.rs[j];
        if(tau!=0.0) row_apply(MQ + r + (size_t)LDA*j, LDA, MBL + j + (size_t)PB*(j+1), PB, NSV-j-1, tau);
      }
    }
    __syncthreads();
    for(int w=tid;w<m*m;w+=NT){ int c=w/m, r2=w-c*m; TB[r2+(size_t)LDV*c]=(r2>=c)? MBL[r2+(size_t)PB*c]:0.0; }
    __syncthreads();
    gebd2_upper(TB, LDV, m, m, &sh, tid);
  }
  if(tid<72){
    g_ws[O_D+tid]=sh.d[tid]; g_ws[O_E+tid]=sh.e[tid];
    g_ws[O_TQ+tid]=sh.tq[tid]; g_ws[O_TP+tid]=sh.tp[tid];
  }
}

// K2a: leaves only (4 per batch, one per wave/SIMD)
__global__ __launch_bounds__(NT)
void k_leaf(int s, int m)
{
  __shared__ Sh sh;
  __shared__ LeafCtx lct[4];
  int tid = threadIdx.x;
  if(tid<72){ sh.d[tid]=g_ws[O_D+tid]; sh.e[tid]=g_ws[O_E+tid]; }
  __syncthreads();
  int wantU = (s==8)?1:0;
  int n_eff = (m==128)? NSV : m;
  if(m==64){
    // dbdsdc_L pre-rotation (rc/rs not needed: wantU=0 for m==64)
    if(tid==0){
      for(int i=0;i<63;++i){
        rl cs,snv,rv;
        dlartg(sh.d[i], sh.e[i], &cs,&snv,&rv);
        sh.d[i]=rv; sh.e[i]=snv*sh.d[i+1]; sh.d[i+1]=cs*sh.d[i+1];
      }
    }
    __syncthreads();
  }
  rl* SUB = g_ws + O_SUB; rl* SVTB = g_ws + O_SVTB;
  for(int w=tid; w<LDV*LDV; w+=NT){
    int c=w/LDV, r2=w-c*LDV; rl v=(r2==c)?1.0:0.0;
    SVTB[w]=v;
    if(wantU) SUB[w]=v;
  }
  __syncthreads();
  if(n_eff<=SML){
    if((tid>>6)==0) leaf_exec(0, n_eff, 0, wantU, &lct[0], &sh, tid&63);
    __syncthreads();
  } else {
    build_ops(n_eff, &sh, tid);
    int no=sh.si[6];
    int o=0;
    while(o<no && sh.opk[o]==0){
      int cnt=1;
      while(o+cnt<no && sh.opk[o+cnt]==0 && cnt<4) ++cnt;
      int wid = tid>>6;
      if(wid<cnt) leaf_exec(sh.opf[o+wid], sh.opa[o+wid], sh.opq[o+wid], wantU, &lct[wid], &sh, tid&63);
      __syncthreads();
      o += cnt;
    }
  }
  if(tid<72){ g_ws[O_D+tid]=sh.d[tid]; g_ws[O_E+tid]=sh.e[tid]; }
}

// K2b: merges only (LDS-resident QV)
__global__ __launch_bounds__(NT)
void k_merge(int s, int m)
{
  __shared__ Sh sh;
  __shared__ rl QV[(size_t)LDV*71];
  int tid = threadIdx.x;
  if(tid<72){ sh.d[tid]=g_ws[O_D+tid]; sh.e[tid]=g_ws[O_E+tid]; }
  __syncthreads();
  int wantU = (s==8)?1:0;
  int n_eff = (m==128)? NSV : m;
  if(n_eff>SML){
    build_ops(n_eff, &sh, tid);
    int no=sh.si[6];
    for(int o=0;o<no;++o){
      if(sh.opk[o]==1)
        lasd1_merge(sh.opf[o], sh.opa[o], sh.opb[o], sh.opq[o], wantU, QV, &sh, tid);
    }
  }
  __syncthreads();
  if(tid<72) g_ws[O_D+tid]=sh.d[tid];
}

// K3: back-transforms + carry / final vec
__global__ __launch_bounds__(NT)
void k_post(const float* __restrict__ ch, int s, int m)
{
  __shared__ Sh sh;
  extern __shared__ rl MBL[];
  int tid = threadIdx.x;
  rl* MU=g_ws+O_MU; rl* MVT=g_ws+O_MVT; rl* MQ=g_ws+O_MQ;
  rl* SUB=g_ws+O_SUB; rl* SVTB=g_ws+O_SVTB; rl* TB=g_ws+O_TB; rl* VT2=g_ws+O_VT2;
  if(tid<72){
    sh.d[tid]=g_ws[O_D+tid];
    sh.tq[tid]=g_ws[O_TQ+tid];
    sh.tp[tid]=g_ws[O_TP+tid];
  }
  __syncthreads();
  int k = (m<64)? m : 64;
  if(m==128){
    if(s==8){
      for(int w=tid;w<128*NSV;w+=NT){ int c=w>>7, r2=w&127; MU[r2+(size_t)LDA*c]=(r2<NSV)? SUB[r2+(size_t)LDV*c]:0.0; }
      for(int w=tid;w<PB*NSV;w+=NT) MBL[w]=g_ws[O_MBLG+w];
      __syncthreads();
      if(tid<NSV){
        int c=tid;
        rl* colb = MU + (size_t)LDA*c;
        for(int i=NSV-1;i>=0;--i){
          rl tau=sh.tq[i];
          if(tau!=0.0) row_apply(colb+i, 1, MBL + (size_t)PB*i + i + 1, 1, 128-i-1, tau);
        }
      }
      __syncthreads();
      if(tid==0){
        rl W00=ch[8*4+0], W01=ch[8*4+1], W10=ch[8*4+2], W11=ch[8*4+3];
        rl P00=1,P01=0,P10=0,P11=1;
        for(int it=0;it<30;++it){
          rl n00=W00*P00+W01*P10, n01=W00*P01+W01*P11;
          rl n10=W10*P00+W11*P10, n11=W10*P01+W11*P11;
          P00=n00;P01=n01;P10=n10;P11=n11;
        }
        sh.sc[0]=P00+P10; sh.sc[1]=P01+P11;
      }
      __syncthreads();
      for(int r2=tid; r2<64; r2+=NT){
        rl acc=0.0;
        for(int l=0;l<64;++l)
          acc += sh.sc[0]*MU[(2*l)+(size_t)LDA*r2] + sh.sc[1]*MU[(2*l+1)+(size_t)LDA*r2];
        g_ws[O_VEC + r2] = acc/188.0;
      }
    } else {
      for(int w=tid;w<LDV*NSV;w+=NT) MVT[w]=SVTB[w];
      for(int w=tid;w<PB*NSV;w+=NT) MBL[w]=g_ws[O_MBLG+w];
      __syncthreads();
      if(tid<NSV){
        int r=tid;
        for(int i=NSV-2;i>=0;--i){
          rl tau=sh.tp[i];
          if(tau!=0.0) row_apply(MVT + r + (size_t)LDV*(i+1), LDV, MBL + i + (size_t)PB*(i+2), PB, NSV-i-2, tau);
        }
      }
      __syncthreads();
      for(int w=tid; w<k*NSV; w+=NT){
        int j=w/k, l=w-j*k;
        g_ws[O_CAR + l + 64*j] = sh.d[l]*MVT[l+(size_t)LDV*j];
      }
    }
  } else if(m==64){
    for(int w=tid;w<64*NSV;w+=NT){ int c=w>>6, r2=w&63; MVT[r2+(size_t)LDV*c]=(c<64)? SVTB[r2+(size_t)LDV*c]:0.0; }
    for(int w=tid;w<PB*NSV;w+=NT) MBL[w]=g_ws[O_MBLG+w];
    __syncthreads();
    if(tid<64){
      int r=tid;
      for(int i=63;i>=0;--i){
        rl tau=sh.tp[i];
        if(tau!=0.0) row_apply(MVT + r + (size_t)LDV*i, LDV, MBL + i + (size_t)PB*(i+1), PB, NSV-i-1, tau);
      }
    }
    __syncthreads();
    for(int w=tid; w<k*NSV; w+=NT){
      int j=w/k, l=w-j*k;
      g_ws[O_CAR + l + 64*j] = sh.d[l]*MVT[l+(size_t)LDV*j];
    }
  } else {
    for(int w=tid;w<m*m;w+=NT){ int c=w/m, r2=w-c*m; VT2[r2+(size_t)LDV*c]=SVTB[r2+(size_t)LDV*c]; }
    __syncthreads();
    if(tid<m){
      int r=tid;
      for(int i=m-2;i>=0;--i){
        rl tau=sh.tp[i];
        if(tau!=0.0) row_apply(VT2 + r + (size_t)LDV*(i+1), LDV, TB + i + (size_t)LDV*(i+2), LDV, m-i-2, tau);
      }
    }
    __syncthreads();
    for(int w=tid;w<m*NSV;w+=NT){
      int c=w/m, r2=w-c*m;
      const rl* vrow = VT2 + r2;
      const rl* qcol = MQ + (size_t)LDA*c;
      rl s2=0.0; int t=0;
      for(; t+16<=m; t+=16){
        rl a[16], b[16];
        #pragma unroll
        for(int u=0;u<16;++u){ a[u]=vrow[(size_t)LDV*(size_t)(t+u)]; b[u]=qcol[t+u]; }
        #pragma unroll
        for(int u=0;u<16;++u) s2 += a[u]*b[u];
      }
      for(; t+4<=m; t+=4){
        rl a0=vrow[(size_t)LDV*t], a1=vrow[(size_t)LDV*(t+1)], a2=vrow[(size_t)LDV*(t+2)], a3=vrow[(size_t)LDV*(t+3)];
        rl b0=qcol[t], b1=qcol[t+1], b2=qcol[t+2], b3=qcol[t+3];
        s2+=a0*b0; s2+=a1*b1; s2+=a2*b2; s2+=a3*b3;
      }
      for(; t<m; ++t) s2 += vrow[(size_t)LDV*t]*qcol[t];
      MVT[r2+(size_t)LDV*c]=s2;
    }
    __syncthreads();
    for(int w=tid; w<k*NSV; w+=NT){
      int j=w/k, l=w-j*k;
      g_ws[O_CAR + l + 64*j] = sh.d[l]*MVT[l+(size_t)LDV*j];
    }
  }
}

__global__ __launch_bounds__(NT)
void head_kernel(const float* __restrict__ hw, const float* __restrict__ hb,
                 float* __restrict__ out)
{
  __shared__ float v[64];
  int tid=threadIdx.x;
  if(tid<64) v[tid]=(float)g_ws[O_VEC + tid];
  __syncthreads();
  int i = blockIdx.x*NT + tid;
  if(i<VOCAB){
    const float4* row = (const float4*)(hw + (size_t)i*64);
    float acc=0.f;
    #pragma unroll
    for(int c4=0;c4<16;++c4){
      float4 r4=row[c4];
      acc += r4.x*v[4*c4] + r4.y*v[4*c4+1] + r4.z*v[4*c4+2] + r4.w*v[4*c4+3];
    }
    out[i]=acc+hb[i];
  }
}

extern "C" void kernel_launch(void* const* d_in, const int* in_sizes, int n_in,
                              void* d_out, int out_size, void* d_ws, size_t ws_size,
                              hipStream_t stream)
{
  const float* ch  = (const float*)d_in[0];
  const float* ci  = (const float*)d_in[1];
  const float* hw  = (const float*)d_in[2];
  const float* hb  = (const float*)d_in[3];
  const float* ict = (const float*)d_in[4];
  const int*   tk  = (const int*)d_in[5];
  (void)d_ws; (void)ws_size; (void)in_sizes; (void)n_in; (void)out_size;

  static const int ms[9] = {2,4,8,16,32,64,128,128,128};
  size_t dynls = (size_t)PB*NSV*sizeof(double);   // 73272 B
  for(int s=0;s<9;++s){
    hipLaunchKernelGGL(k_bidiag, dim3(1), dim3(NT), dynls, stream, ch, ci, ict, tk, s, ms[s]);
    hipLaunchKernelGGL(k_leaf,   dim3(1), dim3(NT), 0,     stream, s, ms[s]);
    if(ms[s] >= 32)
      hipLaunchKernelGGL(k_merge, dim3(1), dim3(NT), 0,    stream, s, ms[s]);
    hipLaunchKernelGGL(k_post,   dim3(1), dim3(NT), dynls, stream, ch, s, ms[s]);
  }
  hipLaunchKernelGGL(head_kernel, dim3((VOCAB+NT-1)/NT), dim3(NT), 0, stream,
                     hw, hb, (float*)d_out);
}

// Round 7
// 7318.795 us; speedup vs baseline: 1.5999x; 1.1099x over previous
//
#include <hip/hip_runtime.h>

typedef double rl;
#define NT 256
#define NSV 71
#define LDA 128
#define LDV 72
#define SML 25
#define VOCAB 128000
#define LP 27   // LDS leaf pitch
#define PB 129  // LDS pitch for bidiag working matrix

// fp32 LAPACK constants (reference is numpy sgesdd in float32)
#define EPS32 1.1920928955078125e-7
#define UNFL32 1.17549435e-38

// g_ws offsets (doubles)
#define O_CAR   0
#define O_COLS  4608
#define O_VEC   4800
#define O_MA    5120
#define O_MBLG  14208   // MBL dump: PB*NSV=9159 doubles
#define O_MU    23552
#define O_MQ    32768
#define O_MVT   41984
#define O_SUB   47168
#define O_SVTB  52352
#define O_U2    57536
#define O_VT2   62720
#define O_QU    67904
#define O_QV    73088
#define O_TB    78272
#define O_D     83456   // cross-kernel scalars (72 each)
#define O_E     83528
#define O_TQ    83600
#define O_TP    83672

__device__ double g_ws[84000];

struct LeafCtx {
  rl LVT[26*LP], LU[26*LP];
  rl b1[26], b2[26], b3[26], b4[26];
  rl sc[6];
  int ia[26], ib[26], ic[26];
  int si[12];
};

// sc/si doubled: slot A uses sc[0..7]/si[0..7], slot B sc[8..15]/si[8..15].
struct Sh {
  rl d[72], e[72], tq[72], tp[72], rc[72], rs[72];
  rl dsig[72], zz[72], zh[72], sigm[72], vals[72];
  rl ta[72], tb[72];
  int srcU[72], srcVT[72], perm[72];
  int ia[72], ib[72], ic[72];
  int opk[12], opf[12], opa[12], opb[12], opq[12];
  rl sc[16];
  int si[24];
};

__device__ __forceinline__ void wsync(){
  asm volatile("s_waitcnt vmcnt(0) lgkmcnt(0)" ::: "memory");
}

__device__ __forceinline__ rl d_sign(rl a, rl b){ return (b >= 0.0) ? fabs(a) : -fabs(a); }
__device__ __forceinline__ rl dlapy2(rl x, rl y){
  rl ax=fabs(x), ay=fabs(y);
  rl w = ax>ay?ax:ay, z = ax>ay?ay:ax;
  if(z==0.0) return w;
  rl t = z/w; return w*sqrt(1.0+t*t);
}
__device__ void dlartg(rl f, rl g, rl* cs, rl* sn, rl* r){
  if(g==0.0){ *cs=1.0; *sn=0.0; *r=f; }
  else if(f==0.0){ *cs=0.0; *sn=d_sign(1.0,g); *r=fabs(g); }
  else{
    rl dd = sqrt(f*f+g*g);
    *cs = fabs(f)/dd;
    *r  = d_sign(dd, f);
    *sn = g/(*r);
  }
}

__device__ void dlas2(rl f, rl g, rl h, rl* ssmin, rl* ssmax){
  rl fa=fabs(f), ga=fabs(g), ha=fabs(h);
  rl fhmn=fmin(fa,ha), fhmx=fmax(fa,ha);
  if(fhmn==0.0){
    *ssmin=0.0;
    if(fhmx==0.0) *ssmax=ga;
    else { rl mx=fmax(fhmx,ga), mn=fmin(fhmx,ga); rl q=mn/mx; *ssmax=mx*sqrt(1.0+q*q); }
  } else {
    if(ga < fhmx){
      rl as=1.0+fhmn/fhmx, at=(fhmx-fhmn)/fhmx;
      rl au=(ga/fhmx); au=au*au;
      rl c=2.0/(sqrt(as*as+au)+sqrt(at*at+au));
      *ssmin=fhmn*c; *ssmax=fhmx/c;
    } else {
      rl au=fhmx/ga;
      if(au==0.0){ *ssmin=(fhmn*fhmx)/ga; *ssmax=ga; }
      else{
        rl as=1.0+fhmn/fhmx, at=(fhmx-fhmn)/fhmx;
        rl c=1.0/(sqrt(1.0+(as*au)*(as*au))+sqrt(1.0+(at*au)*(at*au)));
        *ssmin=(fhmn*c)*au; *ssmin=*ssmin+*ssmin;
        *ssmax=ga/(c+c);
      }
    }
  }
}

__device__ void dlasv2(rl f, rl g, rl h, rl* ssmin, rl* ssmax, rl* snr, rl* csr, rl* snl, rl* csl){
  rl ft=f, fa=fabs(f), ht=h, ha=fabs(h);
  int pmax=1;
  bool swp = (ha > fa);
  if(swp){ pmax=3; rl t=ft; ft=ht; ht=t; t=fa; fa=ha; ha=t; }
  rl gt=g, ga=fabs(g);
  rl clt=0, crt=0, slt=0, srt=0;
  if(ga==0.0){ *ssmin=ha; *ssmax=fa; clt=1.0; crt=1.0; slt=0.0; srt=0.0; }
  else{
    bool gasmal=true;
    if(ga > fa){
      pmax=2;
      if((fa/ga) < EPS32){
        gasmal=false;
        *ssmax=ga;
        if(ha>1.0) *ssmin=fa/(ga/ha); else *ssmin=(fa/ga)*ha;
        clt=1.0; slt=ht/gt; srt=1.0; crt=ft/gt;
      }
    }
    if(gasmal){
      rl dd=fa-ha;
      rl lv = (dd==fa) ? 1.0 : dd/fa;
      rl mq = gt/ft;
      rl tv = 2.0-lv;
      rl mm = mq*mq, tt = tv*tv;
      rl sv = sqrt(tt+mm);
      rl rv = (lv==0.0) ? fabs(mq) : sqrt(lv*lv+mm);
      rl a = 0.5*(sv+rv);
      *ssmin = ha/a; *ssmax = fa*a;
      rl t3;
      if(mm==0.0){
        if(lv==0.0) t3 = d_sign(2.0, ft)*d_sign(1.0, gt);
        else t3 = gt/d_sign(dd, ft) + mq/tv;
      } else {
        t3 = (mq/(sv+tv) + mq/(rv+lv))*(1.0+a);
      }
      rl l2 = sqrt(t3*t3+4.0);
      crt = 2.0/l2; srt = t3/l2;
      clt = (crt + srt*mq)/a;
      slt = (ht/ft)*srt/a;
    }
  }
  if(swp){ *csl=srt; *snl=crt; *csr=slt; *snr=clt; }
  else  { *csl=clt; *snl=slt; *csr=crt; *snr=srt; }
  rl tsign=1.0;
  if(pmax==1) tsign = d_sign(1.0,*csr)*d_sign(1.0,*csl)*d_sign(1.0,f);
  if(pmax==2) tsign = d_sign(1.0,*snr)*d_sign(1.0,*csl)*d_sign(1.0,g);
  if(pmax==3) tsign = d_sign(1.0,*snr)*d_sign(1.0,*snl)*d_sign(1.0,h);
  *ssmax = d_sign(*ssmax, tsign);
  *ssmin = d_sign(*ssmin, tsign*d_sign(1.0,f)*d_sign(1.0,h));
}

// Thread-local Householder apply (16-wide grouped loads, sequential adds).
__device__ __forceinline__ void row_apply(rl* row, size_t ld, const rl* v, size_t vs, int len, rl tau){
  rl s = row[0];
  int i=0;
  for(; i+16<=len; i+=16){
    rl a[16], b[16];
    #pragma unroll
    for(int u=0;u<16;++u){ a[u]=row[ld*(size_t)(1+i+u)]; b[u]=v[vs*(size_t)(i+u)]; }
    #pragma unroll
    for(int u=0;u<16;++u) s += a[u]*b[u];
  }
  for(; i<len; ++i) s += row[ld*(size_t)(1+i)]*v[vs*(size_t)i];
  rl w = s*tau;
  row[0] -= w;
  i=0;
  for(; i+16<=len; i+=16){
    rl b[16];
    #pragma unroll
    for(int u=0;u<16;++u) b[u]=v[vs*(size_t)(i+u)];
    #pragma unroll
    for(int u=0;u<16;++u) row[ld*(size_t)(1+i+u)] -= w*b[u];
  }
  for(; i<len; ++i) row[ld*(size_t)(1+i)] -= w*v[vs*(size_t)i];
}

__device__ __forceinline__ void app_left_s(rl* A, int ld, int r0, int m, int c0, int n, const rl* vbase, rl scl, rl tau, int tid){
  const int len = m - r0 - 1;
  const rl* v = vbase + r0 + 1;
  int c = c0 + tid;
  if(c < n){
    rl* col = A + (size_t)ld*c + r0;
    rl s = col[0];
    int i=0;
    for(; i+16<=len; i+=16){
      rl a[16], b[16];
      #pragma unroll
      for(int u=0;u<16;++u){ a[u]=col[1+i+u]; b[u]=v[i+u]*scl; }
      #pragma unroll
      for(int u=0;u<16;++u) s += a[u]*b[u];
    }
    for(; i<len; ++i) s += col[1+i]*(v[i]*scl);
    rl w = s*tau;
    col[0] -= w;
    i=0;
    for(; i+16<=len; i+=16){
      rl b[16];
      #pragma unroll
      for(int u=0;u<16;++u) b[u]=v[i+u]*scl;
      #pragma unroll
      for(int u=0;u<16;++u) col[1+i+u] -= w*b[u];
    }
    for(; i<len; ++i) col[1+i] -= w*(v[i]*scl);
  }
}
__device__ __forceinline__ void app_right_s(rl* A, int ld, int r0, int m, int c0, int n, const rl* vbase, int vstride, rl scl, rl tau, int tid){
  const int len = n - c0 - 1;
  const rl* v = vbase + (size_t)vstride*(c0+1);
  int r = r0 + tid;
  if(r < m){
    rl* row = A + r + (size_t)ld*c0;
    rl s = row[0];
    int i=0;
    for(; i+16<=len; i+=16){
      rl a[16], b[16];
      #pragma unroll
      for(int u=0;u<16;++u){ a[u]=row[(size_t)ld*(size_t)(1+i+u)]; b[u]=v[(size_t)vstride*(size_t)(i+u)]*scl; }
      #pragma unroll
      for(int u=0;u<16;++u) s += a[u]*b[u];
    }
    for(; i<len; ++i) s += row[(size_t)ld*(1+i)]*(v[(size_t)vstride*i]*scl);
    rl w = s*tau;
    row[0] -= w;
    i=0;
    for(; i+16<=len; i+=16){
      rl b[16];
      #pragma unroll
      for(int u=0;u<16;++u) b[u]=v[(size_t)vstride*(size_t)(i+u)]*scl;
      #pragma unroll
      for(int u=0;u<16;++u) row[(size_t)ld*(size_t)(1+i+u)] -= w*b[u];
    }
    for(; i<len; ++i) row[(size_t)ld*(1+i)] -= w*(v[(size_t)vstride*i]*scl);
  }
}

// ---- wave-scoped dbdsqr on a private LDS leaf block ----
__device__ void bdsqr_wave(int n, rl* d, rl* e, int ncvt, int nru, LeafCtx* lc, int lane){
  if(n>1){
    rl eps=EPS32, unfl=UNFL32;
    rl tolmul=fmax(10.0,fmin(100.0,pow(eps,-0.125)));
    rl tol=tolmul*eps;
    rl thresh=0.0;
    int mm=n-1, oldll=-2, oldm=-2, idir=0, iter=0, maxit=6*n*n;
    if(lane==0){
      rl sminoa=fabs(d[0]);
      if(sminoa!=0.0){
        rl mu=sminoa;
        for(int i=1;i<n;++i){ mu=fabs(d[i])*(mu/(mu+fabs(e[i-1]))); sminoa=fmin(sminoa,mu); if(sminoa==0.0)break; }
      }
      sminoa=sminoa/sqrt((rl)n);
      thresh=fmax(tol*sminoa,(rl)(6*n*n)*unfl);
    }
    while(true){
      if(lane==0){
        int act=0, p_lo=0, p_cnt=0, p_fwd=1, p_mm=0;
        while(mm>0){
          if(iter>maxit) break;
          rl smax=fabs(d[mm]), smin=smax;
          int ll=-1;
          for(int lll=mm-1;lll>=0;--lll){
            rl abss=fabs(d[lll]), abse=fabs(e[lll]);
            if(abse<=thresh){ ll=lll; break; }
            smin=fmin(smin,abss);
            smax=fmax(smax,fmax(abss,abse));
          }
          if(ll==mm-1){ e[ll]=0.0; mm=mm-1; continue; }
          if(ll>=0) e[ll]=0.0;
          int lo=ll+1;
          if(mm==lo+1){
            rl sigmn,sigmx,sinr,cosr,sinl,cosl;
            dlasv2(d[lo],e[lo],d[mm],&sigmn,&sigmx,&sinr,&cosr,&sinl,&cosl);
            d[lo]=sigmx; d[mm]=sigmn; e[lo]=0.0;
            lc->sc[0]=cosr; lc->sc[1]=sinr; lc->sc[2]=cosl; lc->sc[3]=sinl;
            act=2; p_lo=lo; p_mm=mm;
            mm-=2;
            break;
          }
          if(lo>oldm || mm<oldll) idir=(fabs(d[lo])>=fabs(d[mm]))?1:2;
          rl sminl=0.0; int conv=0;
          if(idir==1){
            if(fabs(e[mm-1])<=tol*fabs(d[mm])){ e[mm-1]=0.0; conv=1; }
            if(!conv){
              rl mu=fabs(d[lo]); sminl=mu;
              for(int lll=lo;lll<mm;++lll){
                if(fabs(e[lll])<=tol*mu){ e[lll]=0.0; conv=1; break; }
                mu=fabs(d[lll+1])*(mu/(mu+fabs(e[lll])));
                sminl=fmin(sminl,mu);
              }
            }
          } else {
            if(fabs(e[lo])<=tol*fabs(d[lo])){ e[lo]=0.0; conv=1; }
            if(!conv){
              rl mu=fabs(d[mm]); sminl=mu;
              for(int lll=mm-1;lll>=lo;--lll){
                if(fabs(e[lll])<=tol*mu){ e[lll]=0.0; conv=1; break; }
                mu=fabs(d[lll])*(mu/(mu+fabs(e[lll])));
                sminl=fmin(sminl,mu);
              }
            }
          }
          if(conv) continue;
          oldll=lo; oldm=mm;
          rl shift=0.0, rr_;
          if(!((rl)n*tol*(sminl/smax) <= fmax(eps, 0.01*tol))){
            rl sll;
            if(idir==1){ sll=fabs(d[lo]); dlas2(d[mm-1],e[mm-1],d[mm],&shift,&rr_); }
            else { sll=fabs(d[mm]); dlas2(d[lo],e[lo],d[lo+1],&shift,&rr_); }
            if(sll>0.0){ rl q=shift/sll; if(q*q<eps) shift=0.0; }
          }
          iter += mm-lo;
          int cnt=mm-lo;
          if(shift==0.0){
            if(idir==1){
              rl cs=1.0, oldcs=1.0, sn=0.0, oldsn=0.0, r;
              for(int i=lo;i<mm;++i){
                dlartg(d[i]*cs,e[i],&cs,&sn,&r);
                if(i>lo) e[i-1]=oldsn*r;
                dlartg(oldcs*r, d[i+1]*sn, &oldcs,&oldsn,&d[i]);
                lc->b1[i-lo]=cs; lc->b2[i-lo]=sn; lc->b3[i-lo]=oldcs; lc->b4[i-lo]=oldsn;
              }
              rl h=d[mm]*cs; d[mm]=h*oldcs; e[mm-1]=h*oldsn;
              p_fwd=1;
              if(fabs(e[mm-1])<=thresh) e[mm-1]=0.0;
            } else {
              rl cs=1.0, oldcs=1.0, sn=0.0, oldsn=0.0, r;
              for(int i=mm;i>lo;--i){
                dlartg(d[i]*cs,e[i-1],&cs,&sn,&r);
                if(i<mm) e[i]=oldsn*r;
                dlartg(oldcs*r,d[i-1]*sn,&oldcs,&oldsn,&d[i]);
                int j=i-lo-1;
                lc->b1[j]=oldcs; lc->b2[j]=-oldsn; lc->b3[j]=cs; lc->b4[j]=-sn;
              }
              rl h=d[lo]*cs; d[lo]=h*oldcs; e[lo]=h*oldsn;
              p_fwd=0;
              if(fabs(e[lo])<=thresh) e[lo]=0.0;
            }
          } else {
            if(idir==1){
              rl f2=(fabs(d[lo])-shift)*(d_sign(1.0,d[lo])+shift/d[lo]);
              rl g2=e[lo], r, cosr,sinr,cosl,sinl;
              for(int i=lo;i<mm;++i){
                dlartg(f2,g2,&cosr,&sinr,&r);
                if(i>lo) e[i-1]=r;
                f2=cosr*d[i]+sinr*e[i];
                e[i]=cosr*e[i]-sinr*d[i];
                g2=sinr*d[i+1];
                d[i+1]=cosr*d[i+1];
                dlartg(f2,g2,&cosl,&sinl,&r);
                d[i]=r;
                f2=cosl*e[i]+sinl*d[i+1];
                d[i+1]=cosl*d[i+1]-sinl*e[i];
                if(i<mm-1){ g2=sinl*e[i+1]; e[i+1]=cosl*e[i+1]; }
                lc->b1[i-lo]=cosr; lc->b2[i-lo]=sinr; lc->b3[i-lo]=cosl; lc->b4[i-lo]=sinl;
              }
              e[mm-1]=f2;
              p_fwd=1;
              if(fabs(e[mm-1])<=thresh) e[mm-1]=0.0;
            } else {
              rl f2=(fabs(d[mm])-shift)*(d_sign(1.0,d[mm])+shift/d[mm]);
              rl g2=e[mm-1], r, cosr,sinr,cosl,sinl;
              for(int i=mm;i>lo;--i){
                dlartg(f2,g2,&cosr,&sinr,&r);
                if(i<mm) e[i]=r;
                f2=cosr*d[i]+sinr*e[i-1];
                e[i-1]=cosr*e[i-1]-sinr*d[i];
                g2=sinr*d[i-1];
                d[i-1]=cosr*d[i-1];
                dlartg(f2,g2,&cosl,&sinl,&r);
                d[i]=r;
                f2=cosl*e[i-1]+sinl*d[i-1];
                d[i-1]=cosl*d[i-1]-sinl*e[i-1];
                if(i>lo+1){ g2=sinl*e[i-2]; e[i-2]=cosl*e[i-2]; }
                int j=i-lo-1;
                lc->b1[j]=cosl; lc->b2[j]=-sinl; lc->b3[j]=cosr; lc->b4[j]=-sinr;
              }
              e[lo]=f2;
              p_fwd=0;
              if(fabs(e[lo])<=thresh) e[lo]=0.0;
            }
          }
          act=1; p_lo=lo; p_cnt=cnt;
          break;
        }
        lc->si[7]=act; lc->si[8]=p_lo; lc->si[9]=p_cnt; lc->si[10]=p_fwd; lc->si[11]=p_mm;
      }
      wsync();
      int act=lc->si[7];
      if(act==0) break;
      if(act==1){
        int lo=lc->si[8], cnt=lc->si[9], fwd=lc->si[10];
        if(lane<ncvt){
          int k=lane;
          if(fwd){
            rl cur = lc->LVT[lo*LP+k];
            for(int j=0;j<cnt;++j){
              rl c=lc->b1[j], s=lc->b2[j];
              rl t = lc->LVT[(lo+j+1)*LP+k];
              lc->LVT[(lo+j)*LP+k] = s*t + c*cur;
              cur = c*t - s*cur;
            }
            lc->LVT[(lo+cnt)*LP+k] = cur;
          } else {
            rl tcar = lc->LVT[(lo+cnt)*LP+k];
            for(int j=cnt-1;j>=0;--j){
              rl c=lc->b1[j], s=lc->b2[j];
              rl low = lc->LVT[(lo+j)*LP+k];
              lc->LVT[(lo+j+1)*LP+k] = c*tcar - s*low;
              tcar = s*tcar + c*low;
            }
            lc->LVT[lo*LP+k] = tcar;
          }
        } else if(lane<ncvt+nru){
          int r2=lane-ncvt;
          if(fwd){
            rl cur = lc->LU[r2*LP+lo];
            for(int j=0;j<cnt;++j){
              rl c=lc->b3[j], s=lc->b4[j];
              rl t = lc->LU[r2*LP+(lo+j+1)];
              lc->LU[r2*LP+(lo+j)] = s*t + c*cur;
              cur = c*t - s*cur;
            }
            lc->LU[r2*LP+(lo+cnt)] = cur;
          } else {
            rl tcar = lc->LU[r2*LP+(lo+cnt)];
            for(int j=cnt-1;j>=0;--j){
              rl c=lc->b3[j], s=lc->b4[j];
              rl low = lc->LU[r2*LP+(lo+j)];
              lc->LU[r2*LP+(lo+j+1)] = c*tcar - s*low;
              tcar = s*tcar + c*low;
            }
            lc->LU[r2*LP+lo] = tcar;
          }
        }
      } else {
        int lo=lc->si[8], m2=lc->si[11];
        rl cosr=lc->sc[0], sinr=lc->sc[1], cosl=lc->sc[2], sinl=lc->sc[3];
        if(lane<ncvt){
          rl x=lc->LVT[lo*LP+lane], y=lc->LVT[m2*LP+lane];
          lc->LVT[lo*LP+lane]=cosr*x+sinr*y; lc->LVT[m2*LP+lane]=cosr*y-sinr*x;
        } else if(lane<ncvt+nru){
          int r2=lane-ncvt;
          rl x=lc->LU[r2*LP+lo], y=lc->LU[r2*LP+m2];
          lc->LU[r2*LP+lo]=cosl*x+sinl*y; lc->LU[r2*LP+m2]=cosl*y-sinl*x;
        }
      }
      wsync();
    }
  }
  if(lane==0){
    for(int i=0;i<n;++i){ lc->ic[i]=(d[i]<0.0)?1:0; if(d[i]<0.0) d[i]=-d[i]; }
    int nsw=0;
    for(int i=0;i<n-1;++i){
      int isub=0; rl smin=d[0];
      for(int j=1;j<n-i;++j){ if(d[j]<=smin){ isub=j; smin=d[j]; } }
      int tgt=n-1-i;
      if(isub!=tgt){
        d[isub]=d[tgt]; d[tgt]=smin;
        lc->ia[nsw]=isub; lc->ib[nsw]=tgt; ++nsw;
      }
    }
    lc->si[7]=nsw;
  }
  wsync();
  int nsw=lc->si[7];
  if(lane<ncvt){
    for(int i=0;i<n;++i) if(lc->ic[i]) lc->LVT[i*LP+lane]=-lc->LVT[i*LP+lane];
    for(int w2=0;w2<nsw;++w2){
      int a=lc->ia[w2], b=lc->ib[w2];
      rl t=lc->LVT[a*LP+lane]; lc->LVT[a*LP+lane]=lc->LVT[b*LP+lane]; lc->LVT[b*LP+lane]=t;
    }
  } else if(lane<ncvt+nru){
    int r2=lane-ncvt;
    for(int w2=0;w2<nsw;++w2){
      int a=lc->ia[w2], b=lc->ib[w2];
      rl t=lc->LU[r2*LP+a]; lc->LU[r2*LP+a]=lc->LU[r2*LP+b]; lc->LU[r2*LP+b]=t;
    }
  }
  wsync();
}

// ---- leaf: dlasdq, entirely within one wave ----
__device__ void leaf_exec(int f, int n, int sqre, int wantU, LeafCtx* lc, Sh* sh, int lane){
  rl* SVTB = g_ws + O_SVTB; rl* SUB = g_ws + O_SUB;
  int np = n + sqre;
  for(int w=lane; w<np*np; w+=64){ int r2=w/np, c=w-r2*np; lc->LVT[r2*LP+c]=SVTB[(f+r2)+(size_t)LDV*(f+c)]; }
  if(wantU) for(int w=lane; w<n*n; w+=64){ int r2=w/n, c=w-r2*n; lc->LU[r2*LP+c]=SUB[(f+r2)+(size_t)LDV*(f+c)]; }
  wsync();
  if(sqre==1){
    if(lane==0){
      rl cs,snv,rv; rl* dd=sh->d+f; rl* ee=sh->e+f;
      for(int i=0;i<n;++i){
        dlartg(dd[i],ee[i],&cs,&snv,&rv);
        dd[i]=rv;
        if(i<n-1){ ee[i]=snv*dd[i+1]; dd[i+1]=cs*dd[i+1]; }
        else ee[i]=0.0;
        lc->b1[i]=cs; lc->b2[i]=snv;
      }
    }
    wsync();
    if(lane<np){
      rl cur = lc->LVT[0*LP+lane];
      for(int j=0;j<n;++j){
        rl cj=lc->b1[j], sj=lc->b2[j];
        rl t=lc->LVT[(j+1)*LP+lane];
        lc->LVT[j*LP+lane] = sj*t + cj*cur;
        cur = cj*t - sj*cur;
      }
      lc->LVT[n*LP+lane] = cur;
    }
    wsync();
    if(lane==0){
      rl cs,snv,rv; rl* dd=sh->d+f; rl* ee=sh->e+f;
      for(int i=0;i<n-1;++i){
        dlartg(dd[i],ee[i],&cs,&snv,&rv);
        dd[i]=rv; ee[i]=snv*dd[i+1]; dd[i+1]=cs*dd[i+1];
        lc->b1[i]=cs; lc->b2[i]=snv;
      }
    }
    wsync();
    if(wantU && lane<n){
      rl cur = lc->LU[lane*LP+0];
      for(int j=0;j<n-1;++j){
        rl cj=lc->b1[j], sj=lc->b2[j];
        rl t=lc->LU[lane*LP+(j+1)];
        lc->LU[lane*LP+j] = sj*t + cj*cur;
        cur = cj*t - sj*cur;
      }
      lc->LU[lane*LP+(n-1)] = cur;
    }
    wsync();
  }
  bdsqr_wave(n, sh->d+f, sh->e+f, np, wantU? n:0, lc, lane);
  for(int w=lane; w<np*np; w+=64){ int r2=w/np, c=w-r2*np; SVTB[(f+r2)+(size_t)LDV*(f+c)]=lc->LVT[r2*LP+c]; }
  if(wantU) for(int w=lane; w<n*n; w+=64){ int r2=w/n, c=w-r2*n; SUB[(f+r2)+(size_t)LDV*(f+c)]=lc->LU[r2*LP+c]; }
}

// ---- op-list builder (post-order, leaves stable-partitioned first) ----
__device__ void build_ops(int n, Sh* sh, int tid){
  if(tid==0){
    int sf[12], sn2[12], sq[12], sv[12]; int sp=0, no=0;
    sf[0]=0; sn2[0]=n; sq[0]=0; sv[0]=0; sp=1;
    while(sp>0){
      --sp;
      int f=sf[sp], nn=sn2[sp], q=sq[sp], v=sv[sp];
      if(nn<=SML){ sh->opk[no]=0; sh->opf[no]=f; sh->opa[no]=nn; sh->opb[no]=0; sh->opq[no]=q; ++no; }
      else if(v==0){
        int nl=nn/2, nr=nn-nl-1;
        sf[sp]=f; sn2[sp]=nn; sq[sp]=q; sv[sp]=1; ++sp;
        sf[sp]=f+nl+1; sn2[sp]=nr; sq[sp]=q; sv[sp]=0; ++sp;
        sf[sp]=f; sn2[sp]=nl; sq[sp]=1; sv[sp]=0; ++sp;
      } else {
        int nl=nn/2, nr=nn-nl-1;
        sh->opk[no]=1; sh->opf[no]=f; sh->opa[no]=nl; sh->opb[no]=nr; sh->opq[no]=q; ++no;
      }
    }
    int tk[12], tf2[12], ta2[12], tb3[12], tq3[12]; int c=0;
    for(int i=0;i<no;++i) if(sh->opk[i]==0){ tk[c]=0; tf2[c]=sh->opf[i]; ta2[c]=sh->opa[i]; tb3[c]=sh->opb[i]; tq3[c]=sh->opq[i]; ++c; }
    for(int i=0;i<no;++i) if(sh->opk[i]==1){ tk[c]=1; tf2[c]=sh->opf[i]; ta2[c]=sh->opa[i]; tb3[c]=sh->opb[i]; tq3[c]=sh->opq[i]; ++c; }
    for(int i=0;i<no;++i){ sh->opk[i]=tk[i]; sh->opf[i]=tf2[i]; sh->opa[i]=ta2[i]; sh->opb[i]=tb3[i]; sh->opq[i]=tq3[i]; }
    sh->si[6]=no;
  }
  __syncthreads();
}

// ---- D&C merge, slot-parallel version ----------------------------------
// base = 36*slot row/col/array offset; qofs = 36*slot QV/QU column offset;
// ltid in [0,lnt). All __syncthreads are unconditional at top level so two
// slots (different f/nl/nr/sqre) can execute concurrently in one block.
// Arithmetic and its ordering identical to the serial merge.
__device__ void lasd1_merge2(int f, int nl, int nr, int sqre, int wantU,
                             rl* QVL, int qofs, int base, Sh* sh, int ltid, int lnt){
  rl* SUB = g_ws + O_SUB; rl* SVTB = g_ws + O_SVTB;
  rl* U2 = g_ws + O_U2; rl* VT2 = g_ws + O_VT2; rl* QU = g_ws + O_QU;
  rl* sc = sh->sc + (base?8:0);
  int* si = sh->si + (base?16:0);   // slot A: si[0..5]; slot B: si[16..21] (si[6] reserved for ops)
  int n = nl+nr+1, m = n+sqre;
  // phase 1: parallel construction
  {
    rl alpha = sh->d[f+nl], beta = sh->e[f+nl];
    if(ltid==0){
      sc[0]=alpha; sc[1]=beta;
      sh->vals[base]=0.0;
      sh->zz[base] = alpha*SVTB[(f+nl)+(size_t)LDV*(f+nl)];
      sh->srcU[base]=-1; sh->srcVT[base]=f+nl;
    } else if(ltid<n){
      int i=ltid;
      if(i<=nl){
        sh->vals[base+i]=sh->d[f+i-1];
        sh->zz[base+i]=alpha*SVTB[(f+i-1)+(size_t)LDV*(f+nl)];
        sh->srcU[base+i]=f+i-1; sh->srcVT[base+i]=f+i-1;
      } else {
        int j=i-1-nl;
        sh->vals[base+i]=sh->d[f+nl+1+j];
        sh->zz[base+i]=beta*SVTB[(f+nl+1+j)+(size_t)LDV*(f+nl+1)];
        sh->srcU[base+i]=f+nl+1+j; sh->srcVT[base+i]=f+nl+1+j;
      }
    }
  }
  __syncthreads();
  // phase 2a: sqre head rotation (serial)
  if(ltid==0 && sqre==1){
    rl zM = sc[1]*SVTB[(f+n)+(size_t)LDV*(f+nl+1)];
    rl c,s2,r2;
    dlartg(sh->zz[base], zM, &c, &s2, &r2);
    sh->zz[base]=r2; sc[2]=c; sc[3]=s2;
  }
  __syncthreads();
  // phase 2b: row rotation
  if(sqre==1){
    rl c=sc[2], s=sc[3];
    int ra=f+nl, rb=f+n;
    for(int k=ltid;k<m;k+=lnt){
      size_t ci=(size_t)LDV*(f+k);
      rl a=SVTB[ra+ci], b=SVTB[rb+ci];
      SVTB[ra+ci]=c*a+s*b; SVTB[rb+ci]=-s*a+c*b;
    }
  }
  __syncthreads();
  // phase 3a: tol + deflation count (serial, same order as original)
  if(ltid==0){
    rl maxd=0.0; for(int i=0;i<n;++i) maxd=fmax(maxd,fabs(sh->vals[base+i]));
    rl tol = 8.0*EPS32*fmax(maxd, fmax(fabs(sc[0]), fabs(sc[1])));
    sc[5]=tol;
    int Kc=0;
    for(int j=1;j<n;++j) if(fabs(sh->zz[base+j]) > tol) ++Kc;
    sh->ic[base]=0;
    si[0]=1+Kc; si[1]=n; si[2]=m; si[3]=f; si[4]=nl;
  }
  __syncthreads();
  // phase 3b: parallel stable rank-sort (== insertion-sort permutation)
  {
    rl tol=sc[5];
    if(ltid>=1 && ltid<n){
      bool ndt = fabs(sh->zz[base+ltid])>tol;
      rl vt = sh->vals[base+ltid];
      int rank=0, Kc=0;
      for(int j=1;j<n;++j){
        bool ndj = fabs(sh->zz[base+j])>tol;
        if(ndj) ++Kc;
        if(ndj==ndt){
          rl vj=sh->vals[base+j];
          if(vj<vt || (vj==vt && j<ltid)) ++rank;
        }
      }
      int pos = ndt ? (1+rank) : (1+Kc+rank);
      sh->ic[base+pos]=ltid;
    }
  }
  __syncthreads();
  int K=si[0], n_=si[1], m_=si[2], f_=si[3], nl_=si[4];
  // phase 4: gather through permutation
  if(ltid<n_){ sh->ta[base+ltid]=sh->vals[base+ltid]; sh->tb[base+ltid]=sh->zz[base+ltid]; sh->ia[base+ltid]=sh->srcU[base+ltid]; sh->ib[base+ltid]=sh->srcVT[base+ltid]; }
  __syncthreads();
  if(ltid<n_){
    int p=sh->ic[base+ltid];
    sh->dsig[base+ltid]=sh->ta[base+p]; sh->zz[base+ltid]=sh->tb[base+p]; sh->srcU[base+ltid]=sh->ia[base+p]; sh->srcVT[base+ltid]=sh->ib[base+p];
  }
  __syncthreads();
  // phase 5: rho (serial, order-sensitive) + U2/VT2 gather
  if(ltid==0){
    rl rho=0.0; for(int t=0;t<K;++t){ rl zv=sh->zz[base+t]; rho += zv*zv; }
    sc[4]=rho;
  }
  if(wantU){
    for(int w=ltid; w<n_*n_; w+=lnt){
      int col=w/n_, row=w-col*n_;
      int su=sh->srcU[base+col];
      rl v;
      if(su<0) v = (row==nl_) ? 1.0 : 0.0;
      else v = SUB[(f_+row)+(size_t)LDV*su];
      U2[(base+row)+(size_t)LDV*(base+col)]=v;
    }
  }
  for(int w=ltid; w<n_*m_; w+=lnt){
    int row=w/m_, col=w-row*m_;
    VT2[(base+row)+(size_t)LDV*(base+col)] = SVTB[sh->srcVT[base+row]+(size_t)LDV*(f_+col)];
  }
  __syncthreads();
  // phase 6: secular bisection (one root per thread)
  {
    rl rho=sc[4];
    if(ltid<K){
      int j=ltid;
      rl lo=sh->dsig[base+j];
      rl hi=(j<K-1)? sh->dsig[base+j+1] : sqrt(sh->dsig[base+K-1]*sh->dsig[base+K-1]+rho);
      for(int it=0; it<130; ++it){
        rl mid=0.5*(lo+hi);
        if(mid<=lo || mid>=hi) break;
        rl g=1.0;
        for(int i2=0;i2<K;++i2){
          rl zi=sh->zz[base+i2];
          g += zi*zi/((sh->dsig[base+i2]-mid)*(sh->dsig[base+i2]+mid));
        }
        if(g<0.0) lo=mid; else hi=mid;
      }
      sh->sigm[base+j]=0.5*(lo+hi);
    }
  }
  __syncthreads();
  // phase 7: zh products
  if(ltid<K){
    int i2=ltid;
    rl di=sh->dsig[base+i2];
    rl p=(di - sh->sigm[base+K-1])*(di + sh->sigm[base+K-1]);
    for(int j=0;j<i2;++j)
      p *= (di - sh->sigm[base+j])*(di + sh->sigm[base+j])/((di - sh->dsig[base+j])*(di + sh->dsig[base+j]));
    for(int j=i2;j<K-1;++j)
      p *= (di - sh->sigm[base+j])*(di + sh->sigm[base+j])/((di - sh->dsig[base+j+1])*(di + sh->dsig[base+j+1]));
    sh->zh[base+i2] = d_sign(sqrt(fabs(p)), sh->zz[base+i2]);
  }
  __syncthreads();
  // phase 8: QV/QU columns
  if(ltid<K){
    int j=ltid;
    rl sj=sh->sigm[base+j];
    rl nu=0.0, nv=0.0;
    for(int i2=0;i2<K;++i2){
      rl di=sh->dsig[base+i2];
      rl vv=sh->zh[base+i2]/((di-sj)*(di+sj));
      QVL[i2+(size_t)LDV*(j+qofs)]=vv; nv+=vv*vv;
      if(wantU){
        rl uu=(i2==0)? -1.0 : di*vv;
        QU[i2+(size_t)LDV*(j+qofs)]=uu; nu+=uu*uu;
      }
    }
    nv=1.0/sqrt(nv);
    for(int i2=0;i2<K;++i2) QVL[i2+(size_t)LDV*(j+qofs)]*=nv;
    if(wantU){
      nu=1.0/sqrt(nu);
      for(int i2=0;i2<K;++i2) QU[i2+(size_t)LDV*(j+qofs)]*=nu;
    }
  }
  __syncthreads();
  // phase 9: two-pointer interleave (serial)
  if(ltid==0){
    int nd2=n_-K;
    for(int t=0;t<nd2;++t) sh->ia[base+t]=K+t;
    int ps=K-1, pd=nd2-1;
    int t=0;
    while(t<n_){
      rl vs = (ps>=0)? sh->sigm[base+ps] : -1.0;
      rl vd = (pd>=0)? sh->dsig[base+sh->ia[base+pd]] : -1.0;
      if(vs >= vd){ sh->perm[base+t]=ps; sh->vals[base+t]=vs; --ps; }
      else { sh->perm[base+t]=1000+sh->ia[base+pd]; sh->vals[base+t]=vd; --pd; }
      ++t;
    }
  }
  __syncthreads();
  // phase 10: d writeback + matmuls
  if(ltid<n_) sh->d[f_+ltid]=sh->vals[base+ltid];
  if(wantU){
    for(int w=ltid; w<n_*n_; w+=lnt){
      int t=w/n_, row=w-t*n_;
      int src=sh->perm[base+t];
      rl acc;
      if(src>=1000) acc = U2[(base+row)+(size_t)LDV*(base+(src-1000))];
      else{
        const rl* urow = U2 + (base+row) + (size_t)LDV*base;
        const rl* qcol = QU + (size_t)LDV*(src+qofs);
        rl s=0.0; int i=0;
        for(; i+16<=K; i+=16){
          rl a[16], b[16];
          #pragma unroll
          for(int u=0;u<16;++u){ a[u]=urow[(size_t)LDV*(size_t)(i+u)]; b[u]=qcol[i+u]; }
          #pragma unroll
          for(int u=0;u<16;++u) s += a[u]*b[u];
        }
        for(; i<K; ++i) s += urow[(size_t)LDV*i]*qcol[i];
        acc=s;
      }
      SUB[(f_+row)+(size_t)LDV*(f_+t)] = acc;
    }
  }
  for(int w=ltid; w<n_*m_; w+=lnt){
    int t=w/m_, col=w-t*m_;
    int src=sh->perm[base+t];
    rl acc;
    if(src>=1000) acc = VT2[(base+(src-1000))+(size_t)LDV*(base+col)];
    else{
      const rl* qcol = QVL + (size_t)LDV*(src+qofs);
      const rl* vcol = VT2 + base + (size_t)LDV*(base+col);
      rl s=0.0; int i=0;
      for(; i+16<=K; i+=16){
        rl a[16], b[16];
        #pragma unroll
        for(int u=0;u<16;++u){ a[u]=qcol[i+u]; b[u]=vcol[i+u]; }
        #pragma unroll
        for(int u=0;u<16;++u) s += a[u]*b[u];
      }
      for(; i<K; ++i) s += qcol[i]*vcol[i];
      acc=s;
    }
    SVTB[(f_+t)+(size_t)LDV*(f_+col)] = acc;
  }
  __syncthreads();
}

// ---- bidiagonalization (R2 structure) ----
__device__ __forceinline__ void gebd2_upper(rl* A, int ld, int m, int n, Sh* sh, int tid){
  const int lane = tid & 63;
  rl pend_scl = 0.0; int pend_ds = 0;
  for(int i=0;i<n;++i){
    rl ps=0.0;
    for(int r=i+1+lane;r<m;r+=64){ rl vv=A[r+(size_t)ld*i]; ps+=vv*vv; }
    for(int off=32;off>0;off>>=1) ps += __shfl_xor(ps,off,64);
    rl alpha=A[i+(size_t)ld*i];
    rl xn=sqrt(ps);
    rl beta,tau,scl; int ds;
    if(xn==0.0){ tau=0.0; beta=alpha; scl=0.0; ds=0; }
    else{ beta=-d_sign(dlapy2(alpha,xn),alpha); tau=(beta-alpha)/beta; scl=1.0/(alpha-beta); ds=1; }
    if(tid==0){ sh->d[i]=beta; sh->tq[i]=tau; }
    if(tau!=0.0)
      app_left_s(A, ld, i, m, i+1, n, A+(size_t)ld*i, scl, tau, tid);
    if(pend_ds && tid>=128){
      int c = i+1 + (tid-128);
      if(c < n) A[(i-1)+(size_t)ld*c] *= pend_scl;
    }
    __syncthreads();
    if(i<n-1){
      rl ps2=0.0;
      for(int c=i+2+lane;c<n;c+=64){ rl vv=A[i+(size_t)ld*c]; ps2+=vv*vv; }
      for(int off=32;off>0;off>>=1) ps2 += __shfl_xor(ps2,off,64);
      rl alpha2=A[i+(size_t)ld*(i+1)];
      rl xn2=sqrt(ps2);
      rl beta2,tau2,scl2; int ds2;
      if(xn2==0.0){ tau2=0.0; beta2=alpha2; scl2=0.0; ds2=0; }
      else{ beta2=-d_sign(dlapy2(alpha2,xn2),alpha2); tau2=(beta2-alpha2)/beta2; scl2=1.0/(alpha2-beta2); ds2=1; }
      if(tid==0){ sh->e[i]=beta2; sh->tp[i]=tau2; }
      if(tau2!=0.0)
        app_right_s(A, ld, i+1, m, i+1, n, A+i, ld, scl2, tau2, tid);
      if(ds && tid>=128){
        int r = i+1 + (tid-128);
        if(r < m) A[r+(size_t)ld*i] *= scl;
      }
      pend_ds = ds2; pend_scl = scl2;
      __syncthreads();
    } else {
      if(tid==0) sh->tp[i]=0.0;
      __syncthreads();
      if(ds) for(int r=i+1+tid; r<m; r+=NT) A[r+(size_t)ld*(n-1)] *= scl;
      __syncthreads();
    }
  }
}

__device__ __forceinline__ void gebd2_lower(rl* A, int ld, int m, int n, Sh* sh, int tid){
  const int lane = tid & 63;
  rl pend_scl = 0.0; int pend_ds = 0;
  int last_ds = 0; rl last_scl = 0.0;
  for(int i=0;i<m;++i){
    rl ps=0.0;
    for(int c=i+1+lane;c<n;c+=64){ rl vv=A[i+(size_t)ld*c]; ps+=vv*vv; }
    for(int off=32;off>0;off>>=1) ps += __shfl_xor(ps,off,64);
    rl alpha=A[i+(size_t)ld*i];
    rl xn=sqrt(ps);
    rl beta,tau,scl; int ds;
    if(xn==0.0){ tau=0.0; beta=alpha; scl=0.0; ds=0; }
    else{ beta=-d_sign(dlapy2(alpha,xn),alpha); tau=(beta-alpha)/beta; scl=1.0/(alpha-beta); ds=1; }
    if(tid==0){ sh->d[i]=beta; sh->tp[i]=tau; }
    if(tau!=0.0)
      app_right_s(A, ld, i+1, m, i, n, A+i, ld, scl, tau, tid);
    if(pend_ds && tid>=128){
      int r = i+1 + (tid-128);
      if(r < m) A[r+(size_t)ld*(i-1)] *= pend_scl;
    }
    __syncthreads();
    if(i<m-1){
      rl ps2=0.0;
      for(int r=i+2+lane;r<m;r+=64){ rl vv=A[r+(size_t)ld*i]; ps2+=vv*vv; }
      for(int off=32;off>0;off>>=1) ps2 += __shfl_xor(ps2,off,64);
      rl alpha2=A[(i+1)+(size_t)ld*i];
      rl xn2=sqrt(ps2);
      rl beta2,tau2,scl2; int ds2;
      if(xn2==0.0){ tau2=0.0; beta2=alpha2; scl2=0.0; ds2=0; }
      else{ beta2=-d_sign(dlapy2(alpha2,xn2),alpha2); tau2=(beta2-alpha2)/beta2; scl2=1.0/(alpha2-beta2); ds2=1; }
      if(tid==0){ sh->e[i]=beta2; sh->tq[i]=tau2; }
      if(tau2!=0.0)
        app_left_s(A, ld, i+1, m, i+1, n, A+(size_t)ld*i, scl2, tau2, tid);
      if(ds && tid>=128){
        int c = i+1 + (tid-128);
        if(c < n) A[i+(size_t)ld*c] *= scl;
      }
      pend_ds = ds2; pend_scl = scl2;
      __syncthreads();
    } else {
      last_ds = ds; last_scl = scl;
      __syncthreads();
      if(last_ds) for(int c=i+1+tid; c<n; c+=NT) A[(m-1)+(size_t)ld*c] *= last_scl;
      __syncthreads();
    }
  }
}

__device__ __forceinline__ void gelq2(rl* A, int ld, int m, int n, Sh* sh, int tid){
  const int lane = tid & 63;
  rl pend_scl=0.0, pend_beta=0.0; int pend_ds=0;
  for(int i=0;i<m;++i){
    rl ps=0.0;
    for(int c=i+1+lane;c<n;c+=64){ rl vv=A[i+(size_t)ld*c]; ps+=vv*vv; }
    for(int off=32;off>0;off>>=1) ps += __shfl_xor(ps,off,64);
    rl alpha=A[i+(size_t)ld*i];
    rl xn=sqrt(ps);
    rl beta,tau,scl; int ds;
    if(xn==0.0){ tau=0.0; beta=alpha; scl=0.0; ds=0; }
    else{ beta=-d_sign(dlapy2(alpha,xn),alpha); tau=(beta-alpha)/beta; scl=1.0/(alpha-beta); ds=1; }
    if(tid==0) sh->rs[i]=tau;
    if(i<m-1 && tau!=0.0)
      app_right_s(A, ld, i+1, m, i, n, A+i, ld, scl, tau, tid);
    if(i>0 && tid>=128){
      if(pend_ds){ int c = i + (tid-128); if(c<n) A[(i-1)+(size_t)ld*c] *= pend_scl; }
      if(tid==128) A[(i-1)+(size_t)ld*(i-1)] = pend_beta;
    }
    pend_ds=ds; pend_scl=scl; pend_beta=beta;
    __syncthreads();
  }
  if(tid>=128){
    if(pend_ds){ int c = m + (tid-128); if(c<n) A[(m-1)+(size_t)ld*c] *= pend_scl; }
    if(tid==128) A[(m-1)+(size_t)ld*(m-1)] = pend_beta;
  }
  __syncthreads();
}

// ======================================================================
// K1: build + bidiagonalization + leaves (fused)
// ======================================================================
__global__ __launch_bounds__(NT)
void k_front(const float* __restrict__ ch, const float* __restrict__ ci,
             const float* __restrict__ ictx, const int* __restrict__ tok,
             int s, int m)
{
  __shared__ Sh sh;
  __shared__ LeafCtx lct[4];
  extern __shared__ rl MBL[];
  int tid = threadIdx.x;
  rl* MA = g_ws + O_MA; rl* MQ = g_ws + O_MQ; rl* TB = g_ws + O_TB;
  if(tid==0){
    rl W00=ch[s*4+0], W01=ch[s*4+1], W10=ch[s*4+2], W11=ch[s*4+3];
    rl P00=1,P01=0,P10=0,P11=1;
    for(int mexp=0;mexp<=70;++mexp){
      int j=70-mexp;
      rl v0,v1;
      if(j==0){ v0=ictx[s*2+0]; v1=ictx[s*2+1]; }
      else{
        int b=(tok[j-1]>>(15-s))&1;
        v0=ci[s*4+b]; v1=ci[s*4+2+b];
      }
      g_ws[O_COLS + 0 + 2*j] = P00*v0+P01*v1;
      g_ws[O_COLS + 1 + 2*j] = P10*v0+P11*v1;
      rl n00=W00*P00+W01*P10, n01=W00*P01+W01*P11;
      rl n10=W10*P00+W11*P10, n11=W10*P01+W11*P11;
      P00=n00;P01=n01;P10=n10;P11=n11;
    }
  }
  __syncthreads();
  for(int w=tid; w<m*NSV; w+=NT){
    int j=w/m, r2=w-j*m;
    int l=r2>>1, dd2=r2&1;
    rl cv = g_ws[O_COLS + dd2 + 2*j];
    MA[r2+(size_t)LDA*j] = (s==0)? cv : g_ws[O_CAR + l + 64*j]*cv;
  }
  __syncthreads();
  if(m==128){
    for(int w=tid;w<128*NSV;w+=NT){ int c=w>>7, r2=w&127; MBL[r2+(size_t)PB*c]=MA[r2+(size_t)LDA*c]; }
    __syncthreads();
    gebd2_upper(MBL, PB, 128, NSV, &sh, tid);
    for(int w=tid;w<PB*NSV;w+=NT) g_ws[O_MBLG+w]=MBL[w];
  } else if(m==64){
    for(int w=tid;w<64*NSV;w+=NT){ int c=w>>6, r2=w&63; MBL[r2+(size_t)PB*c]=MA[r2+(size_t)LDA*c]; }
    __syncthreads();
    gebd2_lower(MBL, PB, 64, NSV, &sh, tid);
    for(int w=tid;w<PB*NSV;w+=NT) g_ws[O_MBLG+w]=MBL[w];
    // dbdsdc_L pre-rotation (wantU=0 -> rc/rs not needed later)
    __syncthreads();
    if(tid==0){
      for(int i=0;i<63;++i){
        rl cs,snv,rv;
        dlartg(sh.d[i], sh.e[i], &cs,&snv,&rv);
        sh.d[i]=rv; sh.e[i]=snv*sh.d[i+1]; sh.d[i+1]=cs*sh.d[i+1];
      }
    }
  } else {
    for(int w=tid;w<m*NSV;w+=NT){ int c=w/m, r2=w-c*m; MBL[r2+(size_t)PB*c]=MA[r2+(size_t)LDA*c]; }
    __syncthreads();
    gelq2(MBL, PB, m, NSV, &sh, tid);
    for(int w=tid;w<m*NSV;w+=NT){ int c=w/m, r2=w-c*m; MQ[r2+(size_t)LDA*c]=(r2==c)?1.0:0.0; }
    __syncthreads();
    if(tid<m){
      int r=tid;
      for(int j=m-1;j>=0;--j){
        rl tau=sh.rs[j];
        if(tau!=0.0) row_apply(MQ + r + (size_t)LDA*j, LDA, MBL + j + (size_t)PB*(j+1), PB, NSV-j-1, tau);
      }
    }
    __syncthreads();
    for(int w=tid;w<m*m;w+=NT){ int c=w/m, r2=w-c*m; TB[r2+(size_t)LDV*c]=(r2>=c)? MBL[r2+(size_t)PB*c]:0.0; }
    __syncthreads();
    gebd2_upper(TB, LDV, m, m, &sh, tid);
  }
  __syncthreads();
  // ---- leaves ----
  int wantU = (s==8)?1:0;
  int n_eff = (m==128)? NSV : m;
  rl* SUB = g_ws + O_SUB; rl* SVTB = g_ws + O_SVTB;
  for(int w=tid; w<LDV*LDV; w+=NT){
    int c=w/LDV, r2=w-c*LDV; rl v=(r2==c)?1.0:0.0;
    SVTB[w]=v;
    if(wantU) SUB[w]=v;
  }
  __syncthreads();
  if(n_eff<=SML){
    if((tid>>6)==0) leaf_exec(0, n_eff, 0, wantU, &lct[0], &sh, tid&63);
    __syncthreads();
  } else {
    build_ops(n_eff, &sh, tid);
    int no=sh.si[6];
    int o=0;
    while(o<no && sh.opk[o]==0){
      int cnt=1;
      while(o+cnt<no && sh.opk[o+cnt]==0 && cnt<4) ++cnt;
      int wid = tid>>6;
      if(wid<cnt) leaf_exec(sh.opf[o+wid], sh.opa[o+wid], sh.opq[o+wid], wantU, &lct[wid], &sh, tid&63);
      __syncthreads();
      o += cnt;
    }
  }
  if(tid<72){
    g_ws[O_D+tid]=sh.d[tid]; g_ws[O_E+tid]=sh.e[tid];
    g_ws[O_TQ+tid]=sh.tq[tid]; g_ws[O_TP+tid]=sh.tp[tid];
  }
}

// ======================================================================
// K2: merges (paired level-1 + root) + back-transforms + carry (fused)
// ======================================================================
__global__ __launch_bounds__(NT)
void k_back(const float* __restrict__ ch, int s, int m)
{
  __shared__ Sh sh;
  __shared__ rl QV[(size_t)LDV*72];
  extern __shared__ rl MBL[];
  int tid = threadIdx.x;
  rl* MU=g_ws+O_MU; rl* MVT=g_ws+O_MVT; rl* MQ=g_ws+O_MQ;
  rl* SUB=g_ws+O_SUB; rl* SVTB=g_ws+O_SVTB; rl* TB=g_ws+O_TB; rl* VT2=g_ws+O_VT2;
  if(tid<72){
    sh.d[tid]=g_ws[O_D+tid]; sh.e[tid]=g_ws[O_E+tid];
    sh.tq[tid]=g_ws[O_TQ+tid]; sh.tp[tid]=g_ws[O_TP+tid];
  }
  __syncthreads();
  int wantU = (s==8)?1:0;
  int n_eff = (m==128)? NSV : m;
  // ---- merges ----
  if(n_eff > SML){
    build_ops(n_eff, &sh, tid);
    int no=sh.si[6];
    int mstart=0; while(mstart<no && sh.opk[mstart]==0) ++mstart;
    int nm = no - mstart;
    if(nm==3){
      // two independent level-1 merges: slot A = threads 0..127, slot B = 128..255
      int slot = tid>>7, ltid = tid&127;
      int o = mstart + slot;
      lasd1_merge2(sh.opf[o], sh.opa[o], sh.opb[o], sh.opq[o], wantU,
                   QV, 36*slot, 36*slot, &sh, ltid, 128);
      // root merge, full block
      int r = mstart+2;
      lasd1_merge2(sh.opf[r], sh.opa[r], sh.opb[r], sh.opq[r], wantU,
                   QV, 0, 0, &sh, tid, NT);
    } else {
      for(int o=mstart;o<no;++o)
        lasd1_merge2(sh.opf[o], sh.opa[o], sh.opb[o], sh.opq[o], wantU,
                     QV, 0, 0, &sh, tid, NT);
    }
  }
  __syncthreads();
  // ---- post: back-transforms + carry / final vec ----
  int k = (m<64)? m : 64;
  if(m==128){
    if(s==8){
      for(int w=tid;w<128*NSV;w+=NT){ int c=w>>7, r2=w&127; MU[r2+(size_t)LDA*c]=(r2<NSV)? SUB[r2+(size_t)LDV*c]:0.0; }
      for(int w=tid;w<PB*NSV;w+=NT) MBL[w]=g_ws[O_MBLG+w];
      __syncthreads();
      if(tid<NSV){
        int c=tid;
        rl* colb = MU + (size_t)LDA*c;
        for(int i=NSV-1;i>=0;--i){
          rl tau=sh.tq[i];
          if(tau!=0.0) row_apply(colb+i, 1, MBL + (size_t)PB*i + i + 1, 1, 128-i-1, tau);
        }
      }
      __syncthreads();
      if(tid==0){
        rl W00=ch[8*4+0], W01=ch[8*4+1], W10=ch[8*4+2], W11=ch[8*4+3];
        rl P00=1,P01=0,P10=0,P11=1;
        for(int it=0;it<30;++it){
          rl n00=W00*P00+W01*P10, n01=W00*P01+W01*P11;
          rl n10=W10*P00+W11*P10, n11=W10*P01+W11*P11;
          P00=n00;P01=n01;P10=n10;P11=n11;
        }
        sh.sc[0]=P00+P10; sh.sc[1]=P01+P11;
      }
      __syncthreads();
      for(int r2=tid; r2<64; r2+=NT){
        rl acc=0.0;
        for(int l=0;l<64;++l)
          acc += sh.sc[0]*MU[(2*l)+(size_t)LDA*r2] + sh.sc[1]*MU[(2*l+1)+(size_t)LDA*r2];
        g_ws[O_VEC + r2] = acc/188.0;
      }
    } else {
      for(int w=tid;w<LDV*NSV;w+=NT) MVT[w]=SVTB[w];
      for(int w=tid;w<PB*NSV;w+=NT) MBL[w]=g_ws[O_MBLG+w];
      __syncthreads();
      if(tid<NSV){
        int r=tid;
        for(int i=NSV-2;i>=0;--i){
          rl tau=sh.tp[i];
          if(tau!=0.0) row_apply(MVT + r + (size_t)LDV*(i+1), LDV, MBL + i + (size_t)PB*(i+2), PB, NSV-i-2, tau);
        }
      }
      __syncthreads();
      for(int w=tid; w<k*NSV; w+=NT){
        int j=w/k, l=w-j*k;
        g_ws[O_CAR + l + 64*j] = sh.d[l]*MVT[l+(size_t)LDV*j];
      }
    }
  } else if(m==64){
    for(int w=tid;w<64*NSV;w+=NT){ int c=w>>6, r2=w&63; MVT[r2+(size_t)LDV*c]=(c<64)? SVTB[r2+(size_t)LDV*c]:0.0; }
    for(int w=tid;w<PB*NSV;w+=NT) MBL[w]=g_ws[O_MBLG+w];
    __syncthreads();
    if(tid<64){
      int r=tid;
      for(int i=63;i>=0;--i){
        rl tau=sh.tp[i];
        if(tau!=0.0) row_apply(MVT + r + (size_t)LDV*i, LDV, MBL + i + (size_t)PB*(i+1), PB, NSV-i-1, tau);
      }
    }
    __syncthreads();
    for(int w=tid; w<k*NSV; w+=NT){
      int j=w/k, l=w-j*k;
      g_ws[O_CAR + l + 64*j] = sh.d[l]*MVT[l+(size_t)LDV*j];
    }
  } else {
    for(int w=tid;w<m*m;w+=NT){ int c=w/m, r2=w-c*m; VT2[r2+(size_t)LDV*c]=SVTB[r2+(size_t)LDV*c]; }
    __syncthreads();
    if(tid<m){
      int r=tid;
      for(int i=m-2;i>=0;--i){
        rl tau=sh.tp[i];
        if(tau!=0.0) row_apply(VT2 + r + (size_t)LDV*(i+1), LDV, TB + i + (size_t)LDV*(i+2), LDV, m-i-2, tau);
      }
    }
    __syncthreads();
    for(int w=tid;w<m*NSV;w+=NT){
      int c=w/m, r2=w-c*m;
      const rl* vrow = VT2 + r2;
      const rl* qcol = MQ + (size_t)LDA*c;
      rl s2=0.0; int t=0;
      for(; t+16<=m; t+=16){
        rl a[16], b[16];
        #pragma unroll
        for(int u=0;u<16;++u){ a[u]=vrow[(size_t)LDV*(size_t)(t+u)]; b[u]=qcol[t+u]; }
        #pragma unroll
        for(int u=0;u<16;++u) s2 += a[u]*b[u];
      }
      for(; t+4<=m; t+=4){
        rl a0=vrow[(size_t)LDV*t], a1=vrow[(size_t)LDV*(t+1)], a2=vrow[(size_t)LDV*(t+2)], a3=vrow[(size_t)LDV*(t+3)];
        rl b0=qcol[t], b1=qcol[t+1], b2=qcol[t+2], b3=qcol[t+3];
        s2+=a0*b0; s2+=a1*b1; s2+=a2*b2; s2+=a3*b3;
      }
      for(; t<m; ++t) s2 += vrow[(size_t)LDV*t]*qcol[t];
      MVT[r2+(size_t)LDV*c]=s2;
    }
    __syncthreads();
    for(int w=tid; w<k*NSV; w+=NT){
      int j=w/k, l=w-j*k;
      g_ws[O_CAR + l + 64*j] = sh.d[l]*MVT[l+(size_t)LDV*j];
    }
  }
}

__global__ __launch_bounds__(NT)
void head_kernel(const float* __restrict__ hw, const float* __restrict__ hb,
                 float* __restrict__ out)
{
  __shared__ float v[64];
  int tid=threadIdx.x;
  if(tid<64) v[tid]=(float)g_ws[O_VEC + tid];
  __syncthreads();
  int i = blockIdx.x*NT + tid;
  if(i<VOCAB){
    const float4* row = (const float4*)(hw + (size_t)i*64);
    float acc=0.f;
    #pragma unroll
    for(int c4=0;c4<16;++c4){
      float4 r4=row[c4];
      acc += r4.x*v[4*c4] + r4.y*v[4*c4+1] + r4.z*v[4*c4+2] + r4.w*v[4*c4+3];
    }
    out[i]=acc+hb[i];
  }
}

extern "C" void kernel_launch(void* const* d_in, const int* in_sizes, int n_in,
                              void* d_out, int out_size, void* d_ws, size_t ws_size,
                              hipStream_t stream)
{
  const float* ch  = (const float*)d_in[0];
  const float* ci  = (const float*)d_in[1];
  const float* hw  = (const float*)d_in[2];
  const float* hb  = (const float*)d_in[3];
  const float* ict = (const float*)d_in[4];
  const int*   tk  = (const int*)d_in[5];
  (void)d_ws; (void)ws_size; (void)in_sizes; (void)n_in; (void)out_size;

  static const int ms[9] = {2,4,8,16,32,64,128,128,128};
  size_t dynls = (size_t)PB*NSV*sizeof(double);   // 73272 B
  for(int s=0;s<9;++s){
    hipLaunchKernelGGL(k_front, dim3(1), dim3(NT), dynls, stream, ch, ci, ict, tk, s, ms[s]);
    hipLaunchKernelGGL(k_back,  dim3(1), dim3(NT), dynls, stream, ch, s, ms[s]);
  }
  hipLaunchKernelGGL(head_kernel, dim3((VOCAB+NT-1)/NT), dim3(NT), 0, stream,
                     hw, hb, (float*)d_out);
}

// Round 8
// 7192.256 us; speedup vs baseline: 1.6281x; 1.0176x over previous
//
#include <hip/hip_runtime.h>

typedef double rl;
#define NT 256
#define NSV 71
#define LDA 128
#define LDV 72
#define SML 25
#define VOCAB 128000
#define LP 27   // LDS leaf pitch
#define PB 129  // LDS pitch for bidiag working matrix

// fp32 LAPACK constants (reference is numpy sgesdd in float32)
#define EPS32 1.1920928955078125e-7
#define UNFL32 1.17549435e-38

// g_ws offsets (doubles)
#define O_CAR   0
#define O_COLS  4608
#define O_VEC   4800
#define O_MA    5120
#define O_MU    23552
#define O_MQ    32768
#define O_MVT   41984
#define O_SUB   47168
#define O_SVTB  52352
#define O_U2    57536
#define O_VT2   62720
#define O_QU    67904
#define O_TB    78272

__device__ double g_ws[84000];

struct LeafCtx {
  rl LVT[26*LP], LU[26*LP];
  rl b1[26], b2[26], b3[26], b4[26];
  rl sc[6];
  int ia[26], ib[26], ic[26];
  int si[12];
};

// sc/si doubled: merge slot A uses sc[0..7]/si[0..7], slot B sc[8..15]/si[16..21].
struct Sh {
  rl d[72], e[72], tq[72], tp[72], rc[72], rs[72];
  rl dsig[72], zz[72], zh[72], sigm[72], vals[72];
  rl ta[72], tb[72];
  int srcU[72], srcVT[72], perm[72];
  int ia[72], ib[72], ic[72];
  int opk[12], opf[12], opa[12], opb[12], opq[12];
  rl sc[16];
  int si[24];
};

__device__ __forceinline__ void wsync(){
  asm volatile("s_waitcnt vmcnt(0) lgkmcnt(0)" ::: "memory");
}

__device__ __forceinline__ rl d_sign(rl a, rl b){ return (b >= 0.0) ? fabs(a) : -fabs(a); }
__device__ __forceinline__ rl dlapy2(rl x, rl y){
  rl ax=fabs(x), ay=fabs(y);
  rl w = ax>ay?ax:ay, z = ax>ay?ay:ax;
  if(z==0.0) return w;
  rl t = z/w; return w*sqrt(1.0+t*t);
}
__device__ void dlartg(rl f, rl g, rl* cs, rl* sn, rl* r){
  if(g==0.0){ *cs=1.0; *sn=0.0; *r=f; }
  else if(f==0.0){ *cs=0.0; *sn=d_sign(1.0,g); *r=fabs(g); }
  else{
    rl dd = sqrt(f*f+g*g);
    *cs = fabs(f)/dd;
    *r  = d_sign(dd, f);
    *sn = g/(*r);
  }
}

__device__ void dlas2(rl f, rl g, rl h, rl* ssmin, rl* ssmax){
  rl fa=fabs(f), ga=fabs(g), ha=fabs(h);
  rl fhmn=fmin(fa,ha), fhmx=fmax(fa,ha);
  if(fhmn==0.0){
    *ssmin=0.0;
    if(fhmx==0.0) *ssmax=ga;
    else { rl mx=fmax(fhmx,ga), mn=fmin(fhmx,ga); rl q=mn/mx; *ssmax=mx*sqrt(1.0+q*q); }
  } else {
    if(ga < fhmx){
      rl as=1.0+fhmn/fhmx, at=(fhmx-fhmn)/fhmx;
      rl au=(ga/fhmx); au=au*au;
      rl c=2.0/(sqrt(as*as+au)+sqrt(at*at+au));
      *ssmin=fhmn*c; *ssmax=fhmx/c;
    } else {
      rl au=fhmx/ga;
      if(au==0.0){ *ssmin=(fhmn*fhmx)/ga; *ssmax=ga; }
      else{
        rl as=1.0+fhmn/fhmx, at=(fhmx-fhmn)/fhmx;
        rl c=1.0/(sqrt(1.0+(as*au)*(as*au))+sqrt(1.0+(at*au)*(at*au)));
        *ssmin=(fhmn*c)*au; *ssmin=*ssmin+*ssmin;
        *ssmax=ga/(c+c);
      }
    }
  }
}

__device__ void dlasv2(rl f, rl g, rl h, rl* ssmin, rl* ssmax, rl* snr, rl* csr, rl* snl, rl* csl){
  rl ft=f, fa=fabs(f), ht=h, ha=fabs(h);
  int pmax=1;
  bool swp = (ha > fa);
  if(swp){ pmax=3; rl t=ft; ft=ht; ht=t; t=fa; fa=ha; ha=t; }
  rl gt=g, ga=fabs(g);
  rl clt=0, crt=0, slt=0, srt=0;
  if(ga==0.0){ *ssmin=ha; *ssmax=fa; clt=1.0; crt=1.0; slt=0.0; srt=0.0; }
  else{
    bool gasmal=true;
    if(ga > fa){
      pmax=2;
      if((fa/ga) < EPS32){
        gasmal=false;
        *ssmax=ga;
        if(ha>1.0) *ssmin=fa/(ga/ha); else *ssmin=(fa/ga)*ha;
        clt=1.0; slt=ht/gt; srt=1.0; crt=ft/gt;
      }
    }
    if(gasmal){
      rl dd=fa-ha;
      rl lv = (dd==fa) ? 1.0 : dd/fa;
      rl mq = gt/ft;
      rl tv = 2.0-lv;
      rl mm = mq*mq, tt = tv*tv;
      rl sv = sqrt(tt+mm);
      rl rv = (lv==0.0) ? fabs(mq) : sqrt(lv*lv+mm);
      rl a = 0.5*(sv+rv);
      *ssmin = ha/a; *ssmax = fa*a;
      rl t3;
      if(mm==0.0){
        if(lv==0.0) t3 = d_sign(2.0, ft)*d_sign(1.0, gt);
        else t3 = gt/d_sign(dd, ft) + mq/tv;
      } else {
        t3 = (mq/(sv+tv) + mq/(rv+lv))*(1.0+a);
      }
      rl l2 = sqrt(t3*t3+4.0);
      crt = 2.0/l2; srt = t3/l2;
      clt = (crt + srt*mq)/a;
      slt = (ht/ft)*srt/a;
    }
  }
  if(swp){ *csl=srt; *snl=crt; *csr=slt; *snr=clt; }
  else  { *csl=clt; *snl=slt; *csr=crt; *snr=srt; }
  rl tsign=1.0;
  if(pmax==1) tsign = d_sign(1.0,*csr)*d_sign(1.0,*csl)*d_sign(1.0,f);
  if(pmax==2) tsign = d_sign(1.0,*snr)*d_sign(1.0,*csl)*d_sign(1.0,g);
  if(pmax==3) tsign = d_sign(1.0,*snr)*d_sign(1.0,*snl)*d_sign(1.0,h);
  *ssmax = d_sign(*ssmax, tsign);
  *ssmin = d_sign(*ssmin, tsign*d_sign(1.0,f)*d_sign(1.0,h));
}

// Thread-local Householder apply (16-wide grouped loads, sequential adds).
__device__ __forceinline__ void row_apply(rl* row, size_t ld, const rl* v, size_t vs, int len, rl tau){
  rl s = row[0];
  int i=0;
  for(; i+16<=len; i+=16){
    rl a[16], b[16];
    #pragma unroll
    for(int u=0;u<16;++u){ a[u]=row[ld*(size_t)(1+i+u)]; b[u]=v[vs*(size_t)(i+u)]; }
    #pragma unroll
    for(int u=0;u<16;++u) s += a[u]*b[u];
  }
  for(; i<len; ++i) s += row[ld*(size_t)(1+i)]*v[vs*(size_t)i];
  rl w = s*tau;
  row[0] -= w;
  i=0;
  for(; i+16<=len; i+=16){
    rl b[16];
    #pragma unroll
    for(int u=0;u<16;++u) b[u]=v[vs*(size_t)(i+u)];
    #pragma unroll
    for(int u=0;u<16;++u) row[ld*(size_t)(1+i+u)] -= w*b[u];
  }
  for(; i<len; ++i) row[ld*(size_t)(1+i)] -= w*v[vs*(size_t)i];
}

__device__ __forceinline__ void app_left_s(rl* A, int ld, int r0, int m, int c0, int n, const rl* vbase, rl scl, rl tau, int tid){
  const int len = m - r0 - 1;
  const rl* v = vbase + r0 + 1;
  int c = c0 + tid;
  if(c < n){
    rl* col = A + (size_t)ld*c + r0;
    rl s = col[0];
    int i=0;
    for(; i+16<=len; i+=16){
      rl a[16], b[16];
      #pragma unroll
      for(int u=0;u<16;++u){ a[u]=col[1+i+u]; b[u]=v[i+u]*scl; }
      #pragma unroll
      for(int u=0;u<16;++u) s += a[u]*b[u];
    }
    for(; i<len; ++i) s += col[1+i]*(v[i]*scl);
    rl w = s*tau;
    col[0] -= w;
    i=0;
    for(; i+16<=len; i+=16){
      rl b[16];
      #pragma unroll
      for(int u=0;u<16;++u) b[u]=v[i+u]*scl;
      #pragma unroll
      for(int u=0;u<16;++u) col[1+i+u] -= w*b[u];
    }
    for(; i<len; ++i) col[1+i] -= w*(v[i]*scl);
  }
}
__device__ __forceinline__ void app_right_s(rl* A, int ld, int r0, int m, int c0, int n, const rl* vbase, int vstride, rl scl, rl tau, int tid){
  const int len = n - c0 - 1;
  const rl* v = vbase + (size_t)vstride*(c0+1);
  int r = r0 + tid;
  if(r < m){
    rl* row = A + r + (size_t)ld*c0;
    rl s = row[0];
    int i=0;
    for(; i+16<=len; i+=16){
      rl a[16], b[16];
      #pragma unroll
      for(int u=0;u<16;++u){ a[u]=row[(size_t)ld*(size_t)(1+i+u)]; b[u]=v[(size_t)vstride*(size_t)(i+u)]*scl; }
      #pragma unroll
      for(int u=0;u<16;++u) s += a[u]*b[u];
    }
    for(; i<len; ++i) s += row[(size_t)ld*(1+i)]*(v[(size_t)vstride*i]*scl);
    rl w = s*tau;
    row[0] -= w;
    i=0;
    for(; i+16<=len; i+=16){
      rl b[16];
      #pragma unroll
      for(int u=0;u<16;++u) b[u]=v[(size_t)vstride*(size_t)(i+u)]*scl;
      #pragma unroll
      for(int u=0;u<16;++u) row[(size_t)ld*(size_t)(1+i+u)] -= w*b[u];
    }
    for(; i<len; ++i) row[(size_t)ld*(1+i)] -= w*(v[(size_t)vstride*i]*scl);
  }
}

// ---- wave-scoped dbdsqr on a private LDS leaf block ----
__device__ void bdsqr_wave(int n, rl* d, rl* e, int ncvt, int nru, LeafCtx* lc, int lane){
  if(n>1){
    rl eps=EPS32, unfl=UNFL32;
    rl tolmul=fmax(10.0,fmin(100.0,pow(eps,-0.125)));
    rl tol=tolmul*eps;
    rl thresh=0.0;
    int mm=n-1, oldll=-2, oldm=-2, idir=0, iter=0, maxit=6*n*n;
    if(lane==0){
      rl sminoa=fabs(d[0]);
      if(sminoa!=0.0){
        rl mu=sminoa;
        for(int i=1;i<n;++i){ mu=fabs(d[i])*(mu/(mu+fabs(e[i-1]))); sminoa=fmin(sminoa,mu); if(sminoa==0.0)break; }
      }
      sminoa=sminoa/sqrt((rl)n);
      thresh=fmax(tol*sminoa,(rl)(6*n*n)*unfl);
    }
    while(true){
      if(lane==0){
        int act=0, p_lo=0, p_cnt=0, p_fwd=1, p_mm=0;
        while(mm>0){
          if(iter>maxit) break;
          rl smax=fabs(d[mm]), smin=smax;
          int ll=-1;
          for(int lll=mm-1;lll>=0;--lll){
            rl abss=fabs(d[lll]), abse=fabs(e[lll]);
            if(abse<=thresh){ ll=lll; break; }
            smin=fmin(smin,abss);
            smax=fmax(smax,fmax(abss,abse));
          }
          if(ll==mm-1){ e[ll]=0.0; mm=mm-1; continue; }
          if(ll>=0) e[ll]=0.0;
          int lo=ll+1;
          if(mm==lo+1){
            rl sigmn,sigmx,sinr,cosr,sinl,cosl;
            dlasv2(d[lo],e[lo],d[mm],&sigmn,&sigmx,&sinr,&cosr,&sinl,&cosl);
            d[lo]=sigmx; d[mm]=sigmn; e[lo]=0.0;
            lc->sc[0]=cosr; lc->sc[1]=sinr; lc->sc[2]=cosl; lc->sc[3]=sinl;
            act=2; p_lo=lo; p_mm=mm;
            mm-=2;
            break;
          }
          if(lo>oldm || mm<oldll) idir=(fabs(d[lo])>=fabs(d[mm]))?1:2;
          rl sminl=0.0; int conv=0;
          if(idir==1){
            if(fabs(e[mm-1])<=tol*fabs(d[mm])){ e[mm-1]=0.0; conv=1; }
            if(!conv){
              rl mu=fabs(d[lo]); sminl=mu;
              for(int lll=lo;lll<mm;++lll){
                if(fabs(e[lll])<=tol*mu){ e[lll]=0.0; conv=1; break; }
                mu=fabs(d[lll+1])*(mu/(mu+fabs(e[lll])));
                sminl=fmin(sminl,mu);
              }
            }
          } else {
            if(fabs(e[lo])<=tol*fabs(d[lo])){ e[lo]=0.0; conv=1; }
            if(!conv){
              rl mu=fabs(d[mm]); sminl=mu;
              for(int lll=mm-1;lll>=lo;--lll){
                if(fabs(e[lll])<=tol*mu){ e[lll]=0.0; conv=1; break; }
                mu=fabs(d[lll])*(mu/(mu+fabs(e[lll])));
                sminl=fmin(sminl,mu);
              }
            }
          }
          if(conv) continue;
          oldll=lo; oldm=mm;
          rl shift=0.0, rr_;
          if(!((rl)n*tol*(sminl/smax) <= fmax(eps, 0.01*tol))){
            rl sll;
            if(idir==1){ sll=fabs(d[lo]); dlas2(d[mm-1],e[mm-1],d[mm],&shift,&rr_); }
            else { sll=fabs(d[mm]); dlas2(d[lo],e[lo],d[lo+1],&shift,&rr_); }
            if(sll>0.0){ rl q=shift/sll; if(q*q<eps) shift=0.0; }
          }
          iter += mm-lo;
          int cnt=mm-lo;
          if(shift==0.0){
            if(idir==1){
              rl cs=1.0, oldcs=1.0, sn=0.0, oldsn=0.0, r;
              for(int i=lo;i<mm;++i){
                dlartg(d[i]*cs,e[i],&cs,&sn,&r);
                if(i>lo) e[i-1]=oldsn*r;
                dlartg(oldcs*r, d[i+1]*sn, &oldcs,&oldsn,&d[i]);
                lc->b1[i-lo]=cs; lc->b2[i-lo]=sn; lc->b3[i-lo]=oldcs; lc->b4[i-lo]=oldsn;
              }
              rl h=d[mm]*cs; d[mm]=h*oldcs; e[mm-1]=h*oldsn;
              p_fwd=1;
              if(fabs(e[mm-1])<=thresh) e[mm-1]=0.0;
            } else {
              rl cs=1.0, oldcs=1.0, sn=0.0, oldsn=0.0, r;
              for(int i=mm;i>lo;--i){
                dlartg(d[i]*cs,e[i-1],&cs,&sn,&r);
                if(i<mm) e[i]=oldsn*r;
                dlartg(oldcs*r,d[i-1]*sn,&oldcs,&oldsn,&d[i]);
                int j=i-lo-1;
                lc->b1[j]=oldcs; lc->b2[j]=-oldsn; lc->b3[j]=cs; lc->b4[j]=-sn;
              }
              rl h=d[lo]*cs; d[lo]=h*oldcs; e[lo]=h*oldsn;
              p_fwd=0;
              if(fabs(e[lo])<=thresh) e[lo]=0.0;
            }
          } else {
            if(idir==1){
              rl f2=(fabs(d[lo])-shift)*(d_sign(1.0,d[lo])+shift/d[lo]);
              rl g2=e[lo], r, cosr,sinr,cosl,sinl;
              for(int i=lo;i<mm;++i){
                dlartg(f2,g2,&cosr,&sinr,&r);
                if(i>lo) e[i-1]=r;
                f2=cosr*d[i]+sinr*e[i];
                e[i]=cosr*e[i]-sinr*d[i];
                g2=sinr*d[i+1];
                d[i+1]=cosr*d[i+1];
                dlartg(f2,g2,&cosl,&sinl,&r);
                d[i]=r;
                f2=cosl*e[i]+sinl*d[i+1];
                d[i+1]=cosl*d[i+1]-sinl*e[i];
                if(i<mm-1){ g2=sinl*e[i+1]; e[i+1]=cosl*e[i+1]; }
                lc->b1[i-lo]=cosr; lc->b2[i-lo]=sinr; lc->b3[i-lo]=cosl; lc->b4[i-lo]=sinl;
              }
              e[mm-1]=f2;
              p_fwd=1;
              if(fabs(e[mm-1])<=thresh) e[mm-1]=0.0;
            } else {
              rl f2=(fabs(d[mm])-shift)*(d_sign(1.0,d[mm])+shift/d[mm]);
              rl g2=e[mm-1], r, cosr,sinr,cosl,sinl;
              for(int i=mm;i>lo;--i){
                dlartg(f2,g2,&cosr,&sinr,&r);
                if(i<mm) e[i]=r;
                f2=cosr*d[i]+sinr*e[i-1];
                e[i-1]=cosr*e[i-1]-sinr*d[i];
                g2=sinr*d[i-1];
                d[i-1]=cosr*d[i-1];
                dlartg(f2,g2,&cosl,&sinl,&r);
                d[i]=r;
                f2=cosl*e[i-1]+sinl*d[i-1];
                d[i-1]=cosl*d[i-1]-sinl*e[i-1];
                if(i>lo+1){ g2=sinl*e[i-2]; e[i-2]=cosl*e[i-2]; }
                int j=i-lo-1;
                lc->b1[j]=cosl; lc->b2[j]=-sinl; lc->b3[j]=cosr; lc->b4[j]=-sinr;
              }
              e[lo]=f2;
              p_fwd=0;
              if(fabs(e[lo])<=thresh) e[lo]=0.0;
            }
          }
          act=1; p_lo=lo; p_cnt=cnt;
          break;
        }
        lc->si[7]=act; lc->si[8]=p_lo; lc->si[9]=p_cnt; lc->si[10]=p_fwd; lc->si[11]=p_mm;
      }
      wsync();
      int act=lc->si[7];
      if(act==0) break;
      if(act==1){
        int lo=lc->si[8], cnt=lc->si[9], fwd=lc->si[10];
        if(lane<ncvt){
          int k=lane;
          if(fwd){
            rl cur = lc->LVT[lo*LP+k];
            for(int j=0;j<cnt;++j){
              rl c=lc->b1[j], s=lc->b2[j];
              rl t = lc->LVT[(lo+j+1)*LP+k];
              lc->LVT[(lo+j)*LP+k] = s*t + c*cur;
              cur = c*t - s*cur;
            }
            lc->LVT[(lo+cnt)*LP+k] = cur;
          } else {
            rl tcar = lc->LVT[(lo+cnt)*LP+k];
            for(int j=cnt-1;j>=0;--j){
              rl c=lc->b1[j], s=lc->b2[j];
              rl low = lc->LVT[(lo+j)*LP+k];
              lc->LVT[(lo+j+1)*LP+k] = c*tcar - s*low;
              tcar = s*tcar + c*low;
            }
            lc->LVT[lo*LP+k] = tcar;
          }
        } else if(lane<ncvt+nru){
          int r2=lane-ncvt;
          if(fwd){
            rl cur = lc->LU[r2*LP+lo];
            for(int j=0;j<cnt;++j){
              rl c=lc->b3[j], s=lc->b4[j];
              rl t = lc->LU[r2*LP+(lo+j+1)];
              lc->LU[r2*LP+(lo+j)] = s*t + c*cur;
              cur = c*t - s*cur;
            }
            lc->LU[r2*LP+(lo+cnt)] = cur;
          } else {
            rl tcar = lc->LU[r2*LP+(lo+cnt)];
            for(int j=cnt-1;j>=0;--j){
              rl c=lc->b3[j], s=lc->b4[j];
              rl low = lc->LU[r2*LP+(lo+j)];
              lc->LU[r2*LP+(lo+j+1)] = c*tcar - s*low;
              tcar = s*tcar + c*low;
            }
            lc->LU[r2*LP+lo] = tcar;
          }
        }
      } else {
        int lo=lc->si[8], m2=lc->si[11];
        rl cosr=lc->sc[0], sinr=lc->sc[1], cosl=lc->sc[2], sinl=lc->sc[3];
        if(lane<ncvt){
          rl x=lc->LVT[lo*LP+lane], y=lc->LVT[m2*LP+lane];
          lc->LVT[lo*LP+lane]=cosr*x+sinr*y; lc->LVT[m2*LP+lane]=cosr*y-sinr*x;
        } else if(lane<ncvt+nru){
          int r2=lane-ncvt;
          rl x=lc->LU[r2*LP+lo], y=lc->LU[r2*LP+m2];
          lc->LU[r2*LP+lo]=cosl*x+sinl*y; lc->LU[r2*LP+m2]=cosl*y-sinl*x;
        }
      }
      wsync();
    }
  }
  if(lane==0){
    for(int i=0;i<n;++i){ lc->ic[i]=(d[i]<0.0)?1:0; if(d[i]<0.0) d[i]=-d[i]; }
    int nsw=0;
    for(int i=0;i<n-1;++i){
      int isub=0; rl smin=d[0];
      for(int j=1;j<n-i;++j){ if(d[j]<=smin){ isub=j; smin=d[j]; } }
      int tgt=n-1-i;
      if(isub!=tgt){
        d[isub]=d[tgt]; d[tgt]=smin;
        lc->ia[nsw]=isub; lc->ib[nsw]=tgt; ++nsw;
      }
    }
    lc->si[7]=nsw;
  }
  wsync();
  int nsw=lc->si[7];
  if(lane<ncvt){
    for(int i=0;i<n;++i) if(lc->ic[i]) lc->LVT[i*LP+lane]=-lc->LVT[i*LP+lane];
    for(int w2=0;w2<nsw;++w2){
      int a=lc->ia[w2], b=lc->ib[w2];
      rl t=lc->LVT[a*LP+lane]; lc->LVT[a*LP+lane]=lc->LVT[b*LP+lane]; lc->LVT[b*LP+lane]=t;
    }
  } else if(lane<ncvt+nru){
    int r2=lane-ncvt;
    for(int w2=0;w2<nsw;++w2){
      int a=lc->ia[w2], b=lc->ib[w2];
      rl t=lc->LU[r2*LP+a]; lc->LU[r2*LP+a]=lc->LU[r2*LP+b]; lc->LU[r2*LP+b]=t;
    }
  }
  wsync();
}

// ---- leaf: dlasdq, entirely within one wave ----
__device__ void leaf_exec(int f, int n, int sqre, int wantU, LeafCtx* lc, Sh* sh, int lane){
  rl* SVTB = g_ws + O_SVTB; rl* SUB = g_ws + O_SUB;
  int np = n + sqre;
  for(int w=lane; w<np*np; w+=64){ int r2=w/np, c=w-r2*np; lc->LVT[r2*LP+c]=SVTB[(f+r2)+(size_t)LDV*(f+c)]; }
  if(wantU) for(int w=lane; w<n*n; w+=64){ int r2=w/n, c=w-r2*n; lc->LU[r2*LP+c]=SUB[(f+r2)+(size_t)LDV*(f+c)]; }
  wsync();
  if(sqre==1){
    if(lane==0){
      rl cs,snv,rv; rl* dd=sh->d+f; rl* ee=sh->e+f;
      for(int i=0;i<n;++i){
        dlartg(dd[i],ee[i],&cs,&snv,&rv);
        dd[i]=rv;
        if(i<n-1){ ee[i]=snv*dd[i+1]; dd[i+1]=cs*dd[i+1]; }
        else ee[i]=0.0;
        lc->b1[i]=cs; lc->b2[i]=snv;
      }
    }
    wsync();
    if(lane<np){
      rl cur = lc->LVT[0*LP+lane];
      for(int j=0;j<n;++j){
        rl cj=lc->b1[j], sj=lc->b2[j];
        rl t=lc->LVT[(j+1)*LP+lane];
        lc->LVT[j*LP+lane] = sj*t + cj*cur;
        cur = cj*t - sj*cur;
      }
      lc->LVT[n*LP+lane] = cur;
    }
    wsync();
    if(lane==0){
      rl cs,snv,rv; rl* dd=sh->d+f; rl* ee=sh->e+f;
      for(int i=0;i<n-1;++i){
        dlartg(dd[i],ee[i],&cs,&snv,&rv);
        dd[i]=rv; ee[i]=snv*dd[i+1]; dd[i+1]=cs*dd[i+1];
        lc->b1[i]=cs; lc->b2[i]=snv;
      }
    }
    wsync();
    if(wantU && lane<n){
      rl cur = lc->LU[lane*LP+0];
      for(int j=0;j<n-1;++j){
        rl cj=lc->b1[j], sj=lc->b2[j];
        rl t=lc->LU[lane*LP+(j+1)];
        lc->LU[lane*LP+j] = sj*t + cj*cur;
        cur = cj*t - sj*cur;
      }
      lc->LU[lane*LP+(n-1)] = cur;
    }
    wsync();
  }
  bdsqr_wave(n, sh->d+f, sh->e+f, np, wantU? n:0, lc, lane);
  for(int w=lane; w<np*np; w+=64){ int r2=w/np, c=w-r2*np; SVTB[(f+r2)+(size_t)LDV*(f+c)]=lc->LVT[r2*LP+c]; }
  if(wantU) for(int w=lane; w<n*n; w+=64){ int r2=w/n, c=w-r2*n; SUB[(f+r2)+(size_t)LDV*(f+c)]=lc->LU[r2*LP+c]; }
}

// ---- op-list builder (post-order, leaves stable-partitioned first) ----
__device__ void build_ops(int n, Sh* sh, int tid){
  if(tid==0){
    int sf[12], sn2[12], sq[12], sv[12]; int sp=0, no=0;
    sf[0]=0; sn2[0]=n; sq[0]=0; sv[0]=0; sp=1;
    while(sp>0){
      --sp;
      int f=sf[sp], nn=sn2[sp], q=sq[sp], v=sv[sp];
      if(nn<=SML){ sh->opk[no]=0; sh->opf[no]=f; sh->opa[no]=nn; sh->opb[no]=0; sh->opq[no]=q; ++no; }
      else if(v==0){
        int nl=nn/2, nr=nn-nl-1;
        sf[sp]=f; sn2[sp]=nn; sq[sp]=q; sv[sp]=1; ++sp;
        sf[sp]=f+nl+1; sn2[sp]=nr; sq[sp]=q; sv[sp]=0; ++sp;
        sf[sp]=f; sn2[sp]=nl; sq[sp]=1; sv[sp]=0; ++sp;
      } else {
        int nl=nn/2, nr=nn-nl-1;
        sh->opk[no]=1; sh->opf[no]=f; sh->opa[no]=nl; sh->opb[no]=nr; sh->opq[no]=q; ++no;
      }
    }
    int tk[12], tf2[12], ta2[12], tb3[12], tq3[12]; int c=0;
    for(int i=0;i<no;++i) if(sh->opk[i]==0){ tk[c]=0; tf2[c]=sh->opf[i]; ta2[c]=sh->opa[i]; tb3[c]=sh->opb[i]; tq3[c]=sh->opq[i]; ++c; }
    for(int i=0;i<no;++i) if(sh->opk[i]==1){ tk[c]=1; tf2[c]=sh->opf[i]; ta2[c]=sh->opa[i]; tb3[c]=sh->opb[i]; tq3[c]=sh->opq[i]; ++c; }
    for(int i=0;i<no;++i){ sh->opk[i]=tk[i]; sh->opf[i]=tf2[i]; sh->opa[i]=ta2[i]; sh->opb[i]=tb3[i]; sh->opq[i]=tq3[i]; }
    sh->si[6]=no;
  }
  __syncthreads();
}

// ---- D&C merge, slot-parallel version (R7 structure + zz^2 hoist) ----
__device__ void lasd1_merge2(int f, int nl, int nr, int sqre, int wantU,
                             rl* QVL, int qofs, int base, Sh* sh, int ltid, int lnt){
  rl* SUB = g_ws + O_SUB; rl* SVTB = g_ws + O_SVTB;
  rl* U2 = g_ws + O_U2; rl* VT2 = g_ws + O_VT2; rl* QU = g_ws + O_QU;
  rl* sc = sh->sc + (base?8:0);
  int* si = sh->si + (base?16:0);
  int n = nl+nr+1, m = n+sqre;
  // phase 1: parallel construction
  {
    rl alpha = sh->d[f+nl], beta = sh->e[f+nl];
    if(ltid==0){
      sc[0]=alpha; sc[1]=beta;
      sh->vals[base]=0.0;
      sh->zz[base] = alpha*SVTB[(f+nl)+(size_t)LDV*(f+nl)];
      sh->srcU[base]=-1; sh->srcVT[base]=f+nl;
    } else if(ltid<n){
      int i=ltid;
      if(i<=nl){
        sh->vals[base+i]=sh->d[f+i-1];
        sh->zz[base+i]=alpha*SVTB[(f+i-1)+(size_t)LDV*(f+nl)];
        sh->srcU[base+i]=f+i-1; sh->srcVT[base+i]=f+i-1;
      } else {
        int j=i-1-nl;
        sh->vals[base+i]=sh->d[f+nl+1+j];
        sh->zz[base+i]=beta*SVTB[(f+nl+1+j)+(size_t)LDV*(f+nl+1)];
        sh->srcU[base+i]=f+nl+1+j; sh->srcVT[base+i]=f+nl+1+j;
      }
    }
  }
  __syncthreads();
  if(ltid==0 && sqre==1){
    rl zM = sc[1]*SVTB[(f+n)+(size_t)LDV*(f+nl+1)];
    rl c,s2,r2;
    dlartg(sh->zz[base], zM, &c, &s2, &r2);
    sh->zz[base]=r2; sc[2]=c; sc[3]=s2;
  }
  __syncthreads();
  if(sqre==1){
    rl c=sc[2], s=sc[3];
    int ra=f+nl, rb=f+n;
    for(int k=ltid;k<m;k+=lnt){
      size_t ci=(size_t)LDV*(f+k);
      rl a=SVTB[ra+ci], b=SVTB[rb+ci];
      SVTB[ra+ci]=c*a+s*b; SVTB[rb+ci]=-s*a+c*b;
    }
  }
  __syncthreads();
  // tol + deflation count (serial)
  if(ltid==0){
    rl maxd=0.0; for(int i=0;i<n;++i) maxd=fmax(maxd,fabs(sh->vals[base+i]));
    rl tol = 8.0*EPS32*fmax(maxd, fmax(fabs(sc[0]), fabs(sc[1])));
    sc[5]=tol;
    int Kc=0;
    for(int j=1;j<n;++j) if(fabs(sh->zz[base+j]) > tol) ++Kc;
    sh->ic[base]=0;
    si[0]=1+Kc; si[1]=n; si[2]=m; si[3]=f; si[4]=nl;
  }
  __syncthreads();
  // parallel stable rank-sort (== insertion-sort permutation)
  {
    rl tol=sc[5];
    if(ltid>=1 && ltid<n){
      bool ndt = fabs(sh->zz[base+ltid])>tol;
      rl vt = sh->vals[base+ltid];
      int rank=0, Kc=0;
      for(int j=1;j<n;++j){
        bool ndj = fabs(sh->zz[base+j])>tol;
        if(ndj) ++Kc;
        if(ndj==ndt){
          rl vj=sh->vals[base+j];
          if(vj<vt || (vj==vt && j<ltid)) ++rank;
        }
      }
      int pos = ndt ? (1+rank) : (1+Kc+rank);
      sh->ic[base+pos]=ltid;
    }
  }
  __syncthreads();
  int K=si[0], n_=si[1], m_=si[2], f_=si[3], nl_=si[4];
  if(ltid<n_){ sh->ta[base+ltid]=sh->vals[base+ltid]; sh->tb[base+ltid]=sh->zz[base+ltid]; sh->ia[base+ltid]=sh->srcU[base+ltid]; sh->ib[base+ltid]=sh->srcVT[base+ltid]; }
  __syncthreads();
  if(ltid<n_){
    int p=sh->ic[base+ltid];
    sh->dsig[base+ltid]=sh->ta[base+p]; sh->zz[base+ltid]=sh->tb[base+p]; sh->srcU[base+ltid]=sh->ia[base+p]; sh->srcVT[base+ltid]=sh->ib[base+p];
  }
  __syncthreads();
  // rho (serial, order-sensitive) + zz^2 hoist + U2/VT2 gather
  if(ltid==0){
    rl rho=0.0; for(int t=0;t<K;++t){ rl zv=sh->zz[base+t]; rho += zv*zv; }
    sc[4]=rho;
  }
  // zz^2 precompute: zi*zi is the identical product the bisection loop would
  // compute each iteration -> hoisting it is bit-exact. (tb is dead here.)
  if(ltid<K){ rl zi=sh->zz[base+ltid]; sh->tb[base+ltid]=zi*zi; }
  if(wantU){
    for(int w=ltid; w<n_*n_; w+=lnt){
      int col=w/n_, row=w-col*n_;
      int su=sh->srcU[base+col];
      rl v;
      if(su<0) v = (row==nl_) ? 1.0 : 0.0;
      else v = SUB[(f_+row)+(size_t)LDV*su];
      U2[(base+row)+(size_t)LDV*(base+col)]=v;
    }
  }
  for(int w=ltid; w<n_*m_; w+=lnt){
    int row=w/m_, col=w-row*m_;
    VT2[(base+row)+(size_t)LDV*(base+col)] = SVTB[sh->srcVT[base+row]+(size_t)LDV*(f_+col)];
  }
  __syncthreads();
  // secular bisection (one root per thread), zz^2 from tb
  {
    rl rho=sc[4];
    if(ltid<K){
      int j=ltid;
      rl lo=sh->dsig[base+j];
      rl hi=(j<K-1)? sh->dsig[base+j+1] : sqrt(sh->dsig[base+K-1]*sh->dsig[base+K-1]+rho);
      for(int it=0; it<130; ++it){
        rl mid=0.5*(lo+hi);
        if(mid<=lo || mid>=hi) break;
        rl g=1.0;
        for(int i2=0;i2<K;++i2){
          g += sh->tb[base+i2]/((sh->dsig[base+i2]-mid)*(sh->dsig[base+i2]+mid));
        }
        if(g<0.0) lo=mid; else hi=mid;
      }
      sh->sigm[base+j]=0.5*(lo+hi);
    }
  }
  __syncthreads();
  // zh products
  if(ltid<K){
    int i2=ltid;
    rl di=sh->dsig[base+i2];
    rl p=(di - sh->sigm[base+K-1])*(di + sh->sigm[base+K-1]);
    for(int j=0;j<i2;++j)
      p *= (di - sh->sigm[base+j])*(di + sh->sigm[base+j])/((di - sh->dsig[base+j])*(di + sh->dsig[base+j]));
    for(int j=i2;j<K-1;++j)
      p *= (di - sh->sigm[base+j])*(di + sh->sigm[base+j])/((di - sh->dsig[base+j+1])*(di + sh->dsig[base+j+1]));
    sh->zh[base+i2] = d_sign(sqrt(fabs(p)), sh->zz[base+i2]);
  }
  __syncthreads();
  // QV/QU columns
  if(ltid<K){
    int j=ltid;
    rl sj=sh->sigm[base+j];
    rl nu=0.0, nv=0.0;
    for(int i2=0;i2<K;++i2){
      rl di=sh->dsig[base+i2];
      rl vv=sh->zh[base+i2]/((di-sj)*(di+sj));
      QVL[i2+(size_t)LDV*(j+qofs)]=vv; nv+=vv*vv;
      if(wantU){
        rl uu=(i2==0)? -1.0 : di*vv;
        QU[i2+(size_t)LDV*(j+qofs)]=uu; nu+=uu*uu;
      }
    }
    nv=1.0/sqrt(nv);
    for(int i2=0;i2<K;++i2) QVL[i2+(size_t)LDV*(j+qofs)]*=nv;
    if(wantU){
      nu=1.0/sqrt(nu);
      for(int i2=0;i2<K;++i2) QU[i2+(size_t)LDV*(j+qofs)]*=nu;
    }
  }
  __syncthreads();
  // two-pointer interleave (serial)
  if(ltid==0){
    int nd2=n_-K;
    for(int t=0;t<nd2;++t) sh->ia[base+t]=K+t;
    int ps=K-1, pd=nd2-1;
    int t=0;
    while(t<n_){
      rl vs = (ps>=0)? sh->sigm[base+ps] : -1.0;
      rl vd = (pd>=0)? sh->dsig[base+sh->ia[base+pd]] : -1.0;
      if(vs >= vd){ sh->perm[base+t]=ps; sh->vals[base+t]=vs; --ps; }
      else { sh->perm[base+t]=1000+sh->ia[base+pd]; sh->vals[base+t]=vd; --pd; }
      ++t;
    }
  }
  __syncthreads();
  // d writeback + matmuls
  if(ltid<n_) sh->d[f_+ltid]=sh->vals[base+ltid];
  if(wantU){
    for(int w=ltid; w<n_*n_; w+=lnt){
      int t=w/n_, row=w-t*n_;
      int src=sh->perm[base+t];
      rl acc;
      if(src>=1000) acc = U2[(base+row)+(size_t)LDV*(base+(src-1000))];
      else{
        const rl* urow = U2 + (base+row) + (size_t)LDV*base;
        const rl* qcol = QU + (size_t)LDV*(src+qofs);
        rl s=0.0; int i=0;
        for(; i+16<=K; i+=16){
          rl a[16], b[16];
          #pragma unroll
          for(int u=0;u<16;++u){ a[u]=urow[(size_t)LDV*(size_t)(i+u)]; b[u]=qcol[i+u]; }
          #pragma unroll
          for(int u=0;u<16;++u) s += a[u]*b[u];
        }
        for(; i<K; ++i) s += urow[(size_t)LDV*i]*qcol[i];
        acc=s;
      }
      SUB[(f_+row)+(size_t)LDV*(f_+t)] = acc;
    }
  }
  for(int w=ltid; w<n_*m_; w+=lnt){
    int t=w/m_, col=w-t*m_;
    int src=sh->perm[base+t];
    rl acc;
    if(src>=1000) acc = VT2[(base+(src-1000))+(size_t)LDV*(base+col)];
    else{
      const rl* qcol = QVL + (size_t)LDV*(src+qofs);
      const rl* vcol = VT2 + base + (size_t)LDV*(base+col);
      rl s=0.0; int i=0;
      for(; i+16<=K; i+=16){
        rl a[16], b[16];
        #pragma unroll
        for(int u=0;u<16;++u){ a[u]=qcol[i+u]; b[u]=vcol[i+u]; }
        #pragma unroll
        for(int u=0;u<16;++u) s += a[u]*b[u];
      }
      for(; i<K; ++i) s += qcol[i]*vcol[i];
      acc=s;
    }
    SVTB[(f_+t)+(size_t)LDV*(f_+col)] = acc;
  }
  __syncthreads();
}

// ---- bidiagonalization (R2 structure) ----
__device__ __forceinline__ void gebd2_upper(rl* A, int ld, int m, int n, Sh* sh, int tid){
  const int lane = tid & 63;
  rl pend_scl = 0.0; int pend_ds = 0;
  for(int i=0;i<n;++i){
    rl ps=0.0;
    for(int r=i+1+lane;r<m;r+=64){ rl vv=A[r+(size_t)ld*i]; ps+=vv*vv; }
    for(int off=32;off>0;off>>=1) ps += __shfl_xor(ps,off,64);
    rl alpha=A[i+(size_t)ld*i];
    rl xn=sqrt(ps);
    rl beta,tau,scl; int ds;
    if(xn==0.0){ tau=0.0; beta=alpha; scl=0.0; ds=0; }
    else{ beta=-d_sign(dlapy2(alpha,xn),alpha); tau=(beta-alpha)/beta; scl=1.0/(alpha-beta); ds=1; }
    if(tid==0){ sh->d[i]=beta; sh->tq[i]=tau; }
    if(tau!=0.0)
      app_left_s(A, ld, i, m, i+1, n, A+(size_t)ld*i, scl, tau, tid);
    if(pend_ds && tid>=128){
      int c = i+1 + (tid-128);
      if(c < n) A[(i-1)+(size_t)ld*c] *= pend_scl;
    }
    __syncthreads();
    if(i<n-1){
      rl ps2=0.0;
      for(int c=i+2+lane;c<n;c+=64){ rl vv=A[i+(size_t)ld*c]; ps2+=vv*vv; }
      for(int off=32;off>0;off>>=1) ps2 += __shfl_xor(ps2,off,64);
      rl alpha2=A[i+(size_t)ld*(i+1)];
      rl xn2=sqrt(ps2);
      rl beta2,tau2,scl2; int ds2;
      if(xn2==0.0){ tau2=0.0; beta2=alpha2; scl2=0.0; ds2=0; }
      else{ beta2=-d_sign(dlapy2(alpha2,xn2),alpha2); tau2=(beta2-alpha2)/beta2; scl2=1.0/(alpha2-beta2); ds2=1; }
      if(tid==0){ sh->e[i]=beta2; sh->tp[i]=tau2; }
      if(tau2!=0.0)
        app_right_s(A, ld, i+1, m, i+1, n, A+i, ld, scl2, tau2, tid);
      if(ds && tid>=128){
        int r = i+1 + (tid-128);
        if(r < m) A[r+(size_t)ld*i] *= scl;
      }
      pend_ds = ds2; pend_scl = scl2;
      __syncthreads();
    } else {
      if(tid==0) sh->tp[i]=0.0;
      __syncthreads();
      if(ds) for(int r=i+1+tid; r<m; r+=NT) A[r+(size_t)ld*(n-1)] *= scl;
      __syncthreads();
    }
  }
}

__device__ __forceinline__ void gebd2_lower(rl* A, int ld, int m, int n, Sh* sh, int tid){
  const int lane = tid & 63;
  rl pend_scl = 0.0; int pend_ds = 0;
  int last_ds = 0; rl last_scl = 0.0;
  for(int i=0;i<m;++i){
    rl ps=0.0;
    for(int c=i+1+lane;c<n;c+=64){ rl vv=A[i+(size_t)ld*c]; ps+=vv*vv; }
    for(int off=32;off>0;off>>=1) ps += __shfl_xor(ps,off,64);
    rl alpha=A[i+(size_t)ld*i];
    rl xn=sqrt(ps);
    rl beta,tau,scl; int ds;
    if(xn==0.0){ tau=0.0; beta=alpha; scl=0.0; ds=0; }
    else{ beta=-d_sign(dlapy2(alpha,xn),alpha); tau=(beta-alpha)/beta; scl=1.0/(alpha-beta); ds=1; }
    if(tid==0){ sh->d[i]=beta; sh->tp[i]=tau; }
    if(tau!=0.0)
      app_right_s(A, ld, i+1, m, i, n, A+i, ld, scl, tau, tid);
    if(pend_ds && tid>=128){
      int r = i+1 + (tid-128);
      if(r < m) A[r+(size_t)ld*(i-1)] *= pend_scl;
    }
    __syncthreads();
    if(i<m-1){
      rl ps2=0.0;
      for(int r=i+2+lane;r<m;r+=64){ rl vv=A[r+(size_t)ld*i]; ps2+=vv*vv; }
      for(int off=32;off>0;off>>=1) ps2 += __shfl_xor(ps2,off,64);
      rl alpha2=A[(i+1)+(size_t)ld*i];
      rl xn2=sqrt(ps2);
      rl beta2,tau2,scl2; int ds2;
      if(xn2==0.0){ tau2=0.0; beta2=alpha2; scl2=0.0; ds2=0; }
      else{ beta2=-d_sign(dlapy2(alpha2,xn2),alpha2); tau2=(beta2-alpha2)/beta2; scl2=1.0/(alpha2-beta2); ds2=1; }
      if(tid==0){ sh->e[i]=beta2; sh->tq[i]=tau2; }
      if(tau2!=0.0)
        app_left_s(A, ld, i+1, m, i+1, n, A+(size_t)ld*i, scl2, tau2, tid);
      if(ds && tid>=128){
        int c = i+1 + (tid-128);
        if(c < n) A[i+(size_t)ld*c] *= scl;
      }
      pend_ds = ds2; pend_scl = scl2;
      __syncthreads();
    } else {
      last_ds = ds; last_scl = scl;
      __syncthreads();
      if(last_ds) for(int c=i+1+tid; c<n; c+=NT) A[(m-1)+(size_t)ld*c] *= last_scl;
      __syncthreads();
    }
  }
}

__device__ __forceinline__ void gelq2(rl* A, int ld, int m, int n, Sh* sh, int tid){
  const int lane = tid & 63;
  rl pend_scl=0.0, pend_beta=0.0; int pend_ds=0;
  for(int i=0;i<m;++i){
    rl ps=0.0;
    for(int c=i+1+lane;c<n;c+=64){ rl vv=A[i+(size_t)ld*c]; ps+=vv*vv; }
    for(int off=32;off>0;off>>=1) ps += __shfl_xor(ps,off,64);
    rl alpha=A[i+(size_t)ld*i];
    rl xn=sqrt(ps);
    rl beta,tau,scl; int ds;
    if(xn==0.0){ tau=0.0; beta=alpha; scl=0.0; ds=0; }
    else{ beta=-d_sign(dlapy2(alpha,xn),alpha); tau=(beta-alpha)/beta; scl=1.0/(alpha-beta); ds=1; }
    if(tid==0) sh->rs[i]=tau;
    if(i<m-1 && tau!=0.0)
      app_right_s(A, ld, i+1, m, i, n, A+i, ld, scl, tau, tid);
    if(i>0 && tid>=128){
      if(pend_ds){ int c = i + (tid-128); if(c<n) A[(i-1)+(size_t)ld*c] *= pend_scl; }
      if(tid==128) A[(i-1)+(size_t)ld*(i-1)] = pend_beta;
    }
    pend_ds=ds; pend_scl=scl; pend_beta=beta;
    __syncthreads();
  }
  if(tid>=128){
    if(pend_ds){ int c = m + (tid-128); if(c<n) A[(m-1)+(size_t)ld*c] *= pend_scl; }
    if(tid==128) A[(m-1)+(size_t)ld*(m-1)] = pend_beta;
  }
  __syncthreads();
}

// ======================================================================
// ONE kernel per stage: build + bidiag + leaves + merges + post.
// MBL stays resident in LDS across all phases (no g_ws roundtrip);
// d/e/tq/tp stay in sh. QV overlays the dead lct region during merges.
// ======================================================================
__global__ __launch_bounds__(NT)
void k_stage(const float* __restrict__ ch, const float* __restrict__ ci,
             const float* __restrict__ ictx, const int* __restrict__ tok,
             int s, int m)
{
  __shared__ Sh sh;
  __shared__ LeafCtx lct[4];
  extern __shared__ rl MBL[];
  int tid = threadIdx.x;
  rl* MA = g_ws + O_MA; rl* MQ = g_ws + O_MQ; rl* TB = g_ws + O_TB;
  rl* MU=g_ws+O_MU; rl* MVT=g_ws+O_MVT;
  rl* SUB=g_ws+O_SUB; rl* SVTB=g_ws+O_SVTB; rl* VT2=g_ws+O_VT2;
  // ---- build columns + A ----
  if(tid==0){
    rl W00=ch[s*4+0], W01=ch[s*4+1], W10=ch[s*4+2], W11=ch[s*4+3];
    rl P00=1,P01=0,P10=0,P11=1;
    for(int mexp=0;mexp<=70;++mexp){
      int j=70-mexp;
      rl v0,v1;
      if(j==0){ v0=ictx[s*2+0]; v1=ictx[s*2+1]; }
      else{
        int b=(tok[j-1]>>(15-s))&1;
        v0=ci[s*4+b]; v1=ci[s*4+2+b];
      }
      g_ws[O_COLS + 0 + 2*j] = P00*v0+P01*v1;
      g_ws[O_COLS + 1 + 2*j] = P10*v0+P11*v1;
      rl n00=W00*P00+W01*P10, n01=W00*P01+W01*P11;
      rl n10=W10*P00+W11*P10, n11=W10*P01+W11*P11;
      P00=n00;P01=n01;P10=n10;P11=n11;
    }
  }
  __syncthreads();
  for(int w=tid; w<m*NSV; w+=NT){
    int j=w/m, r2=w-j*m;
    int l=r2>>1, dd2=r2&1;
    rl cv = g_ws[O_COLS + dd2 + 2*j];
    MA[r2+(size_t)LDA*j] = (s==0)? cv : g_ws[O_CAR + l + 64*j]*cv;
  }
  __syncthreads();
  // ---- bidiagonalization ----
  if(m==128){
    for(int w=tid;w<128*NSV;w+=NT){ int c=w>>7, r2=w&127; MBL[r2+(size_t)PB*c]=MA[r2+(size_t)LDA*c]; }
    __syncthreads();
    gebd2_upper(MBL, PB, 128, NSV, &sh, tid);
  } else if(m==64){
    for(int w=tid;w<64*NSV;w+=NT){ int c=w>>6, r2=w&63; MBL[r2+(size_t)PB*c]=MA[r2+(size_t)LDA*c]; }
    __syncthreads();
    gebd2_lower(MBL, PB, 64, NSV, &sh, tid);
    __syncthreads();
    // dbdsdc_L pre-rotation (wantU=0 -> rc/rs not needed later)
    if(tid==0){
      for(int i=0;i<63;++i){
        rl cs,snv,rv;
        dlartg(sh.d[i], sh.e[i], &cs,&snv,&rv);
        sh.d[i]=rv; sh.e[i]=snv*sh.d[i+1]; sh.d[i+1]=cs*sh.d[i+1];
      }
    }
  } else {
    for(int w=tid;w<m*NSV;w+=NT){ int c=w/m, r2=w-c*m; MBL[r2+(size_t)PB*c]=MA[r2+(size_t)LDA*c]; }
    __syncthreads();
    gelq2(MBL, PB, m, NSV, &sh, tid);
    for(int w=tid;w<m*NSV;w+=NT){ int c=w/m, r2=w-c*m; MQ[r2+(size_t)LDA*c]=(r2==c)?1.0:0.0; }
    __syncthreads();
    if(tid<m){
      int r=tid;
      for(int j=m-1;j>=0;--j){
        rl tau=sh.rs[j];
        if(tau!=0.0) row_apply(MQ + r + (size_t)LDA*j, LDA, MBL + j + (size_t)PB*(j+1), PB, NSV-j-1, tau);
      }
    }
    __syncthreads();
    for(int w=tid;w<m*m;w+=NT){ int c=w/m, r2=w-c*m; TB[r2+(size_t)LDV*c]=(r2>=c)? MBL[r2+(size_t)PB*c]:0.0; }
    __syncthreads();
    gebd2_upper(TB, LDV, m, m, &sh, tid);
  }
  __syncthreads();
  // ---- leaves ----
  int wantU = (s==8)?1:0;
  int n_eff = (m==128)? NSV : m;
  for(int w=tid; w<LDV*LDV; w+=NT){
    int c=w/LDV, r2=w-c*LDV; rl v=(r2==c)?1.0:0.0;
    SVTB[w]=v;
    if(wantU) SUB[w]=v;
  }
  __syncthreads();
  if(n_eff<=SML){
    if((tid>>6)==0) leaf_exec(0, n_eff, 0, wantU, &lct[0], &sh, tid&63);
    __syncthreads();
  } else {
    build_ops(n_eff, &sh, tid);
    int no=sh.si[6];
    int o=0;
    while(o<no && sh.opk[o]==0){
      int cnt=1;
      while(o+cnt<no && sh.opk[o+cnt]==0 && cnt<4) ++cnt;
      int wid = tid>>6;
      if(wid<cnt) leaf_exec(sh.opf[o+wid], sh.opa[o+wid], sh.opq[o+wid], wantU, &lct[wid], &sh, tid&63);
      __syncthreads();
      o += cnt;
    }
    // ---- merges (QV overlays lct, dead after leaves) ----
    rl* QV = (rl*)lct;
    int mstart=o;
    int nm = no - mstart;
    if(nm==3){
      int slot = tid>>7, ltid = tid&127;
      int oo = mstart + slot;
      lasd1_merge2(sh.opf[oo], sh.opa[oo], sh.opb[oo], sh.opq[oo], wantU,
                   QV, 36*slot, 36*slot, &sh, ltid, 128);
      int r = mstart+2;
      lasd1_merge2(sh.opf[r], sh.opa[r], sh.opb[r], sh.opq[r], wantU,
                   QV, 0, 0, &sh, tid, NT);
    } else {
      for(int oo=mstart;oo<no;++oo)
        lasd1_merge2(sh.opf[oo], sh.opa[oo], sh.opb[oo], sh.opq[oo], wantU,
                     QV, 0, 0, &sh, tid, NT);
    }
  }
  __syncthreads();
  // ---- post: back-transforms + carry / final vec (MBL still in LDS) ----
  int k = (m<64)? m : 64;
  if(m==128){
    if(s==8){
      for(int w=tid;w<128*NSV;w+=NT){ int c=w>>7, r2=w&127; MU[r2+(size_t)LDA*c]=(r2<NSV)? SUB[r2+(size_t)LDV*c]:0.0; }
      __syncthreads();
      if(tid<NSV){
        int c=tid;
        rl* colb = MU + (size_t)LDA*c;
        for(int i=NSV-1;i>=0;--i){
          rl tau=sh.tq[i];
          if(tau!=0.0) row_apply(colb+i, 1, MBL + (size_t)PB*i + i + 1, 1, 128-i-1, tau);
        }
      }
      __syncthreads();
      if(tid==0){
        rl W00=ch[8*4+0], W01=ch[8*4+1], W10=ch[8*4+2], W11=ch[8*4+3];
        rl P00=1,P01=0,P10=0,P11=1;
        for(int it=0;it<30;++it){
          rl n00=W00*P00+W01*P10, n01=W00*P01+W01*P11;
          rl n10=W10*P00+W11*P10, n11=W10*P01+W11*P11;
          P00=n00;P01=n01;P10=n10;P11=n11;
        }
        sh.sc[0]=P00+P10; sh.sc[1]=P01+P11;
      }
      __syncthreads();
      for(int r2=tid; r2<64; r2+=NT){
        rl acc=0.0;
        for(int l=0;l<64;++l)
          acc += sh.sc[0]*MU[(2*l)+(size_t)LDA*r2] + sh.sc[1]*MU[(2*l+1)+(size_t)LDA*r2];
        g_ws[O_VEC + r2] = acc/188.0;
      }
    } else {
      for(int w=tid;w<LDV*NSV;w+=NT) MVT[w]=SVTB[w];
      __syncthreads();
      if(tid<NSV){
        int r=tid;
        for(int i=NSV-2;i>=0;--i){
          rl tau=sh.tp[i];
          if(tau!=0.0) row_apply(MVT + r + (size_t)LDV*(i+1), LDV, MBL + i + (size_t)PB*(i+2), PB, NSV-i-2, tau);
        }
      }
      __syncthreads();
      for(int w=tid; w<k*NSV; w+=NT){
        int j=w/k, l=w-j*k;
        g_ws[O_CAR + l + 64*j] = sh.d[l]*MVT[l+(size_t)LDV*j];
      }
    }
  } else if(m==64){
    for(int w=tid;w<64*NSV;w+=NT){ int c=w>>6, r2=w&63; MVT[r2+(size_t)LDV*c]=(c<64)? SVTB[r2+(size_t)LDV*c]:0.0; }
    __syncthreads();
    if(tid<64){
      int r=tid;
      for(int i=63;i>=0;--i){
        rl tau=sh.tp[i];
        if(tau!=0.0) row_apply(MVT + r + (size_t)LDV*i, LDV, MBL + i + (size_t)PB*(i+1), PB, NSV-i-1, tau);
      }
    }
    __syncthreads();
    for(int w=tid; w<k*NSV; w+=NT){
      int j=w/k, l=w-j*k;
      g_ws[O_CAR + l + 64*j] = sh.d[l]*MVT[l+(size_t)LDV*j];
    }
  } else {
    for(int w=tid;w<m*m;w+=NT){ int c=w/m, r2=w-c*m; VT2[r2+(size_t)LDV*c]=SVTB[r2+(size_t)LDV*c]; }
    __syncthreads();
    if(tid<m){
      int r=tid;
      for(int i=m-2;i>=0;--i){
        rl tau=sh.tp[i];
        if(tau!=0.0) row_apply(VT2 + r + (size_t)LDV*(i+1), LDV, TB + i + (size_t)LDV*(i+2), LDV, m-i-2, tau);
      }
    }
    __syncthreads();
    for(int w=tid;w<m*NSV;w+=NT){
      int c=w/m, r2=w-c*m;
      const rl* vrow = VT2 + r2;
      const rl* qcol = MQ + (size_t)LDA*c;
      rl s2=0.0; int t=0;
      for(; t+16<=m; t+=16){
        rl a[16], b[16];
        #pragma unroll
        for(int u=0;u<16;++u){ a[u]=vrow[(size_t)LDV*(size_t)(t+u)]; b[u]=qcol[t+u]; }
        #pragma unroll
        for(int u=0;u<16;++u) s2 += a[u]*b[u];
      }
      for(; t+4<=m; t+=4){
        rl a0=vrow[(size_t)LDV*t], a1=vrow[(size_t)LDV*(t+1)], a2=vrow[(size_t)LDV*(t+2)], a3=vrow[(size_t)LDV*(t+3)];
        rl b0=qcol[t], b1=qcol[t+1], b2=qcol[t+2], b3=qcol[t+3];
        s2+=a0*b0; s2+=a1*b1; s2+=a2*b2; s2+=a3*b3;
      }
      for(; t<m; ++t) s2 += vrow[(size_t)LDV*t]*qcol[t];
      MVT[r2+(size_t)LDV*c]=s2;
    }
    __syncthreads();
    for(int w=tid; w<k*NSV; w+=NT){
      int j=w/k, l=w-j*k;
      g_ws[O_CAR + l + 64*j] = sh.d[l]*MVT[l+(size_t)LDV*j];
    }
  }
}

__global__ __launch_bounds__(NT)
void head_kernel(const float* __restrict__ hw, const float* __restrict__ hb,
                 float* __restrict__ out)
{
  __shared__ float v[64];
  int tid=threadIdx.x;
  if(tid<64) v[tid]=(float)g_ws[O_VEC + tid];
  __syncthreads();
  int i = blockIdx.x*NT + tid;
  if(i<VOCAB){
    const float4* row = (const float4*)(hw + (size_t)i*64);
    float acc=0.f;
    #pragma unroll
    for(int c4=0;c4<16;++c4){
      float4 r4=row[c4];
      acc += r4.x*v[4*c4] + r4.y*v[4*c4+1] + r4.z*v[4*c4+2] + r4.w*v[4*c4+3];
    }
    out[i]=acc+hb[i];
  }
}

extern "C" void kernel_launch(void* const* d_in, const int* in_sizes, int n_in,
                              void* d_out, int out_size, void* d_ws, size_t ws_size,
                              hipStream_t stream)
{
  const float* ch  = (const float*)d_in[0];
  const float* ci  = (const float*)d_in[1];
  const float* hw  = (const float*)d_in[2];
  const float* hb  = (const float*)d_in[3];
  const float* ict = (const float*)d_in[4];
  const int*   tk  = (const int*)d_in[5];
  (void)d_ws; (void)ws_size; (void)in_sizes; (void)n_in; (void)out_size;

  static const int ms[9] = {2,4,8,16,32,64,128,128,128};
  size_t dynls = (size_t)PB*NSV*sizeof(double);   // 73272 B
  for(int s=0;s<9;++s){
    hipLaunchKernelGGL(k_stage, dim3(1), dim3(NT), dynls, stream, ch, ci, ict, tk, s, ms[s]);
  }
  hipLaunchKernelGGL(head_kernel, dim3((VOCAB+NT-1)/NT), dim3(NT), 0, stream,
                     hw, hb, (float*)d_out);
}